// Round 8
// baseline (1797.222 us; speedup 1.0000x reference)
//
#include <hip/hip_runtime.h>
#include <hip/hip_bf16.h>

typedef unsigned short u16;

#define BB 16
#define NO 64
#define TT 21
#define NM 768
#define PP 20
#define CAx 29
#define CMx 9
#define DD 256
#define HH 8
#define LL 6
#define KK 16
#define NN (NO + NM)        // 832
#define HDX (DD / HH)       // 32
#define MTOT (BB * NN)      // 13312

// fused_pre block ranges
#define MAPB  (BB * NM / 4)          // 3072
#define AGB   (BB * NO)              // 1024
#define KNNB  (BB * 208)             // 3328
#define PEB   MTOT                   // 13312
#define SWB   (4718592 / 256)        // 18432
#define MAP0  0
#define AG0   (MAP0 + MAPB)
#define KNN0  (AG0 + AGB)
#define PE0   (KNN0 + KNNB)
#define SW0   (PE0 + PEB)
#define TOTB  (SW0 + SWB)

typedef __attribute__((ext_vector_type(8))) short s8v;   // 8 bf16 in 4 VGPRs
typedef __attribute__((ext_vector_type(4))) float f4v;

__device__ __forceinline__ u16 bftrunc(float x) {
    return (u16)(__float_as_uint(x) >> 16);
}
__device__ __forceinline__ float bf2f(u16 u) {
    return __uint_as_float(((unsigned int)u) << 16);
}
__device__ __forceinline__ void split2(float x, u16& hi, u16& lo) {
    hi = bftrunc(x);
    lo = bftrunc(x - bf2f(hi));
}

// async global->LDS, 16B per lane; lds dest = wave-uniform base + lane*16
#define GLOAD_LDS16(gptr, lptr)                                                             \
    __builtin_amdgcn_global_load_lds(                                                       \
        (const __attribute__((address_space(1))) void*)(gptr),                              \
        (__attribute__((address_space(3))) void*)(lptr), 16, 0, 0)

// ================================================================ fused pre-phase
// one dispatch; block-uniform branch per sub-kernel; 27648 B union LDS
__global__ __launch_bounds__(256) void fused_pre(
    // agent pointnet
    const float* __restrict__ obj,
    const float* __restrict__ preW, const float* __restrict__ preB,
    const float* __restrict__ aw1,  const float* __restrict__ ab1,
    const float* __restrict__ aw2,  const float* __restrict__ ab2,
    const float* __restrict__ aow1, const float* __restrict__ aob1,
    const float* __restrict__ aow2, const float* __restrict__ aob2,
    // map pointnet
    const float* __restrict__ mp,
    const float* __restrict__ w1, const float* __restrict__ b1,
    const float* __restrict__ w2, const float* __restrict__ b2,
    const float* __restrict__ w3, const float* __restrict__ b3,
    const float* __restrict__ mw1, const float* __restrict__ mb1,
    const float* __restrict__ mw2, const float* __restrict__ mb2,
    const float* __restrict__ ow1, const float* __restrict__ ob1,
    const float* __restrict__ ow2, const float* __restrict__ ob2,
    // knn / pe
    const float* __restrict__ opos, const float* __restrict__ mpos,
    int* __restrict__ IDX, float* __restrict__ PE,
    // weight split
    const float* __restrict__ wqkv_in, const float* __restrict__ wo_in,
    const float* __restrict__ f1w_in, const float* __restrict__ f2w_in,
    u16* __restrict__ whi, u16* __restrict__ wlo,
    // shared output
    float* __restrict__ X)
{
    __shared__ __align__(16) char smem_raw[27648];
    const int bid = blockIdx.x;
    const int tid = threadIdx.x;

    if (bid < AG0) {
        // -------------------------------------------- map pointnet: 4 polylines/block
        float (*ps)[PP][12]  = (float(*)[PP][12])(smem_raw);            // 3840
        float (*fa)[PP][64]  = (float(*)[PP][64])(smem_raw + 3840);     // 20480
        float (*pooled)[64]  = (float(*)[64])(smem_raw + 24320);        // 1024
        float (*gv)[64]      = (float(*)[64])(smem_raw + 25344);        // 1024
        float (*hv)[64]      = (float(*)[64])(smem_raw + 26368);        // 1024
        const int wave = tid >> 6;
        const int c = tid & 63;
        const int blk = (bid - MAP0) * 4 + wave;     // b*NM + m

        for (int i = c; i < PP * CMx; i += 64) {
            int t = i / CMx, cc = i % CMx;
            ps[wave][t][cc] = mp[(size_t)(blk * PP + t) * CMx + cc];
        }
        __syncthreads();
        {
            float w[9];
            #pragma unroll
            for (int j = 0; j < 9; j++) w[j] = w1[c * 9 + j];
            float bias = b1[c];
            for (int p = 0; p < PP; p++) {
                float s = bias;
                #pragma unroll
                for (int j = 0; j < 9; j++) s += ps[wave][p][j] * w[j];
                fa[wave][p][c] = fmaxf(s, 0.f);
            }
        }
        __syncthreads();
        {   // pre2 (in-place)
            const float* wr = w2 + (size_t)c * 64;
            float acc[PP];
            #pragma unroll
            for (int p = 0; p < PP; p++) acc[p] = b2[c];
            for (int j = 0; j < 64; j += 4) {
                float4 wv = *(const float4*)&wr[j];
                #pragma unroll
                for (int p = 0; p < PP; p++) {
                    float4 f4 = *(const float4*)&fa[wave][p][j];
                    acc[p] += f4.x * wv.x + f4.y * wv.y + f4.z * wv.z + f4.w * wv.w;
                }
            }
            __syncthreads();
            #pragma unroll
            for (int p = 0; p < PP; p++) fa[wave][p][c] = fmaxf(acc[p], 0.f);
        }
        __syncthreads();
        {   // pre3 (in-place)
            const float* wr = w3 + (size_t)c * 64;
            float acc[PP];
            #pragma unroll
            for (int p = 0; p < PP; p++) acc[p] = b3[c];
            for (int j = 0; j < 64; j += 4) {
                float4 wv = *(const float4*)&wr[j];
                #pragma unroll
                for (int p = 0; p < PP; p++) {
                    float4 f4 = *(const float4*)&fa[wave][p][j];
                    acc[p] += f4.x * wv.x + f4.y * wv.y + f4.z * wv.z + f4.w * wv.w;
                }
            }
            __syncthreads();
            #pragma unroll
            for (int p = 0; p < PP; p++) fa[wave][p][c] = fmaxf(acc[p], 0.f);
        }
        __syncthreads();
        {
            float m = fa[wave][0][c];
            for (int p = 1; p < PP; p++) m = fmaxf(m, fa[wave][p][c]);
            pooled[wave][c] = m;
        }
        __syncthreads();
        {   // mid1 (in-place)
            const float* wr = mw1 + (size_t)c * 128;
            float acc[PP];
            #pragma unroll
            for (int p = 0; p < PP; p++) acc[p] = 0.f;
            for (int j = 0; j < 64; j += 4) {
                float4 wv = *(const float4*)&wr[j];
                #pragma unroll
                for (int p = 0; p < PP; p++) {
                    float4 f4 = *(const float4*)&fa[wave][p][j];
                    acc[p] += f4.x * wv.x + f4.y * wv.y + f4.z * wv.z + f4.w * wv.w;
                }
            }
            float pacc = mb1[c];
            for (int j = 0; j < 64; j += 4) {
                float4 wv = *(const float4*)&wr[64 + j];
                float4 p4 = *(const float4*)&pooled[wave][j];
                pacc += p4.x * wv.x + p4.y * wv.y + p4.z * wv.z + p4.w * wv.w;
            }
            __syncthreads();
            #pragma unroll
            for (int p = 0; p < PP; p++) fa[wave][p][c] = fmaxf(acc[p] + pacc, 0.f);
        }
        __syncthreads();
        {   // mid2 (in-place)
            const float* wr = mw2 + (size_t)c * 64;
            float acc[PP];
            #pragma unroll
            for (int p = 0; p < PP; p++) acc[p] = mb2[c];
            for (int j = 0; j < 64; j += 4) {
                float4 wv = *(const float4*)&wr[j];
                #pragma unroll
                for (int p = 0; p < PP; p++) {
                    float4 f4 = *(const float4*)&fa[wave][p][j];
                    acc[p] += f4.x * wv.x + f4.y * wv.y + f4.z * wv.z + f4.w * wv.w;
                }
            }
            __syncthreads();
            #pragma unroll
            for (int p = 0; p < PP; p++) fa[wave][p][c] = fmaxf(acc[p], 0.f);
        }
        __syncthreads();
        {
            float m = fa[wave][0][c];
            for (int p = 1; p < PP; p++) m = fmaxf(m, fa[wave][p][c]);
            gv[wave][c] = m;
        }
        __syncthreads();
        {   // out1
            const float* wr = ow1 + (size_t)c * 64;
            float s = ob1[c];
            for (int j = 0; j < 64; j += 4) {
                float4 wv = *(const float4*)&wr[j];
                float4 g4 = *(const float4*)&gv[wave][j];
                s += g4.x * wv.x + g4.y * wv.y + g4.z * wv.z + g4.w * wv.w;
            }
            hv[wave][c] = fmaxf(s, 0.f);
        }
        __syncthreads();
        {   // out2: 64->256
            int b = blk / NM, m = blk % NM;
            float* xr = &X[((size_t)b * NN + NO + m) * DD];
            for (int q = 0; q < 4; q++) {
                int r = c + 64 * q;
                const float* wr = ow2 + (size_t)r * 64;
                float s = ob2[r];
                for (int j = 0; j < 64; j += 4) {
                    float4 wv = *(const float4*)&wr[j];
                    float4 g4 = *(const float4*)&hv[wave][j];
                    s += g4.x * wv.x + g4.y * wv.y + g4.z * wv.z + g4.w * wv.w;
                }
                xr[r] = s;
            }
        }
    } else if (bid < KNN0) {
        // -------------------------------------------- agent pointnet: one (b,o)/block
        float (*in_s)[32] = (float(*)[32])(smem_raw);                   // 2688
        float (*fa)[DD]   = (float(*)[DD])(smem_raw + 2688);            // 21504
        float *pooled     = (float*)(smem_raw + 24192);                 // 1024
        float *gvec       = (float*)(smem_raw + 25216);                 // 1024
        float *hvec       = (float*)(smem_raw + 26240);                 // 1024
        const int blk = bid - AG0;      // b*NO + o

        for (int i = tid; i < TT * 30; i += 256) {
            int t = i / 30, c = i % 30;
            float v = (c < CAx) ? obj[(size_t)(blk * TT + t) * CAx + c] : 1.0f;
            in_s[t][c] = v;
        }
        __syncthreads();
        const int c = tid;
        {
            float w[30];
            #pragma unroll
            for (int j = 0; j < 30; j++) w[j] = preW[c * 30 + j];
            float bias = preB[c];
            for (int t = 0; t < TT; t++) {
                float s = bias;
                #pragma unroll
                for (int j = 0; j < 30; j++) s += in_s[t][j] * w[j];
                fa[t][c] = fmaxf(s, 0.f);
            }
        }
        __syncthreads();
        {
            float m = fa[0][c];
            for (int t = 1; t < TT; t++) m = fmaxf(m, fa[t][c]);
            pooled[c] = m;
        }
        __syncthreads();
        {   // mlp1 (in-place)
            const float* wr = aw1 + (size_t)c * 512;
            float acc[TT];
            #pragma unroll
            for (int t = 0; t < TT; t++) acc[t] = 0.f;
            for (int j = 0; j < 256; j += 4) {
                float4 wv = *(const float4*)&wr[j];
                #pragma unroll
                for (int t = 0; t < TT; t++) {
                    float4 f4 = *(const float4*)&fa[t][j];
                    acc[t] += f4.x * wv.x + f4.y * wv.y + f4.z * wv.z + f4.w * wv.w;
                }
            }
            float pacc = ab1[c];
            for (int j = 0; j < 256; j += 4) {
                float4 wv = *(const float4*)&wr[256 + j];
                float4 p4 = *(const float4*)&pooled[j];
                pacc += p4.x * wv.x + p4.y * wv.y + p4.z * wv.z + p4.w * wv.w;
            }
            __syncthreads();
            #pragma unroll
            for (int t = 0; t < TT; t++) fa[t][c] = fmaxf(acc[t] + pacc, 0.f);
        }
        __syncthreads();
        {   // mlp2 (in-place)
            const float* wr = aw2 + (size_t)c * 256;
            float acc[TT];
            #pragma unroll
            for (int t = 0; t < TT; t++) acc[t] = ab2[c];
            for (int j = 0; j < 256; j += 4) {
                float4 wv = *(const float4*)&wr[j];
                #pragma unroll
                for (int t = 0; t < TT; t++) {
                    float4 f4 = *(const float4*)&fa[t][j];
                    acc[t] += f4.x * wv.x + f4.y * wv.y + f4.z * wv.z + f4.w * wv.w;
                }
            }
            __syncthreads();
            #pragma unroll
            for (int t = 0; t < TT; t++) fa[t][c] = fmaxf(acc[t], 0.f);
        }
        __syncthreads();
        {
            float m = fa[0][c];
            for (int t = 1; t < TT; t++) m = fmaxf(m, fa[t][c]);
            gvec[c] = m;
        }
        __syncthreads();
        {
            const float* wr = aow1 + (size_t)c * 256;
            float s = aob1[c];
            for (int j = 0; j < 256; j += 4) {
                float4 wv = *(const float4*)&wr[j];
                float4 g4 = *(const float4*)&gvec[j];
                s += g4.x * wv.x + g4.y * wv.y + g4.z * wv.z + g4.w * wv.w;
            }
            hvec[c] = fmaxf(s, 0.f);
        }
        __syncthreads();
        {
            const float* wr = aow2 + (size_t)c * 256;
            float s = aob2[c];
            for (int j = 0; j < 256; j += 4) {
                float4 wv = *(const float4*)&wr[j];
                float4 g4 = *(const float4*)&hvec[j];
                s += g4.x * wv.x + g4.y * wv.y + g4.z * wv.z + g4.w * wv.w;
            }
            int b = blk / NO, o = blk % NO;
            X[((size_t)b * NN + o) * DD + c] = s;
        }
    } else if (bid < PE0) {
        // -------------------------------------------- KNN
        float *px = (float*)(smem_raw);
        float *py = (float*)(smem_raw + 3328);
        float *pz = (float*)(smem_raw + 6656);
        const int kb = bid - KNN0;
        const int b = kb / 208;
        const int blk = kb % 208;
        for (int i = tid; i < NN; i += 256) {
            const float* src = (i < NO) ? &opos[(size_t)(b * NO + i) * 3]
                                        : &mpos[(size_t)(b * NM + (i - NO)) * 3];
            px[i] = src[0]; py[i] = src[1]; pz[i] = src[2];
        }
        __syncthreads();
        const int wave = tid >> 6, lane = tid & 63;
        const int n = blk * 4 + wave;
        const float qx = px[n], qy = py[n], qz = pz[n];
        float d[13];
        #pragma unroll
        for (int s = 0; s < 13; s++) {
            int j = s * 64 + lane;
            float dx = qx - px[j], dy = qy - py[j], dz = qz - pz[j];
            d[s] = dx * dx + dy * dy + dz * dz;
        }
        int keep = 0;
        #pragma unroll
        for (int it = 0; it < 16; it++) {
            float bv = d[0]; int bs = 0;
            #pragma unroll
            for (int s = 1; s < 13; s++) { if (d[s] < bv) { bv = d[s]; bs = s; } }
            float v = bv; int jj = bs * 64 + lane;
            #pragma unroll
            for (int off = 32; off; off >>= 1) {
                float ov = __shfl_xor(v, off);
                int oj = __shfl_xor(jj, off);
                if (ov < v || (ov == v && oj < jj)) { v = ov; jj = oj; }
            }
            if (lane == (jj & 63)) {
                int sl = jj >> 6;
                #pragma unroll
                for (int s = 0; s < 13; s++) if (s == sl) d[s] = 3.4e38f;
            }
            if (lane == it) keep = jj;
        }
        if (lane < 16) IDX[((size_t)(b * NN + n)) * 16 + lane] = keep;
    } else if (bid < SW0) {
        // -------------------------------------------- sine PE
        const int row = bid - PE0;            // b*NN + n
        const int b = row / NN, n = row % NN;
        const int c = tid;
        const float* p = (n < NO) ? &opos[(size_t)(b * NO + n) * 3]
                                  : &mpos[(size_t)(b * NM + (n - NO)) * 3];
        float x = p[0], y = p[1];
        int j = c & 127;
        float v = (c < 128) ? y : x;
        float inv_dt = exp2f(-(float)(j & ~1) * 0.10381025296523f);
        float e = v * 6.283185307179586f * inv_dt;
        PE[(size_t)row * DD + c] = (j & 1) ? cosf(e) : sinf(e);
    } else {
        // -------------------------------------------- weight pre-split
        size_t e = (size_t)(bid - SW0) * 256 + tid;
        int L = (int)(e / 786432);
        int r = (int)(e % 786432);
        float v;
        if (r < 196608)      v = wqkv_in[(size_t)L * 196608 + r];
        else if (r < 262144) v = wo_in[(size_t)L * 65536 + (r - 196608)];
        else if (r < 524288) v = f1w_in[(size_t)L * 262144 + (r - 262144)];
        else                 v = f2w_in[(size_t)L * 262144 + (r - 524288)];
        u16 hi, lo; split2(v, hi, lo);
        whi[e] = hi; wlo[e] = lo;
    }
}

// ---------------------------------------------------------------- initial activation split
__global__ __launch_bounds__(256) void split_x0(
    const float* __restrict__ X, const float* __restrict__ PE,
    u16* __restrict__ Xh, u16* __restrict__ Xl,
    u16* __restrict__ XPh, u16* __restrict__ XPl)
{
    size_t base = ((size_t)blockIdx.x * 256 + threadIdx.x) * 4;
    float4 x = *(const float4*)&X[base];
    float4 p = *(const float4*)&PE[base];
    ushort4 h, l, ph, pl;
    split2(x.x, h.x, l.x); split2(x.y, h.y, l.y); split2(x.z, h.z, l.z); split2(x.w, h.w, l.w);
    split2(x.x + p.x, ph.x, pl.x); split2(x.y + p.y, ph.y, pl.y);
    split2(x.z + p.z, ph.z, pl.z); split2(x.w + p.w, ph.w, pl.w);
    *(ushort4*)&Xh[base] = h;  *(ushort4*)&Xl[base] = l;
    *(ushort4*)&XPh[base] = ph; *(ushort4*)&XPl[base] = pl;
}

// ---------------------------------------------------------------- split-bf16 MFMA GEMM (pre-split operands)
// C = act( A . W^T + bias );  A = Ah+Al (bf16 pair, [M,K]), W = Wh+Wl ([N,K]).
// 3-term: Ah*Wh + Ah*Wl + Al*Wh, fp32 accumulate. tile 128x128, BK=32, 4 waves.
// Staging via global_load_lds width=16 into LINEAR [128][32] LDS tiles.
template<bool RELU, bool SPLIT_OUT>
__global__ __launch_bounds__(256) void gemm_mfma(
    const u16* __restrict__ Ah, const u16* __restrict__ Al,
    const u16* __restrict__ A2h, const u16* __restrict__ A2l, int a2min,
    const u16* __restrict__ Wh, const u16* __restrict__ Wl,
    const float* __restrict__ bias,
    float* __restrict__ Cf, u16* __restrict__ Chi, u16* __restrict__ Clo,
    int K, int ldc, int coff, float scale, int scale_until)
{
    __shared__ __align__(16) u16 AhS[128][32];
    __shared__ __align__(16) u16 AlS[128][32];
    __shared__ __align__(16) u16 WhS[128][32];
    __shared__ __align__(16) u16 WlS[128][32];
    const int m0 = blockIdx.x * 128;
    const int n0 = blockIdx.y * 128;
    const u16* pAh = (n0 >= a2min) ? A2h : Ah;
    const u16* pAl = (n0 >= a2min) ? A2l : Al;
    const int tid = threadIdx.x;
    const int wave = tid >> 6, lane = tid & 63;
    const int wr = wave >> 1, wc = wave & 1;
    const int fr = lane & 15, kb = lane >> 4;
    const int lrow = lane >> 2;
    const int lcol = (lane & 3) * 8;

    f4v acc[4][4];
    #pragma unroll
    for (int i = 0; i < 4; i++)
        #pragma unroll
        for (int j = 0; j < 4; j++) { f4v z = {0.f, 0.f, 0.f, 0.f}; acc[i][j] = z; }

    for (int k0 = 0; k0 < K; k0 += 32) {
        __syncthreads();
        #pragma unroll
        for (int i = 0; i < 2; i++) {
            const int r = wave * 32 + i * 16;
            const size_t grow = (size_t)(r + lrow);
            GLOAD_LDS16(&pAh[(m0 + grow) * K + k0 + lcol], &AhS[r][0]);
            GLOAD_LDS16(&pAl[(m0 + grow) * K + k0 + lcol], &AlS[r][0]);
            GLOAD_LDS16(&Wh [(n0 + grow) * K + k0 + lcol], &WhS[r][0]);
            GLOAD_LDS16(&Wl [(n0 + grow) * K + k0 + lcol], &WlS[r][0]);
        }
        __syncthreads();
        s8v afh[4], afl[4];
        #pragma unroll
        for (int mi = 0; mi < 4; mi++) {
            afh[mi] = *(const s8v*)&AhS[wr * 64 + mi * 16 + fr][kb * 8];
            afl[mi] = *(const s8v*)&AlS[wr * 64 + mi * 16 + fr][kb * 8];
        }
        #pragma unroll
        for (int nj = 0; nj < 4; nj++) {
            s8v bh = *(const s8v*)&WhS[wc * 64 + nj * 16 + fr][kb * 8];
            s8v bl = *(const s8v*)&WlS[wc * 64 + nj * 16 + fr][kb * 8];
            #pragma unroll
            for (int mi = 0; mi < 4; mi++) {
                acc[mi][nj] = __builtin_amdgcn_mfma_f32_16x16x32_bf16(afh[mi], bh, acc[mi][nj], 0, 0, 0);
                acc[mi][nj] = __builtin_amdgcn_mfma_f32_16x16x32_bf16(afh[mi], bl, acc[mi][nj], 0, 0, 0);
                acc[mi][nj] = __builtin_amdgcn_mfma_f32_16x16x32_bf16(afl[mi], bh, acc[mi][nj], 0, 0, 0);
            }
        }
    }
    #pragma unroll
    for (int mi = 0; mi < 4; mi++) {
        #pragma unroll
        for (int nj = 0; nj < 4; nj++) {
            int col = n0 + wc * 64 + nj * 16 + fr;
            float bb = bias[col];
            #pragma unroll
            for (int r = 0; r < 4; r++) {
                int row = m0 + wr * 64 + mi * 16 + (lane >> 4) * 4 + r;
                float v = acc[mi][nj][r] + bb;
                if (RELU) v = fmaxf(v, 0.f);
                if (SPLIT_OUT) {
                    u16 hi, lo; split2(v, hi, lo);
                    Chi[(size_t)row * ldc + col] = hi;
                    Clo[(size_t)row * ldc + col] = lo;
                } else {
                    int gcol = coff + col;
                    if (gcol < scale_until) v *= scale;
                    Cf[(size_t)row * ldc + gcol] = v;
                }
            }
        }
    }
}

// ---------------------------------------------------------------- local KNN attention
__global__ __launch_bounds__(256) void attn_kernel(
    const float* __restrict__ QKV, const int* __restrict__ IDX,
    u16* __restrict__ AOh, u16* __restrict__ AOl)
{
    const int sub = threadIdx.x >> 7;
    const int t = threadIdx.x & 127;
    const int row = blockIdx.x * 2 + sub;     // b*NN + n
    const int b = row / NN;
    __shared__ float p_s[2][HH][16];
    __shared__ int gid_s[2][16];
    const int h = t >> 4, k = t & 15;
    int nb = IDX[(size_t)row * 16 + k];
    int g = b * NN + nb;
    if (h == 0) gid_s[sub][k] = g;
    const float* q = &QKV[(size_t)row * 768 + h * HDX];
    const float* kr = &QKV[(size_t)g * 768 + 256 + h * HDX];
    float s = 0.f;
    #pragma unroll
    for (int d = 0; d < HDX; d += 4) {
        float4 q4 = *(const float4*)&q[d];
        float4 k4 = *(const float4*)&kr[d];
        s += q4.x * k4.x + q4.y * k4.y + q4.z * k4.z + q4.w * k4.w;
    }
    float m = s;
    #pragma unroll
    for (int off = 8; off; off >>= 1) m = fmaxf(m, __shfl_xor(m, off, 16));
    float e = expf(s - m);
    float sum = e;
    #pragma unroll
    for (int off = 8; off; off >>= 1) sum += __shfl_xor(sum, off, 16);
    p_s[sub][h][k] = e / sum;
    __syncthreads();
    const int d0 = t * 2;
    const int hh = d0 >> 5, dd = d0 & 31;
    float o0 = 0.f, o1 = 0.f;
    #pragma unroll
    for (int kk = 0; kk < 16; kk++) {
        int gg = gid_s[sub][kk];
        const float* vr = &QKV[(size_t)gg * 768 + 512 + hh * HDX + dd];
        float p = p_s[sub][hh][kk];
        o0 += p * vr[0];
        o1 += p * vr[1];
    }
    u16 h0, lo0, h1, lo1;
    split2(o0, h0, lo0); split2(o1, h1, lo1);
    size_t base = (size_t)row * DD + d0;
    AOh[base] = h0; AOh[base + 1] = h1;
    AOl[base] = lo0; AOl[base + 1] = lo1;
}

// ---------------------------------------------------------------- residual + layernorm (+ split outputs)
__global__ __launch_bounds__(256) void ln_kernel(
    const float* __restrict__ R1, const float* __restrict__ R2,
    const float* __restrict__ g, const float* __restrict__ bt,
    float* __restrict__ OutF,
    u16* __restrict__ OHi, u16* __restrict__ OLo,
    const float* __restrict__ PEp,
    u16* __restrict__ PHi, u16* __restrict__ PLo)
{
    const int row = blockIdx.x * 4 + (threadIdx.x >> 6);
    const int lane = threadIdx.x & 63;
    size_t base = (size_t)row * DD + lane * 4;
    float4 a = *(const float4*)&R1[base];
    float4 b4 = *(const float4*)&R2[base];
    float x0 = a.x + b4.x, x1 = a.y + b4.y, x2 = a.z + b4.z, x3 = a.w + b4.w;
    float s = x0 + x1 + x2 + x3;
    float sq = x0 * x0 + x1 * x1 + x2 * x2 + x3 * x3;
    #pragma unroll
    for (int off = 32; off; off >>= 1) { s += __shfl_xor(s, off); sq += __shfl_xor(sq, off); }
    float mean = s * (1.f / 256.f);
    float var = sq * (1.f / 256.f) - mean * mean;
    float inv = rsqrtf(var + 1e-5f);
    int c = lane * 4;
    float o0 = (x0 - mean) * inv * g[c + 0] + bt[c + 0];
    float o1 = (x1 - mean) * inv * g[c + 1] + bt[c + 1];
    float o2 = (x2 - mean) * inv * g[c + 2] + bt[c + 2];
    float o3 = (x3 - mean) * inv * g[c + 3] + bt[c + 3];
    *(float4*)&OutF[base] = make_float4(o0, o1, o2, o3);
    if (OHi) {
        ushort4 h, l;
        split2(o0, h.x, l.x); split2(o1, h.y, l.y); split2(o2, h.z, l.z); split2(o3, h.w, l.w);
        *(ushort4*)&OHi[base] = h; *(ushort4*)&OLo[base] = l;
    }
    if (PEp) {
        float4 p = *(const float4*)&PEp[base];
        ushort4 h, l;
        split2(o0 + p.x, h.x, l.x); split2(o1 + p.y, h.y, l.y);
        split2(o2 + p.z, h.z, l.z); split2(o3 + p.w, h.w, l.w);
        *(ushort4*)&PHi[base] = h; *(ushort4*)&PLo[base] = l;
    }
}

// ----------------------------------------------------------------
extern "C" void kernel_launch(void* const* d_in, const int* in_sizes, int n_in,
                              void* d_out, int out_size, void* d_ws, size_t ws_size,
                              hipStream_t stream)
{
    const float* obj      = (const float*)d_in[0];
    const float* mp       = (const float*)d_in[1];
    const float* opos     = (const float*)d_in[2];
    const float* mpos     = (const float*)d_in[3];
    const float* a_pre_w  = (const float*)d_in[4];
    const float* a_pre_b  = (const float*)d_in[5];
    const float* a_mlp_w1 = (const float*)d_in[6];
    const float* a_mlp_b1 = (const float*)d_in[7];
    const float* a_mlp_w2 = (const float*)d_in[8];
    const float* a_mlp_b2 = (const float*)d_in[9];
    const float* a_out_w1 = (const float*)d_in[10];
    const float* a_out_b1 = (const float*)d_in[11];
    const float* a_out_w2 = (const float*)d_in[12];
    const float* a_out_b2 = (const float*)d_in[13];
    const float* m_pre_w1 = (const float*)d_in[14];
    const float* m_pre_b1 = (const float*)d_in[15];
    const float* m_pre_w2 = (const float*)d_in[16];
    const float* m_pre_b2 = (const float*)d_in[17];
    const float* m_pre_w3 = (const float*)d_in[18];
    const float* m_pre_b3 = (const float*)d_in[19];
    const float* m_mlp_w1 = (const float*)d_in[20];
    const float* m_mlp_b1 = (const float*)d_in[21];
    const float* m_mlp_w2 = (const float*)d_in[22];
    const float* m_mlp_b2 = (const float*)d_in[23];
    const float* m_out_w1 = (const float*)d_in[24];
    const float* m_out_b1 = (const float*)d_in[25];
    const float* m_out_w2 = (const float*)d_in[26];
    const float* m_out_b2 = (const float*)d_in[27];
    const float* attn_wqkv = (const float*)d_in[28];
    const float* attn_bqkv = (const float*)d_in[29];
    const float* attn_wo   = (const float*)d_in[30];
    const float* attn_bo   = (const float*)d_in[31];
    const float* ffn_w1    = (const float*)d_in[32];
    const float* ffn_b1    = (const float*)d_in[33];
    const float* ffn_w2    = (const float*)d_in[34];
    const float* ffn_b2    = (const float*)d_in[35];
    const float* ln1_g     = (const float*)d_in[36];
    const float* ln1_b     = (const float*)d_in[37];
    const float* ln2_g     = (const float*)d_in[38];
    const float* ln2_b     = (const float*)d_in[39];

    const size_t M = MTOT;  // 13312
    float* ws   = (float*)d_ws;
    float* X    = ws;                         // M*256 f32
    float* PE   = X   + M * 256;              // M*256 f32
    float* QKV  = PE  + M * 256;              // M*768 f32  (F1l aliases first M*512 f32)
    float* OF2  = QKV + M * 768;              // M*256 f32
    float* H    = OF2 + M * 256;              // M*256 f32  (AOh/AOl alias)
    float* XS   = H   + M * 256;              // M*512 f32  (XPh,XPl,Xh,Xl | F1h aliases)
    float* HS   = XS  + M * 512;              // M*256 f32  (Hh,Hl)
    float* WSp  = HS  + M * 256;              // 4,718,592 f32 (whi+wlo u16)
    int*  IDX   = (int*)(WSp + 4718592);      // M*16 int
    // total ~156 MB

    u16* XPh = (u16*)XS;             // M*256 u16 each
    u16* XPl = XPh + M * 256;
    u16* Xh  = XPl + M * 256;
    u16* Xl  = Xh  + M * 256;
    u16* F1h = (u16*)XS;             // M*1024 u16 (aliases XP/X splits; disjoint lifetime)
    u16* F1l = (u16*)QKV;            // M*1024 u16 (aliases QKV; disjoint lifetime)
    u16* AOh = (u16*)H;              // M*256 u16
    u16* AOl = AOh + M * 256;
    u16* Hh  = (u16*)HS;
    u16* Hl  = Hh + M * 256;
    u16* whi = (u16*)WSp;            // 6*786432 per-layer-packed
    u16* wlo = whi + 4718592;

    // fused pre-phase: map + agent + knn + pe + weight-split in ONE dispatch
    fused_pre<<<TOTB, 256, 0, stream>>>(
        obj, a_pre_w, a_pre_b, a_mlp_w1, a_mlp_b1, a_mlp_w2, a_mlp_b2,
        a_out_w1, a_out_b1, a_out_w2, a_out_b2,
        mp, m_pre_w1, m_pre_b1, m_pre_w2, m_pre_b2, m_pre_w3, m_pre_b3,
        m_mlp_w1, m_mlp_b1, m_mlp_w2, m_mlp_b2, m_out_w1, m_out_b1, m_out_w2, m_out_b2,
        opos, mpos, IDX, PE,
        attn_wqkv, attn_wo, ffn_w1, ffn_w2, whi, wlo,
        X);
    split_x0<<<(int)(M * 256 / 1024), 256, 0, stream>>>(X, PE, Xh, Xl, XPh, XPl);

    const float scal = 0.17677669529663687f;  // 32^-0.5
    const int MB = MTOT / 128;  // 104
    const int NOA2 = 0x7fffffff;
    for (int l = 0; l < LL; l++) {
        const size_t wb = (size_t)l * 786432;
        const u16* wqkv_h = whi + wb;            const u16* wqkv_l = wlo + wb;
        const u16* wo_h   = whi + wb + 196608;   const u16* wo_l   = wlo + wb + 196608;
        const u16* f1_h   = whi + wb + 262144;   const u16* f1_l   = wlo + wb + 262144;
        const u16* f2_h   = whi + wb + 524288;   const u16* f2_l   = wlo + wb + 524288;
        const float* bqkv = attn_bqkv + (size_t)l * 768;
        // merged QKV: cols [0,512) read X+PE splits, cols [512,768) read X splits
        gemm_mfma<false, false><<<dim3(MB, 6), 256, 0, stream>>>(
            XPh, XPl, Xh, Xl, 512, wqkv_h, wqkv_l, bqkv,
            QKV, nullptr, nullptr, 256, 768, 0, scal, 256);
        attn_kernel<<<MTOT / 2, 256, 0, stream>>>(QKV, IDX, AOh, AOl);
        // O-proj
        gemm_mfma<false, false><<<dim3(MB, 2), 256, 0, stream>>>(
            AOh, AOl, nullptr, nullptr, NOA2, wo_h, wo_l, attn_bo + (size_t)l * 256,
            OF2, nullptr, nullptr, 256, 256, 0, 1.f, 0);
        ln_kernel<<<MTOT / 4, 256, 0, stream>>>(X, OF2, ln1_g + l * 256, ln1_b + l * 256,
                                                H, Hh, Hl, nullptr, nullptr, nullptr);
        // FFN1 (relu), split output
        gemm_mfma<true, true><<<dim3(MB, 8), 256, 0, stream>>>(
            Hh, Hl, nullptr, nullptr, NOA2, f1_h, f1_l, ffn_b1 + (size_t)l * 1024,
            nullptr, F1h, F1l, 256, 1024, 0, 1.f, 0);
        // FFN2
        gemm_mfma<false, false><<<dim3(MB, 2), 256, 0, stream>>>(
            F1h, F1l, nullptr, nullptr, NOA2, f2_h, f2_l, ffn_b2 + (size_t)l * 256,
            OF2, nullptr, nullptr, 1024, 256, 0, 1.f, 0);
        if (l == LL - 1) {
            ln_kernel<<<MTOT / 4, 256, 0, stream>>>(H, OF2, ln2_g + l * 256, ln2_b + l * 256,
                                                    (float*)d_out, nullptr, nullptr,
                                                    nullptr, nullptr, nullptr);
        } else {
            ln_kernel<<<MTOT / 4, 256, 0, stream>>>(H, OF2, ln2_g + l * 256, ln2_b + l * 256,
                                                    X, Xh, Xl, PE, XPh, XPl);
        }
    }
}

// Round 9
// 1596.676 us; speedup vs baseline: 1.1256x; 1.1256x over previous
//
#include <hip/hip_runtime.h>
#include <hip/hip_bf16.h>

typedef unsigned short u16;

#define BB 16
#define NO 64
#define TT 21
#define NM 768
#define PP 20
#define CAx 29
#define CMx 9
#define DD 256
#define HH 8
#define LL 6
#define KK 16
#define NN (NO + NM)        // 832
#define HDX (DD / HH)       // 32
#define MTOT (BB * NN)      // 13312

typedef __attribute__((ext_vector_type(8))) short s8v;
typedef __attribute__((ext_vector_type(4))) float f4v;

__device__ __forceinline__ u16 bftrunc(float x) {
    return (u16)(__float_as_uint(x) >> 16);
}
__device__ __forceinline__ float bf2f(u16 u) {
    return __uint_as_float(((unsigned int)u) << 16);
}
__device__ __forceinline__ void split2(float x, u16& hi, u16& lo) {
    hi = bftrunc(x);
    lo = bftrunc(x - bf2f(hi));
}

#define GLOAD_LDS16(gptr, lptr)                                                             \
    __builtin_amdgcn_global_load_lds(                                                       \
        (const __attribute__((address_space(1))) void*)(gptr),                              \
        (__attribute__((address_space(3))) void*)(lptr), 16, 0, 0)

// ---------------------------------------------------------------- KNN (top-16 smallest d2)
__global__ __launch_bounds__(256) void knn_kernel(
    const float* __restrict__ opos, const float* __restrict__ mpos, int* __restrict__ IDX)
{
    const int b = blockIdx.x / 208;
    const int blk = blockIdx.x % 208;
    __shared__ float px[NN], py[NN], pz[NN];
    for (int i = threadIdx.x; i < NN; i += 256) {
        const float* src = (i < NO) ? &opos[(size_t)(b * NO + i) * 3]
                                    : &mpos[(size_t)(b * NM + (i - NO)) * 3];
        px[i] = src[0]; py[i] = src[1]; pz[i] = src[2];
    }
    __syncthreads();
    const int wave = threadIdx.x >> 6, lane = threadIdx.x & 63;
    const int n = blk * 4 + wave;
    const float qx = px[n], qy = py[n], qz = pz[n];
    float d[13];
    #pragma unroll
    for (int s = 0; s < 13; s++) {
        int j = s * 64 + lane;
        float dx = qx - px[j], dy = qy - py[j], dz = qz - pz[j];
        d[s] = dx * dx + dy * dy + dz * dz;
    }
    int keep = 0;
    #pragma unroll
    for (int it = 0; it < 16; it++) {
        float bv = d[0]; int bs = 0;
        #pragma unroll
        for (int s = 1; s < 13; s++) { if (d[s] < bv) { bv = d[s]; bs = s; } }
        float v = bv; int jj = bs * 64 + lane;
        #pragma unroll
        for (int off = 32; off; off >>= 1) {
            float ov = __shfl_xor(v, off);
            int oj = __shfl_xor(jj, off);
            if (ov < v || (ov == v && oj < jj)) { v = ov; jj = oj; }
        }
        if (lane == (jj & 63)) {
            int sl = jj >> 6;
            #pragma unroll
            for (int s = 0; s < 13; s++) if (s == sl) d[s] = 3.4e38f;
        }
        if (lane == it) keep = jj;
    }
    if (lane < 16) IDX[((size_t)(b * NN + n)) * 16 + lane] = keep;
}

// ---------------------------------------------------------------- sine positional embedding
__global__ __launch_bounds__(256) void pe_kernel(
    const float* __restrict__ opos, const float* __restrict__ mpos, float* __restrict__ PE)
{
    const int row = blockIdx.x;            // b*NN + n
    const int b = row / NN, n = row % NN;
    const int c = threadIdx.x;
    const float* p = (n < NO) ? &opos[(size_t)(b * NO + n) * 3]
                              : &mpos[(size_t)(b * NM + (n - NO)) * 3];
    float x = p[0], y = p[1];
    int j = c & 127;
    float v = (c < 128) ? y : x;
    float inv_dt = exp2f(-(float)(j & ~1) * 0.10381025296523f);
    float e = v * 6.283185307179586f * inv_dt;
    PE[(size_t)row * DD + c] = (j & 1) ? cosf(e) : sinf(e);
}

// ---------------------------------------------------------------- transformer weight pre-split
__global__ __launch_bounds__(256) void split_weights(
    const float* __restrict__ wqkv, const float* __restrict__ wo,
    const float* __restrict__ f1w, const float* __restrict__ f2w,
    u16* __restrict__ whi, u16* __restrict__ wlo)
{
    size_t e = (size_t)blockIdx.x * 256 + threadIdx.x;
    int L = (int)(e / 786432);
    int r = (int)(e % 786432);
    float v;
    if (r < 196608)      v = wqkv[(size_t)L * 196608 + r];
    else if (r < 262144) v = wo[(size_t)L * 65536 + (r - 196608)];
    else if (r < 524288) v = f1w[(size_t)L * 262144 + (r - 262144)];
    else                 v = f2w[(size_t)L * 262144 + (r - 524288)];
    u16 hi, lo; split2(v, hi, lo);
    whi[e] = hi; wlo[e] = lo;
}

// ---------------------------------------------------------------- pointnet weight pre-split (packed)
// offsets (u16 elems):
#define W1P_O   0        // map pre1  [64][32]  (pad from [64][9])
#define W2S_O   2048     // map pre2  [64][64]
#define W3S_O   6144     // map pre3  [64][64]
#define MW1A_O  10240    // map mid1 fa   [64][64] (cols 0..63 of [64][128])
#define MW1B_O  14336    // map mid1 pool [64][64] (cols 64..127)
#define MW2S_O  18432    // map mid2  [64][64]
#define OW1S_O  22528    // map out1  [64][64]
#define OW2S_O  26624    // map out2  [256][64]
#define APW_O   43008    // agent pre [256][32] (pad from [256][30])
#define AW1A_O  51200    // agent mlp1 fa   [256][256] (cols 0..255 of [256][512])
#define AW1B_O  116736   // agent mlp1 pool [256][256] (cols 256..511)
#define AW2S_O  182272   // agent mlp2 [256][256]
#define AOW1_O  247808   // agent out1 [256][256]
#define AOW2_O  313344   // agent out2 [256][256]
#define WPN_TOT 378880
__global__ __launch_bounds__(256) void split_pn_weights(
    const float* __restrict__ m_pre_w1, const float* __restrict__ m_pre_w2,
    const float* __restrict__ m_pre_w3, const float* __restrict__ m_mlp_w1,
    const float* __restrict__ m_mlp_w2, const float* __restrict__ m_out_w1,
    const float* __restrict__ m_out_w2,
    const float* __restrict__ a_pre_w,  const float* __restrict__ a_mlp_w1,
    const float* __restrict__ a_mlp_w2, const float* __restrict__ a_out_w1,
    const float* __restrict__ a_out_w2,
    u16* __restrict__ wpnh, u16* __restrict__ wpnl)
{
    int e = blockIdx.x * 256 + threadIdx.x;   // exactly WPN_TOT threads
    float v;
    if (e < W2S_O)       { int n = e >> 5, k = e & 31; v = (k < 9) ? m_pre_w1[n * 9 + k] : 0.f; }
    else if (e < W3S_O)  v = m_pre_w2[e - W2S_O];
    else if (e < MW1A_O) v = m_pre_w3[e - W3S_O];
    else if (e < MW1B_O) { int r = e - MW1A_O; v = m_mlp_w1[(r >> 6) * 128 + (r & 63)]; }
    else if (e < MW2S_O) { int r = e - MW1B_O; v = m_mlp_w1[(r >> 6) * 128 + 64 + (r & 63)]; }
    else if (e < OW1S_O) v = m_mlp_w2[e - MW2S_O];
    else if (e < OW2S_O) v = m_out_w1[e - OW1S_O];
    else if (e < APW_O)  v = m_out_w2[e - OW2S_O];
    else if (e < AW1A_O) { int r = e - APW_O; int n = r >> 5, k = r & 31; v = (k < 30) ? a_pre_w[n * 30 + k] : 0.f; }
    else if (e < AW1B_O) { int r = e - AW1A_O; v = a_mlp_w1[(r >> 8) * 512 + (r & 255)]; }
    else if (e < AW2S_O) { int r = e - AW1B_O; v = a_mlp_w1[(r >> 8) * 512 + 256 + (r & 255)]; }
    else if (e < AOW1_O) v = a_mlp_w2[e - AW2S_O];
    else if (e < AOW2_O) v = a_out_w1[e - AOW1_O];
    else                 v = a_out_w2[e - AOW2_O];
    u16 hi, lo; split2(v, hi, lo);
    wpnh[e] = hi; wpnl[e] = lo;
}

// ---------------------------------------------------------------- pointnet input prep (pad + split)
__global__ __launch_bounds__(256) void prep_map(
    const float* __restrict__ mp, int hoff, u16* __restrict__ pah, u16* __restrict__ pal)
{
    int e = blockIdx.x * 256 + threadIdx.x;   // r*32 + c
    int r = e >> 5, c = e & 31;
    float v = (c < CMx) ? mp[(size_t)(hoff + r) * CMx + c] : 0.f;
    u16 hi, lo; split2(v, hi, lo);
    pah[e] = hi; pal[e] = lo;
}
__global__ __launch_bounds__(256) void prep_agent(
    const float* __restrict__ obj, u16* __restrict__ pah, u16* __restrict__ pal)
{
    int e = blockIdx.x * 256 + threadIdx.x;   // r*32 + c
    int r = e >> 5, c = e & 31;
    float v = (c < CAx) ? obj[(size_t)r * CAx + c] : ((c == CAx) ? 1.0f : 0.f);
    u16 hi, lo; split2(v, hi, lo);
    pah[e] = hi; pal[e] = lo;
}

// ---------------------------------------------------------------- max-pool over P points (split in/out)
template<int P>
__global__ __launch_bounds__(256) void pool_max(
    const u16* __restrict__ inh, const u16* __restrict__ inl,
    u16* __restrict__ outh, u16* __restrict__ outl, int cshift, int gout_off)
{
    int e = blockIdx.x * 256 + threadIdx.x;   // g*C + c
    int C = 1 << cshift;
    int g = e >> cshift, c = e & (C - 1);
    float m = -3.4e38f;
    #pragma unroll
    for (int p = 0; p < P; p++) {
        size_t idx = (size_t)(g * P + p) * C + c;
        float v = bf2f(inh[idx]) + bf2f(inl[idx]);
        m = fmaxf(m, v);
    }
    u16 hi, lo; split2(m, hi, lo);
    size_t o = (size_t)(gout_off + g) * C + c;
    outh[o] = hi; outl[o] = lo;
}

// ---------------------------------------------------------------- pointnet GEMM (split-bf16 MFMA)
// tile 128 x BN (BN=64 or 128), BK=32, 4 waves. gload_lds staging, linear LDS.
// v = A.W^T (+bias) (+addrow[(row/ardiv)*arld + col]); relu opt; split or fp32 out;
// ROWMAP: dest row = row + rm_add + (row/rm_div)*rm_mul (fp32 out only).
template<int BN, bool RELU, bool SPLIT_OUT, bool ROWMAP>
__global__ __launch_bounds__(256) void gemm_pn(
    const u16* __restrict__ Ah, const u16* __restrict__ Al,
    const u16* __restrict__ Wh, const u16* __restrict__ Wl,
    const float* __restrict__ bias,
    const float* __restrict__ addrow, int ardiv, int arld,
    float* __restrict__ Cf, u16* __restrict__ Chi, u16* __restrict__ Clo,
    int K, int ldc, int rm_div, int rm_mul, int rm_add)
{
    constexpr int WAVES_M = (BN == 64) ? 4 : 2;
    constexpr int WM = 128 / (16 * WAVES_M);       // 2 or 4 m-frags per wave
    __shared__ __align__(16) u16 AhS[128][32];
    __shared__ __align__(16) u16 AlS[128][32];
    __shared__ __align__(16) u16 WhS[BN][32];
    __shared__ __align__(16) u16 WlS[BN][32];
    const int m0 = blockIdx.x * 128;
    const int n0 = blockIdx.y * BN;
    const int tid = threadIdx.x;
    const int wave = tid >> 6, lane = tid & 63;
    const int wr = (BN == 64) ? wave : (wave >> 1);
    const int wc = (BN == 64) ? 0 : (wave & 1);
    const int fr = lane & 15, kb = lane >> 4;
    const int lrow = lane >> 2, lcol = (lane & 3) * 8;

    f4v acc[WM][4];
    #pragma unroll
    for (int i = 0; i < WM; i++)
        #pragma unroll
        for (int j = 0; j < 4; j++) { f4v z = {0.f, 0.f, 0.f, 0.f}; acc[i][j] = z; }

    for (int k0 = 0; k0 < K; k0 += 32) {
        __syncthreads();
        #pragma unroll
        for (int i = 0; i < 2; i++) {
            const int r = wave * 32 + i * 16;
            GLOAD_LDS16(&Ah[(size_t)(m0 + r + lrow) * K + k0 + lcol], &AhS[r][0]);
            GLOAD_LDS16(&Al[(size_t)(m0 + r + lrow) * K + k0 + lcol], &AlS[r][0]);
        }
        if constexpr (BN == 64) {
            const int r = wave * 16;
            GLOAD_LDS16(&Wh[(size_t)(n0 + r + lrow) * K + k0 + lcol], &WhS[r][0]);
            GLOAD_LDS16(&Wl[(size_t)(n0 + r + lrow) * K + k0 + lcol], &WlS[r][0]);
        } else {
            #pragma unroll
            for (int i = 0; i < 2; i++) {
                const int r = wave * 32 + i * 16;
                GLOAD_LDS16(&Wh[(size_t)(n0 + r + lrow) * K + k0 + lcol], &WhS[r][0]);
                GLOAD_LDS16(&Wl[(size_t)(n0 + r + lrow) * K + k0 + lcol], &WlS[r][0]);
            }
        }
        __syncthreads();
        s8v afh[WM], afl[WM];
        #pragma unroll
        for (int mi = 0; mi < WM; mi++) {
            afh[mi] = *(const s8v*)&AhS[wr * (WM * 16) + mi * 16 + fr][kb * 8];
            afl[mi] = *(const s8v*)&AlS[wr * (WM * 16) + mi * 16 + fr][kb * 8];
        }
        #pragma unroll
        for (int nj = 0; nj < 4; nj++) {
            s8v bh = *(const s8v*)&WhS[wc * 64 + nj * 16 + fr][kb * 8];
            s8v bl = *(const s8v*)&WlS[wc * 64 + nj * 16 + fr][kb * 8];
            #pragma unroll
            for (int mi = 0; mi < WM; mi++) {
                acc[mi][nj] = __builtin_amdgcn_mfma_f32_16x16x32_bf16(afh[mi], bh, acc[mi][nj], 0, 0, 0);
                acc[mi][nj] = __builtin_amdgcn_mfma_f32_16x16x32_bf16(afh[mi], bl, acc[mi][nj], 0, 0, 0);
                acc[mi][nj] = __builtin_amdgcn_mfma_f32_16x16x32_bf16(afl[mi], bh, acc[mi][nj], 0, 0, 0);
            }
        }
    }
    #pragma unroll
    for (int mi = 0; mi < WM; mi++) {
        #pragma unroll
        for (int nj = 0; nj < 4; nj++) {
            int col = n0 + wc * 64 + nj * 16 + fr;
            float bb = bias ? bias[col] : 0.f;
            #pragma unroll
            for (int r = 0; r < 4; r++) {
                int row = m0 + wr * (WM * 16) + mi * 16 + (lane >> 4) * 4 + r;
                float v = acc[mi][nj][r] + bb;
                if (addrow) v += addrow[(size_t)(row / ardiv) * arld + col];
                if (RELU) v = fmaxf(v, 0.f);
                if (SPLIT_OUT) {
                    u16 hi, lo; split2(v, hi, lo);
                    Chi[(size_t)row * ldc + col] = hi;
                    Clo[(size_t)row * ldc + col] = lo;
                } else {
                    int drow = row;
                    if (ROWMAP) drow = row + rm_add + (row / rm_div) * rm_mul;
                    Cf[(size_t)drow * ldc + col] = v;
                }
            }
        }
    }
}

// ---------------------------------------------------------------- initial activation split
__global__ __launch_bounds__(256) void split_x0(
    const float* __restrict__ X, const float* __restrict__ PE,
    u16* __restrict__ Xh, u16* __restrict__ Xl,
    u16* __restrict__ XPh, u16* __restrict__ XPl)
{
    size_t base = ((size_t)blockIdx.x * 256 + threadIdx.x) * 4;
    float4 x = *(const float4*)&X[base];
    float4 p = *(const float4*)&PE[base];
    ushort4 h, l, ph, pl;
    split2(x.x, h.x, l.x); split2(x.y, h.y, l.y); split2(x.z, h.z, l.z); split2(x.w, h.w, l.w);
    split2(x.x + p.x, ph.x, pl.x); split2(x.y + p.y, ph.y, pl.y);
    split2(x.z + p.z, ph.z, pl.z); split2(x.w + p.w, ph.w, pl.w);
    *(ushort4*)&Xh[base] = h;  *(ushort4*)&Xl[base] = l;
    *(ushort4*)&XPh[base] = ph; *(ushort4*)&XPl[base] = pl;
}

// ---------------------------------------------------------------- transformer split-bf16 MFMA GEMM
template<bool RELU, bool SPLIT_OUT>
__global__ __launch_bounds__(256) void gemm_mfma(
    const u16* __restrict__ Ah, const u16* __restrict__ Al,
    const u16* __restrict__ A2h, const u16* __restrict__ A2l, int a2min,
    const u16* __restrict__ Wh, const u16* __restrict__ Wl,
    const float* __restrict__ bias,
    float* __restrict__ Cf, u16* __restrict__ Chi, u16* __restrict__ Clo,
    int K, int ldc, int coff, float scale, int scale_until)
{
    __shared__ __align__(16) u16 AhS[128][32];
    __shared__ __align__(16) u16 AlS[128][32];
    __shared__ __align__(16) u16 WhS[128][32];
    __shared__ __align__(16) u16 WlS[128][32];
    const int m0 = blockIdx.x * 128;
    const int n0 = blockIdx.y * 128;
    const u16* pAh = (n0 >= a2min) ? A2h : Ah;
    const u16* pAl = (n0 >= a2min) ? A2l : Al;
    const int tid = threadIdx.x;
    const int wave = tid >> 6, lane = tid & 63;
    const int wr = wave >> 1, wc = wave & 1;
    const int fr = lane & 15, kb = lane >> 4;
    const int lrow = lane >> 2;
    const int lcol = (lane & 3) * 8;

    f4v acc[4][4];
    #pragma unroll
    for (int i = 0; i < 4; i++)
        #pragma unroll
        for (int j = 0; j < 4; j++) { f4v z = {0.f, 0.f, 0.f, 0.f}; acc[i][j] = z; }

    for (int k0 = 0; k0 < K; k0 += 32) {
        __syncthreads();
        #pragma unroll
        for (int i = 0; i < 2; i++) {
            const int r = wave * 32 + i * 16;
            const size_t grow = (size_t)(r + lrow);
            GLOAD_LDS16(&pAh[(m0 + grow) * K + k0 + lcol], &AhS[r][0]);
            GLOAD_LDS16(&pAl[(m0 + grow) * K + k0 + lcol], &AlS[r][0]);
            GLOAD_LDS16(&Wh [(n0 + grow) * K + k0 + lcol], &WhS[r][0]);
            GLOAD_LDS16(&Wl [(n0 + grow) * K + k0 + lcol], &WlS[r][0]);
        }
        __syncthreads();
        s8v afh[4], afl[4];
        #pragma unroll
        for (int mi = 0; mi < 4; mi++) {
            afh[mi] = *(const s8v*)&AhS[wr * 64 + mi * 16 + fr][kb * 8];
            afl[mi] = *(const s8v*)&AlS[wr * 64 + mi * 16 + fr][kb * 8];
        }
        #pragma unroll
        for (int nj = 0; nj < 4; nj++) {
            s8v bh = *(const s8v*)&WhS[wc * 64 + nj * 16 + fr][kb * 8];
            s8v bl = *(const s8v*)&WlS[wc * 64 + nj * 16 + fr][kb * 8];
            #pragma unroll
            for (int mi = 0; mi < 4; mi++) {
                acc[mi][nj] = __builtin_amdgcn_mfma_f32_16x16x32_bf16(afh[mi], bh, acc[mi][nj], 0, 0, 0);
                acc[mi][nj] = __builtin_amdgcn_mfma_f32_16x16x32_bf16(afh[mi], bl, acc[mi][nj], 0, 0, 0);
                acc[mi][nj] = __builtin_amdgcn_mfma_f32_16x16x32_bf16(afl[mi], bh, acc[mi][nj], 0, 0, 0);
            }
        }
    }
    #pragma unroll
    for (int mi = 0; mi < 4; mi++) {
        #pragma unroll
        for (int nj = 0; nj < 4; nj++) {
            int col = n0 + wc * 64 + nj * 16 + fr;
            float bb = bias[col];
            #pragma unroll
            for (int r = 0; r < 4; r++) {
                int row = m0 + wr * 64 + mi * 16 + (lane >> 4) * 4 + r;
                float v = acc[mi][nj][r] + bb;
                if (RELU) v = fmaxf(v, 0.f);
                if (SPLIT_OUT) {
                    u16 hi, lo; split2(v, hi, lo);
                    Chi[(size_t)row * ldc + col] = hi;
                    Clo[(size_t)row * ldc + col] = lo;
                } else {
                    int gcol = coff + col;
                    if (gcol < scale_until) v *= scale;
                    Cf[(size_t)row * ldc + gcol] = v;
                }
            }
        }
    }
}

// ---------------------------------------------------------------- local KNN attention
__global__ __launch_bounds__(256) void attn_kernel(
    const float* __restrict__ QKV, const int* __restrict__ IDX,
    u16* __restrict__ AOh, u16* __restrict__ AOl)
{
    const int sub = threadIdx.x >> 7;
    const int t = threadIdx.x & 127;
    const int row = blockIdx.x * 2 + sub;     // b*NN + n
    const int b = row / NN;
    __shared__ float p_s[2][HH][16];
    __shared__ int gid_s[2][16];
    const int h = t >> 4, k = t & 15;
    int nb = IDX[(size_t)row * 16 + k];
    int g = b * NN + nb;
    if (h == 0) gid_s[sub][k] = g;
    const float* q = &QKV[(size_t)row * 768 + h * HDX];
    const float* kr = &QKV[(size_t)g * 768 + 256 + h * HDX];
    float s = 0.f;
    #pragma unroll
    for (int d = 0; d < HDX; d += 4) {
        float4 q4 = *(const float4*)&q[d];
        float4 k4 = *(const float4*)&kr[d];
        s += q4.x * k4.x + q4.y * k4.y + q4.z * k4.z + q4.w * k4.w;
    }
    float m = s;
    #pragma unroll
    for (int off = 8; off; off >>= 1) m = fmaxf(m, __shfl_xor(m, off, 16));
    float e = expf(s - m);
    float sum = e;
    #pragma unroll
    for (int off = 8; off; off >>= 1) sum += __shfl_xor(sum, off, 16);
    p_s[sub][h][k] = e / sum;
    __syncthreads();
    const int d0 = t * 2;
    const int hh = d0 >> 5, dd = d0 & 31;
    float o0 = 0.f, o1 = 0.f;
    #pragma unroll
    for (int kk = 0; kk < 16; kk++) {
        int gg = gid_s[sub][kk];
        const float* vr = &QKV[(size_t)gg * 768 + 512 + hh * HDX + dd];
        float p = p_s[sub][hh][kk];
        o0 += p * vr[0];
        o1 += p * vr[1];
    }
    u16 h0, lo0, h1, lo1;
    split2(o0, h0, lo0); split2(o1, h1, lo1);
    size_t base = (size_t)row * DD + d0;
    AOh[base] = h0; AOh[base + 1] = h1;
    AOl[base] = lo0; AOl[base + 1] = lo1;
}

// ---------------------------------------------------------------- residual + layernorm (+ split outputs)
__global__ __launch_bounds__(256) void ln_kernel(
    const float* __restrict__ R1, const float* __restrict__ R2,
    const float* __restrict__ g, const float* __restrict__ bt,
    float* __restrict__ OutF,
    u16* __restrict__ OHi, u16* __restrict__ OLo,
    const float* __restrict__ PEp,
    u16* __restrict__ PHi, u16* __restrict__ PLo)
{
    const int row = blockIdx.x * 4 + (threadIdx.x >> 6);
    const int lane = threadIdx.x & 63;
    size_t base = (size_t)row * DD + lane * 4;
    float4 a = *(const float4*)&R1[base];
    float4 b4 = *(const float4*)&R2[base];
    float x0 = a.x + b4.x, x1 = a.y + b4.y, x2 = a.z + b4.z, x3 = a.w + b4.w;
    float s = x0 + x1 + x2 + x3;
    float sq = x0 * x0 + x1 * x1 + x2 * x2 + x3 * x3;
    #pragma unroll
    for (int off = 32; off; off >>= 1) { s += __shfl_xor(s, off); sq += __shfl_xor(sq, off); }
    float mean = s * (1.f / 256.f);
    float var = sq * (1.f / 256.f) - mean * mean;
    float inv = rsqrtf(var + 1e-5f);
    int c = lane * 4;
    float o0 = (x0 - mean) * inv * g[c + 0] + bt[c + 0];
    float o1 = (x1 - mean) * inv * g[c + 1] + bt[c + 1];
    float o2 = (x2 - mean) * inv * g[c + 2] + bt[c + 2];
    float o3 = (x3 - mean) * inv * g[c + 3] + bt[c + 3];
    *(float4*)&OutF[base] = make_float4(o0, o1, o2, o3);
    if (OHi) {
        ushort4 h, l;
        split2(o0, h.x, l.x); split2(o1, h.y, l.y); split2(o2, h.z, l.z); split2(o3, h.w, l.w);
        *(ushort4*)&OHi[base] = h; *(ushort4*)&OLo[base] = l;
    }
    if (PEp) {
        float4 p = *(const float4*)&PEp[base];
        ushort4 h, l;
        split2(o0 + p.x, h.x, l.x); split2(o1 + p.y, h.y, l.y);
        split2(o2 + p.z, h.z, l.z); split2(o3 + p.w, h.w, l.w);
        *(ushort4*)&PHi[base] = h; *(ushort4*)&PLo[base] = l;
    }
}

// ----------------------------------------------------------------
extern "C" void kernel_launch(void* const* d_in, const int* in_sizes, int n_in,
                              void* d_out, int out_size, void* d_ws, size_t ws_size,
                              hipStream_t stream)
{
    const float* obj      = (const float*)d_in[0];
    const float* mp       = (const float*)d_in[1];
    const float* opos     = (const float*)d_in[2];
    const float* mpos     = (const float*)d_in[3];
    const float* a_pre_w  = (const float*)d_in[4];
    const float* a_pre_b  = (const float*)d_in[5];
    const float* a_mlp_w1 = (const float*)d_in[6];
    const float* a_mlp_b1 = (const float*)d_in[7];
    const float* a_mlp_w2 = (const float*)d_in[8];
    const float* a_mlp_b2 = (const float*)d_in[9];
    const float* a_out_w1 = (const float*)d_in[10];
    const float* a_out_b1 = (const float*)d_in[11];
    const float* a_out_w2 = (const float*)d_in[12];
    const float* a_out_b2 = (const float*)d_in[13];
    const float* m_pre_w1 = (const float*)d_in[14];
    const float* m_pre_b1 = (const float*)d_in[15];
    const float* m_pre_w2 = (const float*)d_in[16];
    const float* m_pre_b2 = (const float*)d_in[17];
    const float* m_pre_w3 = (const float*)d_in[18];
    const float* m_pre_b3 = (const float*)d_in[19];
    const float* m_mlp_w1 = (const float*)d_in[20];
    const float* m_mlp_b1 = (const float*)d_in[21];
    const float* m_mlp_w2 = (const float*)d_in[22];
    const float* m_mlp_b2 = (const float*)d_in[23];
    const float* m_out_w1 = (const float*)d_in[24];
    const float* m_out_b1 = (const float*)d_in[25];
    const float* m_out_w2 = (const float*)d_in[26];
    const float* m_out_b2 = (const float*)d_in[27];
    const float* attn_wqkv = (const float*)d_in[28];
    const float* attn_bqkv = (const float*)d_in[29];
    const float* attn_wo   = (const float*)d_in[30];
    const float* attn_bo   = (const float*)d_in[31];
    const float* ffn_w1    = (const float*)d_in[32];
    const float* ffn_b1    = (const float*)d_in[33];
    const float* ffn_w2    = (const float*)d_in[34];
    const float* ffn_b2    = (const float*)d_in[35];
    const float* ln1_g     = (const float*)d_in[36];
    const float* ln1_b     = (const float*)d_in[37];
    const float* ln2_g     = (const float*)d_in[38];
    const float* ln2_b     = (const float*)d_in[39];

    const size_t M = MTOT;  // 13312
    float* ws   = (float*)d_ws;
    float* X    = ws;                         // M*256 f32
    float* PE   = X   + M * 256;              // M*256 f32
    float* QKV  = PE  + M * 256;              // M*768 f32
    float* OF2  = QKV + M * 768;              // M*256 f32
    float* H    = OF2 + M * 256;              // M*256 f32
    float* XS   = H   + M * 256;              // M*512 f32
    float* HS   = XS  + M * 512;              // M*256 f32
    float* WSp  = HS  + M * 256;              // 4,718,592 f32 (whi+wlo u16)
    int*  IDX   = (int*)(WSp + 4718592);      // M*16 int
    u16*  wpnh  = (u16*)(IDX + MTOT * 16);    // pointnet weights split
    u16*  wpnl  = wpnh + WPN_TOT;
    // total ~158 MB (<= 165 MB proven in R3)

    // transformer aliases (layer-loop lifetime)
    u16* XPh = (u16*)XS;
    u16* XPl = XPh + M * 256;
    u16* Xh  = XPl + M * 256;
    u16* Xl  = Xh  + M * 256;
    u16* F1h = (u16*)XS;
    u16* F1l = (u16*)QKV;
    u16* AOh = (u16*)H;
    u16* AOl = AOh + M * 256;
    u16* Hh  = (u16*)HS;
    u16* Hl  = Hh + M * 256;
    u16* whi = (u16*)WSp;
    u16* wlo = whi + 4718592;

    // pointnet phase aliases (dead-during-pre region = QKV..HS, 109 MB)
    u16* PN0h = (u16*)QKV;            // 7,864,320 u16 each (122880*64)
    u16* PN0l = PN0h + 7864320;
    u16* PN1h = PN0h + 15728640;
    u16* PN1l = PN0h + 23592960;
    u16* SBp  = PN0h + 31457280;      // small buffers
    u16* PLh  = SBp;                  // 6144*64
    u16* PLl  = SBp + 393216;
    u16* GMh  = SBp + 786432;         // 12288*64
    u16* GMl  = SBp + 1572864;
    u16* HVh  = SBp + 2359296;        // 12288*64
    u16* HVl  = SBp + 3145728;
    u16* APLh = SBp + 3932160;        // 1024*256
    u16* APLl = SBp + 4194304;
    u16* AGMh = SBp + 4456448;
    u16* AGMl = SBp + 4718592;
    u16* AHVh = SBp + 4980736;
    u16* AHVl = SBp + 5242880;
    float* PCf = (float*)(SBp + 5505024);   // 6144*64 f32
    float* APC = PCf + 393216;              // 1024*256 f32

    // ---------------- pre-phase ----------------
    knn_kernel<<<BB * 208, 256, 0, stream>>>(opos, mpos, IDX);
    pe_kernel<<<MTOT, 256, 0, stream>>>(opos, mpos, PE);
    split_weights<<<4718592 / 256, 256, 0, stream>>>(attn_wqkv, attn_wo, ffn_w1, ffn_w2, whi, wlo);
    split_pn_weights<<<WPN_TOT / 256, 256, 0, stream>>>(
        m_pre_w1, m_pre_w2, m_pre_w3, m_mlp_w1, m_mlp_w2, m_out_w1, m_out_w2,
        a_pre_w, a_mlp_w1, a_mlp_w2, a_out_w1, a_out_w2, wpnh, wpnl);

    // ---- agent pointnet as GEMM chain (Ma = 21504 point-rows, Ga = 1024 objects)
    {
        u16* PA32h = PN1h; u16* PA32l = PN1l;    // 21504*32
        u16* PBh = PN0h;   u16* PBl = PN0l;      // 21504*256
        u16* PA2h = PN1h;  u16* PA2l = PN1l;     // 21504*256
        prep_agent<<<21504 * 32 / 256, 256, 0, stream>>>(obj, PA32h, PA32l);
        gemm_pn<128, true, true, false><<<dim3(168, 2), 256, 0, stream>>>(
            PA32h, PA32l, wpnh + APW_O, wpnl + APW_O, a_pre_b, nullptr, 1, 0,
            nullptr, PBh, PBl, 32, 256, 1, 0, 0);
        pool_max<21><<<1024, 256, 0, stream>>>(PBh, PBl, APLh, APLl, 8, 0);
        gemm_pn<128, false, false, false><<<dim3(8, 2), 256, 0, stream>>>(
            APLh, APLl, wpnh + AW1B_O, wpnl + AW1B_O, a_mlp_b1, nullptr, 1, 0,
            APC, nullptr, nullptr, 256, 256, 1, 0, 0);
        gemm_pn<128, true, true, false><<<dim3(168, 2), 256, 0, stream>>>(
            PBh, PBl, wpnh + AW1A_O, wpnl + AW1A_O, nullptr, APC, 21, 256,
            nullptr, PA2h, PA2l, 256, 256, 1, 0, 0);
        gemm_pn<128, true, true, false><<<dim3(168, 2), 256, 0, stream>>>(
            PA2h, PA2l, wpnh + AW2S_O, wpnl + AW2S_O, a_mlp_b2, nullptr, 1, 0,
            nullptr, PBh, PBl, 256, 256, 1, 0, 0);
        pool_max<21><<<1024, 256, 0, stream>>>(PBh, PBl, AGMh, AGMl, 8, 0);
        gemm_pn<128, true, true, false><<<dim3(8, 2), 256, 0, stream>>>(
            AGMh, AGMl, wpnh + AOW1_O, wpnl + AOW1_O, a_out_b1, nullptr, 1, 0,
            nullptr, AHVh, AHVl, 256, 256, 1, 0, 0);
        // out2 -> X with row remap: dest = row + (row/64)*768
        gemm_pn<128, false, false, true><<<dim3(8, 2), 256, 0, stream>>>(
            AHVh, AHVl, wpnh + AOW2_O, wpnl + AOW2_O, a_out_b2, nullptr, 1, 0,
            X, nullptr, nullptr, 256, 256, 64, 768, 0);
    }

    // ---- map pointnet as GEMM chain, two batch halves (Rh = 122880 point-rows each)
    for (int h = 0; h < 2; h++) {
        const int hoff = h * 122880;
        u16* PM32h = PN0h; u16* PM32l = PN0l;
        prep_map<<<122880 * 32 / 256, 256, 0, stream>>>(mp, hoff, PM32h, PM32l);
        gemm_pn<64, true, true, false><<<dim3(960, 1), 256, 0, stream>>>(
            PM32h, PM32l, wpnh + W1P_O, wpnl + W1P_O, m_pre_b1, nullptr, 1, 0,
            nullptr, PN1h, PN1l, 32, 64, 1, 0, 0);
        gemm_pn<64, true, true, false><<<dim3(960, 1), 256, 0, stream>>>(
            PN1h, PN1l, wpnh + W2S_O, wpnl + W2S_O, m_pre_b2, nullptr, 1, 0,
            nullptr, PN0h, PN0l, 64, 64, 1, 0, 0);
        gemm_pn<64, true, true, false><<<dim3(960, 1), 256, 0, stream>>>(
            PN0h, PN0l, wpnh + W3S_O, wpnl + W3S_O, m_pre_b3, nullptr, 1, 0,
            nullptr, PN1h, PN1l, 64, 64, 1, 0, 0);
        pool_max<20><<<1536, 256, 0, stream>>>(PN1h, PN1l, PLh, PLl, 6, 0);
        gemm_pn<64, false, false, false><<<dim3(48, 1), 256, 0, stream>>>(
            PLh, PLl, wpnh + MW1B_O, wpnl + MW1B_O, m_mlp_b1, nullptr, 1, 0,
            PCf, nullptr, nullptr, 64, 64, 1, 0, 0);
        gemm_pn<64, true, true, false><<<dim3(960, 1), 256, 0, stream>>>(
            PN1h, PN1l, wpnh + MW1A_O, wpnl + MW1A_O, nullptr, PCf, 20, 64,
            nullptr, PN0h, PN0l, 64, 64, 1, 0, 0);
        gemm_pn<64, true, true, false><<<dim3(960, 1), 256, 0, stream>>>(
            PN0h, PN0l, wpnh + MW2S_O, wpnl + MW2S_O, m_mlp_b2, nullptr, 1, 0,
            nullptr, PN1h, PN1l, 64, 64, 1, 0, 0);
        pool_max<20><<<1536, 256, 0, stream>>>(PN1h, PN1l, GMh, GMl, 6, h * 6144);
    }
    gemm_pn<64, true, true, false><<<dim3(96, 1), 256, 0, stream>>>(
        GMh, GMl, wpnh + OW1S_O, wpnl + OW1S_O, m_out_b1, nullptr, 1, 0,
        nullptr, HVh, HVl, 64, 64, 1, 0, 0);
    // out2 -> X with row remap: dest = row + 64 + (row/768)*64
    gemm_pn<128, false, false, true><<<dim3(96, 2), 256, 0, stream>>>(
        HVh, HVl, wpnh + OW2S_O, wpnl + OW2S_O, m_out_b2, nullptr, 1, 0,
        X, nullptr, nullptr, 64, 256, 768, 64, 64);

    split_x0<<<(int)(M * 256 / 1024), 256, 0, stream>>>(X, PE, Xh, Xl, XPh, XPl);

    // ---------------- transformer layers ----------------
    const float scal = 0.17677669529663687f;  // 32^-0.5
    const int MB = MTOT / 128;  // 104
    const int NOA2 = 0x7fffffff;
    for (int l = 0; l < LL; l++) {
        const size_t wb = (size_t)l * 786432;
        const u16* wqkv_h = whi + wb;            const u16* wqkv_l = wlo + wb;
        const u16* wo_h   = whi + wb + 196608;   const u16* wo_l   = wlo + wb + 196608;
        const u16* f1_h   = whi + wb + 262144;   const u16* f1_l   = wlo + wb + 262144;
        const u16* f2_h   = whi + wb + 524288;   const u16* f2_l   = wlo + wb + 524288;
        const float* bqkv = attn_bqkv + (size_t)l * 768;
        gemm_mfma<false, false><<<dim3(MB, 6), 256, 0, stream>>>(
            XPh, XPl, Xh, Xl, 512, wqkv_h, wqkv_l, bqkv,
            QKV, nullptr, nullptr, 256, 768, 0, scal, 256);
        attn_kernel<<<MTOT / 2, 256, 0, stream>>>(QKV, IDX, AOh, AOl);
        gemm_mfma<false, false><<<dim3(MB, 2), 256, 0, stream>>>(
            AOh, AOl, nullptr, nullptr, NOA2, wo_h, wo_l, attn_bo + (size_t)l * 256,
            OF2, nullptr, nullptr, 256, 256, 0, 1.f, 0);
        ln_kernel<<<MTOT / 4, 256, 0, stream>>>(X, OF2, ln1_g + l * 256, ln1_b + l * 256,
                                                H, Hh, Hl, nullptr, nullptr, nullptr);
        gemm_mfma<true, true><<<dim3(MB, 8), 256, 0, stream>>>(
            Hh, Hl, nullptr, nullptr, NOA2, f1_h, f1_l, ffn_b1 + (size_t)l * 1024,
            nullptr, F1h, F1l, 256, 1024, 0, 1.f, 0);
        gemm_mfma<false, false><<<dim3(MB, 2), 256, 0, stream>>>(
            F1h, F1l, nullptr, nullptr, NOA2, f2_h, f2_l, ffn_b2 + (size_t)l * 256,
            OF2, nullptr, nullptr, 1024, 256, 0, 1.f, 0);
        if (l == LL - 1) {
            ln_kernel<<<MTOT / 4, 256, 0, stream>>>(H, OF2, ln2_g + l * 256, ln2_b + l * 256,
                                                    (float*)d_out, nullptr, nullptr,
                                                    nullptr, nullptr, nullptr);
        } else {
            ln_kernel<<<MTOT / 4, 256, 0, stream>>>(H, OF2, ln2_g + l * 256, ln2_b + l * 256,
                                                    X, Xh, Xl, PE, XPh, XPl);
        }
    }
}

// Round 10
// 1565.774 us; speedup vs baseline: 1.1478x; 1.0197x over previous
//
#include <hip/hip_runtime.h>
#include <hip/hip_bf16.h>

typedef unsigned short u16;

#define BB 16
#define NO 64
#define TT 21
#define NM 768
#define PP 20
#define CAx 29
#define CMx 9
#define DD 256
#define HH 8
#define LL 6
#define KK 16
#define NN (NO + NM)        // 832
#define HDX (DD / HH)       // 32
#define MTOT (BB * NN)      // 13312

typedef __attribute__((ext_vector_type(8))) short s8v;
typedef __attribute__((ext_vector_type(4))) float f4v;

__device__ __forceinline__ u16 bftrunc(float x) {
    return (u16)(__float_as_uint(x) >> 16);
}
__device__ __forceinline__ float bf2f(u16 u) {
    return __uint_as_float(((unsigned int)u) << 16);
}
__device__ __forceinline__ void split2(float x, u16& hi, u16& lo) {
    hi = bftrunc(x);
    lo = bftrunc(x - bf2f(hi));
}

#define GLOAD_LDS16(gptr, lptr)                                                             \
    __builtin_amdgcn_global_load_lds(                                                       \
        (const __attribute__((address_space(1))) void*)(gptr),                              \
        (__attribute__((address_space(3))) void*)(lptr), 16, 0, 0)

// ---------------------------------------------------------------- KNN (top-16 smallest d2)
__global__ __launch_bounds__(256) void knn_kernel(
    const float* __restrict__ opos, const float* __restrict__ mpos, int* __restrict__ IDX)
{
    const int b = blockIdx.x / 208;
    const int blk = blockIdx.x % 208;
    __shared__ float px[NN], py[NN], pz[NN];
    for (int i = threadIdx.x; i < NN; i += 256) {
        const float* src = (i < NO) ? &opos[(size_t)(b * NO + i) * 3]
                                    : &mpos[(size_t)(b * NM + (i - NO)) * 3];
        px[i] = src[0]; py[i] = src[1]; pz[i] = src[2];
    }
    __syncthreads();
    const int wave = threadIdx.x >> 6, lane = threadIdx.x & 63;
    const int n = blk * 4 + wave;
    const float qx = px[n], qy = py[n], qz = pz[n];
    float d[13];
    #pragma unroll
    for (int s = 0; s < 13; s++) {
        int j = s * 64 + lane;
        float dx = qx - px[j], dy = qy - py[j], dz = qz - pz[j];
        d[s] = dx * dx + dy * dy + dz * dz;
    }
    int keep = 0;
    #pragma unroll
    for (int it = 0; it < 16; it++) {
        float bv = d[0]; int bs = 0;
        #pragma unroll
        for (int s = 1; s < 13; s++) { if (d[s] < bv) { bv = d[s]; bs = s; } }
        float v = bv; int jj = bs * 64 + lane;
        #pragma unroll
        for (int off = 32; off; off >>= 1) {
            float ov = __shfl_xor(v, off);
            int oj = __shfl_xor(jj, off);
            if (ov < v || (ov == v && oj < jj)) { v = ov; jj = oj; }
        }
        if (lane == (jj & 63)) {
            int sl = jj >> 6;
            #pragma unroll
            for (int s = 0; s < 13; s++) if (s == sl) d[s] = 3.4e38f;
        }
        if (lane == it) keep = jj;
    }
    if (lane < 16) IDX[((size_t)(b * NN + n)) * 16 + lane] = keep;
}

// ---------------------------------------------------------------- sine positional embedding
__global__ __launch_bounds__(256) void pe_kernel(
    const float* __restrict__ opos, const float* __restrict__ mpos, float* __restrict__ PE)
{
    const int row = blockIdx.x;            // b*NN + n
    const int b = row / NN, n = row % NN;
    const int c = threadIdx.x;
    const float* p = (n < NO) ? &opos[(size_t)(b * NO + n) * 3]
                              : &mpos[(size_t)(b * NM + (n - NO)) * 3];
    float x = p[0], y = p[1];
    int j = c & 127;
    float v = (c < 128) ? y : x;
    float inv_dt = exp2f(-(float)(j & ~1) * 0.10381025296523f);
    float e = v * 6.283185307179586f * inv_dt;
    PE[(size_t)row * DD + c] = (j & 1) ? cosf(e) : sinf(e);
}

// ---------------------------------------------------------------- transformer weight pre-split
__global__ __launch_bounds__(256) void split_weights(
    const float* __restrict__ wqkv, const float* __restrict__ wo,
    const float* __restrict__ f1w, const float* __restrict__ f2w,
    u16* __restrict__ whi, u16* __restrict__ wlo)
{
    size_t e = (size_t)blockIdx.x * 256 + threadIdx.x;
    int L = (int)(e / 786432);
    int r = (int)(e % 786432);
    float v;
    if (r < 196608)      v = wqkv[(size_t)L * 196608 + r];
    else if (r < 262144) v = wo[(size_t)L * 65536 + (r - 196608)];
    else if (r < 524288) v = f1w[(size_t)L * 262144 + (r - 262144)];
    else                 v = f2w[(size_t)L * 262144 + (r - 524288)];
    u16 hi, lo; split2(v, hi, lo);
    whi[e] = hi; wlo[e] = lo;
}

// ---------------------------------------------------------------- pointnet weight pre-split (packed)
#define W1P_O   0
#define W2S_O   2048
#define W3S_O   6144
#define MW1A_O  10240
#define MW1B_O  14336
#define MW2S_O  18432
#define OW1S_O  22528
#define OW2S_O  26624
#define APW_O   43008
#define AW1A_O  51200
#define AW1B_O  116736
#define AW2S_O  182272
#define AOW1_O  247808
#define AOW2_O  313344
#define WPN_TOT 378880
__global__ __launch_bounds__(256) void split_pn_weights(
    const float* __restrict__ m_pre_w1, const float* __restrict__ m_pre_w2,
    const float* __restrict__ m_pre_w3, const float* __restrict__ m_mlp_w1,
    const float* __restrict__ m_mlp_w2, const float* __restrict__ m_out_w1,
    const float* __restrict__ m_out_w2,
    const float* __restrict__ a_pre_w,  const float* __restrict__ a_mlp_w1,
    const float* __restrict__ a_mlp_w2, const float* __restrict__ a_out_w1,
    const float* __restrict__ a_out_w2,
    u16* __restrict__ wpnh, u16* __restrict__ wpnl)
{
    int e = blockIdx.x * 256 + threadIdx.x;
    float v;
    if (e < W2S_O)       { int n = e >> 5, k = e & 31; v = (k < 9) ? m_pre_w1[n * 9 + k] : 0.f; }
    else if (e < W3S_O)  v = m_pre_w2[e - W2S_O];
    else if (e < MW1A_O) v = m_pre_w3[e - W3S_O];
    else if (e < MW1B_O) { int r = e - MW1A_O; v = m_mlp_w1[(r >> 6) * 128 + (r & 63)]; }
    else if (e < MW2S_O) { int r = e - MW1B_O; v = m_mlp_w1[(r >> 6) * 128 + 64 + (r & 63)]; }
    else if (e < OW1S_O) v = m_mlp_w2[e - MW2S_O];
    else if (e < OW2S_O) v = m_out_w1[e - OW1S_O];
    else if (e < APW_O)  v = m_out_w2[e - OW2S_O];
    else if (e < AW1A_O) { int r = e - APW_O; int n = r >> 5, k = r & 31; v = (k < 30) ? a_pre_w[n * 30 + k] : 0.f; }
    else if (e < AW1B_O) { int r = e - AW1A_O; v = a_mlp_w1[(r >> 8) * 512 + (r & 255)]; }
    else if (e < AW2S_O) { int r = e - AW1B_O; v = a_mlp_w1[(r >> 8) * 512 + 256 + (r & 255)]; }
    else if (e < AOW1_O) v = a_mlp_w2[e - AW2S_O];
    else if (e < AOW2_O) v = a_out_w1[e - AOW1_O];
    else                 v = a_out_w2[e - AOW2_O];
    u16 hi, lo; split2(v, hi, lo);
    wpnh[e] = hi; wpnl[e] = lo;
}

// ---------------------------------------------------------------- pointnet input prep (pad + split)
__global__ __launch_bounds__(256) void prep_map(
    const float* __restrict__ mp, int hoff, u16* __restrict__ pah, u16* __restrict__ pal)
{
    int e = blockIdx.x * 256 + threadIdx.x;
    int r = e >> 5, c = e & 31;
    float v = (c < CMx) ? mp[(size_t)(hoff + r) * CMx + c] : 0.f;
    u16 hi, lo; split2(v, hi, lo);
    pah[e] = hi; pal[e] = lo;
}
__global__ __launch_bounds__(256) void prep_agent(
    const float* __restrict__ obj, u16* __restrict__ pah, u16* __restrict__ pal)
{
    int e = blockIdx.x * 256 + threadIdx.x;
    int r = e >> 5, c = e & 31;
    float v = (c < CAx) ? obj[(size_t)r * CAx + c] : ((c == CAx) ? 1.0f : 0.f);
    u16 hi, lo; split2(v, hi, lo);
    pah[e] = hi; pal[e] = lo;
}

// ---------------------------------------------------------------- max-pool over P points
template<int P>
__global__ __launch_bounds__(256) void pool_max(
    const u16* __restrict__ inh, const u16* __restrict__ inl,
    u16* __restrict__ outh, u16* __restrict__ outl, int cshift, int gout_off)
{
    int e = blockIdx.x * 256 + threadIdx.x;
    int C = 1 << cshift;
    int g = e >> cshift, c = e & (C - 1);
    float m = -3.4e38f;
    #pragma unroll
    for (int p = 0; p < P; p++) {
        size_t idx = (size_t)(g * P + p) * C + c;
        float v = bf2f(inh[idx]) + bf2f(inl[idx]);
        m = fmaxf(m, v);
    }
    u16 hi, lo; split2(m, hi, lo);
    size_t o = (size_t)(gout_off + g) * C + c;
    outh[o] = hi; outl[o] = lo;
}

// ---------------------------------------------------------------- pointnet GEMM (split-bf16 MFMA)
template<int BN, bool RELU, bool SPLIT_OUT, bool ROWMAP>
__global__ __launch_bounds__(256) void gemm_pn(
    const u16* __restrict__ Ah, const u16* __restrict__ Al,
    const u16* __restrict__ Wh, const u16* __restrict__ Wl,
    const float* __restrict__ bias,
    const float* __restrict__ addrow, int ardiv, int arld,
    float* __restrict__ Cf, u16* __restrict__ Chi, u16* __restrict__ Clo,
    int K, int ldc, int rm_div, int rm_mul, int rm_add)
{
    constexpr int WAVES_M = (BN == 64) ? 4 : 2;
    constexpr int WM = 128 / (16 * WAVES_M);
    __shared__ __align__(16) u16 AhS[128][32];
    __shared__ __align__(16) u16 AlS[128][32];
    __shared__ __align__(16) u16 WhS[BN][32];
    __shared__ __align__(16) u16 WlS[BN][32];
    const int m0 = blockIdx.x * 128;
    const int n0 = blockIdx.y * BN;
    const int tid = threadIdx.x;
    const int wave = tid >> 6, lane = tid & 63;
    const int wr = (BN == 64) ? wave : (wave >> 1);
    const int wc = (BN == 64) ? 0 : (wave & 1);
    const int fr = lane & 15, kb = lane >> 4;
    const int lrow = lane >> 2, lcol = (lane & 3) * 8;

    f4v acc[WM][4];
    #pragma unroll
    for (int i = 0; i < WM; i++)
        #pragma unroll
        for (int j = 0; j < 4; j++) { f4v z = {0.f, 0.f, 0.f, 0.f}; acc[i][j] = z; }

    for (int k0 = 0; k0 < K; k0 += 32) {
        __syncthreads();
        #pragma unroll
        for (int i = 0; i < 2; i++) {
            const int r = wave * 32 + i * 16;
            GLOAD_LDS16(&Ah[(size_t)(m0 + r + lrow) * K + k0 + lcol], &AhS[r][0]);
            GLOAD_LDS16(&Al[(size_t)(m0 + r + lrow) * K + k0 + lcol], &AlS[r][0]);
        }
        if constexpr (BN == 64) {
            const int r = wave * 16;
            GLOAD_LDS16(&Wh[(size_t)(n0 + r + lrow) * K + k0 + lcol], &WhS[r][0]);
            GLOAD_LDS16(&Wl[(size_t)(n0 + r + lrow) * K + k0 + lcol], &WlS[r][0]);
        } else {
            #pragma unroll
            for (int i = 0; i < 2; i++) {
                const int r = wave * 32 + i * 16;
                GLOAD_LDS16(&Wh[(size_t)(n0 + r + lrow) * K + k0 + lcol], &WhS[r][0]);
                GLOAD_LDS16(&Wl[(size_t)(n0 + r + lrow) * K + k0 + lcol], &WlS[r][0]);
            }
        }
        __syncthreads();
        s8v afh[WM], afl[WM];
        #pragma unroll
        for (int mi = 0; mi < WM; mi++) {
            afh[mi] = *(const s8v*)&AhS[wr * (WM * 16) + mi * 16 + fr][kb * 8];
            afl[mi] = *(const s8v*)&AlS[wr * (WM * 16) + mi * 16 + fr][kb * 8];
        }
        #pragma unroll
        for (int nj = 0; nj < 4; nj++) {
            s8v bh = *(const s8v*)&WhS[wc * 64 + nj * 16 + fr][kb * 8];
            s8v bl = *(const s8v*)&WlS[wc * 64 + nj * 16 + fr][kb * 8];
            #pragma unroll
            for (int mi = 0; mi < WM; mi++) {
                acc[mi][nj] = __builtin_amdgcn_mfma_f32_16x16x32_bf16(afh[mi], bh, acc[mi][nj], 0, 0, 0);
                acc[mi][nj] = __builtin_amdgcn_mfma_f32_16x16x32_bf16(afh[mi], bl, acc[mi][nj], 0, 0, 0);
                acc[mi][nj] = __builtin_amdgcn_mfma_f32_16x16x32_bf16(afl[mi], bh, acc[mi][nj], 0, 0, 0);
            }
        }
    }
    #pragma unroll
    for (int mi = 0; mi < WM; mi++) {
        #pragma unroll
        for (int nj = 0; nj < 4; nj++) {
            int col = n0 + wc * 64 + nj * 16 + fr;
            float bb = bias ? bias[col] : 0.f;
            #pragma unroll
            for (int r = 0; r < 4; r++) {
                int row = m0 + wr * (WM * 16) + mi * 16 + (lane >> 4) * 4 + r;
                float v = acc[mi][nj][r] + bb;
                if (addrow) v += addrow[(size_t)(row / ardiv) * arld + col];
                if (RELU) v = fmaxf(v, 0.f);
                if (SPLIT_OUT) {
                    u16 hi, lo; split2(v, hi, lo);
                    Chi[(size_t)row * ldc + col] = hi;
                    Clo[(size_t)row * ldc + col] = lo;
                } else {
                    int drow = row;
                    if (ROWMAP) drow = row + rm_add + (row / rm_div) * rm_mul;
                    Cf[(size_t)drow * ldc + col] = v;
                }
            }
        }
    }
}

// ---------------------------------------------------------------- initial activation split
__global__ __launch_bounds__(256) void split_x0(
    const float* __restrict__ X, const float* __restrict__ PE,
    u16* __restrict__ Xh, u16* __restrict__ Xl,
    u16* __restrict__ XPh, u16* __restrict__ XPl)
{
    size_t base = ((size_t)blockIdx.x * 256 + threadIdx.x) * 4;
    float4 x = *(const float4*)&X[base];
    float4 p = *(const float4*)&PE[base];
    ushort4 h, l, ph, pl;
    split2(x.x, h.x, l.x); split2(x.y, h.y, l.y); split2(x.z, h.z, l.z); split2(x.w, h.w, l.w);
    split2(x.x + p.x, ph.x, pl.x); split2(x.y + p.y, ph.y, pl.y);
    split2(x.z + p.z, ph.z, pl.z); split2(x.w + p.w, ph.w, pl.w);
    *(ushort4*)&Xh[base] = h;  *(ushort4*)&Xl[base] = l;
    *(ushort4*)&XPh[base] = ph; *(ushort4*)&XPl[base] = pl;
}

// ---------------------------------------------------------------- transformer split-bf16 MFMA GEMM
template<bool RELU, bool SPLIT_OUT>
__global__ __launch_bounds__(256) void gemm_mfma(
    const u16* __restrict__ Ah, const u16* __restrict__ Al,
    const u16* __restrict__ A2h, const u16* __restrict__ A2l, int a2min,
    const u16* __restrict__ Wh, const u16* __restrict__ Wl,
    const float* __restrict__ bias,
    float* __restrict__ Cf, u16* __restrict__ Chi, u16* __restrict__ Clo,
    int K, int ldc, int coff, float scale, int scale_until)
{
    __shared__ __align__(16) u16 AhS[128][32];
    __shared__ __align__(16) u16 AlS[128][32];
    __shared__ __align__(16) u16 WhS[128][32];
    __shared__ __align__(16) u16 WlS[128][32];
    const int m0 = blockIdx.x * 128;
    const int n0 = blockIdx.y * 128;
    const u16* pAh = (n0 >= a2min) ? A2h : Ah;
    const u16* pAl = (n0 >= a2min) ? A2l : Al;
    const int tid = threadIdx.x;
    const int wave = tid >> 6, lane = tid & 63;
    const int wr = wave >> 1, wc = wave & 1;
    const int fr = lane & 15, kb = lane >> 4;
    const int lrow = lane >> 2;
    const int lcol = (lane & 3) * 8;

    f4v acc[4][4];
    #pragma unroll
    for (int i = 0; i < 4; i++)
        #pragma unroll
        for (int j = 0; j < 4; j++) { f4v z = {0.f, 0.f, 0.f, 0.f}; acc[i][j] = z; }

    for (int k0 = 0; k0 < K; k0 += 32) {
        __syncthreads();
        #pragma unroll
        for (int i = 0; i < 2; i++) {
            const int r = wave * 32 + i * 16;
            const size_t grow = (size_t)(r + lrow);
            GLOAD_LDS16(&pAh[(m0 + grow) * K + k0 + lcol], &AhS[r][0]);
            GLOAD_LDS16(&pAl[(m0 + grow) * K + k0 + lcol], &AlS[r][0]);
            GLOAD_LDS16(&Wh [(n0 + grow) * K + k0 + lcol], &WhS[r][0]);
            GLOAD_LDS16(&Wl [(n0 + grow) * K + k0 + lcol], &WlS[r][0]);
        }
        __syncthreads();
        s8v afh[4], afl[4];
        #pragma unroll
        for (int mi = 0; mi < 4; mi++) {
            afh[mi] = *(const s8v*)&AhS[wr * 64 + mi * 16 + fr][kb * 8];
            afl[mi] = *(const s8v*)&AlS[wr * 64 + mi * 16 + fr][kb * 8];
        }
        #pragma unroll
        for (int nj = 0; nj < 4; nj++) {
            s8v bh = *(const s8v*)&WhS[wc * 64 + nj * 16 + fr][kb * 8];
            s8v bl = *(const s8v*)&WlS[wc * 64 + nj * 16 + fr][kb * 8];
            #pragma unroll
            for (int mi = 0; mi < 4; mi++) {
                acc[mi][nj] = __builtin_amdgcn_mfma_f32_16x16x32_bf16(afh[mi], bh, acc[mi][nj], 0, 0, 0);
                acc[mi][nj] = __builtin_amdgcn_mfma_f32_16x16x32_bf16(afh[mi], bl, acc[mi][nj], 0, 0, 0);
                acc[mi][nj] = __builtin_amdgcn_mfma_f32_16x16x32_bf16(afl[mi], bh, acc[mi][nj], 0, 0, 0);
            }
        }
    }
    #pragma unroll
    for (int mi = 0; mi < 4; mi++) {
        #pragma unroll
        for (int nj = 0; nj < 4; nj++) {
            int col = n0 + wc * 64 + nj * 16 + fr;
            float bb = bias[col];
            #pragma unroll
            for (int r = 0; r < 4; r++) {
                int row = m0 + wr * 64 + mi * 16 + (lane >> 4) * 4 + r;
                float v = acc[mi][nj][r] + bb;
                if (RELU) v = fmaxf(v, 0.f);
                if (SPLIT_OUT) {
                    u16 hi, lo; split2(v, hi, lo);
                    Chi[(size_t)row * ldc + col] = hi;
                    Clo[(size_t)row * ldc + col] = lo;
                } else {
                    int gcol = coff + col;
                    if (gcol < scale_until) v *= scale;
                    Cf[(size_t)row * ldc + gcol] = v;
                }
            }
        }
    }
}

// ---------------------------------------------------------------- local KNN attention
// XCD-affinity swizzle: all blocks of batch b carry index == b (mod 8) so each
// XCD's private L2 serves only 2 batches' K/V gathers (5.1 MB vs 41 MB thrash).
__global__ __launch_bounds__(256) void attn_kernel(
    const float* __restrict__ QKV, const int* __restrict__ IDX,
    u16* __restrict__ AOh, u16* __restrict__ AOl)
{
    const int sub = threadIdx.x >> 7;
    const int t = threadIdx.x & 127;
    const int xcd = blockIdx.x & 7;
    const int j = blockIdx.x >> 3;            // 0..831
    const int b = (j / 416) * 8 + xcd;        // batch
    const int row = b * NN + (j % 416) * 2 + sub;
    __shared__ float p_s[2][HH][16];
    __shared__ int gid_s[2][16];
    const int h = t >> 4, k = t & 15;
    int nb = IDX[(size_t)row * 16 + k];
    int g = b * NN + nb;
    if (h == 0) gid_s[sub][k] = g;
    const float* q = &QKV[(size_t)row * 768 + h * HDX];
    const float* kr = &QKV[(size_t)g * 768 + 256 + h * HDX];
    float s = 0.f;
    #pragma unroll
    for (int d = 0; d < HDX; d += 4) {
        float4 q4 = *(const float4*)&q[d];
        float4 k4 = *(const float4*)&kr[d];
        s += q4.x * k4.x + q4.y * k4.y + q4.z * k4.z + q4.w * k4.w;
    }
    float m = s;
    #pragma unroll
    for (int off = 8; off; off >>= 1) m = fmaxf(m, __shfl_xor(m, off, 16));
    float e = expf(s - m);
    float sum = e;
    #pragma unroll
    for (int off = 8; off; off >>= 1) sum += __shfl_xor(sum, off, 16);
    p_s[sub][h][k] = e / sum;
    __syncthreads();
    const int d0 = t * 2;
    const int hh = d0 >> 5, dd = d0 & 31;
    float o0 = 0.f, o1 = 0.f;
    #pragma unroll
    for (int kk = 0; kk < 16; kk++) {
        int gg = gid_s[sub][kk];
        const float* vr = &QKV[(size_t)gg * 768 + 512 + hh * HDX + dd];
        float p = p_s[sub][hh][kk];
        o0 += p * vr[0];
        o1 += p * vr[1];
    }
    u16 h0, lo0, h1, lo1;
    split2(o0, h0, lo0); split2(o1, h1, lo1);
    size_t base = (size_t)row * DD + d0;
    AOh[base] = h0; AOh[base + 1] = h1;
    AOl[base] = lo0; AOl[base + 1] = lo1;
}

// ---------------------------------------------------------------- residual + layernorm (+ split outputs)
__global__ __launch_bounds__(256) void ln_kernel(
    const float* __restrict__ R1, const float* __restrict__ R2,
    const float* __restrict__ g, const float* __restrict__ bt,
    float* __restrict__ OutF,
    u16* __restrict__ OHi, u16* __restrict__ OLo,
    const float* __restrict__ PEp,
    u16* __restrict__ PHi, u16* __restrict__ PLo)
{
    const int row = blockIdx.x * 4 + (threadIdx.x >> 6);
    const int lane = threadIdx.x & 63;
    size_t base = (size_t)row * DD + lane * 4;
    float4 a = *(const float4*)&R1[base];
    float4 b4 = *(const float4*)&R2[base];
    float x0 = a.x + b4.x, x1 = a.y + b4.y, x2 = a.z + b4.z, x3 = a.w + b4.w;
    float s = x0 + x1 + x2 + x3;
    float sq = x0 * x0 + x1 * x1 + x2 * x2 + x3 * x3;
    #pragma unroll
    for (int off = 32; off; off >>= 1) { s += __shfl_xor(s, off); sq += __shfl_xor(sq, off); }
    float mean = s * (1.f / 256.f);
    float var = sq * (1.f / 256.f) - mean * mean;
    float inv = rsqrtf(var + 1e-5f);
    int c = lane * 4;
    float o0 = (x0 - mean) * inv * g[c + 0] + bt[c + 0];
    float o1 = (x1 - mean) * inv * g[c + 1] + bt[c + 1];
    float o2 = (x2 - mean) * inv * g[c + 2] + bt[c + 2];
    float o3 = (x3 - mean) * inv * g[c + 3] + bt[c + 3];
    *(float4*)&OutF[base] = make_float4(o0, o1, o2, o3);
    if (OHi) {
        ushort4 h, l;
        split2(o0, h.x, l.x); split2(o1, h.y, l.y); split2(o2, h.z, l.z); split2(o3, h.w, l.w);
        *(ushort4*)&OHi[base] = h; *(ushort4*)&OLo[base] = l;
    }
    if (PEp) {
        float4 p = *(const float4*)&PEp[base];
        ushort4 h, l;
        split2(o0 + p.x, h.x, l.x); split2(o1 + p.y, h.y, l.y);
        split2(o2 + p.z, h.z, l.z); split2(o3 + p.w, h.w, l.w);
        *(ushort4*)&PHi[base] = h; *(ushort4*)&PLo[base] = l;
    }
}

// ----------------------------------------------------------------
extern "C" void kernel_launch(void* const* d_in, const int* in_sizes, int n_in,
                              void* d_out, int out_size, void* d_ws, size_t ws_size,
                              hipStream_t stream)
{
    const float* obj      = (const float*)d_in[0];
    const float* mp       = (const float*)d_in[1];
    const float* opos     = (const float*)d_in[2];
    const float* mpos     = (const float*)d_in[3];
    const float* a_pre_w  = (const float*)d_in[4];
    const float* a_pre_b  = (const float*)d_in[5];
    const float* a_mlp_w1 = (const float*)d_in[6];
    const float* a_mlp_b1 = (const float*)d_in[7];
    const float* a_mlp_w2 = (const float*)d_in[8];
    const float* a_mlp_b2 = (const float*)d_in[9];
    const float* a_out_w1 = (const float*)d_in[10];
    const float* a_out_b1 = (const float*)d_in[11];
    const float* a_out_w2 = (const float*)d_in[12];
    const float* a_out_b2 = (const float*)d_in[13];
    const float* m_pre_w1 = (const float*)d_in[14];
    const float* m_pre_b1 = (const float*)d_in[15];
    const float* m_pre_w2 = (const float*)d_in[16];
    const float* m_pre_b2 = (const float*)d_in[17];
    const float* m_pre_w3 = (const float*)d_in[18];
    const float* m_pre_b3 = (const float*)d_in[19];
    const float* m_mlp_w1 = (const float*)d_in[20];
    const float* m_mlp_b1 = (const float*)d_in[21];
    const float* m_mlp_w2 = (const float*)d_in[22];
    const float* m_mlp_b2 = (const float*)d_in[23];
    const float* m_out_w1 = (const float*)d_in[24];
    const float* m_out_b1 = (const float*)d_in[25];
    const float* m_out_w2 = (const float*)d_in[26];
    const float* m_out_b2 = (const float*)d_in[27];
    const float* attn_wqkv = (const float*)d_in[28];
    const float* attn_bqkv = (const float*)d_in[29];
    const float* attn_wo   = (const float*)d_in[30];
    const float* attn_bo   = (const float*)d_in[31];
    const float* ffn_w1    = (const float*)d_in[32];
    const float* ffn_b1    = (const float*)d_in[33];
    const float* ffn_w2    = (const float*)d_in[34];
    const float* ffn_b2    = (const float*)d_in[35];
    const float* ln1_g     = (const float*)d_in[36];
    const float* ln1_b     = (const float*)d_in[37];
    const float* ln2_g     = (const float*)d_in[38];
    const float* ln2_b     = (const float*)d_in[39];

    const size_t M = MTOT;  // 13312
    float* ws   = (float*)d_ws;
    float* X    = ws;                         // M*256 f32
    float* PE   = X   + M * 256;              // M*256 f32
    float* QKV  = PE  + M * 256;              // M*768 f32
    float* OF2  = QKV + M * 768;              // M*256 f32
    float* H    = OF2 + M * 256;              // M*256 f32
    float* XS   = H   + M * 256;              // M*512 f32
    float* HS   = XS  + M * 512;              // M*256 f32
    float* WSp  = HS  + M * 256;              // 4,718,592 f32 (whi+wlo u16)
    int*  IDX   = (int*)(WSp + 4718592);      // M*16 int
    u16*  wpnh  = (u16*)(IDX + MTOT * 16);
    u16*  wpnl  = wpnh + WPN_TOT;

    u16* XPh = (u16*)XS;
    u16* XPl = XPh + M * 256;
    u16* Xh  = XPl + M * 256;
    u16* Xl  = Xh  + M * 256;
    u16* F1h = (u16*)XS;
    u16* F1l = (u16*)QKV;
    u16* AOh = (u16*)H;
    u16* AOl = AOh + M * 256;
    u16* Hh  = (u16*)HS;
    u16* Hl  = Hh + M * 256;
    u16* whi = (u16*)WSp;
    u16* wlo = whi + 4718592;

    u16* PN0h = (u16*)QKV;
    u16* PN0l = PN0h + 7864320;
    u16* PN1h = PN0h + 15728640;
    u16* PN1l = PN0h + 23592960;
    u16* SBp  = PN0h + 31457280;
    u16* PLh  = SBp;
    u16* PLl  = SBp + 393216;
    u16* GMh  = SBp + 786432;
    u16* GMl  = SBp + 1572864;
    u16* HVh  = SBp + 2359296;
    u16* HVl  = SBp + 3145728;
    u16* APLh = SBp + 3932160;
    u16* APLl = SBp + 4194304;
    u16* AGMh = SBp + 4456448;
    u16* AGMl = SBp + 4718592;
    u16* AHVh = SBp + 4980736;
    u16* AHVl = SBp + 5242880;
    float* PCf = (float*)(SBp + 5505024);
    float* APC = PCf + 393216;

    // ---------------- pre-phase ----------------
    knn_kernel<<<BB * 208, 256, 0, stream>>>(opos, mpos, IDX);
    pe_kernel<<<MTOT, 256, 0, stream>>>(opos, mpos, PE);
    split_weights<<<4718592 / 256, 256, 0, stream>>>(attn_wqkv, attn_wo, ffn_w1, ffn_w2, whi, wlo);
    split_pn_weights<<<WPN_TOT / 256, 256, 0, stream>>>(
        m_pre_w1, m_pre_w2, m_pre_w3, m_mlp_w1, m_mlp_w2, m_out_w1, m_out_w2,
        a_pre_w, a_mlp_w1, a_mlp_w2, a_out_w1, a_out_w2, wpnh, wpnl);

    // ---- agent pointnet as GEMM chain
    {
        u16* PA32h = PN1h; u16* PA32l = PN1l;
        u16* PBh = PN0h;   u16* PBl = PN0l;
        u16* PA2h = PN1h;  u16* PA2l = PN1l;
        prep_agent<<<21504 * 32 / 256, 256, 0, stream>>>(obj, PA32h, PA32l);
        gemm_pn<128, true, true, false><<<dim3(168, 2), 256, 0, stream>>>(
            PA32h, PA32l, wpnh + APW_O, wpnl + APW_O, a_pre_b, nullptr, 1, 0,
            nullptr, PBh, PBl, 32, 256, 1, 0, 0);
        pool_max<21><<<1024, 256, 0, stream>>>(PBh, PBl, APLh, APLl, 8, 0);
        gemm_pn<128, false, false, false><<<dim3(8, 2), 256, 0, stream>>>(
            APLh, APLl, wpnh + AW1B_O, wpnl + AW1B_O, a_mlp_b1, nullptr, 1, 0,
            APC, nullptr, nullptr, 256, 256, 1, 0, 0);
        gemm_pn<128, true, true, false><<<dim3(168, 2), 256, 0, stream>>>(
            PBh, PBl, wpnh + AW1A_O, wpnl + AW1A_O, nullptr, APC, 21, 256,
            nullptr, PA2h, PA2l, 256, 256, 1, 0, 0);
        gemm_pn<128, true, true, false><<<dim3(168, 2), 256, 0, stream>>>(
            PA2h, PA2l, wpnh + AW2S_O, wpnl + AW2S_O, a_mlp_b2, nullptr, 1, 0,
            nullptr, PBh, PBl, 256, 256, 1, 0, 0);
        pool_max<21><<<1024, 256, 0, stream>>>(PBh, PBl, AGMh, AGMl, 8, 0);
        gemm_pn<128, true, true, false><<<dim3(8, 2), 256, 0, stream>>>(
            AGMh, AGMl, wpnh + AOW1_O, wpnl + AOW1_O, a_out_b1, nullptr, 1, 0,
            nullptr, AHVh, AHVl, 256, 256, 1, 0, 0);
        gemm_pn<128, false, false, true><<<dim3(8, 2), 256, 0, stream>>>(
            AHVh, AHVl, wpnh + AOW2_O, wpnl + AOW2_O, a_out_b2, nullptr, 1, 0,
            X, nullptr, nullptr, 256, 256, 64, 768, 0);
    }

    // ---- map pointnet as GEMM chain, two batch halves
    for (int h = 0; h < 2; h++) {
        const int hoff = h * 122880;
        u16* PM32h = PN0h; u16* PM32l = PN0l;
        prep_map<<<122880 * 32 / 256, 256, 0, stream>>>(mp, hoff, PM32h, PM32l);
        gemm_pn<64, true, true, false><<<dim3(960, 1), 256, 0, stream>>>(
            PM32h, PM32l, wpnh + W1P_O, wpnl + W1P_O, m_pre_b1, nullptr, 1, 0,
            nullptr, PN1h, PN1l, 32, 64, 1, 0, 0);
        gemm_pn<64, true, true, false><<<dim3(960, 1), 256, 0, stream>>>(
            PN1h, PN1l, wpnh + W2S_O, wpnl + W2S_O, m_pre_b2, nullptr, 1, 0,
            nullptr, PN0h, PN0l, 64, 64, 1, 0, 0);
        gemm_pn<64, true, true, false><<<dim3(960, 1), 256, 0, stream>>>(
            PN0h, PN0l, wpnh + W3S_O, wpnl + W3S_O, m_pre_b3, nullptr, 1, 0,
            nullptr, PN1h, PN1l, 64, 64, 1, 0, 0);
        pool_max<20><<<1536, 256, 0, stream>>>(PN1h, PN1l, PLh, PLl, 6, 0);
        gemm_pn<64, false, false, false><<<dim3(48, 1), 256, 0, stream>>>(
            PLh, PLl, wpnh + MW1B_O, wpnl + MW1B_O, m_mlp_b1, nullptr, 1, 0,
            PCf, nullptr, nullptr, 64, 64, 1, 0, 0);
        gemm_pn<64, true, true, false><<<dim3(960, 1), 256, 0, stream>>>(
            PN1h, PN1l, wpnh + MW1A_O, wpnl + MW1A_O, nullptr, PCf, 20, 64,
            nullptr, PN0h, PN0l, 64, 64, 1, 0, 0);
        gemm_pn<64, true, true, false><<<dim3(960, 1), 256, 0, stream>>>(
            PN0h, PN0l, wpnh + MW2S_O, wpnl + MW2S_O, m_mlp_b2, nullptr, 1, 0,
            nullptr, PN1h, PN1l, 64, 64, 1, 0, 0);
        pool_max<20><<<1536, 256, 0, stream>>>(PN1h, PN1l, GMh, GMl, 6, h * 6144);
    }
    gemm_pn<64, true, true, false><<<dim3(96, 1), 256, 0, stream>>>(
        GMh, GMl, wpnh + OW1S_O, wpnl + OW1S_O, m_out_b1, nullptr, 1, 0,
        nullptr, HVh, HVl, 64, 64, 1, 0, 0);
    gemm_pn<128, false, false, true><<<dim3(96, 2), 256, 0, stream>>>(
        HVh, HVl, wpnh + OW2S_O, wpnl + OW2S_O, m_out_b2, nullptr, 1, 0,
        X, nullptr, nullptr, 64, 256, 768, 64, 64);

    split_x0<<<(int)(M * 256 / 1024), 256, 0, stream>>>(X, PE, Xh, Xl, XPh, XPl);

    // ---------------- transformer layers ----------------
    const float scal = 0.17677669529663687f;  // 32^-0.5
    const int MB = MTOT / 128;  // 104
    const int NOA2 = 0x7fffffff;
    for (int l = 0; l < LL; l++) {
        const size_t wb = (size_t)l * 786432;
        const u16* wqkv_h = whi + wb;            const u16* wqkv_l = wlo + wb;
        const u16* wo_h   = whi + wb + 196608;   const u16* wo_l   = wlo + wb + 196608;
        const u16* f1_h   = whi + wb + 262144;   const u16* f1_l   = wlo + wb + 262144;
        const u16* f2_h   = whi + wb + 524288;   const u16* f2_l   = wlo + wb + 524288;
        const float* bqkv = attn_bqkv + (size_t)l * 768;
        gemm_mfma<false, false><<<dim3(MB, 6), 256, 0, stream>>>(
            XPh, XPl, Xh, Xl, 512, wqkv_h, wqkv_l, bqkv,
            QKV, nullptr, nullptr, 256, 768, 0, scal, 256);
        attn_kernel<<<MTOT / 2, 256, 0, stream>>>(QKV, IDX, AOh, AOl);
        gemm_mfma<false, false><<<dim3(MB, 2), 256, 0, stream>>>(
            AOh, AOl, nullptr, nullptr, NOA2, wo_h, wo_l, attn_bo + (size_t)l * 256,
            OF2, nullptr, nullptr, 256, 256, 0, 1.f, 0);
        ln_kernel<<<MTOT / 4, 256, 0, stream>>>(X, OF2, ln1_g + l * 256, ln1_b + l * 256,
                                                H, Hh, Hl, nullptr, nullptr, nullptr);
        gemm_mfma<true, true><<<dim3(MB, 8), 256, 0, stream>>>(
            Hh, Hl, nullptr, nullptr, NOA2, f1_h, f1_l, ffn_b1 + (size_t)l * 1024,
            nullptr, F1h, F1l, 256, 1024, 0, 1.f, 0);
        gemm_mfma<false, false><<<dim3(MB, 2), 256, 0, stream>>>(
            F1h, F1l, nullptr, nullptr, NOA2, f2_h, f2_l, ffn_b2 + (size_t)l * 256,
            OF2, nullptr, nullptr, 1024, 256, 0, 1.f, 0);
        if (l == LL - 1) {
            ln_kernel<<<MTOT / 4, 256, 0, stream>>>(H, OF2, ln2_g + l * 256, ln2_b + l * 256,
                                                    (float*)d_out, nullptr, nullptr,
                                                    nullptr, nullptr, nullptr);
        } else {
            ln_kernel<<<MTOT / 4, 256, 0, stream>>>(H, OF2, ln2_g + l * 256, ln2_b + l * 256,
                                                    X, Xh, Xl, PE, XPh, XPl);
        }
    }
}

// Round 11
// 1466.246 us; speedup vs baseline: 1.2257x; 1.0679x over previous
//
#include <hip/hip_runtime.h>
#include <hip/hip_bf16.h>

typedef unsigned short u16;

#define BB 16
#define NO 64
#define TT 21
#define NM 768
#define PP 20
#define CAx 29
#define CMx 9
#define DD 256
#define HH 8
#define LL 6
#define KK 16
#define NN (NO + NM)        // 832
#define HDX (DD / HH)       // 32
#define MTOT (BB * NN)      // 13312

typedef __attribute__((ext_vector_type(8))) short s8v;
typedef __attribute__((ext_vector_type(4))) float f4v;

__device__ __forceinline__ u16 bftrunc(float x) {
    return (u16)(__float_as_uint(x) >> 16);
}
__device__ __forceinline__ float bf2f(u16 u) {
    return __uint_as_float(((unsigned int)u) << 16);
}
__device__ __forceinline__ void split2(float x, u16& hi, u16& lo) {
    hi = bftrunc(x);
    lo = bftrunc(x - bf2f(hi));
}

#define GLOAD_LDS16(gptr, lptr)                                                             \
    __builtin_amdgcn_global_load_lds(                                                       \
        (const __attribute__((address_space(1))) void*)(gptr),                              \
        (__attribute__((address_space(3))) void*)(lptr), 16, 0, 0)

// ---------------------------------------------------------------- KNN (top-16 smallest d2)
__global__ __launch_bounds__(256) void knn_kernel(
    const float* __restrict__ opos, const float* __restrict__ mpos, int* __restrict__ IDX)
{
    const int b = blockIdx.x / 208;
    const int blk = blockIdx.x % 208;
    __shared__ float px[NN], py[NN], pz[NN];
    for (int i = threadIdx.x; i < NN; i += 256) {
        const float* src = (i < NO) ? &opos[(size_t)(b * NO + i) * 3]
                                    : &mpos[(size_t)(b * NM + (i - NO)) * 3];
        px[i] = src[0]; py[i] = src[1]; pz[i] = src[2];
    }
    __syncthreads();
    const int wave = threadIdx.x >> 6, lane = threadIdx.x & 63;
    const int n = blk * 4 + wave;
    const float qx = px[n], qy = py[n], qz = pz[n];
    float d[13];
    #pragma unroll
    for (int s = 0; s < 13; s++) {
        int j = s * 64 + lane;
        float dx = qx - px[j], dy = qy - py[j], dz = qz - pz[j];
        d[s] = dx * dx + dy * dy + dz * dz;
    }
    int keep = 0;
    #pragma unroll
    for (int it = 0; it < 16; it++) {
        float bv = d[0]; int bs = 0;
        #pragma unroll
        for (int s = 1; s < 13; s++) { if (d[s] < bv) { bv = d[s]; bs = s; } }
        float v = bv; int jj = bs * 64 + lane;
        #pragma unroll
        for (int off = 32; off; off >>= 1) {
            float ov = __shfl_xor(v, off);
            int oj = __shfl_xor(jj, off);
            if (ov < v || (ov == v && oj < jj)) { v = ov; jj = oj; }
        }
        if (lane == (jj & 63)) {
            int sl = jj >> 6;
            #pragma unroll
            for (int s = 0; s < 13; s++) if (s == sl) d[s] = 3.4e38f;
        }
        if (lane == it) keep = jj;
    }
    if (lane < 16) IDX[((size_t)(b * NN + n)) * 16 + lane] = keep;
}

// ---------------------------------------------------------------- sine positional embedding
__global__ __launch_bounds__(256) void pe_kernel(
    const float* __restrict__ opos, const float* __restrict__ mpos, float* __restrict__ PE)
{
    const int row = blockIdx.x;            // b*NN + n
    const int b = row / NN, n = row % NN;
    const int c = threadIdx.x;
    const float* p = (n < NO) ? &opos[(size_t)(b * NO + n) * 3]
                              : &mpos[(size_t)(b * NM + (n - NO)) * 3];
    float x = p[0], y = p[1];
    int j = c & 127;
    float v = (c < 128) ? y : x;
    float inv_dt = exp2f(-(float)(j & ~1) * 0.10381025296523f);
    float e = v * 6.283185307179586f * inv_dt;
    PE[(size_t)row * DD + c] = (j & 1) ? cosf(e) : sinf(e);
}

// ---------------------------------------------------------------- transformer weight pre-split
__global__ __launch_bounds__(256) void split_weights(
    const float* __restrict__ wqkv, const float* __restrict__ wo,
    const float* __restrict__ f1w, const float* __restrict__ f2w,
    u16* __restrict__ whi, u16* __restrict__ wlo)
{
    size_t e = (size_t)blockIdx.x * 256 + threadIdx.x;
    int L = (int)(e / 786432);
    int r = (int)(e % 786432);
    float v;
    if (r < 196608)      v = wqkv[(size_t)L * 196608 + r];
    else if (r < 262144) v = wo[(size_t)L * 65536 + (r - 196608)];
    else if (r < 524288) v = f1w[(size_t)L * 262144 + (r - 262144)];
    else                 v = f2w[(size_t)L * 262144 + (r - 524288)];
    u16 hi, lo; split2(v, hi, lo);
    whi[e] = hi; wlo[e] = lo;
}

// ---------------------------------------------------------------- pointnet weight pre-split (packed)
#define W1P_O   0
#define W2S_O   2048
#define W3S_O   6144
#define MW1A_O  10240
#define MW1B_O  14336
#define MW2S_O  18432
#define OW1S_O  22528
#define OW2S_O  26624
#define APW_O   43008
#define AW1A_O  51200
#define AW1B_O  116736
#define AW2S_O  182272
#define AOW1_O  247808
#define AOW2_O  313344
#define WPN_TOT 378880
__global__ __launch_bounds__(256) void split_pn_weights(
    const float* __restrict__ m_pre_w1, const float* __restrict__ m_pre_w2,
    const float* __restrict__ m_pre_w3, const float* __restrict__ m_mlp_w1,
    const float* __restrict__ m_mlp_w2, const float* __restrict__ m_out_w1,
    const float* __restrict__ m_out_w2,
    const float* __restrict__ a_pre_w,  const float* __restrict__ a_mlp_w1,
    const float* __restrict__ a_mlp_w2, const float* __restrict__ a_out_w1,
    const float* __restrict__ a_out_w2,
    u16* __restrict__ wpnh, u16* __restrict__ wpnl)
{
    int e = blockIdx.x * 256 + threadIdx.x;
    float v;
    if (e < W2S_O)       { int n = e >> 5, k = e & 31; v = (k < 9) ? m_pre_w1[n * 9 + k] : 0.f; }
    else if (e < W3S_O)  v = m_pre_w2[e - W2S_O];
    else if (e < MW1A_O) v = m_pre_w3[e - W3S_O];
    else if (e < MW1B_O) { int r = e - MW1A_O; v = m_mlp_w1[(r >> 6) * 128 + (r & 63)]; }
    else if (e < MW2S_O) { int r = e - MW1B_O; v = m_mlp_w1[(r >> 6) * 128 + 64 + (r & 63)]; }
    else if (e < OW1S_O) v = m_mlp_w2[e - MW2S_O];
    else if (e < OW2S_O) v = m_out_w1[e - OW1S_O];
    else if (e < APW_O)  v = m_out_w2[e - OW2S_O];
    else if (e < AW1A_O) { int r = e - APW_O; int n = r >> 5, k = r & 31; v = (k < 30) ? a_pre_w[n * 30 + k] : 0.f; }
    else if (e < AW1B_O) { int r = e - AW1A_O; v = a_mlp_w1[(r >> 8) * 512 + (r & 255)]; }
    else if (e < AW2S_O) { int r = e - AW1B_O; v = a_mlp_w1[(r >> 8) * 512 + 256 + (r & 255)]; }
    else if (e < AOW1_O) v = a_mlp_w2[e - AW2S_O];
    else if (e < AOW2_O) v = a_out_w1[e - AOW1_O];
    else                 v = a_out_w2[e - AOW2_O];
    u16 hi, lo; split2(v, hi, lo);
    wpnh[e] = hi; wpnl[e] = lo;
}

// ---------------------------------------------------------------- pointnet input prep (pad + split)
__global__ __launch_bounds__(256) void prep_map(
    const float* __restrict__ mp, int hoff, u16* __restrict__ pah, u16* __restrict__ pal)
{
    int e = blockIdx.x * 256 + threadIdx.x;
    int r = e >> 5, c = e & 31;
    float v = (c < CMx) ? mp[(size_t)(hoff + r) * CMx + c] : 0.f;
    u16 hi, lo; split2(v, hi, lo);
    pah[e] = hi; pal[e] = lo;
}
__global__ __launch_bounds__(256) void prep_agent(
    const float* __restrict__ obj, u16* __restrict__ pah, u16* __restrict__ pal)
{
    int e = blockIdx.x * 256 + threadIdx.x;
    int r = e >> 5, c = e & 31;
    float v = (c < CAx) ? obj[(size_t)r * CAx + c] : ((c == CAx) ? 1.0f : 0.f);
    u16 hi, lo; split2(v, hi, lo);
    pah[e] = hi; pal[e] = lo;
}

// ---------------------------------------------------------------- max-pool over P points
template<int P>
__global__ __launch_bounds__(256) void pool_max(
    const u16* __restrict__ inh, const u16* __restrict__ inl,
    u16* __restrict__ outh, u16* __restrict__ outl, int cshift, int gout_off)
{
    int e = blockIdx.x * 256 + threadIdx.x;
    int C = 1 << cshift;
    int g = e >> cshift, c = e & (C - 1);
    float m = -3.4e38f;
    #pragma unroll
    for (int p = 0; p < P; p++) {
        size_t idx = (size_t)(g * P + p) * C + c;
        float v = bf2f(inh[idx]) + bf2f(inl[idx]);
        m = fmaxf(m, v);
    }
    u16 hi, lo; split2(m, hi, lo);
    size_t o = (size_t)(gout_off + g) * C + c;
    outh[o] = hi; outl[o] = lo;
}

// ---------------------------------------------------------------- pointnet GEMM (split-bf16 MFMA)
template<int BN, bool RELU, bool SPLIT_OUT, bool ROWMAP>
__global__ __launch_bounds__(256) void gemm_pn(
    const u16* __restrict__ Ah, const u16* __restrict__ Al,
    const u16* __restrict__ Wh, const u16* __restrict__ Wl,
    const float* __restrict__ bias,
    const float* __restrict__ addrow, int ardiv, int arld,
    float* __restrict__ Cf, u16* __restrict__ Chi, u16* __restrict__ Clo,
    int K, int ldc, int rm_div, int rm_mul, int rm_add)
{
    constexpr int WAVES_M = (BN == 64) ? 4 : 2;
    constexpr int WM = 128 / (16 * WAVES_M);
    __shared__ __align__(16) u16 AhS[128][32];
    __shared__ __align__(16) u16 AlS[128][32];
    __shared__ __align__(16) u16 WhS[BN][32];
    __shared__ __align__(16) u16 WlS[BN][32];
    const int m0 = blockIdx.x * 128;
    const int n0 = blockIdx.y * BN;
    const int tid = threadIdx.x;
    const int wave = tid >> 6, lane = tid & 63;
    const int wr = (BN == 64) ? wave : (wave >> 1);
    const int wc = (BN == 64) ? 0 : (wave & 1);
    const int fr = lane & 15, kb = lane >> 4;
    const int lrow = lane >> 2, lcol = (lane & 3) * 8;

    f4v acc[WM][4];
    #pragma unroll
    for (int i = 0; i < WM; i++)
        #pragma unroll
        for (int j = 0; j < 4; j++) { f4v z = {0.f, 0.f, 0.f, 0.f}; acc[i][j] = z; }

    for (int k0 = 0; k0 < K; k0 += 32) {
        __syncthreads();
        #pragma unroll
        for (int i = 0; i < 2; i++) {
            const int r = wave * 32 + i * 16;
            GLOAD_LDS16(&Ah[(size_t)(m0 + r + lrow) * K + k0 + lcol], &AhS[r][0]);
            GLOAD_LDS16(&Al[(size_t)(m0 + r + lrow) * K + k0 + lcol], &AlS[r][0]);
        }
        if constexpr (BN == 64) {
            const int r = wave * 16;
            GLOAD_LDS16(&Wh[(size_t)(n0 + r + lrow) * K + k0 + lcol], &WhS[r][0]);
            GLOAD_LDS16(&Wl[(size_t)(n0 + r + lrow) * K + k0 + lcol], &WlS[r][0]);
        } else {
            #pragma unroll
            for (int i = 0; i < 2; i++) {
                const int r = wave * 32 + i * 16;
                GLOAD_LDS16(&Wh[(size_t)(n0 + r + lrow) * K + k0 + lcol], &WhS[r][0]);
                GLOAD_LDS16(&Wl[(size_t)(n0 + r + lrow) * K + k0 + lcol], &WlS[r][0]);
            }
        }
        __syncthreads();
        s8v afh[WM], afl[WM];
        #pragma unroll
        for (int mi = 0; mi < WM; mi++) {
            afh[mi] = *(const s8v*)&AhS[wr * (WM * 16) + mi * 16 + fr][kb * 8];
            afl[mi] = *(const s8v*)&AlS[wr * (WM * 16) + mi * 16 + fr][kb * 8];
        }
        #pragma unroll
        for (int nj = 0; nj < 4; nj++) {
            s8v bh = *(const s8v*)&WhS[wc * 64 + nj * 16 + fr][kb * 8];
            s8v bl = *(const s8v*)&WlS[wc * 64 + nj * 16 + fr][kb * 8];
            #pragma unroll
            for (int mi = 0; mi < WM; mi++) {
                acc[mi][nj] = __builtin_amdgcn_mfma_f32_16x16x32_bf16(afh[mi], bh, acc[mi][nj], 0, 0, 0);
                acc[mi][nj] = __builtin_amdgcn_mfma_f32_16x16x32_bf16(afh[mi], bl, acc[mi][nj], 0, 0, 0);
                acc[mi][nj] = __builtin_amdgcn_mfma_f32_16x16x32_bf16(afl[mi], bh, acc[mi][nj], 0, 0, 0);
            }
        }
    }
    #pragma unroll
    for (int mi = 0; mi < WM; mi++) {
        #pragma unroll
        for (int nj = 0; nj < 4; nj++) {
            int col = n0 + wc * 64 + nj * 16 + fr;
            float bb = bias ? bias[col] : 0.f;
            #pragma unroll
            for (int r = 0; r < 4; r++) {
                int row = m0 + wr * (WM * 16) + mi * 16 + (lane >> 4) * 4 + r;
                float v = acc[mi][nj][r] + bb;
                if (addrow) v += addrow[(size_t)(row / ardiv) * arld + col];
                if (RELU) v = fmaxf(v, 0.f);
                if (SPLIT_OUT) {
                    u16 hi, lo; split2(v, hi, lo);
                    Chi[(size_t)row * ldc + col] = hi;
                    Clo[(size_t)row * ldc + col] = lo;
                } else {
                    int drow = row;
                    if (ROWMAP) drow = row + rm_add + (row / rm_div) * rm_mul;
                    Cf[(size_t)drow * ldc + col] = v;
                }
            }
        }
    }
}

// ---------------------------------------------------------------- initial activation split
__global__ __launch_bounds__(256) void split_x0(
    const float* __restrict__ X, const float* __restrict__ PE,
    u16* __restrict__ Xh, u16* __restrict__ Xl,
    u16* __restrict__ XPh, u16* __restrict__ XPl)
{
    size_t base = ((size_t)blockIdx.x * 256 + threadIdx.x) * 4;
    float4 x = *(const float4*)&X[base];
    float4 p = *(const float4*)&PE[base];
    ushort4 h, l, ph, pl;
    split2(x.x, h.x, l.x); split2(x.y, h.y, l.y); split2(x.z, h.z, l.z); split2(x.w, h.w, l.w);
    split2(x.x + p.x, ph.x, pl.x); split2(x.y + p.y, ph.y, pl.y);
    split2(x.z + p.z, ph.z, pl.z); split2(x.w + p.w, ph.w, pl.w);
    *(ushort4*)&Xh[base] = h;  *(ushort4*)&Xl[base] = l;
    *(ushort4*)&XPh[base] = ph; *(ushort4*)&XPl[base] = pl;
}

// ---------------------------------------------------------------- transformer split-bf16 MFMA GEMM
template<bool RELU, bool SPLIT_OUT>
__global__ __launch_bounds__(256) void gemm_mfma(
    const u16* __restrict__ Ah, const u16* __restrict__ Al,
    const u16* __restrict__ A2h, const u16* __restrict__ A2l, int a2min,
    const u16* __restrict__ Wh, const u16* __restrict__ Wl,
    const float* __restrict__ bias,
    float* __restrict__ Cf, u16* __restrict__ Chi, u16* __restrict__ Clo,
    int K, int ldc, int coff, float scale, int scale_until)
{
    __shared__ __align__(16) u16 AhS[128][32];
    __shared__ __align__(16) u16 AlS[128][32];
    __shared__ __align__(16) u16 WhS[128][32];
    __shared__ __align__(16) u16 WlS[128][32];
    const int m0 = blockIdx.x * 128;
    const int n0 = blockIdx.y * 128;
    const u16* pAh = (n0 >= a2min) ? A2h : Ah;
    const u16* pAl = (n0 >= a2min) ? A2l : Al;
    const int tid = threadIdx.x;
    const int wave = tid >> 6, lane = tid & 63;
    const int wr = wave >> 1, wc = wave & 1;
    const int fr = lane & 15, kb = lane >> 4;
    const int lrow = lane >> 2;
    const int lcol = (lane & 3) * 8;

    f4v acc[4][4];
    #pragma unroll
    for (int i = 0; i < 4; i++)
        #pragma unroll
        for (int j = 0; j < 4; j++) { f4v z = {0.f, 0.f, 0.f, 0.f}; acc[i][j] = z; }

    for (int k0 = 0; k0 < K; k0 += 32) {
        __syncthreads();
        #pragma unroll
        for (int i = 0; i < 2; i++) {
            const int r = wave * 32 + i * 16;
            const size_t grow = (size_t)(r + lrow);
            GLOAD_LDS16(&pAh[(m0 + grow) * K + k0 + lcol], &AhS[r][0]);
            GLOAD_LDS16(&pAl[(m0 + grow) * K + k0 + lcol], &AlS[r][0]);
            GLOAD_LDS16(&Wh [(n0 + grow) * K + k0 + lcol], &WhS[r][0]);
            GLOAD_LDS16(&Wl [(n0 + grow) * K + k0 + lcol], &WlS[r][0]);
        }
        __syncthreads();
        s8v afh[4], afl[4];
        #pragma unroll
        for (int mi = 0; mi < 4; mi++) {
            afh[mi] = *(const s8v*)&AhS[wr * 64 + mi * 16 + fr][kb * 8];
            afl[mi] = *(const s8v*)&AlS[wr * 64 + mi * 16 + fr][kb * 8];
        }
        #pragma unroll
        for (int nj = 0; nj < 4; nj++) {
            s8v bh = *(const s8v*)&WhS[wc * 64 + nj * 16 + fr][kb * 8];
            s8v bl = *(const s8v*)&WlS[wc * 64 + nj * 16 + fr][kb * 8];
            #pragma unroll
            for (int mi = 0; mi < 4; mi++) {
                acc[mi][nj] = __builtin_amdgcn_mfma_f32_16x16x32_bf16(afh[mi], bh, acc[mi][nj], 0, 0, 0);
                acc[mi][nj] = __builtin_amdgcn_mfma_f32_16x16x32_bf16(afh[mi], bl, acc[mi][nj], 0, 0, 0);
                acc[mi][nj] = __builtin_amdgcn_mfma_f32_16x16x32_bf16(afl[mi], bh, acc[mi][nj], 0, 0, 0);
            }
        }
    }
    #pragma unroll
    for (int mi = 0; mi < 4; mi++) {
        #pragma unroll
        for (int nj = 0; nj < 4; nj++) {
            int col = n0 + wc * 64 + nj * 16 + fr;
            float bb = bias[col];
            #pragma unroll
            for (int r = 0; r < 4; r++) {
                int row = m0 + wr * 64 + mi * 16 + (lane >> 4) * 4 + r;
                float v = acc[mi][nj][r] + bb;
                if (RELU) v = fmaxf(v, 0.f);
                if (SPLIT_OUT) {
                    u16 hi, lo; split2(v, hi, lo);
                    Chi[(size_t)row * ldc + col] = hi;
                    Clo[(size_t)row * ldc + col] = lo;
                } else {
                    int gcol = coff + col;
                    if (gcol < scale_until) v *= scale;
                    Cf[(size_t)row * ldc + gcol] = v;
                }
            }
        }
    }
}

// ---------------------------------------------------------------- local KNN attention
// XCD-affinity swizzle (R10) + LDS-staged K gather (R11): each neighbor's 1KB K
// slice is staged by ONE coalesced global_load_lds wave-instruction (8 lines)
// instead of being gathered scattered (64 lines/instr) in the QK phase.
__global__ __launch_bounds__(256) void attn_kernel(
    const float* __restrict__ QKV, const int* __restrict__ IDX,
    u16* __restrict__ AOh, u16* __restrict__ AOl)
{
    __shared__ __align__(16) float Ks[32][260];   // 32 slices, +4 pad
    __shared__ float p_s[2][HH][16];
    __shared__ int gid_s[2][16];
    const int sub = threadIdx.x >> 7;
    const int t = threadIdx.x & 127;
    const int wave = threadIdx.x >> 6, lane = threadIdx.x & 63;
    const int xcd = blockIdx.x & 7;
    const int j = blockIdx.x >> 3;            // 0..831
    const int b = (j / 416) * 8 + xcd;        // batch
    const int row = b * NN + (j % 416) * 2 + sub;
    const int h = t >> 4, k = t & 15;
    int nb = IDX[(size_t)row * 16 + k];
    int g = b * NN + nb;
    if (h == 0) gid_s[sub][k] = g;
    __syncthreads();
    // stage 32 K slices (2 rows x 16 neighbors); wave w stages slices w*8..w*8+7
    #pragma unroll
    for (int i = 0; i < 8; i++) {
        int s = wave * 8 + i;
        int gs = gid_s[s >> 4][s & 15];
        GLOAD_LDS16(&QKV[(size_t)gs * 768 + 256 + lane * 4], &Ks[s][0]);
    }
    __syncthreads();   // drains vmcnt -> Ks visible
    const float* q = &QKV[(size_t)row * 768 + h * HDX];
    const float* kr = &Ks[sub * 16 + k][h * HDX];
    float s = 0.f;
    #pragma unroll
    for (int d = 0; d < HDX; d += 4) {
        float4 q4 = *(const float4*)&q[d];
        float4 k4 = *(const float4*)&kr[d];
        s += q4.x * k4.x + q4.y * k4.y + q4.z * k4.z + q4.w * k4.w;
    }
    float m = s;
    #pragma unroll
    for (int off = 8; off; off >>= 1) m = fmaxf(m, __shfl_xor(m, off, 16));
    float e = expf(s - m);
    float sum = e;
    #pragma unroll
    for (int off = 8; off; off >>= 1) sum += __shfl_xor(sum, off, 16);
    p_s[sub][h][k] = e / sum;
    __syncthreads();
    const int d0 = t * 2;
    const int hh = d0 >> 5, dd = d0 & 31;
    float o0 = 0.f, o1 = 0.f;
    #pragma unroll
    for (int kk = 0; kk < 16; kk++) {
        int gg = gid_s[sub][kk];
        const float* vr = &QKV[(size_t)gg * 768 + 512 + hh * HDX + dd];
        float p = p_s[sub][hh][kk];
        o0 += p * vr[0];
        o1 += p * vr[1];
    }
    u16 h0, lo0, h1, lo1;
    split2(o0, h0, lo0); split2(o1, h1, lo1);
    size_t base = (size_t)row * DD + d0;
    AOh[base] = h0; AOh[base + 1] = h1;
    AOl[base] = lo0; AOl[base + 1] = lo1;
}

// ---------------------------------------------------------------- residual + layernorm (+ split outputs)
__global__ __launch_bounds__(256) void ln_kernel(
    const float* __restrict__ R1, const float* __restrict__ R2,
    const float* __restrict__ g, const float* __restrict__ bt,
    float* __restrict__ OutF,
    u16* __restrict__ OHi, u16* __restrict__ OLo,
    const float* __restrict__ PEp,
    u16* __restrict__ PHi, u16* __restrict__ PLo)
{
    const int row = blockIdx.x * 4 + (threadIdx.x >> 6);
    const int lane = threadIdx.x & 63;
    size_t base = (size_t)row * DD + lane * 4;
    float4 a = *(const float4*)&R1[base];
    float4 b4 = *(const float4*)&R2[base];
    float x0 = a.x + b4.x, x1 = a.y + b4.y, x2 = a.z + b4.z, x3 = a.w + b4.w;
    float s = x0 + x1 + x2 + x3;
    float sq = x0 * x0 + x1 * x1 + x2 * x2 + x3 * x3;
    #pragma unroll
    for (int off = 32; off; off >>= 1) { s += __shfl_xor(s, off); sq += __shfl_xor(sq, off); }
    float mean = s * (1.f / 256.f);
    float var = sq * (1.f / 256.f) - mean * mean;
    float inv = rsqrtf(var + 1e-5f);
    int c = lane * 4;
    float o0 = (x0 - mean) * inv * g[c + 0] + bt[c + 0];
    float o1 = (x1 - mean) * inv * g[c + 1] + bt[c + 1];
    float o2 = (x2 - mean) * inv * g[c + 2] + bt[c + 2];
    float o3 = (x3 - mean) * inv * g[c + 3] + bt[c + 3];
    *(float4*)&OutF[base] = make_float4(o0, o1, o2, o3);
    if (OHi) {
        ushort4 h, l;
        split2(o0, h.x, l.x); split2(o1, h.y, l.y); split2(o2, h.z, l.z); split2(o3, h.w, l.w);
        *(ushort4*)&OHi[base] = h; *(ushort4*)&OLo[base] = l;
    }
    if (PEp) {
        float4 p = *(const float4*)&PEp[base];
        ushort4 h, l;
        split2(o0 + p.x, h.x, l.x); split2(o1 + p.y, h.y, l.y);
        split2(o2 + p.z, h.z, l.z); split2(o3 + p.w, h.w, l.w);
        *(ushort4*)&PHi[base] = h; *(ushort4*)&PLo[base] = l;
    }
}

// ----------------------------------------------------------------
extern "C" void kernel_launch(void* const* d_in, const int* in_sizes, int n_in,
                              void* d_out, int out_size, void* d_ws, size_t ws_size,
                              hipStream_t stream)
{
    const float* obj      = (const float*)d_in[0];
    const float* mp       = (const float*)d_in[1];
    const float* opos     = (const float*)d_in[2];
    const float* mpos     = (const float*)d_in[3];
    const float* a_pre_w  = (const float*)d_in[4];
    const float* a_pre_b  = (const float*)d_in[5];
    const float* a_mlp_w1 = (const float*)d_in[6];
    const float* a_mlp_b1 = (const float*)d_in[7];
    const float* a_mlp_w2 = (const float*)d_in[8];
    const float* a_mlp_b2 = (const float*)d_in[9];
    const float* a_out_w1 = (const float*)d_in[10];
    const float* a_out_b1 = (const float*)d_in[11];
    const float* a_out_w2 = (const float*)d_in[12];
    const float* a_out_b2 = (const float*)d_in[13];
    const float* m_pre_w1 = (const float*)d_in[14];
    const float* m_pre_b1 = (const float*)d_in[15];
    const float* m_pre_w2 = (const float*)d_in[16];
    const float* m_pre_b2 = (const float*)d_in[17];
    const float* m_pre_w3 = (const float*)d_in[18];
    const float* m_pre_b3 = (const float*)d_in[19];
    const float* m_mlp_w1 = (const float*)d_in[20];
    const float* m_mlp_b1 = (const float*)d_in[21];
    const float* m_mlp_w2 = (const float*)d_in[22];
    const float* m_mlp_b2 = (const float*)d_in[23];
    const float* m_out_w1 = (const float*)d_in[24];
    const float* m_out_b1 = (const float*)d_in[25];
    const float* m_out_w2 = (const float*)d_in[26];
    const float* m_out_b2 = (const float*)d_in[27];
    const float* attn_wqkv = (const float*)d_in[28];
    const float* attn_bqkv = (const float*)d_in[29];
    const float* attn_wo   = (const float*)d_in[30];
    const float* attn_bo   = (const float*)d_in[31];
    const float* ffn_w1    = (const float*)d_in[32];
    const float* ffn_b1    = (const float*)d_in[33];
    const float* ffn_w2    = (const float*)d_in[34];
    const float* ffn_b2    = (const float*)d_in[35];
    const float* ln1_g     = (const float*)d_in[36];
    const float* ln1_b     = (const float*)d_in[37];
    const float* ln2_g     = (const float*)d_in[38];
    const float* ln2_b     = (const float*)d_in[39];

    const size_t M = MTOT;  // 13312
    float* ws   = (float*)d_ws;
    float* X    = ws;
    float* PE   = X   + M * 256;
    float* QKV  = PE  + M * 256;
    float* OF2  = QKV + M * 768;
    float* H    = OF2 + M * 256;
    float* XS   = H   + M * 256;
    float* HS   = XS  + M * 512;
    float* WSp  = HS  + M * 256;
    int*  IDX   = (int*)(WSp + 4718592);
    u16*  wpnh  = (u16*)(IDX + MTOT * 16);
    u16*  wpnl  = wpnh + WPN_TOT;

    u16* XPh = (u16*)XS;
    u16* XPl = XPh + M * 256;
    u16* Xh  = XPl + M * 256;
    u16* Xl  = Xh  + M * 256;
    u16* F1h = (u16*)XS;
    u16* F1l = (u16*)QKV;
    u16* AOh = (u16*)H;
    u16* AOl = AOh + M * 256;
    u16* Hh  = (u16*)HS;
    u16* Hl  = Hh + M * 256;
    u16* whi = (u16*)WSp;
    u16* wlo = whi + 4718592;

    u16* PN0h = (u16*)QKV;
    u16* PN0l = PN0h + 7864320;
    u16* PN1h = PN0h + 15728640;
    u16* PN1l = PN0h + 23592960;
    u16* SBp  = PN0h + 31457280;
    u16* PLh  = SBp;
    u16* PLl  = SBp + 393216;
    u16* GMh  = SBp + 786432;
    u16* GMl  = SBp + 1572864;
    u16* HVh  = SBp + 2359296;
    u16* HVl  = SBp + 3145728;
    u16* APLh = SBp + 3932160;
    u16* APLl = SBp + 4194304;
    u16* AGMh = SBp + 4456448;
    u16* AGMl = SBp + 4718592;
    u16* AHVh = SBp + 4980736;
    u16* AHVl = SBp + 5242880;
    float* PCf = (float*)(SBp + 5505024);
    float* APC = PCf + 393216;

    // ---------------- pre-phase ----------------
    knn_kernel<<<BB * 208, 256, 0, stream>>>(opos, mpos, IDX);
    pe_kernel<<<MTOT, 256, 0, stream>>>(opos, mpos, PE);
    split_weights<<<4718592 / 256, 256, 0, stream>>>(attn_wqkv, attn_wo, ffn_w1, ffn_w2, whi, wlo);
    split_pn_weights<<<WPN_TOT / 256, 256, 0, stream>>>(
        m_pre_w1, m_pre_w2, m_pre_w3, m_mlp_w1, m_mlp_w2, m_out_w1, m_out_w2,
        a_pre_w, a_mlp_w1, a_mlp_w2, a_out_w1, a_out_w2, wpnh, wpnl);

    // ---- agent pointnet as GEMM chain
    {
        u16* PA32h = PN1h; u16* PA32l = PN1l;
        u16* PBh = PN0h;   u16* PBl = PN0l;
        u16* PA2h = PN1h;  u16* PA2l = PN1l;
        prep_agent<<<21504 * 32 / 256, 256, 0, stream>>>(obj, PA32h, PA32l);
        gemm_pn<128, true, true, false><<<dim3(168, 2), 256, 0, stream>>>(
            PA32h, PA32l, wpnh + APW_O, wpnl + APW_O, a_pre_b, nullptr, 1, 0,
            nullptr, PBh, PBl, 32, 256, 1, 0, 0);
        pool_max<21><<<1024, 256, 0, stream>>>(PBh, PBl, APLh, APLl, 8, 0);
        gemm_pn<128, false, false, false><<<dim3(8, 2), 256, 0, stream>>>(
            APLh, APLl, wpnh + AW1B_O, wpnl + AW1B_O, a_mlp_b1, nullptr, 1, 0,
            APC, nullptr, nullptr, 256, 256, 1, 0, 0);
        gemm_pn<128, true, true, false><<<dim3(168, 2), 256, 0, stream>>>(
            PBh, PBl, wpnh + AW1A_O, wpnl + AW1A_O, nullptr, APC, 21, 256,
            nullptr, PA2h, PA2l, 256, 256, 1, 0, 0);
        gemm_pn<128, true, true, false><<<dim3(168, 2), 256, 0, stream>>>(
            PA2h, PA2l, wpnh + AW2S_O, wpnl + AW2S_O, a_mlp_b2, nullptr, 1, 0,
            nullptr, PBh, PBl, 256, 256, 1, 0, 0);
        pool_max<21><<<1024, 256, 0, stream>>>(PBh, PBl, AGMh, AGMl, 8, 0);
        gemm_pn<128, true, true, false><<<dim3(8, 2), 256, 0, stream>>>(
            AGMh, AGMl, wpnh + AOW1_O, wpnl + AOW1_O, a_out_b1, nullptr, 1, 0,
            nullptr, AHVh, AHVl, 256, 256, 1, 0, 0);
        gemm_pn<128, false, false, true><<<dim3(8, 2), 256, 0, stream>>>(
            AHVh, AHVl, wpnh + AOW2_O, wpnl + AOW2_O, a_out_b2, nullptr, 1, 0,
            X, nullptr, nullptr, 256, 256, 64, 768, 0);
    }

    // ---- map pointnet as GEMM chain, two batch halves
    for (int h = 0; h < 2; h++) {
        const int hoff = h * 122880;
        u16* PM32h = PN0h; u16* PM32l = PN0l;
        prep_map<<<122880 * 32 / 256, 256, 0, stream>>>(mp, hoff, PM32h, PM32l);
        gemm_pn<64, true, true, false><<<dim3(960, 1), 256, 0, stream>>>(
            PM32h, PM32l, wpnh + W1P_O, wpnl + W1P_O, m_pre_b1, nullptr, 1, 0,
            nullptr, PN1h, PN1l, 32, 64, 1, 0, 0);
        gemm_pn<64, true, true, false><<<dim3(960, 1), 256, 0, stream>>>(
            PN1h, PN1l, wpnh + W2S_O, wpnl + W2S_O, m_pre_b2, nullptr, 1, 0,
            nullptr, PN0h, PN0l, 64, 64, 1, 0, 0);
        gemm_pn<64, true, true, false><<<dim3(960, 1), 256, 0, stream>>>(
            PN0h, PN0l, wpnh + W3S_O, wpnl + W3S_O, m_pre_b3, nullptr, 1, 0,
            nullptr, PN1h, PN1l, 64, 64, 1, 0, 0);
        pool_max<20><<<1536, 256, 0, stream>>>(PN1h, PN1l, PLh, PLl, 6, 0);
        gemm_pn<64, false, false, false><<<dim3(48, 1), 256, 0, stream>>>(
            PLh, PLl, wpnh + MW1B_O, wpnl + MW1B_O, m_mlp_b1, nullptr, 1, 0,
            PCf, nullptr, nullptr, 64, 64, 1, 0, 0);
        gemm_pn<64, true, true, false><<<dim3(960, 1), 256, 0, stream>>>(
            PN1h, PN1l, wpnh + MW1A_O, wpnl + MW1A_O, nullptr, PCf, 20, 64,
            nullptr, PN0h, PN0l, 64, 64, 1, 0, 0);
        gemm_pn<64, true, true, false><<<dim3(960, 1), 256, 0, stream>>>(
            PN0h, PN0l, wpnh + MW2S_O, wpnl + MW2S_O, m_mlp_b2, nullptr, 1, 0,
            nullptr, PN1h, PN1l, 64, 64, 1, 0, 0);
        pool_max<20><<<1536, 256, 0, stream>>>(PN1h, PN1l, GMh, GMl, 6, h * 6144);
    }
    gemm_pn<64, true, true, false><<<dim3(96, 1), 256, 0, stream>>>(
        GMh, GMl, wpnh + OW1S_O, wpnl + OW1S_O, m_out_b1, nullptr, 1, 0,
        nullptr, HVh, HVl, 64, 64, 1, 0, 0);
    gemm_pn<128, false, false, true><<<dim3(96, 2), 256, 0, stream>>>(
        HVh, HVl, wpnh + OW2S_O, wpnl + OW2S_O, m_out_b2, nullptr, 1, 0,
        X, nullptr, nullptr, 64, 256, 768, 64, 64);

    split_x0<<<(int)(M * 256 / 1024), 256, 0, stream>>>(X, PE, Xh, Xl, XPh, XPl);

    // ---------------- transformer layers ----------------
    const float scal = 0.17677669529663687f;  // 32^-0.5
    const int MB = MTOT / 128;  // 104
    const int NOA2 = 0x7fffffff;
    for (int l = 0; l < LL; l++) {
        const size_t wb = (size_t)l * 786432;
        const u16* wqkv_h = whi + wb;            const u16* wqkv_l = wlo + wb;
        const u16* wo_h   = whi + wb + 196608;   const u16* wo_l   = wlo + wb + 196608;
        const u16* f1_h   = whi + wb + 262144;   const u16* f1_l   = wlo + wb + 262144;
        const u16* f2_h   = whi + wb + 524288;   const u16* f2_l   = wlo + wb + 524288;
        const float* bqkv = attn_bqkv + (size_t)l * 768;
        gemm_mfma<false, false><<<dim3(MB, 6), 256, 0, stream>>>(
            XPh, XPl, Xh, Xl, 512, wqkv_h, wqkv_l, bqkv,
            QKV, nullptr, nullptr, 256, 768, 0, scal, 256);
        attn_kernel<<<MTOT / 2, 256, 0, stream>>>(QKV, IDX, AOh, AOl);
        gemm_mfma<false, false><<<dim3(MB, 2), 256, 0, stream>>>(
            AOh, AOl, nullptr, nullptr, NOA2, wo_h, wo_l, attn_bo + (size_t)l * 256,
            OF2, nullptr, nullptr, 256, 256, 0, 1.f, 0);
        ln_kernel<<<MTOT / 4, 256, 0, stream>>>(X, OF2, ln1_g + l * 256, ln1_b + l * 256,
                                                H, Hh, Hl, nullptr, nullptr, nullptr);
        gemm_mfma<true, true><<<dim3(MB, 8), 256, 0, stream>>>(
            Hh, Hl, nullptr, nullptr, NOA2, f1_h, f1_l, ffn_b1 + (size_t)l * 1024,
            nullptr, F1h, F1l, 256, 1024, 0, 1.f, 0);
        gemm_mfma<false, false><<<dim3(MB, 2), 256, 0, stream>>>(
            F1h, F1l, nullptr, nullptr, NOA2, f2_h, f2_l, ffn_b2 + (size_t)l * 256,
            OF2, nullptr, nullptr, 1024, 256, 0, 1.f, 0);
        if (l == LL - 1) {
            ln_kernel<<<MTOT / 4, 256, 0, stream>>>(H, OF2, ln2_g + l * 256, ln2_b + l * 256,
                                                    (float*)d_out, nullptr, nullptr,
                                                    nullptr, nullptr, nullptr);
        } else {
            ln_kernel<<<MTOT / 4, 256, 0, stream>>>(H, OF2, ln2_g + l * 256, ln2_b + l * 256,
                                                    X, Xh, Xl, PE, XPh, XPl);
        }
    }
}

// Round 12
// 1424.812 us; speedup vs baseline: 1.2614x; 1.0291x over previous
//
#include <hip/hip_runtime.h>
#include <hip/hip_bf16.h>

typedef unsigned short u16;

#define BB 16
#define NO 64
#define TT 21
#define NM 768
#define PP 20
#define CAx 29
#define CMx 9
#define DD 256
#define HH 8
#define LL 6
#define KK 16
#define NN (NO + NM)        // 832
#define HDX (DD / HH)       // 32
#define MTOT (BB * NN)      // 13312

typedef __attribute__((ext_vector_type(8))) short s8v;
typedef __attribute__((ext_vector_type(4))) float f4v;

__device__ __forceinline__ u16 bftrunc(float x) {
    return (u16)(__float_as_uint(x) >> 16);
}
__device__ __forceinline__ float bf2f(u16 u) {
    return __uint_as_float(((unsigned int)u) << 16);
}
__device__ __forceinline__ void split2(float x, u16& hi, u16& lo) {
    hi = bftrunc(x);
    lo = bftrunc(x - bf2f(hi));
}

#define GLOAD_LDS16(gptr, lptr)                                                             \
    __builtin_amdgcn_global_load_lds(                                                       \
        (const __attribute__((address_space(1))) void*)(gptr),                              \
        (__attribute__((address_space(3))) void*)(lptr), 16, 0, 0)

// ---------------------------------------------------------------- KNN (top-16 smallest d2)
__global__ __launch_bounds__(256) void knn_kernel(
    const float* __restrict__ opos, const float* __restrict__ mpos, int* __restrict__ IDX)
{
    const int b = blockIdx.x / 208;
    const int blk = blockIdx.x % 208;
    __shared__ float px[NN], py[NN], pz[NN];
    for (int i = threadIdx.x; i < NN; i += 256) {
        const float* src = (i < NO) ? &opos[(size_t)(b * NO + i) * 3]
                                    : &mpos[(size_t)(b * NM + (i - NO)) * 3];
        px[i] = src[0]; py[i] = src[1]; pz[i] = src[2];
    }
    __syncthreads();
    const int wave = threadIdx.x >> 6, lane = threadIdx.x & 63;
    const int n = blk * 4 + wave;
    const float qx = px[n], qy = py[n], qz = pz[n];
    float d[13];
    #pragma unroll
    for (int s = 0; s < 13; s++) {
        int j = s * 64 + lane;
        float dx = qx - px[j], dy = qy - py[j], dz = qz - pz[j];
        d[s] = dx * dx + dy * dy + dz * dz;
    }
    int keep = 0;
    #pragma unroll
    for (int it = 0; it < 16; it++) {
        float bv = d[0]; int bs = 0;
        #pragma unroll
        for (int s = 1; s < 13; s++) { if (d[s] < bv) { bv = d[s]; bs = s; } }
        float v = bv; int jj = bs * 64 + lane;
        #pragma unroll
        for (int off = 32; off; off >>= 1) {
            float ov = __shfl_xor(v, off);
            int oj = __shfl_xor(jj, off);
            if (ov < v || (ov == v && oj < jj)) { v = ov; jj = oj; }
        }
        if (lane == (jj & 63)) {
            int sl = jj >> 6;
            #pragma unroll
            for (int s = 0; s < 13; s++) if (s == sl) d[s] = 3.4e38f;
        }
        if (lane == it) keep = jj;
    }
    if (lane < 16) IDX[((size_t)(b * NN + n)) * 16 + lane] = keep;
}

// ---------------------------------------------------------------- sine positional embedding
__global__ __launch_bounds__(256) void pe_kernel(
    const float* __restrict__ opos, const float* __restrict__ mpos, float* __restrict__ PE)
{
    const int row = blockIdx.x;            // b*NN + n
    const int b = row / NN, n = row % NN;
    const int c = threadIdx.x;
    const float* p = (n < NO) ? &opos[(size_t)(b * NO + n) * 3]
                              : &mpos[(size_t)(b * NM + (n - NO)) * 3];
    float x = p[0], y = p[1];
    int j = c & 127;
    float v = (c < 128) ? y : x;
    float inv_dt = exp2f(-(float)(j & ~1) * 0.10381025296523f);
    float e = v * 6.283185307179586f * inv_dt;
    PE[(size_t)row * DD + c] = (j & 1) ? cosf(e) : sinf(e);
}

// ---------------------------------------------------------------- transformer weight pre-split
__global__ __launch_bounds__(256) void split_weights(
    const float* __restrict__ wqkv, const float* __restrict__ wo,
    const float* __restrict__ f1w, const float* __restrict__ f2w,
    u16* __restrict__ whi, u16* __restrict__ wlo)
{
    size_t e = (size_t)blockIdx.x * 256 + threadIdx.x;
    int L = (int)(e / 786432);
    int r = (int)(e % 786432);
    float v;
    if (r < 196608)      v = wqkv[(size_t)L * 196608 + r];
    else if (r < 262144) v = wo[(size_t)L * 65536 + (r - 196608)];
    else if (r < 524288) v = f1w[(size_t)L * 262144 + (r - 262144)];
    else                 v = f2w[(size_t)L * 262144 + (r - 524288)];
    u16 hi, lo; split2(v, hi, lo);
    whi[e] = hi; wlo[e] = lo;
}

// ---------------------------------------------------------------- pointnet weight pre-split (packed)
#define W1P_O   0
#define W2S_O   2048
#define W3S_O   6144
#define MW1A_O  10240
#define MW1B_O  14336
#define MW2S_O  18432
#define OW1S_O  22528
#define OW2S_O  26624
#define APW_O   43008
#define AW1A_O  51200
#define AW1B_O  116736
#define AW2S_O  182272
#define AOW1_O  247808
#define AOW2_O  313344
#define WPN_TOT 378880
__global__ __launch_bounds__(256) void split_pn_weights(
    const float* __restrict__ m_pre_w1, const float* __restrict__ m_pre_w2,
    const float* __restrict__ m_pre_w3, const float* __restrict__ m_mlp_w1,
    const float* __restrict__ m_mlp_w2, const float* __restrict__ m_out_w1,
    const float* __restrict__ m_out_w2,
    const float* __restrict__ a_pre_w,  const float* __restrict__ a_mlp_w1,
    const float* __restrict__ a_mlp_w2, const float* __restrict__ a_out_w1,
    const float* __restrict__ a_out_w2,
    u16* __restrict__ wpnh, u16* __restrict__ wpnl)
{
    int e = blockIdx.x * 256 + threadIdx.x;
    float v;
    if (e < W2S_O)       { int n = e >> 5, k = e & 31; v = (k < 9) ? m_pre_w1[n * 9 + k] : 0.f; }
    else if (e < W3S_O)  v = m_pre_w2[e - W2S_O];
    else if (e < MW1A_O) v = m_pre_w3[e - W3S_O];
    else if (e < MW1B_O) { int r = e - MW1A_O; v = m_mlp_w1[(r >> 6) * 128 + (r & 63)]; }
    else if (e < MW2S_O) { int r = e - MW1B_O; v = m_mlp_w1[(r >> 6) * 128 + 64 + (r & 63)]; }
    else if (e < OW1S_O) v = m_mlp_w2[e - MW2S_O];
    else if (e < OW2S_O) v = m_out_w1[e - OW1S_O];
    else if (e < APW_O)  v = m_out_w2[e - OW2S_O];
    else if (e < AW1A_O) { int r = e - APW_O; int n = r >> 5, k = r & 31; v = (k < 30) ? a_pre_w[n * 30 + k] : 0.f; }
    else if (e < AW1B_O) { int r = e - AW1A_O; v = a_mlp_w1[(r >> 8) * 512 + (r & 255)]; }
    else if (e < AW2S_O) { int r = e - AW1B_O; v = a_mlp_w1[(r >> 8) * 512 + 256 + (r & 255)]; }
    else if (e < AOW1_O) v = a_mlp_w2[e - AW2S_O];
    else if (e < AOW2_O) v = a_out_w1[e - AOW1_O];
    else                 v = a_out_w2[e - AOW2_O];
    u16 hi, lo; split2(v, hi, lo);
    wpnh[e] = hi; wpnl[e] = lo;
}

// ---------------------------------------------------------------- pointnet input prep (pad + split)
__global__ __launch_bounds__(256) void prep_map(
    const float* __restrict__ mp, int hoff, u16* __restrict__ pah, u16* __restrict__ pal)
{
    int e = blockIdx.x * 256 + threadIdx.x;
    int r = e >> 5, c = e & 31;
    float v = (c < CMx) ? mp[(size_t)(hoff + r) * CMx + c] : 0.f;
    u16 hi, lo; split2(v, hi, lo);
    pah[e] = hi; pal[e] = lo;
}
__global__ __launch_bounds__(256) void prep_agent(
    const float* __restrict__ obj, u16* __restrict__ pah, u16* __restrict__ pal)
{
    int e = blockIdx.x * 256 + threadIdx.x;
    int r = e >> 5, c = e & 31;
    float v = (c < CAx) ? obj[(size_t)r * CAx + c] : ((c == CAx) ? 1.0f : 0.f);
    u16 hi, lo; split2(v, hi, lo);
    pah[e] = hi; pal[e] = lo;
}

// ---------------------------------------------------------------- max-pool over P points
template<int P>
__global__ __launch_bounds__(256) void pool_max(
    const u16* __restrict__ inh, const u16* __restrict__ inl,
    u16* __restrict__ outh, u16* __restrict__ outl, int cshift, int gout_off)
{
    int e = blockIdx.x * 256 + threadIdx.x;
    int C = 1 << cshift;
    int g = e >> cshift, c = e & (C - 1);
    float m = -3.4e38f;
    #pragma unroll
    for (int p = 0; p < P; p++) {
        size_t idx = (size_t)(g * P + p) * C + c;
        float v = bf2f(inh[idx]) + bf2f(inl[idx]);
        m = fmaxf(m, v);
    }
    u16 hi, lo; split2(m, hi, lo);
    size_t o = (size_t)(gout_off + g) * C + c;
    outh[o] = hi; outl[o] = lo;
}

// ---------------------------------------------------------------- pointnet GEMM (split-bf16 MFMA)
template<int BN, bool RELU, bool SPLIT_OUT, bool ROWMAP>
__global__ __launch_bounds__(256) void gemm_pn(
    const u16* __restrict__ Ah, const u16* __restrict__ Al,
    const u16* __restrict__ Wh, const u16* __restrict__ Wl,
    const float* __restrict__ bias,
    const float* __restrict__ addrow, int ardiv, int arld,
    float* __restrict__ Cf, u16* __restrict__ Chi, u16* __restrict__ Clo,
    int K, int ldc, int rm_div, int rm_mul, int rm_add)
{
    constexpr int WAVES_M = (BN == 64) ? 4 : 2;
    constexpr int WM = 128 / (16 * WAVES_M);
    __shared__ __align__(16) u16 AhS[128][32];
    __shared__ __align__(16) u16 AlS[128][32];
    __shared__ __align__(16) u16 WhS[BN][32];
    __shared__ __align__(16) u16 WlS[BN][32];
    const int m0 = blockIdx.x * 128;
    const int n0 = blockIdx.y * BN;
    const int tid = threadIdx.x;
    const int wave = tid >> 6, lane = tid & 63;
    const int wr = (BN == 64) ? wave : (wave >> 1);
    const int wc = (BN == 64) ? 0 : (wave & 1);
    const int fr = lane & 15, kb = lane >> 4;
    const int lrow = lane >> 2, lcol = (lane & 3) * 8;

    f4v acc[WM][4];
    #pragma unroll
    for (int i = 0; i < WM; i++)
        #pragma unroll
        for (int j = 0; j < 4; j++) { f4v z = {0.f, 0.f, 0.f, 0.f}; acc[i][j] = z; }

    for (int k0 = 0; k0 < K; k0 += 32) {
        __syncthreads();
        #pragma unroll
        for (int i = 0; i < 2; i++) {
            const int r = wave * 32 + i * 16;
            GLOAD_LDS16(&Ah[(size_t)(m0 + r + lrow) * K + k0 + lcol], &AhS[r][0]);
            GLOAD_LDS16(&Al[(size_t)(m0 + r + lrow) * K + k0 + lcol], &AlS[r][0]);
        }
        if constexpr (BN == 64) {
            const int r = wave * 16;
            GLOAD_LDS16(&Wh[(size_t)(n0 + r + lrow) * K + k0 + lcol], &WhS[r][0]);
            GLOAD_LDS16(&Wl[(size_t)(n0 + r + lrow) * K + k0 + lcol], &WlS[r][0]);
        } else {
            #pragma unroll
            for (int i = 0; i < 2; i++) {
                const int r = wave * 32 + i * 16;
                GLOAD_LDS16(&Wh[(size_t)(n0 + r + lrow) * K + k0 + lcol], &WhS[r][0]);
                GLOAD_LDS16(&Wl[(size_t)(n0 + r + lrow) * K + k0 + lcol], &WlS[r][0]);
            }
        }
        __syncthreads();
        s8v afh[WM], afl[WM];
        #pragma unroll
        for (int mi = 0; mi < WM; mi++) {
            afh[mi] = *(const s8v*)&AhS[wr * (WM * 16) + mi * 16 + fr][kb * 8];
            afl[mi] = *(const s8v*)&AlS[wr * (WM * 16) + mi * 16 + fr][kb * 8];
        }
        #pragma unroll
        for (int nj = 0; nj < 4; nj++) {
            s8v bh = *(const s8v*)&WhS[wc * 64 + nj * 16 + fr][kb * 8];
            s8v bl = *(const s8v*)&WlS[wc * 64 + nj * 16 + fr][kb * 8];
            #pragma unroll
            for (int mi = 0; mi < WM; mi++) {
                acc[mi][nj] = __builtin_amdgcn_mfma_f32_16x16x32_bf16(afh[mi], bh, acc[mi][nj], 0, 0, 0);
                acc[mi][nj] = __builtin_amdgcn_mfma_f32_16x16x32_bf16(afh[mi], bl, acc[mi][nj], 0, 0, 0);
                acc[mi][nj] = __builtin_amdgcn_mfma_f32_16x16x32_bf16(afl[mi], bh, acc[mi][nj], 0, 0, 0);
            }
        }
    }
    #pragma unroll
    for (int mi = 0; mi < WM; mi++) {
        #pragma unroll
        for (int nj = 0; nj < 4; nj++) {
            int col = n0 + wc * 64 + nj * 16 + fr;
            float bb = bias ? bias[col] : 0.f;
            #pragma unroll
            for (int r = 0; r < 4; r++) {
                int row = m0 + wr * (WM * 16) + mi * 16 + (lane >> 4) * 4 + r;
                float v = acc[mi][nj][r] + bb;
                if (addrow) v += addrow[(size_t)(row / ardiv) * arld + col];
                if (RELU) v = fmaxf(v, 0.f);
                if (SPLIT_OUT) {
                    u16 hi, lo; split2(v, hi, lo);
                    Chi[(size_t)row * ldc + col] = hi;
                    Clo[(size_t)row * ldc + col] = lo;
                } else {
                    int drow = row;
                    if (ROWMAP) drow = row + rm_add + (row / rm_div) * rm_mul;
                    Cf[(size_t)drow * ldc + col] = v;
                }
            }
        }
    }
}

// ---------------------------------------------------------------- initial activation split
__global__ __launch_bounds__(256) void split_x0(
    const float* __restrict__ X, const float* __restrict__ PE,
    u16* __restrict__ Xh, u16* __restrict__ Xl,
    u16* __restrict__ XPh, u16* __restrict__ XPl)
{
    size_t base = ((size_t)blockIdx.x * 256 + threadIdx.x) * 4;
    float4 x = *(const float4*)&X[base];
    float4 p = *(const float4*)&PE[base];
    ushort4 h, l, ph, pl;
    split2(x.x, h.x, l.x); split2(x.y, h.y, l.y); split2(x.z, h.z, l.z); split2(x.w, h.w, l.w);
    split2(x.x + p.x, ph.x, pl.x); split2(x.y + p.y, ph.y, pl.y);
    split2(x.z + p.z, ph.z, pl.z); split2(x.w + p.w, ph.w, pl.w);
    *(ushort4*)&Xh[base] = h;  *(ushort4*)&Xl[base] = l;
    *(ushort4*)&XPh[base] = ph; *(ushort4*)&XPl[base] = pl;
}

// ---------------------------------------------------------------- transformer split-bf16 MFMA GEMM
template<bool RELU, bool SPLIT_OUT>
__global__ __launch_bounds__(256) void gemm_mfma(
    const u16* __restrict__ Ah, const u16* __restrict__ Al,
    const u16* __restrict__ A2h, const u16* __restrict__ A2l, int a2min,
    const u16* __restrict__ Wh, const u16* __restrict__ Wl,
    const float* __restrict__ bias,
    float* __restrict__ Cf, u16* __restrict__ Chi, u16* __restrict__ Clo,
    int K, int ldc, int coff, float scale, int scale_until)
{
    __shared__ __align__(16) u16 AhS[128][32];
    __shared__ __align__(16) u16 AlS[128][32];
    __shared__ __align__(16) u16 WhS[128][32];
    __shared__ __align__(16) u16 WlS[128][32];
    const int m0 = blockIdx.x * 128;
    const int n0 = blockIdx.y * 128;
    const u16* pAh = (n0 >= a2min) ? A2h : Ah;
    const u16* pAl = (n0 >= a2min) ? A2l : Al;
    const int tid = threadIdx.x;
    const int wave = tid >> 6, lane = tid & 63;
    const int wr = wave >> 1, wc = wave & 1;
    const int fr = lane & 15, kb = lane >> 4;
    const int lrow = lane >> 2;
    const int lcol = (lane & 3) * 8;

    f4v acc[4][4];
    #pragma unroll
    for (int i = 0; i < 4; i++)
        #pragma unroll
        for (int j = 0; j < 4; j++) { f4v z = {0.f, 0.f, 0.f, 0.f}; acc[i][j] = z; }

    for (int k0 = 0; k0 < K; k0 += 32) {
        __syncthreads();
        #pragma unroll
        for (int i = 0; i < 2; i++) {
            const int r = wave * 32 + i * 16;
            const size_t grow = (size_t)(r + lrow);
            GLOAD_LDS16(&pAh[(m0 + grow) * K + k0 + lcol], &AhS[r][0]);
            GLOAD_LDS16(&pAl[(m0 + grow) * K + k0 + lcol], &AlS[r][0]);
            GLOAD_LDS16(&Wh [(n0 + grow) * K + k0 + lcol], &WhS[r][0]);
            GLOAD_LDS16(&Wl [(n0 + grow) * K + k0 + lcol], &WlS[r][0]);
        }
        __syncthreads();
        s8v afh[4], afl[4];
        #pragma unroll
        for (int mi = 0; mi < 4; mi++) {
            afh[mi] = *(const s8v*)&AhS[wr * 64 + mi * 16 + fr][kb * 8];
            afl[mi] = *(const s8v*)&AlS[wr * 64 + mi * 16 + fr][kb * 8];
        }
        #pragma unroll
        for (int nj = 0; nj < 4; nj++) {
            s8v bh = *(const s8v*)&WhS[wc * 64 + nj * 16 + fr][kb * 8];
            s8v bl = *(const s8v*)&WlS[wc * 64 + nj * 16 + fr][kb * 8];
            #pragma unroll
            for (int mi = 0; mi < 4; mi++) {
                acc[mi][nj] = __builtin_amdgcn_mfma_f32_16x16x32_bf16(afh[mi], bh, acc[mi][nj], 0, 0, 0);
                acc[mi][nj] = __builtin_amdgcn_mfma_f32_16x16x32_bf16(afh[mi], bl, acc[mi][nj], 0, 0, 0);
                acc[mi][nj] = __builtin_amdgcn_mfma_f32_16x16x32_bf16(afl[mi], bh, acc[mi][nj], 0, 0, 0);
            }
        }
    }
    #pragma unroll
    for (int mi = 0; mi < 4; mi++) {
        #pragma unroll
        for (int nj = 0; nj < 4; nj++) {
            int col = n0 + wc * 64 + nj * 16 + fr;
            float bb = bias[col];
            #pragma unroll
            for (int r = 0; r < 4; r++) {
                int row = m0 + wr * 64 + mi * 16 + (lane >> 4) * 4 + r;
                float v = acc[mi][nj][r] + bb;
                if (RELU) v = fmaxf(v, 0.f);
                if (SPLIT_OUT) {
                    u16 hi, lo; split2(v, hi, lo);
                    Chi[(size_t)row * ldc + col] = hi;
                    Clo[(size_t)row * ldc + col] = lo;
                } else {
                    int gcol = coff + col;
                    if (gcol < scale_until) v *= scale;
                    Cf[(size_t)row * ldc + gcol] = v;
                }
            }
        }
    }
}

// ---------------------------------------------------------------- GEMM + residual + LayerNorm fused
// tile 32 rows x 256 cols (full row per block) -> LN block-local.
// out = LN( R1[row] + A.W^T + bias ) * g + bt
// PEMODE 0: write OutF + split(out) -> (OHi,OLo)          [O-proj + ln1 -> H]
// PEMODE 1: + split(out + PE) -> (PHi,PLo)                [FFN2 + ln2 -> X]
// PEMODE 2: write OutF only                               [final layer -> d_out]
template<int PEMODE>
__global__ __launch_bounds__(256) void gemm_ln(
    const u16* __restrict__ Ah, const u16* __restrict__ Al,
    const u16* __restrict__ Wh, const u16* __restrict__ Wl,
    const float* __restrict__ bias, const float* __restrict__ R1,
    const float* __restrict__ g, const float* __restrict__ bt,
    float* __restrict__ OutF, u16* __restrict__ OHi, u16* __restrict__ OLo,
    const float* __restrict__ PEp, u16* __restrict__ PHi, u16* __restrict__ PLo,
    int K)
{
    __shared__ __align__(16) u16 AhS[32][32];
    __shared__ __align__(16) u16 AlS[32][32];
    __shared__ __align__(16) u16 WhS[256][32];
    __shared__ __align__(16) u16 WlS[256][32];
    __shared__ float red_s[2][4][32];
    const int m0 = blockIdx.x * 32;
    const int tid = threadIdx.x;
    const int wave = tid >> 6, lane = tid & 63;
    const int fr = lane & 15, kb = lane >> 4;
    const int lrow = lane >> 2, lcol = (lane & 3) * 8;

    f4v acc[2][4];
    #pragma unroll
    for (int i = 0; i < 2; i++)
        #pragma unroll
        for (int j = 0; j < 4; j++) { f4v z = {0.f, 0.f, 0.f, 0.f}; acc[i][j] = z; }

    for (int k0 = 0; k0 < K; k0 += 32) {
        __syncthreads();
        // A: 32 rows; waves 0/1 stage hi chunks, 2/3 stage lo chunks (wave-uniform dests)
        if (wave < 2) {
            GLOAD_LDS16(&Ah[(size_t)(m0 + wave * 16 + lrow) * K + k0 + lcol], &AhS[wave * 16][0]);
        } else {
            GLOAD_LDS16(&Al[(size_t)(m0 + (wave - 2) * 16 + lrow) * K + k0 + lcol], &AlS[(wave - 2) * 16][0]);
        }
        // W: 256 rows, wave w stages rows [w*64, w*64+64)
        #pragma unroll
        for (int i = 0; i < 4; i++) {
            const int r = wave * 64 + i * 16;
            GLOAD_LDS16(&Wh[(size_t)(r + lrow) * K + k0 + lcol], &WhS[r][0]);
            GLOAD_LDS16(&Wl[(size_t)(r + lrow) * K + k0 + lcol], &WlS[r][0]);
        }
        __syncthreads();
        s8v afh[2], afl[2];
        #pragma unroll
        for (int mi = 0; mi < 2; mi++) {
            afh[mi] = *(const s8v*)&AhS[mi * 16 + fr][kb * 8];
            afl[mi] = *(const s8v*)&AlS[mi * 16 + fr][kb * 8];
        }
        #pragma unroll
        for (int nj = 0; nj < 4; nj++) {
            s8v bh = *(const s8v*)&WhS[wave * 64 + nj * 16 + fr][kb * 8];
            s8v bl = *(const s8v*)&WlS[wave * 64 + nj * 16 + fr][kb * 8];
            #pragma unroll
            for (int mi = 0; mi < 2; mi++) {
                acc[mi][nj] = __builtin_amdgcn_mfma_f32_16x16x32_bf16(afh[mi], bh, acc[mi][nj], 0, 0, 0);
                acc[mi][nj] = __builtin_amdgcn_mfma_f32_16x16x32_bf16(afh[mi], bl, acc[mi][nj], 0, 0, 0);
                acc[mi][nj] = __builtin_amdgcn_mfma_f32_16x16x32_bf16(afl[mi], bh, acc[mi][nj], 0, 0, 0);
            }
        }
    }
    // ---- epilogue: x = R1 + (acc + bias); block-local LN over 256 cols
    float x[2][4][4];
    float rsum[2][4], rsq[2][4];
    #pragma unroll
    for (int mi = 0; mi < 2; mi++)
        #pragma unroll
        for (int r = 0; r < 4; r++) { rsum[mi][r] = 0.f; rsq[mi][r] = 0.f; }
    #pragma unroll
    for (int mi = 0; mi < 2; mi++) {
        #pragma unroll
        for (int nj = 0; nj < 4; nj++) {
            int col = wave * 64 + nj * 16 + fr;
            float bb = bias[col];
            #pragma unroll
            for (int r = 0; r < 4; r++) {
                int row = m0 + mi * 16 + kb * 4 + r;
                float v = acc[mi][nj][r] + bb + R1[(size_t)row * 256 + col];
                x[mi][nj][r] = v;
                rsum[mi][r] += v;
                rsq[mi][r] += v * v;
            }
        }
    }
    #pragma unroll
    for (int off = 1; off < 16; off <<= 1) {
        #pragma unroll
        for (int mi = 0; mi < 2; mi++)
            #pragma unroll
            for (int r = 0; r < 4; r++) {
                rsum[mi][r] += __shfl_xor(rsum[mi][r], off);
                rsq[mi][r]  += __shfl_xor(rsq[mi][r], off);
            }
    }
    if (fr == 0) {
        #pragma unroll
        for (int mi = 0; mi < 2; mi++)
            #pragma unroll
            for (int r = 0; r < 4; r++) {
                int rid = mi * 16 + kb * 4 + r;
                red_s[0][wave][rid] = rsum[mi][r];
                red_s[1][wave][rid] = rsq[mi][r];
            }
    }
    __syncthreads();
    #pragma unroll
    for (int mi = 0; mi < 2; mi++) {
        #pragma unroll
        for (int r = 0; r < 4; r++) {
            int rid = mi * 16 + kb * 4 + r;
            float s  = red_s[0][0][rid] + red_s[0][1][rid] + red_s[0][2][rid] + red_s[0][3][rid];
            float sq = red_s[1][0][rid] + red_s[1][1][rid] + red_s[1][2][rid] + red_s[1][3][rid];
            float mean = s * (1.f / 256.f);
            float var = sq * (1.f / 256.f) - mean * mean;
            float inv = rsqrtf(var + 1e-5f);
            #pragma unroll
            for (int nj = 0; nj < 4; nj++) {
                int col = wave * 64 + nj * 16 + fr;
                float o = (x[mi][nj][r] - mean) * inv * g[col] + bt[col];
                size_t idx = (size_t)(m0 + rid) * 256 + col;
                OutF[idx] = o;
                if (PEMODE == 0 || PEMODE == 1) {
                    u16 hi, lo; split2(o, hi, lo);
                    OHi[idx] = hi; OLo[idx] = lo;
                }
                if (PEMODE == 1) {
                    float p = PEp[idx];
                    u16 ph, pl; split2(o + p, ph, pl);
                    PHi[idx] = ph; PLo[idx] = pl;
                }
            }
        }
    }
}

// ---------------------------------------------------------------- local KNN attention
// XCD-affinity swizzle + LDS-staged K gather
__global__ __launch_bounds__(256) void attn_kernel(
    const float* __restrict__ QKV, const int* __restrict__ IDX,
    u16* __restrict__ AOh, u16* __restrict__ AOl)
{
    __shared__ __align__(16) float Ks[32][260];   // 32 slices, +4 pad
    __shared__ float p_s[2][HH][16];
    __shared__ int gid_s[2][16];
    const int sub = threadIdx.x >> 7;
    const int t = threadIdx.x & 127;
    const int wave = threadIdx.x >> 6, lane = threadIdx.x & 63;
    const int xcd = blockIdx.x & 7;
    const int j = blockIdx.x >> 3;            // 0..831
    const int b = (j / 416) * 8 + xcd;        // batch
    const int row = b * NN + (j % 416) * 2 + sub;
    const int h = t >> 4, k = t & 15;
    int nb = IDX[(size_t)row * 16 + k];
    int g = b * NN + nb;
    if (h == 0) gid_s[sub][k] = g;
    __syncthreads();
    #pragma unroll
    for (int i = 0; i < 8; i++) {
        int s = wave * 8 + i;
        int gs = gid_s[s >> 4][s & 15];
        GLOAD_LDS16(&QKV[(size_t)gs * 768 + 256 + lane * 4], &Ks[s][0]);
    }
    __syncthreads();
    const float* q = &QKV[(size_t)row * 768 + h * HDX];
    const float* kr = &Ks[sub * 16 + k][h * HDX];
    float s = 0.f;
    #pragma unroll
    for (int d = 0; d < HDX; d += 4) {
        float4 q4 = *(const float4*)&q[d];
        float4 k4 = *(const float4*)&kr[d];
        s += q4.x * k4.x + q4.y * k4.y + q4.z * k4.z + q4.w * k4.w;
    }
    float m = s;
    #pragma unroll
    for (int off = 8; off; off >>= 1) m = fmaxf(m, __shfl_xor(m, off, 16));
    float e = expf(s - m);
    float sum = e;
    #pragma unroll
    for (int off = 8; off; off >>= 1) sum += __shfl_xor(sum, off, 16);
    p_s[sub][h][k] = e / sum;
    __syncthreads();
    const int d0 = t * 2;
    const int hh = d0 >> 5, dd = d0 & 31;
    float o0 = 0.f, o1 = 0.f;
    #pragma unroll
    for (int kk = 0; kk < 16; kk++) {
        int gg = gid_s[sub][kk];
        const float* vr = &QKV[(size_t)gg * 768 + 512 + hh * HDX + dd];
        float p = p_s[sub][hh][kk];
        o0 += p * vr[0];
        o1 += p * vr[1];
    }
    u16 h0, lo0, h1, lo1;
    split2(o0, h0, lo0); split2(o1, h1, lo1);
    size_t base = (size_t)row * DD + d0;
    AOh[base] = h0; AOh[base + 1] = h1;
    AOl[base] = lo0; AOl[base + 1] = lo1;
}

// ----------------------------------------------------------------
extern "C" void kernel_launch(void* const* d_in, const int* in_sizes, int n_in,
                              void* d_out, int out_size, void* d_ws, size_t ws_size,
                              hipStream_t stream)
{
    const float* obj      = (const float*)d_in[0];
    const float* mp       = (const float*)d_in[1];
    const float* opos     = (const float*)d_in[2];
    const float* mpos     = (const float*)d_in[3];
    const float* a_pre_w  = (const float*)d_in[4];
    const float* a_pre_b  = (const float*)d_in[5];
    const float* a_mlp_w1 = (const float*)d_in[6];
    const float* a_mlp_b1 = (const float*)d_in[7];
    const float* a_mlp_w2 = (const float*)d_in[8];
    const float* a_mlp_b2 = (const float*)d_in[9];
    const float* a_out_w1 = (const float*)d_in[10];
    const float* a_out_b1 = (const float*)d_in[11];
    const float* a_out_w2 = (const float*)d_in[12];
    const float* a_out_b2 = (const float*)d_in[13];
    const float* m_pre_w1 = (const float*)d_in[14];
    const float* m_pre_b1 = (const float*)d_in[15];
    const float* m_pre_w2 = (const float*)d_in[16];
    const float* m_pre_b2 = (const float*)d_in[17];
    const float* m_pre_w3 = (const float*)d_in[18];
    const float* m_pre_b3 = (const float*)d_in[19];
    const float* m_mlp_w1 = (const float*)d_in[20];
    const float* m_mlp_b1 = (const float*)d_in[21];
    const float* m_mlp_w2 = (const float*)d_in[22];
    const float* m_mlp_b2 = (const float*)d_in[23];
    const float* m_out_w1 = (const float*)d_in[24];
    const float* m_out_b1 = (const float*)d_in[25];
    const float* m_out_w2 = (const float*)d_in[26];
    const float* m_out_b2 = (const float*)d_in[27];
    const float* attn_wqkv = (const float*)d_in[28];
    const float* attn_bqkv = (const float*)d_in[29];
    const float* attn_wo   = (const float*)d_in[30];
    const float* attn_bo   = (const float*)d_in[31];
    const float* ffn_w1    = (const float*)d_in[32];
    const float* ffn_b1    = (const float*)d_in[33];
    const float* ffn_w2    = (const float*)d_in[34];
    const float* ffn_b2    = (const float*)d_in[35];
    const float* ln1_g     = (const float*)d_in[36];
    const float* ln1_b     = (const float*)d_in[37];
    const float* ln2_g     = (const float*)d_in[38];
    const float* ln2_b     = (const float*)d_in[39];

    const size_t M = MTOT;  // 13312
    float* ws   = (float*)d_ws;
    float* X    = ws;                 // M*256 f32
    float* PE   = X   + M * 256;      // M*256 f32
    float* QKV  = PE  + M * 256;      // M*768 f32
    float* AO   = QKV + M * 768;      // M*256 f32  (AOh/AOl; F1 spans QKV..AO)
    float* H    = AO  + M * 256;      // M*256 f32
    float* XS   = H   + M * 256;      // M*512 f32  (XPh,XPl,Xh,Xl)
    float* HS   = XS  + M * 512;      // M*256 f32  (Hh,Hl)
    float* WSp  = HS  + M * 256;      // 4,718,592 f32 (whi+wlo u16)
    int*  IDX   = (int*)(WSp + 4718592);
    u16*  wpnh  = (u16*)(IDX + MTOT * 16);
    u16*  wpnl  = wpnh + WPN_TOT;

    u16* XPh = (u16*)XS;
    u16* XPl = XPh + M * 256;
    u16* Xh  = XPl + M * 256;
    u16* Xl  = Xh  + M * 256;
    u16* F1h = (u16*)QKV;            // M*1024 u16 over QKV (dead after attn)
    u16* F1l = F1h + M * 1024;       // M*1024 u16 spilling into AO (dead after O-proj)
    u16* AOh = (u16*)AO;             // M*256 u16 each -- wait: see F1l overlap note below
    u16* AOl = AOh + M * 256;
    u16* Hh  = (u16*)HS;
    u16* Hl  = Hh + M * 256;
    u16* whi = (u16*)WSp;
    u16* wlo = whi + 4718592;
    // lifetime check per layer: QKV-gemm writes QKV (F1 dead); attn reads QKV,
    // writes AO (disjoint); gemm_ln<0> reads AO, writes H/HS; FFN1 writes F1
    // over QKV(+first half of AO region)  [QKV: M*1536 u16 holds F1h(M*1024)
    // + F1l first M*512; F1l remaining M*512 lands in AO's M*512 u16 -- AO dead];
    // gemm_ln<1> reads F1 + H, writes X/XS. No overlap live at once.

    u16* PN0h = (u16*)QKV;
    u16* PN0l = PN0h + 7864320;
    u16* PN1h = PN0h + 15728640;
    u16* PN1l = PN0h + 23592960;
    u16* SBp  = PN0h + 31457280;
    u16* PLh  = SBp;
    u16* PLl  = SBp + 393216;
    u16* GMh  = SBp + 786432;
    u16* GMl  = SBp + 1572864;
    u16* HVh  = SBp + 2359296;
    u16* HVl  = SBp + 3145728;
    u16* APLh = SBp + 3932160;
    u16* APLl = SBp + 4194304;
    u16* AGMh = SBp + 4456448;
    u16* AGMl = SBp + 4718592;
    u16* AHVh = SBp + 4980736;
    u16* AHVl = SBp + 5242880;
    float* PCf = (float*)(SBp + 5505024);
    float* APC = PCf + 393216;

    // ---------------- pre-phase ----------------
    knn_kernel<<<BB * 208, 256, 0, stream>>>(opos, mpos, IDX);
    pe_kernel<<<MTOT, 256, 0, stream>>>(opos, mpos, PE);
    split_weights<<<4718592 / 256, 256, 0, stream>>>(attn_wqkv, attn_wo, ffn_w1, ffn_w2, whi, wlo);
    split_pn_weights<<<WPN_TOT / 256, 256, 0, stream>>>(
        m_pre_w1, m_pre_w2, m_pre_w3, m_mlp_w1, m_mlp_w2, m_out_w1, m_out_w2,
        a_pre_w, a_mlp_w1, a_mlp_w2, a_out_w1, a_out_w2, wpnh, wpnl);

    // ---- agent pointnet as GEMM chain
    {
        u16* PA32h = PN1h; u16* PA32l = PN1l;
        u16* PBh = PN0h;   u16* PBl = PN0l;
        u16* PA2h = PN1h;  u16* PA2l = PN1l;
        prep_agent<<<21504 * 32 / 256, 256, 0, stream>>>(obj, PA32h, PA32l);
        gemm_pn<128, true, true, false><<<dim3(168, 2), 256, 0, stream>>>(
            PA32h, PA32l, wpnh + APW_O, wpnl + APW_O, a_pre_b, nullptr, 1, 0,
            nullptr, PBh, PBl, 32, 256, 1, 0, 0);
        pool_max<21><<<1024, 256, 0, stream>>>(PBh, PBl, APLh, APLl, 8, 0);
        gemm_pn<128, false, false, false><<<dim3(8, 2), 256, 0, stream>>>(
            APLh, APLl, wpnh + AW1B_O, wpnl + AW1B_O, a_mlp_b1, nullptr, 1, 0,
            APC, nullptr, nullptr, 256, 256, 1, 0, 0);
        gemm_pn<128, true, true, false><<<dim3(168, 2), 256, 0, stream>>>(
            PBh, PBl, wpnh + AW1A_O, wpnl + AW1A_O, nullptr, APC, 21, 256,
            nullptr, PA2h, PA2l, 256, 256, 1, 0, 0);
        gemm_pn<128, true, true, false><<<dim3(168, 2), 256, 0, stream>>>(
            PA2h, PA2l, wpnh + AW2S_O, wpnl + AW2S_O, a_mlp_b2, nullptr, 1, 0,
            nullptr, PBh, PBl, 256, 256, 1, 0, 0);
        pool_max<21><<<1024, 256, 0, stream>>>(PBh, PBl, AGMh, AGMl, 8, 0);
        gemm_pn<128, true, true, false><<<dim3(8, 2), 256, 0, stream>>>(
            AGMh, AGMl, wpnh + AOW1_O, wpnl + AOW1_O, a_out_b1, nullptr, 1, 0,
            nullptr, AHVh, AHVl, 256, 256, 1, 0, 0);
        gemm_pn<128, false, false, true><<<dim3(8, 2), 256, 0, stream>>>(
            AHVh, AHVl, wpnh + AOW2_O, wpnl + AOW2_O, a_out_b2, nullptr, 1, 0,
            X, nullptr, nullptr, 256, 256, 64, 768, 0);
    }

    // ---- map pointnet as GEMM chain, two batch halves
    for (int h = 0; h < 2; h++) {
        const int hoff = h * 122880;
        u16* PM32h = PN0h; u16* PM32l = PN0l;
        prep_map<<<122880 * 32 / 256, 256, 0, stream>>>(mp, hoff, PM32h, PM32l);
        gemm_pn<64, true, true, false><<<dim3(960, 1), 256, 0, stream>>>(
            PM32h, PM32l, wpnh + W1P_O, wpnl + W1P_O, m_pre_b1, nullptr, 1, 0,
            nullptr, PN1h, PN1l, 32, 64, 1, 0, 0);
        gemm_pn<64, true, true, false><<<dim3(960, 1), 256, 0, stream>>>(
            PN1h, PN1l, wpnh + W2S_O, wpnl + W2S_O, m_pre_b2, nullptr, 1, 0,
            nullptr, PN0h, PN0l, 64, 64, 1, 0, 0);
        gemm_pn<64, true, true, false><<<dim3(960, 1), 256, 0, stream>>>(
            PN0h, PN0l, wpnh + W3S_O, wpnl + W3S_O, m_pre_b3, nullptr, 1, 0,
            nullptr, PN1h, PN1l, 64, 64, 1, 0, 0);
        pool_max<20><<<1536, 256, 0, stream>>>(PN1h, PN1l, PLh, PLl, 6, 0);
        gemm_pn<64, false, false, false><<<dim3(48, 1), 256, 0, stream>>>(
            PLh, PLl, wpnh + MW1B_O, wpnl + MW1B_O, m_mlp_b1, nullptr, 1, 0,
            PCf, nullptr, nullptr, 64, 64, 1, 0, 0);
        gemm_pn<64, true, true, false><<<dim3(960, 1), 256, 0, stream>>>(
            PN1h, PN1l, wpnh + MW1A_O, wpnl + MW1A_O, nullptr, PCf, 20, 64,
            nullptr, PN0h, PN0l, 64, 64, 1, 0, 0);
        gemm_pn<64, true, true, false><<<dim3(960, 1), 256, 0, stream>>>(
            PN0h, PN0l, wpnh + MW2S_O, wpnl + MW2S_O, m_mlp_b2, nullptr, 1, 0,
            nullptr, PN1h, PN1l, 64, 64, 1, 0, 0);
        pool_max<20><<<1536, 256, 0, stream>>>(PN1h, PN1l, GMh, GMl, 6, h * 6144);
    }
    gemm_pn<64, true, true, false><<<dim3(96, 1), 256, 0, stream>>>(
        GMh, GMl, wpnh + OW1S_O, wpnl + OW1S_O, m_out_b1, nullptr, 1, 0,
        nullptr, HVh, HVl, 64, 64, 1, 0, 0);
    gemm_pn<128, false, false, true><<<dim3(96, 2), 256, 0, stream>>>(
        HVh, HVl, wpnh + OW2S_O, wpnl + OW2S_O, m_out_b2, nullptr, 1, 0,
        X, nullptr, nullptr, 64, 256, 768, 64, 64);

    split_x0<<<(int)(M * 256 / 1024), 256, 0, stream>>>(X, PE, Xh, Xl, XPh, XPl);

    // ---------------- transformer layers ----------------
    const float scal = 0.17677669529663687f;  // 32^-0.5
    const int MB = MTOT / 128;  // 104
    const int NOA2 = 0x7fffffff;
    for (int l = 0; l < LL; l++) {
        const size_t wb = (size_t)l * 786432;
        const u16* wqkv_h = whi + wb;            const u16* wqkv_l = wlo + wb;
        const u16* wo_h   = whi + wb + 196608;   const u16* wo_l   = wlo + wb + 196608;
        const u16* f1_h   = whi + wb + 262144;   const u16* f1_l   = wlo + wb + 262144;
        const u16* f2_h   = whi + wb + 524288;   const u16* f2_l   = wlo + wb + 524288;
        const float* bqkv = attn_bqkv + (size_t)l * 768;
        // QKV (merged): cols [0,512) read X+PE splits, cols [512,768) read X splits
        gemm_mfma<false, false><<<dim3(MB, 6), 256, 0, stream>>>(
            XPh, XPl, Xh, Xl, 512, wqkv_h, wqkv_l, bqkv,
            QKV, nullptr, nullptr, 256, 768, 0, scal, 256);
        attn_kernel<<<MTOT / 2, 256, 0, stream>>>(QKV, IDX, AOh, AOl);
        // O-proj + residual(X) + ln1 -> H, Hh, Hl
        gemm_ln<0><<<MTOT / 32, 256, 0, stream>>>(
            AOh, AOl, wo_h, wo_l, attn_bo + (size_t)l * 256, X,
            ln1_g + l * 256, ln1_b + l * 256,
            H, Hh, Hl, nullptr, nullptr, nullptr, 256);
        // FFN1 (relu), split output into F1 (over dead QKV/AO)
        gemm_mfma<true, true><<<dim3(MB, 8), 256, 0, stream>>>(
            Hh, Hl, nullptr, nullptr, NOA2, f1_h, f1_l, ffn_b1 + (size_t)l * 1024,
            nullptr, F1h, F1l, 256, 1024, 0, 1.f, 0);
        // FFN2 + residual(H) + ln2 -> X (+splits) or d_out
        if (l == LL - 1) {
            gemm_ln<2><<<MTOT / 32, 256, 0, stream>>>(
                F1h, F1l, f2_h, f2_l, ffn_b2 + (size_t)l * 256, H,
                ln2_g + l * 256, ln2_b + l * 256,
                (float*)d_out, nullptr, nullptr, nullptr, nullptr, nullptr, 1024);
        } else {
            gemm_ln<1><<<MTOT / 32, 256, 0, stream>>>(
                F1h, F1l, f2_h, f2_l, ffn_b2 + (size_t)l * 256, H,
                ln2_g + l * 256, ln2_b + l * 256,
                X, Xh, Xl, PE, XPh, XPl, 1024);
        }
    }
}

// Round 13
// 1409.911 us; speedup vs baseline: 1.2747x; 1.0106x over previous
//
#include <hip/hip_runtime.h>
#include <hip/hip_bf16.h>

typedef unsigned short u16;

#define BB 16
#define NO 64
#define TT 21
#define NM 768
#define PP 20
#define CAx 29
#define CMx 9
#define DD 256
#define HH 8
#define LL 6
#define KK 16
#define NN (NO + NM)        // 832
#define HDX (DD / HH)       // 32
#define MTOT (BB * NN)      // 13312

typedef __attribute__((ext_vector_type(8))) short s8v;
typedef __attribute__((ext_vector_type(4))) float f4v;

__device__ __forceinline__ u16 bftrunc(float x) {
    return (u16)(__float_as_uint(x) >> 16);
}
__device__ __forceinline__ float bf2f(u16 u) {
    return __uint_as_float(((unsigned int)u) << 16);
}
__device__ __forceinline__ void split2(float x, u16& hi, u16& lo) {
    hi = bftrunc(x);
    lo = bftrunc(x - bf2f(hi));
}

#define GLOAD_LDS16(gptr, lptr)                                                             \
    __builtin_amdgcn_global_load_lds(                                                       \
        (const __attribute__((address_space(1))) void*)(gptr),                              \
        (__attribute__((address_space(3))) void*)(lptr), 16, 0, 0)

// Bank-conflict swizzle for [rows][32]-u16 linear tiles (gload_lds-compatible):
// physical 16B slot s_phys at row R holds logical k-slot s_phys ^ ((R>>1)&3).
// Staging lane l (covers row base+l>>2, phys slot l&3) fetches global k-slot
// (l&3)^((l>>3)&3); fragment read of logical kb at row base+fr (base%16==0)
// uses phys slot kb^((fr>>1)&3). Involution -> bit-exact data, 8-way -> 2-way.
#define SWZ_LCOL(lane)   ((((lane) & 3) ^ (((lane) >> 3) & 3)) * 8)
#define SWZ_RD(kb, fr)   ((((kb) ^ (((fr) >> 1) & 3))) * 8)

// ---------------------------------------------------------------- KNN (top-16 smallest d2)
__global__ __launch_bounds__(256) void knn_kernel(
    const float* __restrict__ opos, const float* __restrict__ mpos, int* __restrict__ IDX)
{
    const int b = blockIdx.x / 208;
    const int blk = blockIdx.x % 208;
    __shared__ float px[NN], py[NN], pz[NN];
    for (int i = threadIdx.x; i < NN; i += 256) {
        const float* src = (i < NO) ? &opos[(size_t)(b * NO + i) * 3]
                                    : &mpos[(size_t)(b * NM + (i - NO)) * 3];
        px[i] = src[0]; py[i] = src[1]; pz[i] = src[2];
    }
    __syncthreads();
    const int wave = threadIdx.x >> 6, lane = threadIdx.x & 63;
    const int n = blk * 4 + wave;
    const float qx = px[n], qy = py[n], qz = pz[n];
    float d[13];
    #pragma unroll
    for (int s = 0; s < 13; s++) {
        int j = s * 64 + lane;
        float dx = qx - px[j], dy = qy - py[j], dz = qz - pz[j];
        d[s] = dx * dx + dy * dy + dz * dz;
    }
    int keep = 0;
    #pragma unroll
    for (int it = 0; it < 16; it++) {
        float bv = d[0]; int bs = 0;
        #pragma unroll
        for (int s = 1; s < 13; s++) { if (d[s] < bv) { bv = d[s]; bs = s; } }
        float v = bv; int jj = bs * 64 + lane;
        #pragma unroll
        for (int off = 32; off; off >>= 1) {
            float ov = __shfl_xor(v, off);
            int oj = __shfl_xor(jj, off);
            if (ov < v || (ov == v && oj < jj)) { v = ov; jj = oj; }
        }
        if (lane == (jj & 63)) {
            int sl = jj >> 6;
            #pragma unroll
            for (int s = 0; s < 13; s++) if (s == sl) d[s] = 3.4e38f;
        }
        if (lane == it) keep = jj;
    }
    if (lane < 16) IDX[((size_t)(b * NN + n)) * 16 + lane] = keep;
}

// ---------------------------------------------------------------- sine positional embedding
__global__ __launch_bounds__(256) void pe_kernel(
    const float* __restrict__ opos, const float* __restrict__ mpos, float* __restrict__ PE)
{
    const int row = blockIdx.x;            // b*NN + n
    const int b = row / NN, n = row % NN;
    const int c = threadIdx.x;
    const float* p = (n < NO) ? &opos[(size_t)(b * NO + n) * 3]
                              : &mpos[(size_t)(b * NM + (n - NO)) * 3];
    float x = p[0], y = p[1];
    int j = c & 127;
    float v = (c < 128) ? y : x;
    float inv_dt = exp2f(-(float)(j & ~1) * 0.10381025296523f);
    float e = v * 6.283185307179586f * inv_dt;
    PE[(size_t)row * DD + c] = (j & 1) ? cosf(e) : sinf(e);
}

// ---------------------------------------------------------------- transformer weight pre-split
__global__ __launch_bounds__(256) void split_weights(
    const float* __restrict__ wqkv, const float* __restrict__ wo,
    const float* __restrict__ f1w, const float* __restrict__ f2w,
    u16* __restrict__ whi, u16* __restrict__ wlo)
{
    size_t e = (size_t)blockIdx.x * 256 + threadIdx.x;
    int L = (int)(e / 786432);
    int r = (int)(e % 786432);
    float v;
    if (r < 196608)      v = wqkv[(size_t)L * 196608 + r];
    else if (r < 262144) v = wo[(size_t)L * 65536 + (r - 196608)];
    else if (r < 524288) v = f1w[(size_t)L * 262144 + (r - 262144)];
    else                 v = f2w[(size_t)L * 262144 + (r - 524288)];
    u16 hi, lo; split2(v, hi, lo);
    whi[e] = hi; wlo[e] = lo;
}

// ---------------------------------------------------------------- pointnet weight pre-split (packed)
#define W1P_O   0
#define W2S_O   2048
#define W3S_O   6144
#define MW1A_O  10240
#define MW1B_O  14336
#define MW2S_O  18432
#define OW1S_O  22528
#define OW2S_O  26624
#define APW_O   43008
#define AW1A_O  51200
#define AW1B_O  116736
#define AW2S_O  182272
#define AOW1_O  247808
#define AOW2_O  313344
#define WPN_TOT 378880
__global__ __launch_bounds__(256) void split_pn_weights(
    const float* __restrict__ m_pre_w1, const float* __restrict__ m_pre_w2,
    const float* __restrict__ m_pre_w3, const float* __restrict__ m_mlp_w1,
    const float* __restrict__ m_mlp_w2, const float* __restrict__ m_out_w1,
    const float* __restrict__ m_out_w2,
    const float* __restrict__ a_pre_w,  const float* __restrict__ a_mlp_w1,
    const float* __restrict__ a_mlp_w2, const float* __restrict__ a_out_w1,
    const float* __restrict__ a_out_w2,
    u16* __restrict__ wpnh, u16* __restrict__ wpnl)
{
    int e = blockIdx.x * 256 + threadIdx.x;
    float v;
    if (e < W2S_O)       { int n = e >> 5, k = e & 31; v = (k < 9) ? m_pre_w1[n * 9 + k] : 0.f; }
    else if (e < W3S_O)  v = m_pre_w2[e - W2S_O];
    else if (e < MW1A_O) v = m_pre_w3[e - W3S_O];
    else if (e < MW1B_O) { int r = e - MW1A_O; v = m_mlp_w1[(r >> 6) * 128 + (r & 63)]; }
    else if (e < MW2S_O) { int r = e - MW1B_O; v = m_mlp_w1[(r >> 6) * 128 + 64 + (r & 63)]; }
    else if (e < OW1S_O) v = m_mlp_w2[e - MW2S_O];
    else if (e < OW2S_O) v = m_out_w1[e - OW1S_O];
    else if (e < APW_O)  v = m_out_w2[e - OW2S_O];
    else if (e < AW1A_O) { int r = e - APW_O; int n = r >> 5, k = r & 31; v = (k < 30) ? a_pre_w[n * 30 + k] : 0.f; }
    else if (e < AW1B_O) { int r = e - AW1A_O; v = a_mlp_w1[(r >> 8) * 512 + (r & 255)]; }
    else if (e < AW2S_O) { int r = e - AW1B_O; v = a_mlp_w1[(r >> 8) * 512 + 256 + (r & 255)]; }
    else if (e < AOW1_O) v = a_mlp_w2[e - AW2S_O];
    else if (e < AOW2_O) v = a_out_w1[e - AOW1_O];
    else                 v = a_out_w2[e - AOW2_O];
    u16 hi, lo; split2(v, hi, lo);
    wpnh[e] = hi; wpnl[e] = lo;
}

// ---------------------------------------------------------------- pointnet input prep (pad + split)
__global__ __launch_bounds__(256) void prep_map(
    const float* __restrict__ mp, int hoff, u16* __restrict__ pah, u16* __restrict__ pal)
{
    int e = blockIdx.x * 256 + threadIdx.x;
    int r = e >> 5, c = e & 31;
    float v = (c < CMx) ? mp[(size_t)(hoff + r) * CMx + c] : 0.f;
    u16 hi, lo; split2(v, hi, lo);
    pah[e] = hi; pal[e] = lo;
}
__global__ __launch_bounds__(256) void prep_agent(
    const float* __restrict__ obj, u16* __restrict__ pah, u16* __restrict__ pal)
{
    int e = blockIdx.x * 256 + threadIdx.x;
    int r = e >> 5, c = e & 31;
    float v = (c < CAx) ? obj[(size_t)r * CAx + c] : ((c == CAx) ? 1.0f : 0.f);
    u16 hi, lo; split2(v, hi, lo);
    pah[e] = hi; pal[e] = lo;
}

// ---------------------------------------------------------------- max-pool over P points
template<int P>
__global__ __launch_bounds__(256) void pool_max(
    const u16* __restrict__ inh, const u16* __restrict__ inl,
    u16* __restrict__ outh, u16* __restrict__ outl, int cshift, int gout_off)
{
    int e = blockIdx.x * 256 + threadIdx.x;
    int C = 1 << cshift;
    int g = e >> cshift, c = e & (C - 1);
    float m = -3.4e38f;
    #pragma unroll
    for (int p = 0; p < P; p++) {
        size_t idx = (size_t)(g * P + p) * C + c;
        float v = bf2f(inh[idx]) + bf2f(inl[idx]);
        m = fmaxf(m, v);
    }
    u16 hi, lo; split2(m, hi, lo);
    size_t o = (size_t)(gout_off + g) * C + c;
    outh[o] = hi; outl[o] = lo;
}

// ---------------------------------------------------------------- pointnet GEMM (split-bf16 MFMA)
template<int BN, bool RELU, bool SPLIT_OUT, bool ROWMAP>
__global__ __launch_bounds__(256) void gemm_pn(
    const u16* __restrict__ Ah, const u16* __restrict__ Al,
    const u16* __restrict__ Wh, const u16* __restrict__ Wl,
    const float* __restrict__ bias,
    const float* __restrict__ addrow, int ardiv, int arld,
    float* __restrict__ Cf, u16* __restrict__ Chi, u16* __restrict__ Clo,
    int K, int ldc, int rm_div, int rm_mul, int rm_add)
{
    constexpr int WAVES_M = (BN == 64) ? 4 : 2;
    constexpr int WM = 128 / (16 * WAVES_M);
    __shared__ __align__(16) u16 AhS[128][32];
    __shared__ __align__(16) u16 AlS[128][32];
    __shared__ __align__(16) u16 WhS[BN][32];
    __shared__ __align__(16) u16 WlS[BN][32];
    const int m0 = blockIdx.x * 128;
    const int n0 = blockIdx.y * BN;
    const int tid = threadIdx.x;
    const int wave = tid >> 6, lane = tid & 63;
    const int wr = (BN == 64) ? wave : (wave >> 1);
    const int wc = (BN == 64) ? 0 : (wave & 1);
    const int fr = lane & 15, kb = lane >> 4;
    const int lrow = lane >> 2, lcol = SWZ_LCOL(lane);
    const int rdo = SWZ_RD(kb, fr);

    f4v acc[WM][4];
    #pragma unroll
    for (int i = 0; i < WM; i++)
        #pragma unroll
        for (int j = 0; j < 4; j++) { f4v z = {0.f, 0.f, 0.f, 0.f}; acc[i][j] = z; }

    for (int k0 = 0; k0 < K; k0 += 32) {
        __syncthreads();
        #pragma unroll
        for (int i = 0; i < 2; i++) {
            const int r = wave * 32 + i * 16;
            GLOAD_LDS16(&Ah[(size_t)(m0 + r + lrow) * K + k0 + lcol], &AhS[r][0]);
            GLOAD_LDS16(&Al[(size_t)(m0 + r + lrow) * K + k0 + lcol], &AlS[r][0]);
        }
        if constexpr (BN == 64) {
            const int r = wave * 16;
            GLOAD_LDS16(&Wh[(size_t)(n0 + r + lrow) * K + k0 + lcol], &WhS[r][0]);
            GLOAD_LDS16(&Wl[(size_t)(n0 + r + lrow) * K + k0 + lcol], &WlS[r][0]);
        } else {
            #pragma unroll
            for (int i = 0; i < 2; i++) {
                const int r = wave * 32 + i * 16;
                GLOAD_LDS16(&Wh[(size_t)(n0 + r + lrow) * K + k0 + lcol], &WhS[r][0]);
                GLOAD_LDS16(&Wl[(size_t)(n0 + r + lrow) * K + k0 + lcol], &WlS[r][0]);
            }
        }
        __syncthreads();
        s8v afh[WM], afl[WM];
        #pragma unroll
        for (int mi = 0; mi < WM; mi++) {
            afh[mi] = *(const s8v*)&AhS[wr * (WM * 16) + mi * 16 + fr][rdo];
            afl[mi] = *(const s8v*)&AlS[wr * (WM * 16) + mi * 16 + fr][rdo];
        }
        #pragma unroll
        for (int nj = 0; nj < 4; nj++) {
            s8v bh = *(const s8v*)&WhS[wc * 64 + nj * 16 + fr][rdo];
            s8v bl = *(const s8v*)&WlS[wc * 64 + nj * 16 + fr][rdo];
            #pragma unroll
            for (int mi = 0; mi < WM; mi++) {
                acc[mi][nj] = __builtin_amdgcn_mfma_f32_16x16x32_bf16(afh[mi], bh, acc[mi][nj], 0, 0, 0);
                acc[mi][nj] = __builtin_amdgcn_mfma_f32_16x16x32_bf16(afh[mi], bl, acc[mi][nj], 0, 0, 0);
                acc[mi][nj] = __builtin_amdgcn_mfma_f32_16x16x32_bf16(afl[mi], bh, acc[mi][nj], 0, 0, 0);
            }
        }
    }
    #pragma unroll
    for (int mi = 0; mi < WM; mi++) {
        #pragma unroll
        for (int nj = 0; nj < 4; nj++) {
            int col = n0 + wc * 64 + nj * 16 + fr;
            float bb = bias ? bias[col] : 0.f;
            #pragma unroll
            for (int r = 0; r < 4; r++) {
                int row = m0 + wr * (WM * 16) + mi * 16 + (lane >> 4) * 4 + r;
                float v = acc[mi][nj][r] + bb;
                if (addrow) v += addrow[(size_t)(row / ardiv) * arld + col];
                if (RELU) v = fmaxf(v, 0.f);
                if (SPLIT_OUT) {
                    u16 hi, lo; split2(v, hi, lo);
                    Chi[(size_t)row * ldc + col] = hi;
                    Clo[(size_t)row * ldc + col] = lo;
                } else {
                    int drow = row;
                    if (ROWMAP) drow = row + rm_add + (row / rm_div) * rm_mul;
                    Cf[(size_t)drow * ldc + col] = v;
                }
            }
        }
    }
}

// ---------------------------------------------------------------- initial activation split
__global__ __launch_bounds__(256) void split_x0(
    const float* __restrict__ X, const float* __restrict__ PE,
    u16* __restrict__ Xh, u16* __restrict__ Xl,
    u16* __restrict__ XPh, u16* __restrict__ XPl)
{
    size_t base = ((size_t)blockIdx.x * 256 + threadIdx.x) * 4;
    float4 x = *(const float4*)&X[base];
    float4 p = *(const float4*)&PE[base];
    ushort4 h, l, ph, pl;
    split2(x.x, h.x, l.x); split2(x.y, h.y, l.y); split2(x.z, h.z, l.z); split2(x.w, h.w, l.w);
    split2(x.x + p.x, ph.x, pl.x); split2(x.y + p.y, ph.y, pl.y);
    split2(x.z + p.z, ph.z, pl.z); split2(x.w + p.w, ph.w, pl.w);
    *(ushort4*)&Xh[base] = h;  *(ushort4*)&Xl[base] = l;
    *(ushort4*)&XPh[base] = ph; *(ushort4*)&XPl[base] = pl;
}

// ---------------------------------------------------------------- transformer split-bf16 MFMA GEMM
template<bool RELU, bool SPLIT_OUT>
__global__ __launch_bounds__(256) void gemm_mfma(
    const u16* __restrict__ Ah, const u16* __restrict__ Al,
    const u16* __restrict__ A2h, const u16* __restrict__ A2l, int a2min,
    const u16* __restrict__ Wh, const u16* __restrict__ Wl,
    const float* __restrict__ bias,
    float* __restrict__ Cf, u16* __restrict__ Chi, u16* __restrict__ Clo,
    int K, int ldc, int coff, float scale, int scale_until)
{
    __shared__ __align__(16) u16 AhS[128][32];
    __shared__ __align__(16) u16 AlS[128][32];
    __shared__ __align__(16) u16 WhS[128][32];
    __shared__ __align__(16) u16 WlS[128][32];
    const int m0 = blockIdx.x * 128;
    const int n0 = blockIdx.y * 128;
    const u16* pAh = (n0 >= a2min) ? A2h : Ah;
    const u16* pAl = (n0 >= a2min) ? A2l : Al;
    const int tid = threadIdx.x;
    const int wave = tid >> 6, lane = tid & 63;
    const int wr = wave >> 1, wc = wave & 1;
    const int fr = lane & 15, kb = lane >> 4;
    const int lrow = lane >> 2;
    const int lcol = SWZ_LCOL(lane);
    const int rdo = SWZ_RD(kb, fr);

    f4v acc[4][4];
    #pragma unroll
    for (int i = 0; i < 4; i++)
        #pragma unroll
        for (int j = 0; j < 4; j++) { f4v z = {0.f, 0.f, 0.f, 0.f}; acc[i][j] = z; }

    for (int k0 = 0; k0 < K; k0 += 32) {
        __syncthreads();
        #pragma unroll
        for (int i = 0; i < 2; i++) {
            const int r = wave * 32 + i * 16;
            const size_t grow = (size_t)(r + lrow);
            GLOAD_LDS16(&pAh[(m0 + grow) * K + k0 + lcol], &AhS[r][0]);
            GLOAD_LDS16(&pAl[(m0 + grow) * K + k0 + lcol], &AlS[r][0]);
            GLOAD_LDS16(&Wh [(n0 + grow) * K + k0 + lcol], &WhS[r][0]);
            GLOAD_LDS16(&Wl [(n0 + grow) * K + k0 + lcol], &WlS[r][0]);
        }
        __syncthreads();
        s8v afh[4], afl[4];
        #pragma unroll
        for (int mi = 0; mi < 4; mi++) {
            afh[mi] = *(const s8v*)&AhS[wr * 64 + mi * 16 + fr][rdo];
            afl[mi] = *(const s8v*)&AlS[wr * 64 + mi * 16 + fr][rdo];
        }
        #pragma unroll
        for (int nj = 0; nj < 4; nj++) {
            s8v bh = *(const s8v*)&WhS[wc * 64 + nj * 16 + fr][rdo];
            s8v bl = *(const s8v*)&WlS[wc * 64 + nj * 16 + fr][rdo];
            #pragma unroll
            for (int mi = 0; mi < 4; mi++) {
                acc[mi][nj] = __builtin_amdgcn_mfma_f32_16x16x32_bf16(afh[mi], bh, acc[mi][nj], 0, 0, 0);
                acc[mi][nj] = __builtin_amdgcn_mfma_f32_16x16x32_bf16(afh[mi], bl, acc[mi][nj], 0, 0, 0);
                acc[mi][nj] = __builtin_amdgcn_mfma_f32_16x16x32_bf16(afl[mi], bh, acc[mi][nj], 0, 0, 0);
            }
        }
    }
    #pragma unroll
    for (int mi = 0; mi < 4; mi++) {
        #pragma unroll
        for (int nj = 0; nj < 4; nj++) {
            int col = n0 + wc * 64 + nj * 16 + fr;
            float bb = bias[col];
            #pragma unroll
            for (int r = 0; r < 4; r++) {
                int row = m0 + wr * 64 + mi * 16 + (lane >> 4) * 4 + r;
                float v = acc[mi][nj][r] + bb;
                if (RELU) v = fmaxf(v, 0.f);
                if (SPLIT_OUT) {
                    u16 hi, lo; split2(v, hi, lo);
                    Chi[(size_t)row * ldc + col] = hi;
                    Clo[(size_t)row * ldc + col] = lo;
                } else {
                    int gcol = coff + col;
                    if (gcol < scale_until) v *= scale;
                    Cf[(size_t)row * ldc + gcol] = v;
                }
            }
        }
    }
}

// ---------------------------------------------------------------- GEMM + residual + LayerNorm fused
// tile 32 rows x 256 cols (full row per block) -> LN block-local.
template<int PEMODE>
__global__ __launch_bounds__(256) void gemm_ln(
    const u16* __restrict__ Ah, const u16* __restrict__ Al,
    const u16* __restrict__ Wh, const u16* __restrict__ Wl,
    const float* __restrict__ bias, const float* __restrict__ R1,
    const float* __restrict__ g, const float* __restrict__ bt,
    float* __restrict__ OutF, u16* __restrict__ OHi, u16* __restrict__ OLo,
    const float* __restrict__ PEp, u16* __restrict__ PHi, u16* __restrict__ PLo,
    int K)
{
    __shared__ __align__(16) u16 AhS[32][32];
    __shared__ __align__(16) u16 AlS[32][32];
    __shared__ __align__(16) u16 WhS[256][32];
    __shared__ __align__(16) u16 WlS[256][32];
    __shared__ float red_s[2][4][32];
    const int m0 = blockIdx.x * 32;
    const int tid = threadIdx.x;
    const int wave = tid >> 6, lane = tid & 63;
    const int fr = lane & 15, kb = lane >> 4;
    const int lrow = lane >> 2, lcol = SWZ_LCOL(lane);
    const int rdo = SWZ_RD(kb, fr);

    f4v acc[2][4];
    #pragma unroll
    for (int i = 0; i < 2; i++)
        #pragma unroll
        for (int j = 0; j < 4; j++) { f4v z = {0.f, 0.f, 0.f, 0.f}; acc[i][j] = z; }

    for (int k0 = 0; k0 < K; k0 += 32) {
        __syncthreads();
        if (wave < 2) {
            GLOAD_LDS16(&Ah[(size_t)(m0 + wave * 16 + lrow) * K + k0 + lcol], &AhS[wave * 16][0]);
        } else {
            GLOAD_LDS16(&Al[(size_t)(m0 + (wave - 2) * 16 + lrow) * K + k0 + lcol], &AlS[(wave - 2) * 16][0]);
        }
        #pragma unroll
        for (int i = 0; i < 4; i++) {
            const int r = wave * 64 + i * 16;
            GLOAD_LDS16(&Wh[(size_t)(r + lrow) * K + k0 + lcol], &WhS[r][0]);
            GLOAD_LDS16(&Wl[(size_t)(r + lrow) * K + k0 + lcol], &WlS[r][0]);
        }
        __syncthreads();
        s8v afh[2], afl[2];
        #pragma unroll
        for (int mi = 0; mi < 2; mi++) {
            afh[mi] = *(const s8v*)&AhS[mi * 16 + fr][rdo];
            afl[mi] = *(const s8v*)&AlS[mi * 16 + fr][rdo];
        }
        #pragma unroll
        for (int nj = 0; nj < 4; nj++) {
            s8v bh = *(const s8v*)&WhS[wave * 64 + nj * 16 + fr][rdo];
            s8v bl = *(const s8v*)&WlS[wave * 64 + nj * 16 + fr][rdo];
            #pragma unroll
            for (int mi = 0; mi < 2; mi++) {
                acc[mi][nj] = __builtin_amdgcn_mfma_f32_16x16x32_bf16(afh[mi], bh, acc[mi][nj], 0, 0, 0);
                acc[mi][nj] = __builtin_amdgcn_mfma_f32_16x16x32_bf16(afh[mi], bl, acc[mi][nj], 0, 0, 0);
                acc[mi][nj] = __builtin_amdgcn_mfma_f32_16x16x32_bf16(afl[mi], bh, acc[mi][nj], 0, 0, 0);
            }
        }
    }
    // ---- epilogue: x = R1 + (acc + bias); block-local LN over 256 cols
    float x[2][4][4];
    float rsum[2][4], rsq[2][4];
    #pragma unroll
    for (int mi = 0; mi < 2; mi++)
        #pragma unroll
        for (int r = 0; r < 4; r++) { rsum[mi][r] = 0.f; rsq[mi][r] = 0.f; }
    #pragma unroll
    for (int mi = 0; mi < 2; mi++) {
        #pragma unroll
        for (int nj = 0; nj < 4; nj++) {
            int col = wave * 64 + nj * 16 + fr;
            float bb = bias[col];
            #pragma unroll
            for (int r = 0; r < 4; r++) {
                int row = m0 + mi * 16 + kb * 4 + r;
                float v = acc[mi][nj][r] + bb + R1[(size_t)row * 256 + col];
                x[mi][nj][r] = v;
                rsum[mi][r] += v;
                rsq[mi][r] += v * v;
            }
        }
    }
    #pragma unroll
    for (int off = 1; off < 16; off <<= 1) {
        #pragma unroll
        for (int mi = 0; mi < 2; mi++)
            #pragma unroll
            for (int r = 0; r < 4; r++) {
                rsum[mi][r] += __shfl_xor(rsum[mi][r], off);
                rsq[mi][r]  += __shfl_xor(rsq[mi][r], off);
            }
    }
    if (fr == 0) {
        #pragma unroll
        for (int mi = 0; mi < 2; mi++)
            #pragma unroll
            for (int r = 0; r < 4; r++) {
                int rid = mi * 16 + kb * 4 + r;
                red_s[0][wave][rid] = rsum[mi][r];
                red_s[1][wave][rid] = rsq[mi][r];
            }
    }
    __syncthreads();
    #pragma unroll
    for (int mi = 0; mi < 2; mi++) {
        #pragma unroll
        for (int r = 0; r < 4; r++) {
            int rid = mi * 16 + kb * 4 + r;
            float s  = red_s[0][0][rid] + red_s[0][1][rid] + red_s[0][2][rid] + red_s[0][3][rid];
            float sq = red_s[1][0][rid] + red_s[1][1][rid] + red_s[1][2][rid] + red_s[1][3][rid];
            float mean = s * (1.f / 256.f);
            float var = sq * (1.f / 256.f) - mean * mean;
            float inv = rsqrtf(var + 1e-5f);
            #pragma unroll
            for (int nj = 0; nj < 4; nj++) {
                int col = wave * 64 + nj * 16 + fr;
                float o = (x[mi][nj][r] - mean) * inv * g[col] + bt[col];
                size_t idx = (size_t)(m0 + rid) * 256 + col;
                OutF[idx] = o;
                if (PEMODE == 0 || PEMODE == 1) {
                    u16 hi, lo; split2(o, hi, lo);
                    OHi[idx] = hi; OLo[idx] = lo;
                }
                if (PEMODE == 1) {
                    float p = PEp[idx];
                    u16 ph, pl; split2(o + p, ph, pl);
                    PHi[idx] = ph; PLo[idx] = pl;
                }
            }
        }
    }
}

// ---------------------------------------------------------------- local KNN attention
// XCD-affinity swizzle + LDS-staged K gather
__global__ __launch_bounds__(256) void attn_kernel(
    const float* __restrict__ QKV, const int* __restrict__ IDX,
    u16* __restrict__ AOh, u16* __restrict__ AOl)
{
    __shared__ __align__(16) float Ks[32][260];   // 32 slices, +4 pad
    __shared__ float p_s[2][HH][16];
    __shared__ int gid_s[2][16];
    const int sub = threadIdx.x >> 7;
    const int t = threadIdx.x & 127;
    const int wave = threadIdx.x >> 6, lane = threadIdx.x & 63;
    const int xcd = blockIdx.x & 7;
    const int j = blockIdx.x >> 3;            // 0..831
    const int b = (j / 416) * 8 + xcd;        // batch
    const int row = b * NN + (j % 416) * 2 + sub;
    const int h = t >> 4, k = t & 15;
    int nb = IDX[(size_t)row * 16 + k];
    int g = b * NN + nb;
    if (h == 0) gid_s[sub][k] = g;
    __syncthreads();
    #pragma unroll
    for (int i = 0; i < 8; i++) {
        int s = wave * 8 + i;
        int gs = gid_s[s >> 4][s & 15];
        GLOAD_LDS16(&QKV[(size_t)gs * 768 + 256 + lane * 4], &Ks[s][0]);
    }
    __syncthreads();
    const float* q = &QKV[(size_t)row * 768 + h * HDX];
    const float* kr = &Ks[sub * 16 + k][h * HDX];
    float s = 0.f;
    #pragma unroll
    for (int d = 0; d < HDX; d += 4) {
        float4 q4 = *(const float4*)&q[d];
        float4 k4 = *(const float4*)&kr[d];
        s += q4.x * k4.x + q4.y * k4.y + q4.z * k4.z + q4.w * k4.w;
    }
    float m = s;
    #pragma unroll
    for (int off = 8; off; off >>= 1) m = fmaxf(m, __shfl_xor(m, off, 16));
    float e = expf(s - m);
    float sum = e;
    #pragma unroll
    for (int off = 8; off; off >>= 1) sum += __shfl_xor(sum, off, 16);
    p_s[sub][h][k] = e / sum;
    __syncthreads();
    const int d0 = t * 2;
    const int hh = d0 >> 5, dd = d0 & 31;
    float o0 = 0.f, o1 = 0.f;
    #pragma unroll
    for (int kk = 0; kk < 16; kk++) {
        int gg = gid_s[sub][kk];
        const float* vr = &QKV[(size_t)gg * 768 + 512 + hh * HDX + dd];
        float p = p_s[sub][hh][kk];
        o0 += p * vr[0];
        o1 += p * vr[1];
    }
    u16 h0, lo0, h1, lo1;
    split2(o0, h0, lo0); split2(o1, h1, lo1);
    size_t base = (size_t)row * DD + d0;
    AOh[base] = h0; AOh[base + 1] = h1;
    AOl[base] = lo0; AOl[base + 1] = lo1;
}

// ----------------------------------------------------------------
extern "C" void kernel_launch(void* const* d_in, const int* in_sizes, int n_in,
                              void* d_out, int out_size, void* d_ws, size_t ws_size,
                              hipStream_t stream)
{
    const float* obj      = (const float*)d_in[0];
    const float* mp       = (const float*)d_in[1];
    const float* opos     = (const float*)d_in[2];
    const float* mpos     = (const float*)d_in[3];
    const float* a_pre_w  = (const float*)d_in[4];
    const float* a_pre_b  = (const float*)d_in[5];
    const float* a_mlp_w1 = (const float*)d_in[6];
    const float* a_mlp_b1 = (const float*)d_in[7];
    const float* a_mlp_w2 = (const float*)d_in[8];
    const float* a_mlp_b2 = (const float*)d_in[9];
    const float* a_out_w1 = (const float*)d_in[10];
    const float* a_out_b1 = (const float*)d_in[11];
    const float* a_out_w2 = (const float*)d_in[12];
    const float* a_out_b2 = (const float*)d_in[13];
    const float* m_pre_w1 = (const float*)d_in[14];
    const float* m_pre_b1 = (const float*)d_in[15];
    const float* m_pre_w2 = (const float*)d_in[16];
    const float* m_pre_b2 = (const float*)d_in[17];
    const float* m_pre_w3 = (const float*)d_in[18];
    const float* m_pre_b3 = (const float*)d_in[19];
    const float* m_mlp_w1 = (const float*)d_in[20];
    const float* m_mlp_b1 = (const float*)d_in[21];
    const float* m_mlp_w2 = (const float*)d_in[22];
    const float* m_mlp_b2 = (const float*)d_in[23];
    const float* m_out_w1 = (const float*)d_in[24];
    const float* m_out_b1 = (const float*)d_in[25];
    const float* m_out_w2 = (const float*)d_in[26];
    const float* m_out_b2 = (const float*)d_in[27];
    const float* attn_wqkv = (const float*)d_in[28];
    const float* attn_bqkv = (const float*)d_in[29];
    const float* attn_wo   = (const float*)d_in[30];
    const float* attn_bo   = (const float*)d_in[31];
    const float* ffn_w1    = (const float*)d_in[32];
    const float* ffn_b1    = (const float*)d_in[33];
    const float* ffn_w2    = (const float*)d_in[34];
    const float* ffn_b2    = (const float*)d_in[35];
    const float* ln1_g     = (const float*)d_in[36];
    const float* ln1_b     = (const float*)d_in[37];
    const float* ln2_g     = (const float*)d_in[38];
    const float* ln2_b     = (const float*)d_in[39];

    const size_t M = MTOT;  // 13312
    float* ws   = (float*)d_ws;
    float* X    = ws;                 // M*256 f32
    float* PE   = X   + M * 256;      // M*256 f32
    float* QKV  = PE  + M * 256;      // M*768 f32
    float* AO   = QKV + M * 768;      // M*256 f32
    float* H    = AO  + M * 256;      // M*256 f32
    float* XS   = H   + M * 256;      // M*512 f32
    float* HS   = XS  + M * 512;      // M*256 f32
    float* WSp  = HS  + M * 256;      // 4,718,592 f32 (whi+wlo u16)
    int*  IDX   = (int*)(WSp + 4718592);
    u16*  wpnh  = (u16*)(IDX + MTOT * 16);
    u16*  wpnl  = wpnh + WPN_TOT;

    u16* XPh = (u16*)XS;
    u16* XPl = XPh + M * 256;
    u16* Xh  = XPl + M * 256;
    u16* Xl  = Xh  + M * 256;
    u16* F1h = (u16*)QKV;            // M*1024 u16 over QKV (dead after attn)
    u16* F1l = F1h + M * 1024;       // M*1024 u16 spilling into AO (dead after O-proj)
    u16* AOh = (u16*)AO;
    u16* AOl = AOh + M * 256;
    u16* Hh  = (u16*)HS;
    u16* Hl  = Hh + M * 256;
    u16* whi = (u16*)WSp;
    u16* wlo = whi + 4718592;

    u16* PN0h = (u16*)QKV;
    u16* PN0l = PN0h + 7864320;
    u16* PN1h = PN0h + 15728640;
    u16* PN1l = PN0h + 23592960;
    u16* SBp  = PN0h + 31457280;
    u16* PLh  = SBp;
    u16* PLl  = SBp + 393216;
    u16* GMh  = SBp + 786432;
    u16* GMl  = SBp + 1572864;
    u16* HVh  = SBp + 2359296;
    u16* HVl  = SBp + 3145728;
    u16* APLh = SBp + 3932160;
    u16* APLl = SBp + 4194304;
    u16* AGMh = SBp + 4456448;
    u16* AGMl = SBp + 4718592;
    u16* AHVh = SBp + 4980736;
    u16* AHVl = SBp + 5242880;
    float* PCf = (float*)(SBp + 5505024);
    float* APC = PCf + 393216;

    // ---------------- pre-phase ----------------
    knn_kernel<<<BB * 208, 256, 0, stream>>>(opos, mpos, IDX);
    pe_kernel<<<MTOT, 256, 0, stream>>>(opos, mpos, PE);
    split_weights<<<4718592 / 256, 256, 0, stream>>>(attn_wqkv, attn_wo, ffn_w1, ffn_w2, whi, wlo);
    split_pn_weights<<<WPN_TOT / 256, 256, 0, stream>>>(
        m_pre_w1, m_pre_w2, m_pre_w3, m_mlp_w1, m_mlp_w2, m_out_w1, m_out_w2,
        a_pre_w, a_mlp_w1, a_mlp_w2, a_out_w1, a_out_w2, wpnh, wpnl);

    // ---- agent pointnet as GEMM chain
    {
        u16* PA32h = PN1h; u16* PA32l = PN1l;
        u16* PBh = PN0h;   u16* PBl = PN0l;
        u16* PA2h = PN1h;  u16* PA2l = PN1l;
        prep_agent<<<21504 * 32 / 256, 256, 0, stream>>>(obj, PA32h, PA32l);
        gemm_pn<128, true, true, false><<<dim3(168, 2), 256, 0, stream>>>(
            PA32h, PA32l, wpnh + APW_O, wpnl + APW_O, a_pre_b, nullptr, 1, 0,
            nullptr, PBh, PBl, 32, 256, 1, 0, 0);
        pool_max<21><<<1024, 256, 0, stream>>>(PBh, PBl, APLh, APLl, 8, 0);
        gemm_pn<128, false, false, false><<<dim3(8, 2), 256, 0, stream>>>(
            APLh, APLl, wpnh + AW1B_O, wpnl + AW1B_O, a_mlp_b1, nullptr, 1, 0,
            APC, nullptr, nullptr, 256, 256, 1, 0, 0);
        gemm_pn<128, true, true, false><<<dim3(168, 2), 256, 0, stream>>>(
            PBh, PBl, wpnh + AW1A_O, wpnl + AW1A_O, nullptr, APC, 21, 256,
            nullptr, PA2h, PA2l, 256, 256, 1, 0, 0);
        gemm_pn<128, true, true, false><<<dim3(168, 2), 256, 0, stream>>>(
            PA2h, PA2l, wpnh + AW2S_O, wpnl + AW2S_O, a_mlp_b2, nullptr, 1, 0,
            nullptr, PBh, PBl, 256, 256, 1, 0, 0);
        pool_max<21><<<1024, 256, 0, stream>>>(PBh, PBl, AGMh, AGMl, 8, 0);
        gemm_pn<128, true, true, false><<<dim3(8, 2), 256, 0, stream>>>(
            AGMh, AGMl, wpnh + AOW1_O, wpnl + AOW1_O, a_out_b1, nullptr, 1, 0,
            nullptr, AHVh, AHVl, 256, 256, 1, 0, 0);
        gemm_pn<128, false, false, true><<<dim3(8, 2), 256, 0, stream>>>(
            AHVh, AHVl, wpnh + AOW2_O, wpnl + AOW2_O, a_out_b2, nullptr, 1, 0,
            X, nullptr, nullptr, 256, 256, 64, 768, 0);
    }

    // ---- map pointnet as GEMM chain, two batch halves
    for (int h = 0; h < 2; h++) {
        const int hoff = h * 122880;
        u16* PM32h = PN0h; u16* PM32l = PN0l;
        prep_map<<<122880 * 32 / 256, 256, 0, stream>>>(mp, hoff, PM32h, PM32l);
        gemm_pn<64, true, true, false><<<dim3(960, 1), 256, 0, stream>>>(
            PM32h, PM32l, wpnh + W1P_O, wpnl + W1P_O, m_pre_b1, nullptr, 1, 0,
            nullptr, PN1h, PN1l, 32, 64, 1, 0, 0);
        gemm_pn<64, true, true, false><<<dim3(960, 1), 256, 0, stream>>>(
            PN1h, PN1l, wpnh + W2S_O, wpnl + W2S_O, m_pre_b2, nullptr, 1, 0,
            nullptr, PN0h, PN0l, 64, 64, 1, 0, 0);
        gemm_pn<64, true, true, false><<<dim3(960, 1), 256, 0, stream>>>(
            PN0h, PN0l, wpnh + W3S_O, wpnl + W3S_O, m_pre_b3, nullptr, 1, 0,
            nullptr, PN1h, PN1l, 64, 64, 1, 0, 0);
        pool_max<20><<<1536, 256, 0, stream>>>(PN1h, PN1l, PLh, PLl, 6, 0);
        gemm_pn<64, false, false, false><<<dim3(48, 1), 256, 0, stream>>>(
            PLh, PLl, wpnh + MW1B_O, wpnl + MW1B_O, m_mlp_b1, nullptr, 1, 0,
            PCf, nullptr, nullptr, 64, 64, 1, 0, 0);
        gemm_pn<64, true, true, false><<<dim3(960, 1), 256, 0, stream>>>(
            PN1h, PN1l, wpnh + MW1A_O, wpnl + MW1A_O, nullptr, PCf, 20, 64,
            nullptr, PN0h, PN0l, 64, 64, 1, 0, 0);
        gemm_pn<64, true, true, false><<<dim3(960, 1), 256, 0, stream>>>(
            PN0h, PN0l, wpnh + MW2S_O, wpnl + MW2S_O, m_mlp_b2, nullptr, 1, 0,
            nullptr, PN1h, PN1l, 64, 64, 1, 0, 0);
        pool_max<20><<<1536, 256, 0, stream>>>(PN1h, PN1l, GMh, GMl, 6, h * 6144);
    }
    gemm_pn<64, true, true, false><<<dim3(96, 1), 256, 0, stream>>>(
        GMh, GMl, wpnh + OW1S_O, wpnl + OW1S_O, m_out_b1, nullptr, 1, 0,
        nullptr, HVh, HVl, 64, 64, 1, 0, 0);
    gemm_pn<128, false, false, true><<<dim3(96, 2), 256, 0, stream>>>(
        HVh, HVl, wpnh + OW2S_O, wpnl + OW2S_O, m_out_b2, nullptr, 1, 0,
        X, nullptr, nullptr, 64, 256, 768, 64, 64);

    split_x0<<<(int)(M * 256 / 1024), 256, 0, stream>>>(X, PE, Xh, Xl, XPh, XPl);

    // ---------------- transformer layers ----------------
    const float scal = 0.17677669529663687f;  // 32^-0.5
    const int MB = MTOT / 128;  // 104
    const int NOA2 = 0x7fffffff;
    for (int l = 0; l < LL; l++) {
        const size_t wb = (size_t)l * 786432;
        const u16* wqkv_h = whi + wb;            const u16* wqkv_l = wlo + wb;
        const u16* wo_h   = whi + wb + 196608;   const u16* wo_l   = wlo + wb + 196608;
        const u16* f1_h   = whi + wb + 262144;   const u16* f1_l   = wlo + wb + 262144;
        const u16* f2_h   = whi + wb + 524288;   const u16* f2_l   = wlo + wb + 524288;
        const float* bqkv = attn_bqkv + (size_t)l * 768;
        gemm_mfma<false, false><<<dim3(MB, 6), 256, 0, stream>>>(
            XPh, XPl, Xh, Xl, 512, wqkv_h, wqkv_l, bqkv,
            QKV, nullptr, nullptr, 256, 768, 0, scal, 256);
        attn_kernel<<<MTOT / 2, 256, 0, stream>>>(QKV, IDX, AOh, AOl);
        gemm_ln<0><<<MTOT / 32, 256, 0, stream>>>(
            AOh, AOl, wo_h, wo_l, attn_bo + (size_t)l * 256, X,
            ln1_g + l * 256, ln1_b + l * 256,
            H, Hh, Hl, nullptr, nullptr, nullptr, 256);
        gemm_mfma<true, true><<<dim3(MB, 8), 256, 0, stream>>>(
            Hh, Hl, nullptr, nullptr, NOA2, f1_h, f1_l, ffn_b1 + (size_t)l * 1024,
            nullptr, F1h, F1l, 256, 1024, 0, 1.f, 0);
        if (l == LL - 1) {
            gemm_ln<2><<<MTOT / 32, 256, 0, stream>>>(
                F1h, F1l, f2_h, f2_l, ffn_b2 + (size_t)l * 256, H,
                ln2_g + l * 256, ln2_b + l * 256,
                (float*)d_out, nullptr, nullptr, nullptr, nullptr, nullptr, 1024);
        } else {
            gemm_ln<1><<<MTOT / 32, 256, 0, stream>>>(
                F1h, F1l, f2_h, f2_l, ffn_b2 + (size_t)l * 256, H,
                ln2_g + l * 256, ln2_b + l * 256,
                X, Xh, Xl, PE, XPh, XPl, 1024);
        }
    }
}

// Round 14
// 1388.185 us; speedup vs baseline: 1.2947x; 1.0157x over previous
//
#include <hip/hip_runtime.h>
#include <hip/hip_bf16.h>

typedef unsigned short u16;

#define BB 16
#define NO 64
#define TT 21
#define NM 768
#define PP 20
#define CAx 29
#define CMx 9
#define DD 256
#define HH 8
#define LL 6
#define KK 16
#define NN (NO + NM)        // 832
#define HDX (DD / HH)       // 32
#define MTOT (BB * NN)      // 13312

typedef __attribute__((ext_vector_type(8))) short s8v;
typedef __attribute__((ext_vector_type(4))) float f4v;

__device__ __forceinline__ u16 bftrunc(float x) {
    return (u16)(__float_as_uint(x) >> 16);
}
__device__ __forceinline__ float bf2f(u16 u) {
    return __uint_as_float(((unsigned int)u) << 16);
}
__device__ __forceinline__ void split2(float x, u16& hi, u16& lo) {
    hi = bftrunc(x);
    lo = bftrunc(x - bf2f(hi));
}

#define GLOAD_LDS16(gptr, lptr)                                                             \
    __builtin_amdgcn_global_load_lds(                                                       \
        (const __attribute__((address_space(1))) void*)(gptr),                              \
        (__attribute__((address_space(3))) void*)(lptr), 16, 0, 0)

// Bank-conflict swizzle for [rows][32]-u16 linear tiles (gload_lds-compatible):
// physical 16B slot s_phys at row R holds logical k-slot s_phys ^ ((R>>1)&3).
#define SWZ_LCOL(lane)   ((((lane) & 3) ^ (((lane) >> 3) & 3)) * 8)
#define SWZ_RD(kb, fr)   ((((kb) ^ (((fr) >> 1) & 3))) * 8)

// ---------------------------------------------------------------- KNN (top-16 smallest d2)
__global__ __launch_bounds__(256) void knn_kernel(
    const float* __restrict__ opos, const float* __restrict__ mpos, int* __restrict__ IDX)
{
    const int b = blockIdx.x / 208;
    const int blk = blockIdx.x % 208;
    __shared__ float px[NN], py[NN], pz[NN];
    for (int i = threadIdx.x; i < NN; i += 256) {
        const float* src = (i < NO) ? &opos[(size_t)(b * NO + i) * 3]
                                    : &mpos[(size_t)(b * NM + (i - NO)) * 3];
        px[i] = src[0]; py[i] = src[1]; pz[i] = src[2];
    }
    __syncthreads();
    const int wave = threadIdx.x >> 6, lane = threadIdx.x & 63;
    const int n = blk * 4 + wave;
    const float qx = px[n], qy = py[n], qz = pz[n];
    float d[13];
    #pragma unroll
    for (int s = 0; s < 13; s++) {
        int j = s * 64 + lane;
        float dx = qx - px[j], dy = qy - py[j], dz = qz - pz[j];
        d[s] = dx * dx + dy * dy + dz * dz;
    }
    int keep = 0;
    #pragma unroll
    for (int it = 0; it < 16; it++) {
        float bv = d[0]; int bs = 0;
        #pragma unroll
        for (int s = 1; s < 13; s++) { if (d[s] < bv) { bv = d[s]; bs = s; } }
        float v = bv; int jj = bs * 64 + lane;
        #pragma unroll
        for (int off = 32; off; off >>= 1) {
            float ov = __shfl_xor(v, off);
            int oj = __shfl_xor(jj, off);
            if (ov < v || (ov == v && oj < jj)) { v = ov; jj = oj; }
        }
        if (lane == (jj & 63)) {
            int sl = jj >> 6;
            #pragma unroll
            for (int s = 0; s < 13; s++) if (s == sl) d[s] = 3.4e38f;
        }
        if (lane == it) keep = jj;
    }
    if (lane < 16) IDX[((size_t)(b * NN + n)) * 16 + lane] = keep;
}

// ---------------------------------------------------------------- sine positional embedding
__global__ __launch_bounds__(256) void pe_kernel(
    const float* __restrict__ opos, const float* __restrict__ mpos, float* __restrict__ PE)
{
    const int row = blockIdx.x;            // b*NN + n
    const int b = row / NN, n = row % NN;
    const int c = threadIdx.x;
    const float* p = (n < NO) ? &opos[(size_t)(b * NO + n) * 3]
                              : &mpos[(size_t)(b * NM + (n - NO)) * 3];
    float x = p[0], y = p[1];
    int j = c & 127;
    float v = (c < 128) ? y : x;
    float inv_dt = exp2f(-(float)(j & ~1) * 0.10381025296523f);
    float e = v * 6.283185307179586f * inv_dt;
    PE[(size_t)row * DD + c] = (j & 1) ? cosf(e) : sinf(e);
}

// ---------------------------------------------------------------- transformer weight pre-split
__global__ __launch_bounds__(256) void split_weights(
    const float* __restrict__ wqkv, const float* __restrict__ wo,
    const float* __restrict__ f1w, const float* __restrict__ f2w,
    u16* __restrict__ whi, u16* __restrict__ wlo)
{
    size_t e = (size_t)blockIdx.x * 256 + threadIdx.x;
    int L = (int)(e / 786432);
    int r = (int)(e % 786432);
    float v;
    if (r < 196608)      v = wqkv[(size_t)L * 196608 + r];
    else if (r < 262144) v = wo[(size_t)L * 65536 + (r - 196608)];
    else if (r < 524288) v = f1w[(size_t)L * 262144 + (r - 262144)];
    else                 v = f2w[(size_t)L * 262144 + (r - 524288)];
    u16 hi, lo; split2(v, hi, lo);
    whi[e] = hi; wlo[e] = lo;
}

// ---------------------------------------------------------------- pointnet weight pre-split (packed)
#define W1P_O   0
#define W2S_O   2048
#define W3S_O   6144
#define MW1A_O  10240
#define MW1B_O  14336
#define MW2S_O  18432
#define OW1S_O  22528
#define OW2S_O  26624
#define APW_O   43008
#define AW1A_O  51200
#define AW1B_O  116736
#define AW2S_O  182272
#define AOW1_O  247808
#define AOW2_O  313344
#define WPN_TOT 378880
__global__ __launch_bounds__(256) void split_pn_weights(
    const float* __restrict__ m_pre_w1, const float* __restrict__ m_pre_w2,
    const float* __restrict__ m_pre_w3, const float* __restrict__ m_mlp_w1,
    const float* __restrict__ m_mlp_w2, const float* __restrict__ m_out_w1,
    const float* __restrict__ m_out_w2,
    const float* __restrict__ a_pre_w,  const float* __restrict__ a_mlp_w1,
    const float* __restrict__ a_mlp_w2, const float* __restrict__ a_out_w1,
    const float* __restrict__ a_out_w2,
    u16* __restrict__ wpnh, u16* __restrict__ wpnl)
{
    int e = blockIdx.x * 256 + threadIdx.x;
    float v;
    if (e < W2S_O)       { int n = e >> 5, k = e & 31; v = (k < 9) ? m_pre_w1[n * 9 + k] : 0.f; }
    else if (e < W3S_O)  v = m_pre_w2[e - W2S_O];
    else if (e < MW1A_O) v = m_pre_w3[e - W3S_O];
    else if (e < MW1B_O) { int r = e - MW1A_O; v = m_mlp_w1[(r >> 6) * 128 + (r & 63)]; }
    else if (e < MW2S_O) { int r = e - MW1B_O; v = m_mlp_w1[(r >> 6) * 128 + 64 + (r & 63)]; }
    else if (e < OW1S_O) v = m_mlp_w2[e - MW2S_O];
    else if (e < OW2S_O) v = m_out_w1[e - OW1S_O];
    else if (e < APW_O)  v = m_out_w2[e - OW2S_O];
    else if (e < AW1A_O) { int r = e - APW_O; int n = r >> 5, k = r & 31; v = (k < 30) ? a_pre_w[n * 30 + k] : 0.f; }
    else if (e < AW1B_O) { int r = e - AW1A_O; v = a_mlp_w1[(r >> 8) * 512 + (r & 255)]; }
    else if (e < AW2S_O) { int r = e - AW1B_O; v = a_mlp_w1[(r >> 8) * 512 + 256 + (r & 255)]; }
    else if (e < AOW1_O) v = a_mlp_w2[e - AW2S_O];
    else if (e < AOW2_O) v = a_out_w1[e - AOW1_O];
    else                 v = a_out_w2[e - AOW2_O];
    u16 hi, lo; split2(v, hi, lo);
    wpnh[e] = hi; wpnl[e] = lo;
}

// ---------------------------------------------------------------- pointnet input prep (pad + split)
__global__ __launch_bounds__(256) void prep_map(
    const float* __restrict__ mp, int hoff, u16* __restrict__ pah, u16* __restrict__ pal)
{
    int e = blockIdx.x * 256 + threadIdx.x;
    int r = e >> 5, c = e & 31;
    float v = (c < CMx) ? mp[(size_t)(hoff + r) * CMx + c] : 0.f;
    u16 hi, lo; split2(v, hi, lo);
    pah[e] = hi; pal[e] = lo;
}
__global__ __launch_bounds__(256) void prep_agent(
    const float* __restrict__ obj, u16* __restrict__ pah, u16* __restrict__ pal)
{
    int e = blockIdx.x * 256 + threadIdx.x;
    int r = e >> 5, c = e & 31;
    float v = (c < CAx) ? obj[(size_t)r * CAx + c] : ((c == CAx) ? 1.0f : 0.f);
    u16 hi, lo; split2(v, hi, lo);
    pah[e] = hi; pal[e] = lo;
}

// ---------------------------------------------------------------- max-pool over P points
template<int P>
__global__ __launch_bounds__(256) void pool_max(
    const u16* __restrict__ inh, const u16* __restrict__ inl,
    u16* __restrict__ outh, u16* __restrict__ outl, int cshift, int gout_off)
{
    int e = blockIdx.x * 256 + threadIdx.x;
    int C = 1 << cshift;
    int g = e >> cshift, c = e & (C - 1);
    float m = -3.4e38f;
    #pragma unroll
    for (int p = 0; p < P; p++) {
        size_t idx = (size_t)(g * P + p) * C + c;
        float v = bf2f(inh[idx]) + bf2f(inl[idx]);
        m = fmaxf(m, v);
    }
    u16 hi, lo; split2(m, hi, lo);
    size_t o = (size_t)(gout_off + g) * C + c;
    outh[o] = hi; outl[o] = lo;
}

// ---------------------------------------------------------------- pointnet GEMM (split-bf16 MFMA)
template<int BN, bool RELU, bool SPLIT_OUT, bool ROWMAP>
__global__ __launch_bounds__(256) void gemm_pn(
    const u16* __restrict__ Ah, const u16* __restrict__ Al,
    const u16* __restrict__ Wh, const u16* __restrict__ Wl,
    const float* __restrict__ bias,
    const float* __restrict__ addrow, int ardiv, int arld,
    float* __restrict__ Cf, u16* __restrict__ Chi, u16* __restrict__ Clo,
    int K, int ldc, int rm_div, int rm_mul, int rm_add)
{
    constexpr int WAVES_M = (BN == 64) ? 4 : 2;
    constexpr int WM = 128 / (16 * WAVES_M);
    __shared__ __align__(16) u16 AhS[128][32];
    __shared__ __align__(16) u16 AlS[128][32];
    __shared__ __align__(16) u16 WhS[BN][32];
    __shared__ __align__(16) u16 WlS[BN][32];
    const int m0 = blockIdx.x * 128;
    const int n0 = blockIdx.y * BN;
    const int tid = threadIdx.x;
    const int wave = tid >> 6, lane = tid & 63;
    const int wr = (BN == 64) ? wave : (wave >> 1);
    const int wc = (BN == 64) ? 0 : (wave & 1);
    const int fr = lane & 15, kb = lane >> 4;
    const int lrow = lane >> 2, lcol = SWZ_LCOL(lane);
    const int rdo = SWZ_RD(kb, fr);

    f4v acc[WM][4];
    #pragma unroll
    for (int i = 0; i < WM; i++)
        #pragma unroll
        for (int j = 0; j < 4; j++) { f4v z = {0.f, 0.f, 0.f, 0.f}; acc[i][j] = z; }

    for (int k0 = 0; k0 < K; k0 += 32) {
        __syncthreads();
        #pragma unroll
        for (int i = 0; i < 2; i++) {
            const int r = wave * 32 + i * 16;
            GLOAD_LDS16(&Ah[(size_t)(m0 + r + lrow) * K + k0 + lcol], &AhS[r][0]);
            GLOAD_LDS16(&Al[(size_t)(m0 + r + lrow) * K + k0 + lcol], &AlS[r][0]);
        }
        if constexpr (BN == 64) {
            const int r = wave * 16;
            GLOAD_LDS16(&Wh[(size_t)(n0 + r + lrow) * K + k0 + lcol], &WhS[r][0]);
            GLOAD_LDS16(&Wl[(size_t)(n0 + r + lrow) * K + k0 + lcol], &WlS[r][0]);
        } else {
            #pragma unroll
            for (int i = 0; i < 2; i++) {
                const int r = wave * 32 + i * 16;
                GLOAD_LDS16(&Wh[(size_t)(n0 + r + lrow) * K + k0 + lcol], &WhS[r][0]);
                GLOAD_LDS16(&Wl[(size_t)(n0 + r + lrow) * K + k0 + lcol], &WlS[r][0]);
            }
        }
        __syncthreads();
        s8v afh[WM], afl[WM];
        #pragma unroll
        for (int mi = 0; mi < WM; mi++) {
            afh[mi] = *(const s8v*)&AhS[wr * (WM * 16) + mi * 16 + fr][rdo];
            afl[mi] = *(const s8v*)&AlS[wr * (WM * 16) + mi * 16 + fr][rdo];
        }
        #pragma unroll
        for (int nj = 0; nj < 4; nj++) {
            s8v bh = *(const s8v*)&WhS[wc * 64 + nj * 16 + fr][rdo];
            s8v bl = *(const s8v*)&WlS[wc * 64 + nj * 16 + fr][rdo];
            #pragma unroll
            for (int mi = 0; mi < WM; mi++) {
                acc[mi][nj] = __builtin_amdgcn_mfma_f32_16x16x32_bf16(afh[mi], bh, acc[mi][nj], 0, 0, 0);
                acc[mi][nj] = __builtin_amdgcn_mfma_f32_16x16x32_bf16(afh[mi], bl, acc[mi][nj], 0, 0, 0);
                acc[mi][nj] = __builtin_amdgcn_mfma_f32_16x16x32_bf16(afl[mi], bh, acc[mi][nj], 0, 0, 0);
            }
        }
    }
    #pragma unroll
    for (int mi = 0; mi < WM; mi++) {
        #pragma unroll
        for (int nj = 0; nj < 4; nj++) {
            int col = n0 + wc * 64 + nj * 16 + fr;
            float bb = bias ? bias[col] : 0.f;
            #pragma unroll
            for (int r = 0; r < 4; r++) {
                int row = m0 + wr * (WM * 16) + mi * 16 + (lane >> 4) * 4 + r;
                float v = acc[mi][nj][r] + bb;
                if (addrow) v += addrow[(size_t)(row / ardiv) * arld + col];
                if (RELU) v = fmaxf(v, 0.f);
                if (SPLIT_OUT) {
                    u16 hi, lo; split2(v, hi, lo);
                    Chi[(size_t)row * ldc + col] = hi;
                    Clo[(size_t)row * ldc + col] = lo;
                } else {
                    int drow = row;
                    if (ROWMAP) drow = row + rm_add + (row / rm_div) * rm_mul;
                    Cf[(size_t)drow * ldc + col] = v;
                }
            }
        }
    }
}

// ---------------------------------------------------------------- initial activation split
__global__ __launch_bounds__(256) void split_x0(
    const float* __restrict__ X, const float* __restrict__ PE,
    u16* __restrict__ Xh, u16* __restrict__ Xl,
    u16* __restrict__ XPh, u16* __restrict__ XPl)
{
    size_t base = ((size_t)blockIdx.x * 256 + threadIdx.x) * 4;
    float4 x = *(const float4*)&X[base];
    float4 p = *(const float4*)&PE[base];
    ushort4 h, l, ph, pl;
    split2(x.x, h.x, l.x); split2(x.y, h.y, l.y); split2(x.z, h.z, l.z); split2(x.w, h.w, l.w);
    split2(x.x + p.x, ph.x, pl.x); split2(x.y + p.y, ph.y, pl.y);
    split2(x.z + p.z, ph.z, pl.z); split2(x.w + p.w, ph.w, pl.w);
    *(ushort4*)&Xh[base] = h;  *(ushort4*)&Xl[base] = l;
    *(ushort4*)&XPh[base] = ph; *(ushort4*)&XPl[base] = pl;
}

// ---------------------------------------------------------------- transformer split-bf16 MFMA GEMM
template<bool RELU, bool SPLIT_OUT>
__global__ __launch_bounds__(256) void gemm_mfma(
    const u16* __restrict__ Ah, const u16* __restrict__ Al,
    const u16* __restrict__ A2h, const u16* __restrict__ A2l, int a2min,
    const u16* __restrict__ Wh, const u16* __restrict__ Wl,
    const float* __restrict__ bias,
    float* __restrict__ Cf, u16* __restrict__ Chi, u16* __restrict__ Clo,
    int K, int ldc, int coff, float scale, int scale_until)
{
    __shared__ __align__(16) u16 AhS[128][32];
    __shared__ __align__(16) u16 AlS[128][32];
    __shared__ __align__(16) u16 WhS[128][32];
    __shared__ __align__(16) u16 WlS[128][32];
    const int m0 = blockIdx.x * 128;
    const int n0 = blockIdx.y * 128;
    const u16* pAh = (n0 >= a2min) ? A2h : Ah;
    const u16* pAl = (n0 >= a2min) ? A2l : Al;
    const int tid = threadIdx.x;
    const int wave = tid >> 6, lane = tid & 63;
    const int wr = wave >> 1, wc = wave & 1;
    const int fr = lane & 15, kb = lane >> 4;
    const int lrow = lane >> 2;
    const int lcol = SWZ_LCOL(lane);
    const int rdo = SWZ_RD(kb, fr);

    f4v acc[4][4];
    #pragma unroll
    for (int i = 0; i < 4; i++)
        #pragma unroll
        for (int j = 0; j < 4; j++) { f4v z = {0.f, 0.f, 0.f, 0.f}; acc[i][j] = z; }

    for (int k0 = 0; k0 < K; k0 += 32) {
        __syncthreads();
        #pragma unroll
        for (int i = 0; i < 2; i++) {
            const int r = wave * 32 + i * 16;
            const size_t grow = (size_t)(r + lrow);
            GLOAD_LDS16(&pAh[(m0 + grow) * K + k0 + lcol], &AhS[r][0]);
            GLOAD_LDS16(&pAl[(m0 + grow) * K + k0 + lcol], &AlS[r][0]);
            GLOAD_LDS16(&Wh [(n0 + grow) * K + k0 + lcol], &WhS[r][0]);
            GLOAD_LDS16(&Wl [(n0 + grow) * K + k0 + lcol], &WlS[r][0]);
        }
        __syncthreads();
        s8v afh[4], afl[4];
        #pragma unroll
        for (int mi = 0; mi < 4; mi++) {
            afh[mi] = *(const s8v*)&AhS[wr * 64 + mi * 16 + fr][rdo];
            afl[mi] = *(const s8v*)&AlS[wr * 64 + mi * 16 + fr][rdo];
        }
        #pragma unroll
        for (int nj = 0; nj < 4; nj++) {
            s8v bh = *(const s8v*)&WhS[wc * 64 + nj * 16 + fr][rdo];
            s8v bl = *(const s8v*)&WlS[wc * 64 + nj * 16 + fr][rdo];
            #pragma unroll
            for (int mi = 0; mi < 4; mi++) {
                acc[mi][nj] = __builtin_amdgcn_mfma_f32_16x16x32_bf16(afh[mi], bh, acc[mi][nj], 0, 0, 0);
                acc[mi][nj] = __builtin_amdgcn_mfma_f32_16x16x32_bf16(afh[mi], bl, acc[mi][nj], 0, 0, 0);
                acc[mi][nj] = __builtin_amdgcn_mfma_f32_16x16x32_bf16(afl[mi], bh, acc[mi][nj], 0, 0, 0);
            }
        }
    }
    #pragma unroll
    for (int mi = 0; mi < 4; mi++) {
        #pragma unroll
        for (int nj = 0; nj < 4; nj++) {
            int col = n0 + wc * 64 + nj * 16 + fr;
            float bb = bias[col];
            #pragma unroll
            for (int r = 0; r < 4; r++) {
                int row = m0 + wr * 64 + mi * 16 + (lane >> 4) * 4 + r;
                float v = acc[mi][nj][r] + bb;
                if (RELU) v = fmaxf(v, 0.f);
                if (SPLIT_OUT) {
                    u16 hi, lo; split2(v, hi, lo);
                    Chi[(size_t)row * ldc + col] = hi;
                    Clo[(size_t)row * ldc + col] = lo;
                } else {
                    int gcol = coff + col;
                    if (gcol < scale_until) v *= scale;
                    Cf[(size_t)row * ldc + gcol] = v;
                }
            }
        }
    }
}

// ---------------------------------------------------------------- GEMM + residual + LayerNorm fused
// tile 32 rows x 256 cols, 8 waves (512 thr): wave w owns cols [w*32, w*32+32).
// Doubled waves vs R12/R13 (was 4) to lift grid-starved occupancy (16% -> ~32%).
template<int PEMODE>
__global__ __launch_bounds__(512) void gemm_ln(
    const u16* __restrict__ Ah, const u16* __restrict__ Al,
    const u16* __restrict__ Wh, const u16* __restrict__ Wl,
    const float* __restrict__ bias, const float* __restrict__ R1,
    const float* __restrict__ g, const float* __restrict__ bt,
    float* __restrict__ OutF, u16* __restrict__ OHi, u16* __restrict__ OLo,
    const float* __restrict__ PEp, u16* __restrict__ PHi, u16* __restrict__ PLo,
    int K)
{
    __shared__ __align__(16) u16 AhS[32][32];
    __shared__ __align__(16) u16 AlS[32][32];
    __shared__ __align__(16) u16 WhS[256][32];
    __shared__ __align__(16) u16 WlS[256][32];
    __shared__ float red_s[2][8][32];
    const int m0 = blockIdx.x * 32;
    const int tid = threadIdx.x;
    const int wave = tid >> 6, lane = tid & 63;
    const int fr = lane & 15, kb = lane >> 4;
    const int lrow = lane >> 2, lcol = SWZ_LCOL(lane);
    const int rdo = SWZ_RD(kb, fr);

    f4v acc[2][2];
    #pragma unroll
    for (int i = 0; i < 2; i++)
        #pragma unroll
        for (int j = 0; j < 2; j++) { f4v z = {0.f, 0.f, 0.f, 0.f}; acc[i][j] = z; }

    for (int k0 = 0; k0 < K; k0 += 32) {
        __syncthreads();
        if (wave < 2) {
            GLOAD_LDS16(&Ah[(size_t)(m0 + wave * 16 + lrow) * K + k0 + lcol], &AhS[wave * 16][0]);
        } else if (wave < 4) {
            GLOAD_LDS16(&Al[(size_t)(m0 + (wave - 2) * 16 + lrow) * K + k0 + lcol], &AlS[(wave - 2) * 16][0]);
        }
        #pragma unroll
        for (int i = 0; i < 2; i++) {
            const int r = wave * 32 + i * 16;
            GLOAD_LDS16(&Wh[(size_t)(r + lrow) * K + k0 + lcol], &WhS[r][0]);
            GLOAD_LDS16(&Wl[(size_t)(r + lrow) * K + k0 + lcol], &WlS[r][0]);
        }
        __syncthreads();
        s8v afh[2], afl[2];
        #pragma unroll
        for (int mi = 0; mi < 2; mi++) {
            afh[mi] = *(const s8v*)&AhS[mi * 16 + fr][rdo];
            afl[mi] = *(const s8v*)&AlS[mi * 16 + fr][rdo];
        }
        #pragma unroll
        for (int nj = 0; nj < 2; nj++) {
            s8v bh = *(const s8v*)&WhS[wave * 32 + nj * 16 + fr][rdo];
            s8v bl = *(const s8v*)&WlS[wave * 32 + nj * 16 + fr][rdo];
            #pragma unroll
            for (int mi = 0; mi < 2; mi++) {
                acc[mi][nj] = __builtin_amdgcn_mfma_f32_16x16x32_bf16(afh[mi], bh, acc[mi][nj], 0, 0, 0);
                acc[mi][nj] = __builtin_amdgcn_mfma_f32_16x16x32_bf16(afh[mi], bl, acc[mi][nj], 0, 0, 0);
                acc[mi][nj] = __builtin_amdgcn_mfma_f32_16x16x32_bf16(afl[mi], bh, acc[mi][nj], 0, 0, 0);
            }
        }
    }
    // ---- epilogue: x = R1 + (acc + bias); block-local LN over 256 cols
    float x[2][2][4];
    float rsum[2][4], rsq[2][4];
    #pragma unroll
    for (int mi = 0; mi < 2; mi++)
        #pragma unroll
        for (int r = 0; r < 4; r++) { rsum[mi][r] = 0.f; rsq[mi][r] = 0.f; }
    #pragma unroll
    for (int mi = 0; mi < 2; mi++) {
        #pragma unroll
        for (int nj = 0; nj < 2; nj++) {
            int col = wave * 32 + nj * 16 + fr;
            float bb = bias[col];
            #pragma unroll
            for (int r = 0; r < 4; r++) {
                int row = m0 + mi * 16 + kb * 4 + r;
                float v = acc[mi][nj][r] + bb + R1[(size_t)row * 256 + col];
                x[mi][nj][r] = v;
                rsum[mi][r] += v;
                rsq[mi][r] += v * v;
            }
        }
    }
    #pragma unroll
    for (int off = 1; off < 16; off <<= 1) {
        #pragma unroll
        for (int mi = 0; mi < 2; mi++)
            #pragma unroll
            for (int r = 0; r < 4; r++) {
                rsum[mi][r] += __shfl_xor(rsum[mi][r], off);
                rsq[mi][r]  += __shfl_xor(rsq[mi][r], off);
            }
    }
    if (fr == 0) {
        #pragma unroll
        for (int mi = 0; mi < 2; mi++)
            #pragma unroll
            for (int r = 0; r < 4; r++) {
                int rid = mi * 16 + kb * 4 + r;
                red_s[0][wave][rid] = rsum[mi][r];
                red_s[1][wave][rid] = rsq[mi][r];
            }
    }
    __syncthreads();
    #pragma unroll
    for (int mi = 0; mi < 2; mi++) {
        #pragma unroll
        for (int r = 0; r < 4; r++) {
            int rid = mi * 16 + kb * 4 + r;
            float s = 0.f, sq = 0.f;
            #pragma unroll
            for (int w = 0; w < 8; w++) { s += red_s[0][w][rid]; sq += red_s[1][w][rid]; }
            float mean = s * (1.f / 256.f);
            float var = sq * (1.f / 256.f) - mean * mean;
            float inv = rsqrtf(var + 1e-5f);
            #pragma unroll
            for (int nj = 0; nj < 2; nj++) {
                int col = wave * 32 + nj * 16 + fr;
                float o = (x[mi][nj][r] - mean) * inv * g[col] + bt[col];
                size_t idx = (size_t)(m0 + rid) * 256 + col;
                OutF[idx] = o;
                if (PEMODE == 0 || PEMODE == 1) {
                    u16 hi, lo; split2(o, hi, lo);
                    OHi[idx] = hi; OLo[idx] = lo;
                }
                if (PEMODE == 1) {
                    float p = PEp[idx];
                    u16 ph, pl; split2(o + p, ph, pl);
                    PHi[idx] = ph; PLo[idx] = pl;
                }
            }
        }
    }
}

// ---------------------------------------------------------------- local KNN attention
// XCD-affinity swizzle + LDS-staged K gather
__global__ __launch_bounds__(256) void attn_kernel(
    const float* __restrict__ QKV, const int* __restrict__ IDX,
    u16* __restrict__ AOh, u16* __restrict__ AOl)
{
    __shared__ __align__(16) float Ks[32][260];   // 32 slices, +4 pad
    __shared__ float p_s[2][HH][16];
    __shared__ int gid_s[2][16];
    const int sub = threadIdx.x >> 7;
    const int t = threadIdx.x & 127;
    const int wave = threadIdx.x >> 6, lane = threadIdx.x & 63;
    const int xcd = blockIdx.x & 7;
    const int j = blockIdx.x >> 3;            // 0..831
    const int b = (j / 416) * 8 + xcd;        // batch
    const int row = b * NN + (j % 416) * 2 + sub;
    const int h = t >> 4, k = t & 15;
    int nb = IDX[(size_t)row * 16 + k];
    int g = b * NN + nb;
    if (h == 0) gid_s[sub][k] = g;
    __syncthreads();
    #pragma unroll
    for (int i = 0; i < 8; i++) {
        int s = wave * 8 + i;
        int gs = gid_s[s >> 4][s & 15];
        GLOAD_LDS16(&QKV[(size_t)gs * 768 + 256 + lane * 4], &Ks[s][0]);
    }
    __syncthreads();
    const float* q = &QKV[(size_t)row * 768 + h * HDX];
    const float* kr = &Ks[sub * 16 + k][h * HDX];
    float s = 0.f;
    #pragma unroll
    for (int d = 0; d < HDX; d += 4) {
        float4 q4 = *(const float4*)&q[d];
        float4 k4 = *(const float4*)&kr[d];
        s += q4.x * k4.x + q4.y * k4.y + q4.z * k4.z + q4.w * k4.w;
    }
    float m = s;
    #pragma unroll
    for (int off = 8; off; off >>= 1) m = fmaxf(m, __shfl_xor(m, off, 16));
    float e = expf(s - m);
    float sum = e;
    #pragma unroll
    for (int off = 8; off; off >>= 1) sum += __shfl_xor(sum, off, 16);
    p_s[sub][h][k] = e / sum;
    __syncthreads();
    const int d0 = t * 2;
    const int hh = d0 >> 5, dd = d0 & 31;
    float o0 = 0.f, o1 = 0.f;
    #pragma unroll
    for (int kk = 0; kk < 16; kk++) {
        int gg = gid_s[sub][kk];
        const float* vr = &QKV[(size_t)gg * 768 + 512 + hh * HDX + dd];
        float p = p_s[sub][hh][kk];
        o0 += p * vr[0];
        o1 += p * vr[1];
    }
    u16 h0, lo0, h1, lo1;
    split2(o0, h0, lo0); split2(o1, h1, lo1);
    size_t base = (size_t)row * DD + d0;
    AOh[base] = h0; AOh[base + 1] = h1;
    AOl[base] = lo0; AOl[base + 1] = lo1;
}

// ----------------------------------------------------------------
extern "C" void kernel_launch(void* const* d_in, const int* in_sizes, int n_in,
                              void* d_out, int out_size, void* d_ws, size_t ws_size,
                              hipStream_t stream)
{
    const float* obj      = (const float*)d_in[0];
    const float* mp       = (const float*)d_in[1];
    const float* opos     = (const float*)d_in[2];
    const float* mpos     = (const float*)d_in[3];
    const float* a_pre_w  = (const float*)d_in[4];
    const float* a_pre_b  = (const float*)d_in[5];
    const float* a_mlp_w1 = (const float*)d_in[6];
    const float* a_mlp_b1 = (const float*)d_in[7];
    const float* a_mlp_w2 = (const float*)d_in[8];
    const float* a_mlp_b2 = (const float*)d_in[9];
    const float* a_out_w1 = (const float*)d_in[10];
    const float* a_out_b1 = (const float*)d_in[11];
    const float* a_out_w2 = (const float*)d_in[12];
    const float* a_out_b2 = (const float*)d_in[13];
    const float* m_pre_w1 = (const float*)d_in[14];
    const float* m_pre_b1 = (const float*)d_in[15];
    const float* m_pre_w2 = (const float*)d_in[16];
    const float* m_pre_b2 = (const float*)d_in[17];
    const float* m_pre_w3 = (const float*)d_in[18];
    const float* m_pre_b3 = (const float*)d_in[19];
    const float* m_mlp_w1 = (const float*)d_in[20];
    const float* m_mlp_b1 = (const float*)d_in[21];
    const float* m_mlp_w2 = (const float*)d_in[22];
    const float* m_mlp_b2 = (const float*)d_in[23];
    const float* m_out_w1 = (const float*)d_in[24];
    const float* m_out_b1 = (const float*)d_in[25];
    const float* m_out_w2 = (const float*)d_in[26];
    const float* m_out_b2 = (const float*)d_in[27];
    const float* attn_wqkv = (const float*)d_in[28];
    const float* attn_bqkv = (const float*)d_in[29];
    const float* attn_wo   = (const float*)d_in[30];
    const float* attn_bo   = (const float*)d_in[31];
    const float* ffn_w1    = (const float*)d_in[32];
    const float* ffn_b1    = (const float*)d_in[33];
    const float* ffn_w2    = (const float*)d_in[34];
    const float* ffn_b2    = (const float*)d_in[35];
    const float* ln1_g     = (const float*)d_in[36];
    const float* ln1_b     = (const float*)d_in[37];
    const float* ln2_g     = (const float*)d_in[38];
    const float* ln2_b     = (const float*)d_in[39];

    const size_t M = MTOT;  // 13312
    float* ws   = (float*)d_ws;
    float* X    = ws;                 // M*256 f32
    float* PE   = X   + M * 256;      // M*256 f32
    float* QKV  = PE  + M * 256;      // M*768 f32
    float* AO   = QKV + M * 768;      // M*256 f32
    float* H    = AO  + M * 256;      // M*256 f32
    float* XS   = H   + M * 256;      // M*512 f32
    float* HS   = XS  + M * 512;      // M*256 f32
    float* WSp  = HS  + M * 256;      // 4,718,592 f32 (whi+wlo u16)
    int*  IDX   = (int*)(WSp + 4718592);
    u16*  wpnh  = (u16*)(IDX + MTOT * 16);
    u16*  wpnl  = wpnh + WPN_TOT;

    u16* XPh = (u16*)XS;
    u16* XPl = XPh + M * 256;
    u16* Xh  = XPl + M * 256;
    u16* Xl  = Xh  + M * 256;
    u16* F1h = (u16*)QKV;            // M*1024 u16 over QKV (dead after attn)
    u16* F1l = F1h + M * 1024;       // M*1024 u16 spilling into AO (dead after O-proj)
    u16* AOh = (u16*)AO;
    u16* AOl = AOh + M * 256;
    u16* Hh  = (u16*)HS;
    u16* Hl  = Hh + M * 256;
    u16* whi = (u16*)WSp;
    u16* wlo = whi + 4718592;

    u16* PN0h = (u16*)QKV;
    u16* PN0l = PN0h + 7864320;
    u16* PN1h = PN0h + 15728640;
    u16* PN1l = PN0h + 23592960;
    u16* SBp  = PN0h + 31457280;
    u16* PLh  = SBp;
    u16* PLl  = SBp + 393216;
    u16* GMh  = SBp + 786432;
    u16* GMl  = SBp + 1572864;
    u16* HVh  = SBp + 2359296;
    u16* HVl  = SBp + 3145728;
    u16* APLh = SBp + 3932160;
    u16* APLl = SBp + 4194304;
    u16* AGMh = SBp + 4456448;
    u16* AGMl = SBp + 4718592;
    u16* AHVh = SBp + 4980736;
    u16* AHVl = SBp + 5242880;
    float* PCf = (float*)(SBp + 5505024);
    float* APC = PCf + 393216;

    // ---------------- pre-phase ----------------
    knn_kernel<<<BB * 208, 256, 0, stream>>>(opos, mpos, IDX);
    pe_kernel<<<MTOT, 256, 0, stream>>>(opos, mpos, PE);
    split_weights<<<4718592 / 256, 256, 0, stream>>>(attn_wqkv, attn_wo, ffn_w1, ffn_w2, whi, wlo);
    split_pn_weights<<<WPN_TOT / 256, 256, 0, stream>>>(
        m_pre_w1, m_pre_w2, m_pre_w3, m_mlp_w1, m_mlp_w2, m_out_w1, m_out_w2,
        a_pre_w, a_mlp_w1, a_mlp_w2, a_out_w1, a_out_w2, wpnh, wpnl);

    // ---- agent pointnet as GEMM chain
    {
        u16* PA32h = PN1h; u16* PA32l = PN1l;
        u16* PBh = PN0h;   u16* PBl = PN0l;
        u16* PA2h = PN1h;  u16* PA2l = PN1l;
        prep_agent<<<21504 * 32 / 256, 256, 0, stream>>>(obj, PA32h, PA32l);
        gemm_pn<128, true, true, false><<<dim3(168, 2), 256, 0, stream>>>(
            PA32h, PA32l, wpnh + APW_O, wpnl + APW_O, a_pre_b, nullptr, 1, 0,
            nullptr, PBh, PBl, 32, 256, 1, 0, 0);
        pool_max<21><<<1024, 256, 0, stream>>>(PBh, PBl, APLh, APLl, 8, 0);
        gemm_pn<128, false, false, false><<<dim3(8, 2), 256, 0, stream>>>(
            APLh, APLl, wpnh + AW1B_O, wpnl + AW1B_O, a_mlp_b1, nullptr, 1, 0,
            APC, nullptr, nullptr, 256, 256, 1, 0, 0);
        gemm_pn<128, true, true, false><<<dim3(168, 2), 256, 0, stream>>>(
            PBh, PBl, wpnh + AW1A_O, wpnl + AW1A_O, nullptr, APC, 21, 256,
            nullptr, PA2h, PA2l, 256, 256, 1, 0, 0);
        gemm_pn<128, true, true, false><<<dim3(168, 2), 256, 0, stream>>>(
            PA2h, PA2l, wpnh + AW2S_O, wpnl + AW2S_O, a_mlp_b2, nullptr, 1, 0,
            nullptr, PBh, PBl, 256, 256, 1, 0, 0);
        pool_max<21><<<1024, 256, 0, stream>>>(PBh, PBl, AGMh, AGMl, 8, 0);
        gemm_pn<128, true, true, false><<<dim3(8, 2), 256, 0, stream>>>(
            AGMh, AGMl, wpnh + AOW1_O, wpnl + AOW1_O, a_out_b1, nullptr, 1, 0,
            nullptr, AHVh, AHVl, 256, 256, 1, 0, 0);
        gemm_pn<128, false, false, true><<<dim3(8, 2), 256, 0, stream>>>(
            AHVh, AHVl, wpnh + AOW2_O, wpnl + AOW2_O, a_out_b2, nullptr, 1, 0,
            X, nullptr, nullptr, 256, 256, 64, 768, 0);
    }

    // ---- map pointnet as GEMM chain, two batch halves
    for (int h = 0; h < 2; h++) {
        const int hoff = h * 122880;
        u16* PM32h = PN0h; u16* PM32l = PN0l;
        prep_map<<<122880 * 32 / 256, 256, 0, stream>>>(mp, hoff, PM32h, PM32l);
        gemm_pn<64, true, true, false><<<dim3(960, 1), 256, 0, stream>>>(
            PM32h, PM32l, wpnh + W1P_O, wpnl + W1P_O, m_pre_b1, nullptr, 1, 0,
            nullptr, PN1h, PN1l, 32, 64, 1, 0, 0);
        gemm_pn<64, true, true, false><<<dim3(960, 1), 256, 0, stream>>>(
            PN1h, PN1l, wpnh + W2S_O, wpnl + W2S_O, m_pre_b2, nullptr, 1, 0,
            nullptr, PN0h, PN0l, 64, 64, 1, 0, 0);
        gemm_pn<64, true, true, false><<<dim3(960, 1), 256, 0, stream>>>(
            PN0h, PN0l, wpnh + W3S_O, wpnl + W3S_O, m_pre_b3, nullptr, 1, 0,
            nullptr, PN1h, PN1l, 64, 64, 1, 0, 0);
        pool_max<20><<<1536, 256, 0, stream>>>(PN1h, PN1l, PLh, PLl, 6, 0);
        gemm_pn<64, false, false, false><<<dim3(48, 1), 256, 0, stream>>>(
            PLh, PLl, wpnh + MW1B_O, wpnl + MW1B_O, m_mlp_b1, nullptr, 1, 0,
            PCf, nullptr, nullptr, 64, 64, 1, 0, 0);
        gemm_pn<64, true, true, false><<<dim3(960, 1), 256, 0, stream>>>(
            PN1h, PN1l, wpnh + MW1A_O, wpnl + MW1A_O, nullptr, PCf, 20, 64,
            nullptr, PN0h, PN0l, 64, 64, 1, 0, 0);
        gemm_pn<64, true, true, false><<<dim3(960, 1), 256, 0, stream>>>(
            PN0h, PN0l, wpnh + MW2S_O, wpnl + MW2S_O, m_mlp_b2, nullptr, 1, 0,
            nullptr, PN1h, PN1l, 64, 64, 1, 0, 0);
        pool_max<20><<<1536, 256, 0, stream>>>(PN1h, PN1l, GMh, GMl, 6, h * 6144);
    }
    gemm_pn<64, true, true, false><<<dim3(96, 1), 256, 0, stream>>>(
        GMh, GMl, wpnh + OW1S_O, wpnl + OW1S_O, m_out_b1, nullptr, 1, 0,
        nullptr, HVh, HVl, 64, 64, 1, 0, 0);
    gemm_pn<128, false, false, true><<<dim3(96, 2), 256, 0, stream>>>(
        HVh, HVl, wpnh + OW2S_O, wpnl + OW2S_O, m_out_b2, nullptr, 1, 0,
        X, nullptr, nullptr, 64, 256, 768, 64, 64);

    split_x0<<<(int)(M * 256 / 1024), 256, 0, stream>>>(X, PE, Xh, Xl, XPh, XPl);

    // ---------------- transformer layers ----------------
    const float scal = 0.17677669529663687f;  // 32^-0.5
    const int MB = MTOT / 128;  // 104
    const int NOA2 = 0x7fffffff;
    for (int l = 0; l < LL; l++) {
        const size_t wb = (size_t)l * 786432;
        const u16* wqkv_h = whi + wb;            const u16* wqkv_l = wlo + wb;
        const u16* wo_h   = whi + wb + 196608;   const u16* wo_l   = wlo + wb + 196608;
        const u16* f1_h   = whi + wb + 262144;   const u16* f1_l   = wlo + wb + 262144;
        const u16* f2_h   = whi + wb + 524288;   const u16* f2_l   = wlo + wb + 524288;
        const float* bqkv = attn_bqkv + (size_t)l * 768;
        gemm_mfma<false, false><<<dim3(MB, 6), 256, 0, stream>>>(
            XPh, XPl, Xh, Xl, 512, wqkv_h, wqkv_l, bqkv,
            QKV, nullptr, nullptr, 256, 768, 0, scal, 256);
        attn_kernel<<<MTOT / 2, 256, 0, stream>>>(QKV, IDX, AOh, AOl);
        gemm_ln<0><<<MTOT / 32, 512, 0, stream>>>(
            AOh, AOl, wo_h, wo_l, attn_bo + (size_t)l * 256, X,
            ln1_g + l * 256, ln1_b + l * 256,
            H, Hh, Hl, nullptr, nullptr, nullptr, 256);
        gemm_mfma<true, true><<<dim3(MB, 8), 256, 0, stream>>>(
            Hh, Hl, nullptr, nullptr, NOA2, f1_h, f1_l, ffn_b1 + (size_t)l * 1024,
            nullptr, F1h, F1l, 256, 1024, 0, 1.f, 0);
        if (l == LL - 1) {
            gemm_ln<2><<<MTOT / 32, 512, 0, stream>>>(
                F1h, F1l, f2_h, f2_l, ffn_b2 + (size_t)l * 256, H,
                ln2_g + l * 256, ln2_b + l * 256,
                (float*)d_out, nullptr, nullptr, nullptr, nullptr, nullptr, 1024);
        } else {
            gemm_ln<1><<<MTOT / 32, 512, 0, stream>>>(
                F1h, F1l, f2_h, f2_l, ffn_b2 + (size_t)l * 256, H,
                ln2_g + l * 256, ln2_b + l * 256,
                X, Xh, Xl, PE, XPh, XPl, 1024);
        }
    }
}

// Round 15
// 996.985 us; speedup vs baseline: 1.8027x; 1.3924x over previous
//
#include <hip/hip_runtime.h>
#include <hip/hip_bf16.h>

typedef unsigned short u16;
typedef _Float16 h16;

#define BB 16
#define NO 64
#define TT 21
#define NM 768
#define PP 20
#define CAx 29
#define CMx 9
#define DD 256
#define HH 8
#define LL 6
#define KK 16
#define NN (NO + NM)        // 832
#define HDX (DD / HH)       // 32
#define MTOT (BB * NN)      // 13312

typedef __attribute__((ext_vector_type(8))) h16 h8v;    // 8 fp16 in 4 VGPRs
typedef __attribute__((ext_vector_type(4))) h16 h4v;
typedef __attribute__((ext_vector_type(4))) float f4v;

#define GLOAD_LDS16(gptr, lptr)                                                             \
    __builtin_amdgcn_global_load_lds(                                                       \
        (const __attribute__((address_space(1))) void*)(gptr),                              \
        (__attribute__((address_space(3))) void*)(lptr), 16, 0, 0)

// Bank-conflict swizzle for [rows][32]-fp16 linear tiles (gload_lds-compatible):
// physical 16B slot s_phys at row R holds logical k-slot s_phys ^ ((R>>1)&3).
#define SWZ_LCOL(lane)   ((((lane) & 3) ^ (((lane) >> 3) & 3)) * 8)
#define SWZ_RD(kb, fr)   ((((kb) ^ (((fr) >> 1) & 3))) * 8)

// ---------------------------------------------------------------- KNN (top-16 smallest d2)
__global__ __launch_bounds__(256) void knn_kernel(
    const float* __restrict__ opos, const float* __restrict__ mpos, int* __restrict__ IDX)
{
    const int b = blockIdx.x / 208;
    const int blk = blockIdx.x % 208;
    __shared__ float px[NN], py[NN], pz[NN];
    for (int i = threadIdx.x; i < NN; i += 256) {
        const float* src = (i < NO) ? &opos[(size_t)(b * NO + i) * 3]
                                    : &mpos[(size_t)(b * NM + (i - NO)) * 3];
        px[i] = src[0]; py[i] = src[1]; pz[i] = src[2];
    }
    __syncthreads();
    const int wave = threadIdx.x >> 6, lane = threadIdx.x & 63;
    const int n = blk * 4 + wave;
    const float qx = px[n], qy = py[n], qz = pz[n];
    float d[13];
    #pragma unroll
    for (int s = 0; s < 13; s++) {
        int j = s * 64 + lane;
        float dx = qx - px[j], dy = qy - py[j], dz = qz - pz[j];
        d[s] = dx * dx + dy * dy + dz * dz;
    }
    int keep = 0;
    #pragma unroll
    for (int it = 0; it < 16; it++) {
        float bv = d[0]; int bs = 0;
        #pragma unroll
        for (int s = 1; s < 13; s++) { if (d[s] < bv) { bv = d[s]; bs = s; } }
        float v = bv; int jj = bs * 64 + lane;
        #pragma unroll
        for (int off = 32; off; off >>= 1) {
            float ov = __shfl_xor(v, off);
            int oj = __shfl_xor(jj, off);
            if (ov < v || (ov == v && oj < jj)) { v = ov; jj = oj; }
        }
        if (lane == (jj & 63)) {
            int sl = jj >> 6;
            #pragma unroll
            for (int s = 0; s < 13; s++) if (s == sl) d[s] = 3.4e38f;
        }
        if (lane == it) keep = jj;
    }
    if (lane < 16) IDX[((size_t)(b * NN + n)) * 16 + lane] = keep;
}

// ---------------------------------------------------------------- sine positional embedding
__global__ __launch_bounds__(256) void pe_kernel(
    const float* __restrict__ opos, const float* __restrict__ mpos, float* __restrict__ PE)
{
    const int row = blockIdx.x;            // b*NN + n
    const int b = row / NN, n = row % NN;
    const int c = threadIdx.x;
    const float* p = (n < NO) ? &opos[(size_t)(b * NO + n) * 3]
                              : &mpos[(size_t)(b * NM + (n - NO)) * 3];
    float x = p[0], y = p[1];
    int j = c & 127;
    float v = (c < 128) ? y : x;
    float inv_dt = exp2f(-(float)(j & ~1) * 0.10381025296523f);
    float e = v * 6.283185307179586f * inv_dt;
    PE[(size_t)row * DD + c] = (j & 1) ? cosf(e) : sinf(e);
}

// ---------------------------------------------------------------- transformer weight cvt->fp16
__global__ __launch_bounds__(256) void cvt_weights(
    const float* __restrict__ wqkv, const float* __restrict__ wo,
    const float* __restrict__ f1w, const float* __restrict__ f2w,
    h16* __restrict__ whf)
{
    size_t e = (size_t)blockIdx.x * 256 + threadIdx.x;
    int L = (int)(e / 786432);
    int r = (int)(e % 786432);
    float v;
    if (r < 196608)      v = wqkv[(size_t)L * 196608 + r];
    else if (r < 262144) v = wo[(size_t)L * 65536 + (r - 196608)];
    else if (r < 524288) v = f1w[(size_t)L * 262144 + (r - 262144)];
    else                 v = f2w[(size_t)L * 262144 + (r - 524288)];
    whf[e] = (h16)v;
}

// ---------------------------------------------------------------- pointnet weight cvt (packed)
#define W1P_O   0
#define W2S_O   2048
#define W3S_O   6144
#define MW1A_O  10240
#define MW1B_O  14336
#define MW2S_O  18432
#define OW1S_O  22528
#define OW2S_O  26624
#define APW_O   43008
#define AW1A_O  51200
#define AW1B_O  116736
#define AW2S_O  182272
#define AOW1_O  247808
#define AOW2_O  313344
#define WPN_TOT 378880
__global__ __launch_bounds__(256) void cvt_pn_weights(
    const float* __restrict__ m_pre_w1, const float* __restrict__ m_pre_w2,
    const float* __restrict__ m_pre_w3, const float* __restrict__ m_mlp_w1,
    const float* __restrict__ m_mlp_w2, const float* __restrict__ m_out_w1,
    const float* __restrict__ m_out_w2,
    const float* __restrict__ a_pre_w,  const float* __restrict__ a_mlp_w1,
    const float* __restrict__ a_mlp_w2, const float* __restrict__ a_out_w1,
    const float* __restrict__ a_out_w2,
    h16* __restrict__ wpnf)
{
    int e = blockIdx.x * 256 + threadIdx.x;
    float v;
    if (e < W2S_O)       { int n = e >> 5, k = e & 31; v = (k < 9) ? m_pre_w1[n * 9 + k] : 0.f; }
    else if (e < W3S_O)  v = m_pre_w2[e - W2S_O];
    else if (e < MW1A_O) v = m_pre_w3[e - W3S_O];
    else if (e < MW1B_O) { int r = e - MW1A_O; v = m_mlp_w1[(r >> 6) * 128 + (r & 63)]; }
    else if (e < MW2S_O) { int r = e - MW1B_O; v = m_mlp_w1[(r >> 6) * 128 + 64 + (r & 63)]; }
    else if (e < OW1S_O) v = m_mlp_w2[e - MW2S_O];
    else if (e < OW2S_O) v = m_out_w1[e - OW1S_O];
    else if (e < APW_O)  v = m_out_w2[e - OW2S_O];
    else if (e < AW1A_O) { int r = e - APW_O; int n = r >> 5, k = r & 31; v = (k < 30) ? a_pre_w[n * 30 + k] : 0.f; }
    else if (e < AW1B_O) { int r = e - AW1A_O; v = a_mlp_w1[(r >> 8) * 512 + (r & 255)]; }
    else if (e < AW2S_O) { int r = e - AW1B_O; v = a_mlp_w1[(r >> 8) * 512 + 256 + (r & 255)]; }
    else if (e < AOW1_O) v = a_mlp_w2[e - AW2S_O];
    else if (e < AOW2_O) v = a_out_w1[e - AOW1_O];
    else                 v = a_out_w2[e - AOW2_O];
    wpnf[e] = (h16)v;
}

// ---------------------------------------------------------------- pointnet input prep (pad + cvt)
__global__ __launch_bounds__(256) void prep_map(
    const float* __restrict__ mp, int hoff, h16* __restrict__ pa)
{
    int e = blockIdx.x * 256 + threadIdx.x;
    int r = e >> 5, c = e & 31;
    float v = (c < CMx) ? mp[(size_t)(hoff + r) * CMx + c] : 0.f;
    pa[e] = (h16)v;
}
__global__ __launch_bounds__(256) void prep_agent(
    const float* __restrict__ obj, h16* __restrict__ pa)
{
    int e = blockIdx.x * 256 + threadIdx.x;
    int r = e >> 5, c = e & 31;
    float v = (c < CAx) ? obj[(size_t)r * CAx + c] : ((c == CAx) ? 1.0f : 0.f);
    pa[e] = (h16)v;
}

// ---------------------------------------------------------------- max-pool over P points
template<int P>
__global__ __launch_bounds__(256) void pool_max(
    const h16* __restrict__ in, h16* __restrict__ out, int cshift, int gout_off)
{
    int e = blockIdx.x * 256 + threadIdx.x;
    int C = 1 << cshift;
    int g = e >> cshift, c = e & (C - 1);
    float m = -3.4e38f;
    #pragma unroll
    for (int p = 0; p < P; p++) {
        float v = (float)in[(size_t)(g * P + p) * C + c];
        m = fmaxf(m, v);
    }
    out[(size_t)(gout_off + g) * C + c] = (h16)m;
}

// ---------------------------------------------------------------- pointnet GEMM (fp16 MFMA)
template<int BN, bool RELU, bool F16OUT, bool ROWMAP>
__global__ __launch_bounds__(256) void gemm_pn(
    const h16* __restrict__ A, const h16* __restrict__ W,
    const float* __restrict__ bias,
    const float* __restrict__ addrow, int ardiv, int arld,
    float* __restrict__ Cf, h16* __restrict__ C16,
    int K, int ldc, int rm_div, int rm_mul, int rm_add)
{
    constexpr int WAVES_M = (BN == 64) ? 4 : 2;
    constexpr int WM = 128 / (16 * WAVES_M);
    __shared__ __align__(16) h16 AS[128][32];
    __shared__ __align__(16) h16 WS[BN][32];
    const int m0 = blockIdx.x * 128;
    const int n0 = blockIdx.y * BN;
    const int tid = threadIdx.x;
    const int wave = tid >> 6, lane = tid & 63;
    const int wr = (BN == 64) ? wave : (wave >> 1);
    const int wc = (BN == 64) ? 0 : (wave & 1);
    const int fr = lane & 15, kb = lane >> 4;
    const int lrow = lane >> 2, lcol = SWZ_LCOL(lane);
    const int rdo = SWZ_RD(kb, fr);

    f4v acc[WM][4];
    #pragma unroll
    for (int i = 0; i < WM; i++)
        #pragma unroll
        for (int j = 0; j < 4; j++) { f4v z = {0.f, 0.f, 0.f, 0.f}; acc[i][j] = z; }

    for (int k0 = 0; k0 < K; k0 += 32) {
        __syncthreads();
        #pragma unroll
        for (int i = 0; i < 2; i++) {
            const int r = wave * 32 + i * 16;
            GLOAD_LDS16(&A[(size_t)(m0 + r + lrow) * K + k0 + lcol], &AS[r][0]);
        }
        if constexpr (BN == 64) {
            const int r = wave * 16;
            GLOAD_LDS16(&W[(size_t)(n0 + r + lrow) * K + k0 + lcol], &WS[r][0]);
        } else {
            #pragma unroll
            for (int i = 0; i < 2; i++) {
                const int r = wave * 32 + i * 16;
                GLOAD_LDS16(&W[(size_t)(n0 + r + lrow) * K + k0 + lcol], &WS[r][0]);
            }
        }
        __syncthreads();
        h8v af[WM];
        #pragma unroll
        for (int mi = 0; mi < WM; mi++)
            af[mi] = *(const h8v*)&AS[wr * (WM * 16) + mi * 16 + fr][rdo];
        #pragma unroll
        for (int nj = 0; nj < 4; nj++) {
            h8v bf = *(const h8v*)&WS[wc * 64 + nj * 16 + fr][rdo];
            #pragma unroll
            for (int mi = 0; mi < WM; mi++)
                acc[mi][nj] = __builtin_amdgcn_mfma_f32_16x16x32_f16(af[mi], bf, acc[mi][nj], 0, 0, 0);
        }
    }
    #pragma unroll
    for (int mi = 0; mi < WM; mi++) {
        #pragma unroll
        for (int nj = 0; nj < 4; nj++) {
            int col = n0 + wc * 64 + nj * 16 + fr;
            float bb = bias ? bias[col] : 0.f;
            #pragma unroll
            for (int r = 0; r < 4; r++) {
                int row = m0 + wr * (WM * 16) + mi * 16 + (lane >> 4) * 4 + r;
                float v = acc[mi][nj][r] + bb;
                if (addrow) v += addrow[(size_t)(row / ardiv) * arld + col];
                if (RELU) v = fmaxf(v, 0.f);
                if (F16OUT) {
                    C16[(size_t)row * ldc + col] = (h16)v;
                } else {
                    int drow = row;
                    if (ROWMAP) drow = row + rm_add + (row / rm_div) * rm_mul;
                    Cf[(size_t)drow * ldc + col] = v;
                }
            }
        }
    }
}

// ---------------------------------------------------------------- initial activation cvt
__global__ __launch_bounds__(256) void split_x0(
    const float* __restrict__ X, const float* __restrict__ PE,
    h16* __restrict__ X16, h16* __restrict__ XP16)
{
    size_t base = ((size_t)blockIdx.x * 256 + threadIdx.x) * 4;
    float4 x = *(const float4*)&X[base];
    float4 p = *(const float4*)&PE[base];
    h4v a, b;
    a.x = (h16)x.x; a.y = (h16)x.y; a.z = (h16)x.z; a.w = (h16)x.w;
    b.x = (h16)(x.x + p.x); b.y = (h16)(x.y + p.y);
    b.z = (h16)(x.z + p.z); b.w = (h16)(x.w + p.w);
    *(h4v*)&X16[base] = a;
    *(h4v*)&XP16[base] = b;
}

// ---------------------------------------------------------------- transformer fp16 MFMA GEMM
template<bool RELU, bool F16OUT>
__global__ __launch_bounds__(256) void gemm_mfma(
    const h16* __restrict__ A, const h16* __restrict__ A2, int a2min,
    const h16* __restrict__ W, const float* __restrict__ bias,
    float* __restrict__ Cf, h16* __restrict__ C16,
    int K, int ldc, int coff, float scale, int scale_until)
{
    __shared__ __align__(16) h16 AS[128][32];
    __shared__ __align__(16) h16 WS[128][32];
    const int m0 = blockIdx.x * 128;
    const int n0 = blockIdx.y * 128;
    const h16* pA = (n0 >= a2min) ? A2 : A;
    const int tid = threadIdx.x;
    const int wave = tid >> 6, lane = tid & 63;
    const int wr = wave >> 1, wc = wave & 1;
    const int fr = lane & 15, kb = lane >> 4;
    const int lrow = lane >> 2;
    const int lcol = SWZ_LCOL(lane);
    const int rdo = SWZ_RD(kb, fr);

    f4v acc[4][4];
    #pragma unroll
    for (int i = 0; i < 4; i++)
        #pragma unroll
        for (int j = 0; j < 4; j++) { f4v z = {0.f, 0.f, 0.f, 0.f}; acc[i][j] = z; }

    for (int k0 = 0; k0 < K; k0 += 32) {
        __syncthreads();
        #pragma unroll
        for (int i = 0; i < 2; i++) {
            const int r = wave * 32 + i * 16;
            const size_t grow = (size_t)(r + lrow);
            GLOAD_LDS16(&pA[(m0 + grow) * K + k0 + lcol], &AS[r][0]);
            GLOAD_LDS16(&W [(n0 + grow) * K + k0 + lcol], &WS[r][0]);
        }
        __syncthreads();
        h8v af[4];
        #pragma unroll
        for (int mi = 0; mi < 4; mi++)
            af[mi] = *(const h8v*)&AS[wr * 64 + mi * 16 + fr][rdo];
        #pragma unroll
        for (int nj = 0; nj < 4; nj++) {
            h8v bf = *(const h8v*)&WS[wc * 64 + nj * 16 + fr][rdo];
            #pragma unroll
            for (int mi = 0; mi < 4; mi++)
                acc[mi][nj] = __builtin_amdgcn_mfma_f32_16x16x32_f16(af[mi], bf, acc[mi][nj], 0, 0, 0);
        }
    }
    #pragma unroll
    for (int mi = 0; mi < 4; mi++) {
        #pragma unroll
        for (int nj = 0; nj < 4; nj++) {
            int col = n0 + wc * 64 + nj * 16 + fr;
            float bb = bias[col];
            #pragma unroll
            for (int r = 0; r < 4; r++) {
                int row = m0 + wr * 64 + mi * 16 + (lane >> 4) * 4 + r;
                float v = acc[mi][nj][r] + bb;
                if (RELU) v = fmaxf(v, 0.f);
                if (F16OUT) {
                    C16[(size_t)row * ldc + col] = (h16)v;
                } else {
                    int gcol = coff + col;
                    if (gcol < scale_until) v *= scale;
                    Cf[(size_t)row * ldc + gcol] = v;
                }
            }
        }
    }
}

// ---------------------------------------------------------------- GEMM + residual + LayerNorm fused
// tile 32 rows x 256 cols, 8 waves (512 thr): wave w owns cols [w*32, w*32+32).
template<int PEMODE>
__global__ __launch_bounds__(512) void gemm_ln(
    const h16* __restrict__ A, const h16* __restrict__ W,
    const float* __restrict__ bias, const float* __restrict__ R1,
    const float* __restrict__ g, const float* __restrict__ bt,
    float* __restrict__ OutF, h16* __restrict__ O16,
    const float* __restrict__ PEp, h16* __restrict__ P16,
    int K)
{
    __shared__ __align__(16) h16 AS[32][32];
    __shared__ __align__(16) h16 WS[256][32];
    __shared__ float red_s[2][8][32];
    const int m0 = blockIdx.x * 32;
    const int tid = threadIdx.x;
    const int wave = tid >> 6, lane = tid & 63;
    const int fr = lane & 15, kb = lane >> 4;
    const int lrow = lane >> 2, lcol = SWZ_LCOL(lane);
    const int rdo = SWZ_RD(kb, fr);

    f4v acc[2][2];
    #pragma unroll
    for (int i = 0; i < 2; i++)
        #pragma unroll
        for (int j = 0; j < 2; j++) { f4v z = {0.f, 0.f, 0.f, 0.f}; acc[i][j] = z; }

    for (int k0 = 0; k0 < K; k0 += 32) {
        __syncthreads();
        if (wave < 2) {
            GLOAD_LDS16(&A[(size_t)(m0 + wave * 16 + lrow) * K + k0 + lcol], &AS[wave * 16][0]);
        }
        #pragma unroll
        for (int i = 0; i < 2; i++) {
            const int r = wave * 32 + i * 16;
            GLOAD_LDS16(&W[(size_t)(r + lrow) * K + k0 + lcol], &WS[r][0]);
        }
        __syncthreads();
        h8v af[2];
        #pragma unroll
        for (int mi = 0; mi < 2; mi++)
            af[mi] = *(const h8v*)&AS[mi * 16 + fr][rdo];
        #pragma unroll
        for (int nj = 0; nj < 2; nj++) {
            h8v bf = *(const h8v*)&WS[wave * 32 + nj * 16 + fr][rdo];
            #pragma unroll
            for (int mi = 0; mi < 2; mi++)
                acc[mi][nj] = __builtin_amdgcn_mfma_f32_16x16x32_f16(af[mi], bf, acc[mi][nj], 0, 0, 0);
        }
    }
    // ---- epilogue: x = R1 + (acc + bias); block-local LN over 256 cols
    float x[2][2][4];
    float rsum[2][4], rsq[2][4];
    #pragma unroll
    for (int mi = 0; mi < 2; mi++)
        #pragma unroll
        for (int r = 0; r < 4; r++) { rsum[mi][r] = 0.f; rsq[mi][r] = 0.f; }
    #pragma unroll
    for (int mi = 0; mi < 2; mi++) {
        #pragma unroll
        for (int nj = 0; nj < 2; nj++) {
            int col = wave * 32 + nj * 16 + fr;
            float bb = bias[col];
            #pragma unroll
            for (int r = 0; r < 4; r++) {
                int row = m0 + mi * 16 + kb * 4 + r;
                float v = acc[mi][nj][r] + bb + R1[(size_t)row * 256 + col];
                x[mi][nj][r] = v;
                rsum[mi][r] += v;
                rsq[mi][r] += v * v;
            }
        }
    }
    #pragma unroll
    for (int off = 1; off < 16; off <<= 1) {
        #pragma unroll
        for (int mi = 0; mi < 2; mi++)
            #pragma unroll
            for (int r = 0; r < 4; r++) {
                rsum[mi][r] += __shfl_xor(rsum[mi][r], off);
                rsq[mi][r]  += __shfl_xor(rsq[mi][r], off);
            }
    }
    if (fr == 0) {
        #pragma unroll
        for (int mi = 0; mi < 2; mi++)
            #pragma unroll
            for (int r = 0; r < 4; r++) {
                int rid = mi * 16 + kb * 4 + r;
                red_s[0][wave][rid] = rsum[mi][r];
                red_s[1][wave][rid] = rsq[mi][r];
            }
    }
    __syncthreads();
    #pragma unroll
    for (int mi = 0; mi < 2; mi++) {
        #pragma unroll
        for (int r = 0; r < 4; r++) {
            int rid = mi * 16 + kb * 4 + r;
            float s = 0.f, sq = 0.f;
            #pragma unroll
            for (int w = 0; w < 8; w++) { s += red_s[0][w][rid]; sq += red_s[1][w][rid]; }
            float mean = s * (1.f / 256.f);
            float var = sq * (1.f / 256.f) - mean * mean;
            float inv = rsqrtf(var + 1e-5f);
            #pragma unroll
            for (int nj = 0; nj < 2; nj++) {
                int col = wave * 32 + nj * 16 + fr;
                float o = (x[mi][nj][r] - mean) * inv * g[col] + bt[col];
                size_t idx = (size_t)(m0 + rid) * 256 + col;
                OutF[idx] = o;
                if (PEMODE == 0 || PEMODE == 1) O16[idx] = (h16)o;
                if (PEMODE == 1) P16[idx] = (h16)(o + PEp[idx]);
            }
        }
    }
}

// ---------------------------------------------------------------- local KNN attention
// XCD-affinity swizzle + LDS-staged K gather
__global__ __launch_bounds__(256) void attn_kernel(
    const float* __restrict__ QKV, const int* __restrict__ IDX,
    h16* __restrict__ AO16)
{
    __shared__ __align__(16) float Ks[32][260];   // 32 slices, +4 pad
    __shared__ float p_s[2][HH][16];
    __shared__ int gid_s[2][16];
    const int sub = threadIdx.x >> 7;
    const int t = threadIdx.x & 127;
    const int wave = threadIdx.x >> 6, lane = threadIdx.x & 63;
    const int xcd = blockIdx.x & 7;
    const int j = blockIdx.x >> 3;            // 0..831
    const int b = (j / 416) * 8 + xcd;        // batch
    const int row = b * NN + (j % 416) * 2 + sub;
    const int h = t >> 4, k = t & 15;
    int nb = IDX[(size_t)row * 16 + k];
    int g = b * NN + nb;
    if (h == 0) gid_s[sub][k] = g;
    __syncthreads();
    #pragma unroll
    for (int i = 0; i < 8; i++) {
        int s = wave * 8 + i;
        int gs = gid_s[s >> 4][s & 15];
        GLOAD_LDS16(&QKV[(size_t)gs * 768 + 256 + lane * 4], &Ks[s][0]);
    }
    __syncthreads();
    const float* q = &QKV[(size_t)row * 768 + h * HDX];
    const float* kr = &Ks[sub * 16 + k][h * HDX];
    float s = 0.f;
    #pragma unroll
    for (int d = 0; d < HDX; d += 4) {
        float4 q4 = *(const float4*)&q[d];
        float4 k4 = *(const float4*)&kr[d];
        s += q4.x * k4.x + q4.y * k4.y + q4.z * k4.z + q4.w * k4.w;
    }
    float m = s;
    #pragma unroll
    for (int off = 8; off; off >>= 1) m = fmaxf(m, __shfl_xor(m, off, 16));
    float e = expf(s - m);
    float sum = e;
    #pragma unroll
    for (int off = 8; off; off >>= 1) sum += __shfl_xor(sum, off, 16);
    p_s[sub][h][k] = e / sum;
    __syncthreads();
    const int d0 = t * 2;
    const int hh = d0 >> 5, dd = d0 & 31;
    float o0 = 0.f, o1 = 0.f;
    #pragma unroll
    for (int kk = 0; kk < 16; kk++) {
        int gg = gid_s[sub][kk];
        const float* vr = &QKV[(size_t)gg * 768 + 512 + hh * HDX + dd];
        float p = p_s[sub][hh][kk];
        o0 += p * vr[0];
        o1 += p * vr[1];
    }
    size_t base = (size_t)row * DD + d0;
    AO16[base] = (h16)o0;
    AO16[base + 1] = (h16)o1;
}

// ----------------------------------------------------------------
extern "C" void kernel_launch(void* const* d_in, const int* in_sizes, int n_in,
                              void* d_out, int out_size, void* d_ws, size_t ws_size,
                              hipStream_t stream)
{
    const float* obj      = (const float*)d_in[0];
    const float* mp       = (const float*)d_in[1];
    const float* opos     = (const float*)d_in[2];
    const float* mpos     = (const float*)d_in[3];
    const float* a_pre_w  = (const float*)d_in[4];
    const float* a_pre_b  = (const float*)d_in[5];
    const float* a_mlp_w1 = (const float*)d_in[6];
    const float* a_mlp_b1 = (const float*)d_in[7];
    const float* a_mlp_w2 = (const float*)d_in[8];
    const float* a_mlp_b2 = (const float*)d_in[9];
    const float* a_out_w1 = (const float*)d_in[10];
    const float* a_out_b1 = (const float*)d_in[11];
    const float* a_out_w2 = (const float*)d_in[12];
    const float* a_out_b2 = (const float*)d_in[13];
    const float* m_pre_w1 = (const float*)d_in[14];
    const float* m_pre_b1 = (const float*)d_in[15];
    const float* m_pre_w2 = (const float*)d_in[16];
    const float* m_pre_b2 = (const float*)d_in[17];
    const float* m_pre_w3 = (const float*)d_in[18];
    const float* m_pre_b3 = (const float*)d_in[19];
    const float* m_mlp_w1 = (const float*)d_in[20];
    const float* m_mlp_b1 = (const float*)d_in[21];
    const float* m_mlp_w2 = (const float*)d_in[22];
    const float* m_mlp_b2 = (const float*)d_in[23];
    const float* m_out_w1 = (const float*)d_in[24];
    const float* m_out_b1 = (const float*)d_in[25];
    const float* m_out_w2 = (const float*)d_in[26];
    const float* m_out_b2 = (const float*)d_in[27];
    const float* attn_wqkv = (const float*)d_in[28];
    const float* attn_bqkv = (const float*)d_in[29];
    const float* attn_wo   = (const float*)d_in[30];
    const float* attn_bo   = (const float*)d_in[31];
    const float* ffn_w1    = (const float*)d_in[32];
    const float* ffn_b1    = (const float*)d_in[33];
    const float* ffn_w2    = (const float*)d_in[34];
    const float* ffn_b2    = (const float*)d_in[35];
    const float* ln1_g     = (const float*)d_in[36];
    const float* ln1_b     = (const float*)d_in[37];
    const float* ln2_g     = (const float*)d_in[38];
    const float* ln2_b     = (const float*)d_in[39];

    const size_t M = MTOT;  // 13312
    float* ws   = (float*)d_ws;
    float* X    = ws;                 // M*256 f32
    float* PE   = X   + M * 256;      // M*256 f32
    float* QKV  = PE  + M * 256;      // M*768 f32  (aliased: pointnet bufs, F116)
    float* H    = QKV + M * 768;      // M*256 f32  (aliased: small pointnet bufs)
    h16* AO16   = (h16*)(H + M * 256);   // M*256 fp16
    h16* X16    = AO16 + M * 256;
    h16* XP16   = X16  + M * 256;
    h16* H16    = XP16 + M * 256;
    h16* whf    = H16  + M * 256;     // 4,718,592 fp16
    h16* wpnf   = whf  + 4718592;     // WPN_TOT fp16
    int* IDX    = (int*)(wpnf + WPN_TOT);
    // total ~120 MB (< 165 MB proven in R3)

    h16* F116 = (h16*)QKV;            // M*1024 fp16 over QKV (dead after attn)

    // pointnet-phase aliases
    h16* PN0f = (h16*)QKV;            // 7,864,320 fp16
    h16* PN1f = PN0f + 7864320;
    h16* SB   = (h16*)H;
    h16* PLf  = SB;                   // 6144*64
    h16* GMf  = SB + 393216;          // 12288*64
    h16* HVf  = SB + 1179648;         // 12288*64
    h16* APLf = SB + 1966080;         // 1024*256
    h16* AGMf = SB + 2228224;
    h16* AHVf = SB + 2490368;
    float* PCf = (float*)(SB + 2752512);  // 6144*64 f32
    float* APC = PCf + 393216;            // 1024*256 f32

    // ---------------- pre-phase ----------------
    knn_kernel<<<BB * 208, 256, 0, stream>>>(opos, mpos, IDX);
    pe_kernel<<<MTOT, 256, 0, stream>>>(opos, mpos, PE);
    cvt_weights<<<4718592 / 256, 256, 0, stream>>>(attn_wqkv, attn_wo, ffn_w1, ffn_w2, whf);
    cvt_pn_weights<<<WPN_TOT / 256, 256, 0, stream>>>(
        m_pre_w1, m_pre_w2, m_pre_w3, m_mlp_w1, m_mlp_w2, m_out_w1, m_out_w2,
        a_pre_w, a_mlp_w1, a_mlp_w2, a_out_w1, a_out_w2, wpnf);

    // ---- agent pointnet as GEMM chain
    {
        h16* PA32 = PN1f;
        h16* PB   = PN0f;
        h16* PA2  = PN1f;
        prep_agent<<<21504 * 32 / 256, 256, 0, stream>>>(obj, PA32);
        gemm_pn<128, true, true, false><<<dim3(168, 2), 256, 0, stream>>>(
            PA32, wpnf + APW_O, a_pre_b, nullptr, 1, 0,
            nullptr, PB, 32, 256, 1, 0, 0);
        pool_max<21><<<1024, 256, 0, stream>>>(PB, APLf, 8, 0);
        gemm_pn<128, false, false, false><<<dim3(8, 2), 256, 0, stream>>>(
            APLf, wpnf + AW1B_O, a_mlp_b1, nullptr, 1, 0,
            APC, nullptr, 256, 256, 1, 0, 0);
        gemm_pn<128, true, true, false><<<dim3(168, 2), 256, 0, stream>>>(
            PB, wpnf + AW1A_O, nullptr, APC, 21, 256,
            nullptr, PA2, 256, 256, 1, 0, 0);
        gemm_pn<128, true, true, false><<<dim3(168, 2), 256, 0, stream>>>(
            PA2, wpnf + AW2S_O, a_mlp_b2, nullptr, 1, 0,
            nullptr, PB, 256, 256, 1, 0, 0);
        pool_max<21><<<1024, 256, 0, stream>>>(PB, AGMf, 8, 0);
        gemm_pn<128, true, true, false><<<dim3(8, 2), 256, 0, stream>>>(
            AGMf, wpnf + AOW1_O, a_out_b1, nullptr, 1, 0,
            nullptr, AHVf, 256, 256, 1, 0, 0);
        gemm_pn<128, false, false, true><<<dim3(8, 2), 256, 0, stream>>>(
            AHVf, wpnf + AOW2_O, a_out_b2, nullptr, 1, 0,
            X, nullptr, 256, 256, 64, 768, 0);
    }

    // ---- map pointnet as GEMM chain, two batch halves
    for (int h = 0; h < 2; h++) {
        const int hoff = h * 122880;
        prep_map<<<122880 * 32 / 256, 256, 0, stream>>>(mp, hoff, PN0f);
        gemm_pn<64, true, true, false><<<dim3(960, 1), 256, 0, stream>>>(
            PN0f, wpnf + W1P_O, m_pre_b1, nullptr, 1, 0,
            nullptr, PN1f, 32, 64, 1, 0, 0);
        gemm_pn<64, true, true, false><<<dim3(960, 1), 256, 0, stream>>>(
            PN1f, wpnf + W2S_O, m_pre_b2, nullptr, 1, 0,
            nullptr, PN0f, 64, 64, 1, 0, 0);
        gemm_pn<64, true, true, false><<<dim3(960, 1), 256, 0, stream>>>(
            PN0f, wpnf + W3S_O, m_pre_b3, nullptr, 1, 0,
            nullptr, PN1f, 64, 64, 1, 0, 0);
        pool_max<20><<<1536, 256, 0, stream>>>(PN1f, PLf, 6, 0);
        gemm_pn<64, false, false, false><<<dim3(48, 1), 256, 0, stream>>>(
            PLf, wpnf + MW1B_O, m_mlp_b1, nullptr, 1, 0,
            PCf, nullptr, 64, 64, 1, 0, 0);
        gemm_pn<64, true, true, false><<<dim3(960, 1), 256, 0, stream>>>(
            PN1f, wpnf + MW1A_O, nullptr, PCf, 20, 64,
            nullptr, PN0f, 64, 64, 1, 0, 0);
        gemm_pn<64, true, true, false><<<dim3(960, 1), 256, 0, stream>>>(
            PN0f, wpnf + MW2S_O, m_mlp_b2, nullptr, 1, 0,
            nullptr, PN1f, 64, 64, 1, 0, 0);
        pool_max<20><<<1536, 256, 0, stream>>>(PN1f, GMf, 6, h * 6144);
    }
    gemm_pn<64, true, true, false><<<dim3(96, 1), 256, 0, stream>>>(
        GMf, wpnf + OW1S_O, m_out_b1, nullptr, 1, 0,
        nullptr, HVf, 64, 64, 1, 0, 0);
    gemm_pn<128, false, false, true><<<dim3(96, 2), 256, 0, stream>>>(
        HVf, wpnf + OW2S_O, m_out_b2, nullptr, 1, 0,
        X, nullptr, 64, 256, 768, 64, 64);

    split_x0<<<(int)(M * 256 / 1024), 256, 0, stream>>>(X, PE, X16, XP16);

    // ---------------- transformer layers ----------------
    const float scal = 0.17677669529663687f;  // 32^-0.5
    const int MB = MTOT / 128;  // 104
    const int NOA2 = 0x7fffffff;
    for (int l = 0; l < LL; l++) {
        const size_t wb = (size_t)l * 786432;
        const h16* wqkv_f = whf + wb;
        const h16* wo_f   = whf + wb + 196608;
        const h16* f1_f   = whf + wb + 262144;
        const h16* f2_f   = whf + wb + 524288;
        const float* bqkv = attn_bqkv + (size_t)l * 768;
        // QKV (merged): cols [0,512) read XP16, cols [512,768) read X16
        gemm_mfma<false, false><<<dim3(MB, 6), 256, 0, stream>>>(
            XP16, X16, 512, wqkv_f, bqkv,
            QKV, nullptr, 256, 768, 0, scal, 256);
        attn_kernel<<<MTOT / 2, 256, 0, stream>>>(QKV, IDX, AO16);
        // O-proj + residual(X) + ln1 -> H, H16
        gemm_ln<0><<<MTOT / 32, 512, 0, stream>>>(
            AO16, wo_f, attn_bo + (size_t)l * 256, X,
            ln1_g + l * 256, ln1_b + l * 256,
            H, H16, nullptr, nullptr, 256);
        // FFN1 (relu) -> F116 (over dead QKV)
        gemm_mfma<true, true><<<dim3(MB, 8), 256, 0, stream>>>(
            H16, nullptr, NOA2, f1_f, ffn_b1 + (size_t)l * 1024,
            nullptr, F116, 256, 1024, 0, 1.f, 0);
        // FFN2 + residual(H) + ln2 -> X (+cvt) or d_out
        if (l == LL - 1) {
            gemm_ln<2><<<MTOT / 32, 512, 0, stream>>>(
                F116, f2_f, ffn_b2 + (size_t)l * 256, H,
                ln2_g + l * 256, ln2_b + l * 256,
                (float*)d_out, nullptr, nullptr, nullptr, 1024);
        } else {
            gemm_ln<1><<<MTOT / 32, 512, 0, stream>>>(
                F116, f2_f, ffn_b2 + (size_t)l * 256, H,
                ln2_g + l * 256, ln2_b + l * 256,
                X, X16, PE, XP16, 1024);
        }
    }
}

// Round 16
// 862.050 us; speedup vs baseline: 2.0848x; 1.1565x over previous
//
#include <hip/hip_runtime.h>
#include <hip/hip_bf16.h>

typedef unsigned short u16;
typedef _Float16 h16;

#define BB 16
#define NO 64
#define TT 21
#define NM 768
#define PP 20
#define CAx 29
#define CMx 9
#define DD 256
#define HH 8
#define LL 6
#define KK 16
#define NN (NO + NM)        // 832
#define HDX (DD / HH)       // 32
#define MTOT (BB * NN)      // 13312
#define MAPR (BB * NM * PP) // 245760 map point-rows

typedef __attribute__((ext_vector_type(8))) h16 h8v;    // 8 fp16 in 4 VGPRs
typedef __attribute__((ext_vector_type(4))) h16 h4v;
typedef __attribute__((ext_vector_type(4))) float f4v;

#define GLOAD_LDS16(gptr, lptr)                                                             \
    __builtin_amdgcn_global_load_lds(                                                       \
        (const __attribute__((address_space(1))) void*)(gptr),                              \
        (__attribute__((address_space(3))) void*)(lptr), 16, 0, 0)

// Bank-conflict swizzle for [rows][32]-fp16 linear tiles (gload_lds-compatible):
// physical 16B slot s_phys at row R holds logical k-slot s_phys ^ ((R>>1)&3).
#define SWZ_LCOL(lane)   ((((lane) & 3) ^ (((lane) >> 3) & 3)) * 8)
#define SWZ_RD(kb, fr)   ((((kb) ^ (((fr) >> 1) & 3))) * 8)

// ---------------------------------------------------------------- KNN (top-16 smallest d2)
__global__ __launch_bounds__(256) void knn_kernel(
    const float* __restrict__ opos, const float* __restrict__ mpos, int* __restrict__ IDX)
{
    const int b = blockIdx.x / 208;
    const int blk = blockIdx.x % 208;
    __shared__ float px[NN], py[NN], pz[NN];
    for (int i = threadIdx.x; i < NN; i += 256) {
        const float* src = (i < NO) ? &opos[(size_t)(b * NO + i) * 3]
                                    : &mpos[(size_t)(b * NM + (i - NO)) * 3];
        px[i] = src[0]; py[i] = src[1]; pz[i] = src[2];
    }
    __syncthreads();
    const int wave = threadIdx.x >> 6, lane = threadIdx.x & 63;
    const int n = blk * 4 + wave;
    const float qx = px[n], qy = py[n], qz = pz[n];
    float d[13];
    #pragma unroll
    for (int s = 0; s < 13; s++) {
        int j = s * 64 + lane;
        float dx = qx - px[j], dy = qy - py[j], dz = qz - pz[j];
        d[s] = dx * dx + dy * dy + dz * dz;
    }
    int keep = 0;
    #pragma unroll
    for (int it = 0; it < 16; it++) {
        float bv = d[0]; int bs = 0;
        #pragma unroll
        for (int s = 1; s < 13; s++) { if (d[s] < bv) { bv = d[s]; bs = s; } }
        float v = bv; int jj = bs * 64 + lane;
        #pragma unroll
        for (int off = 32; off; off >>= 1) {
            float ov = __shfl_xor(v, off);
            int oj = __shfl_xor(jj, off);
            if (ov < v || (ov == v && oj < jj)) { v = ov; jj = oj; }
        }
        if (lane == (jj & 63)) {
            int sl = jj >> 6;
            #pragma unroll
            for (int s = 0; s < 13; s++) if (s == sl) d[s] = 3.4e38f;
        }
        if (lane == it) keep = jj;
    }
    if (lane < 16) IDX[((size_t)(b * NN + n)) * 16 + lane] = keep;
}

// ---------------------------------------------------------------- sine positional embedding
__global__ __launch_bounds__(256) void pe_kernel(
    const float* __restrict__ opos, const float* __restrict__ mpos, float* __restrict__ PE)
{
    const int row = blockIdx.x;            // b*NN + n
    const int b = row / NN, n = row % NN;
    const int c = threadIdx.x;
    const float* p = (n < NO) ? &opos[(size_t)(b * NO + n) * 3]
                              : &mpos[(size_t)(b * NM + (n - NO)) * 3];
    float x = p[0], y = p[1];
    int j = c & 127;
    float v = (c < 128) ? y : x;
    float inv_dt = exp2f(-(float)(j & ~1) * 0.10381025296523f);
    float e = v * 6.283185307179586f * inv_dt;
    PE[(size_t)row * DD + c] = (j & 1) ? cosf(e) : sinf(e);
}

// ---------------------------------------------------------------- transformer weight cvt->fp16
__global__ __launch_bounds__(256) void cvt_weights(
    const float* __restrict__ wqkv, const float* __restrict__ wo,
    const float* __restrict__ f1w, const float* __restrict__ f2w,
    h16* __restrict__ whf)
{
    size_t e = (size_t)blockIdx.x * 256 + threadIdx.x;
    int L = (int)(e / 786432);
    int r = (int)(e % 786432);
    float v;
    if (r < 196608)      v = wqkv[(size_t)L * 196608 + r];
    else if (r < 262144) v = wo[(size_t)L * 65536 + (r - 196608)];
    else if (r < 524288) v = f1w[(size_t)L * 262144 + (r - 262144)];
    else                 v = f2w[(size_t)L * 262144 + (r - 524288)];
    whf[e] = (h16)v;
}

// ---------------------------------------------------------------- pointnet weight cvt (packed)
#define W1P_O   0
#define W2S_O   2048
#define W3S_O   6144
#define MW1A_O  10240
#define MW1B_O  14336
#define MW2S_O  18432
#define OW1S_O  22528
#define OW2S_O  26624
#define APW_O   43008
#define AW1A_O  51200
#define AW1B_O  116736
#define AW2S_O  182272
#define AOW1_O  247808
#define AOW2_O  313344
#define WPN_TOT 378880
__global__ __launch_bounds__(256) void cvt_pn_weights(
    const float* __restrict__ m_pre_w1, const float* __restrict__ m_pre_w2,
    const float* __restrict__ m_pre_w3, const float* __restrict__ m_mlp_w1,
    const float* __restrict__ m_mlp_w2, const float* __restrict__ m_out_w1,
    const float* __restrict__ m_out_w2,
    const float* __restrict__ a_pre_w,  const float* __restrict__ a_mlp_w1,
    const float* __restrict__ a_mlp_w2, const float* __restrict__ a_out_w1,
    const float* __restrict__ a_out_w2,
    h16* __restrict__ wpnf)
{
    int e = blockIdx.x * 256 + threadIdx.x;
    float v;
    if (e < W2S_O)       { int n = e >> 5, k = e & 31; v = (k < 9) ? m_pre_w1[n * 9 + k] : 0.f; }
    else if (e < W3S_O)  v = m_pre_w2[e - W2S_O];
    else if (e < MW1A_O) v = m_pre_w3[e - W3S_O];
    else if (e < MW1B_O) { int r = e - MW1A_O; v = m_mlp_w1[(r >> 6) * 128 + (r & 63)]; }
    else if (e < MW2S_O) { int r = e - MW1B_O; v = m_mlp_w1[(r >> 6) * 128 + 64 + (r & 63)]; }
    else if (e < OW1S_O) v = m_mlp_w2[e - MW2S_O];
    else if (e < OW2S_O) v = m_out_w1[e - OW1S_O];
    else if (e < APW_O)  v = m_out_w2[e - OW2S_O];
    else if (e < AW1A_O) { int r = e - APW_O; int n = r >> 5, k = r & 31; v = (k < 30) ? a_pre_w[n * 30 + k] : 0.f; }
    else if (e < AW1B_O) { int r = e - AW1A_O; v = a_mlp_w1[(r >> 8) * 512 + (r & 255)]; }
    else if (e < AW2S_O) { int r = e - AW1B_O; v = a_mlp_w1[(r >> 8) * 512 + 256 + (r & 255)]; }
    else if (e < AOW1_O) v = a_mlp_w2[e - AW2S_O];
    else if (e < AOW2_O) v = a_out_w1[e - AOW1_O];
    else                 v = a_out_w2[e - AOW2_O];
    wpnf[e] = (h16)v;
}

// ---------------------------------------------------------------- pointnet input prep (pad + cvt)
__global__ __launch_bounds__(256) void prep_map(
    const float* __restrict__ mp, h16* __restrict__ pa)
{
    int e = blockIdx.x * 256 + threadIdx.x;
    int r = e >> 5, c = e & 31;
    float v = (c < CMx) ? mp[(size_t)r * CMx + c] : 0.f;
    pa[e] = (h16)v;
}
__global__ __launch_bounds__(256) void prep_agent(
    const float* __restrict__ obj, h16* __restrict__ pa)
{
    int e = blockIdx.x * 256 + threadIdx.x;
    int r = e >> 5, c = e & 31;
    float v = (c < CAx) ? obj[(size_t)r * CAx + c] : ((c == CAx) ? 1.0f : 0.f);
    pa[e] = (h16)v;
}

// ---------------------------------------------------------------- max-pool over P points
template<int P>
__global__ __launch_bounds__(256) void pool_max(
    const h16* __restrict__ in, h16* __restrict__ out, int cshift, int gout_off)
{
    int e = blockIdx.x * 256 + threadIdx.x;
    int C = 1 << cshift;
    int g = e >> cshift, c = e & (C - 1);
    float m = -3.4e38f;
    #pragma unroll
    for (int p = 0; p < P; p++) {
        float v = (float)in[(size_t)(g * P + p) * C + c];
        m = fmaxf(m, v);
    }
    out[(size_t)(gout_off + g) * C + c] = (h16)m;
}

// ---------------------------------------------------------------- pointnet GEMM (fp16 MFMA)
template<int BN, bool RELU, bool F16OUT, bool ROWMAP>
__global__ __launch_bounds__(256) void gemm_pn(
    const h16* __restrict__ A, const h16* __restrict__ W,
    const float* __restrict__ bias,
    const float* __restrict__ addrow, int ardiv, int arld,
    float* __restrict__ Cf, h16* __restrict__ C16,
    int K, int ldc, int rm_div, int rm_mul, int rm_add)
{
    constexpr int WAVES_M = (BN == 64) ? 4 : 2;
    constexpr int WM = 128 / (16 * WAVES_M);
    __shared__ __align__(16) h16 AS[128][32];
    __shared__ __align__(16) h16 WS[BN][32];
    const int m0 = blockIdx.x * 128;
    const int n0 = blockIdx.y * BN;
    const int tid = threadIdx.x;
    const int wave = tid >> 6, lane = tid & 63;
    const int wr = (BN == 64) ? wave : (wave >> 1);
    const int wc = (BN == 64) ? 0 : (wave & 1);
    const int fr = lane & 15, kb = lane >> 4;
    const int lrow = lane >> 2, lcol = SWZ_LCOL(lane);
    const int rdo = SWZ_RD(kb, fr);

    f4v acc[WM][4];
    #pragma unroll
    for (int i = 0; i < WM; i++)
        #pragma unroll
        for (int j = 0; j < 4; j++) { f4v z = {0.f, 0.f, 0.f, 0.f}; acc[i][j] = z; }

    for (int k0 = 0; k0 < K; k0 += 32) {
        __syncthreads();
        #pragma unroll
        for (int i = 0; i < 2; i++) {
            const int r = wave * 32 + i * 16;
            GLOAD_LDS16(&A[(size_t)(m0 + r + lrow) * K + k0 + lcol], &AS[r][0]);
        }
        if constexpr (BN == 64) {
            const int r = wave * 16;
            GLOAD_LDS16(&W[(size_t)(n0 + r + lrow) * K + k0 + lcol], &WS[r][0]);
        } else {
            #pragma unroll
            for (int i = 0; i < 2; i++) {
                const int r = wave * 32 + i * 16;
                GLOAD_LDS16(&W[(size_t)(n0 + r + lrow) * K + k0 + lcol], &WS[r][0]);
            }
        }
        __syncthreads();
        h8v af[WM];
        #pragma unroll
        for (int mi = 0; mi < WM; mi++)
            af[mi] = *(const h8v*)&AS[wr * (WM * 16) + mi * 16 + fr][rdo];
        #pragma unroll
        for (int nj = 0; nj < 4; nj++) {
            h8v bf = *(const h8v*)&WS[wc * 64 + nj * 16 + fr][rdo];
            #pragma unroll
            for (int mi = 0; mi < WM; mi++)
                acc[mi][nj] = __builtin_amdgcn_mfma_f32_16x16x32_f16(af[mi], bf, acc[mi][nj], 0, 0, 0);
        }
    }
    #pragma unroll
    for (int mi = 0; mi < WM; mi++) {
        #pragma unroll
        for (int nj = 0; nj < 4; nj++) {
            int col = n0 + wc * 64 + nj * 16 + fr;
            float bb = bias ? bias[col] : 0.f;
            #pragma unroll
            for (int r = 0; r < 4; r++) {
                int row = m0 + wr * (WM * 16) + mi * 16 + (lane >> 4) * 4 + r;
                float v = acc[mi][nj][r] + bb;
                if (addrow) v += addrow[(size_t)(row / ardiv) * arld + col];
                if (RELU) v = fmaxf(v, 0.f);
                if (F16OUT) {
                    C16[(size_t)row * ldc + col] = (h16)v;
                } else {
                    int drow = row;
                    if (ROWMAP) drow = row + rm_add + (row / rm_div) * rm_mul;
                    Cf[(size_t)drow * ldc + col] = v;
                }
            }
        }
    }
}

// ---------------------------------------------------------------- initial activation cvt
__global__ __launch_bounds__(256) void split_x0(
    const float* __restrict__ X, const float* __restrict__ PE,
    h16* __restrict__ X16, h16* __restrict__ XP16)
{
    size_t base = ((size_t)blockIdx.x * 256 + threadIdx.x) * 4;
    float4 x = *(const float4*)&X[base];
    float4 p = *(const float4*)&PE[base];
    h4v a, b;
    a.x = (h16)x.x; a.y = (h16)x.y; a.z = (h16)x.z; a.w = (h16)x.w;
    b.x = (h16)(x.x + p.x); b.y = (h16)(x.y + p.y);
    b.z = (h16)(x.z + p.z); b.w = (h16)(x.w + p.w);
    *(h4v*)&X16[base] = a;
    *(h4v*)&XP16[base] = b;
}

// ---------------------------------------------------------------- transformer fp16 MFMA GEMM
template<bool RELU, bool F16OUT>
__global__ __launch_bounds__(256) void gemm_mfma(
    const h16* __restrict__ A, const h16* __restrict__ A2, int a2min,
    const h16* __restrict__ W, const float* __restrict__ bias,
    float* __restrict__ Cf, h16* __restrict__ C16,
    int K, int ldc, int coff, float scale, int scale_until)
{
    __shared__ __align__(16) h16 AS[128][32];
    __shared__ __align__(16) h16 WS[128][32];
    const int m0 = blockIdx.x * 128;
    const int n0 = blockIdx.y * 128;
    const h16* pA = (n0 >= a2min) ? A2 : A;
    const int tid = threadIdx.x;
    const int wave = tid >> 6, lane = tid & 63;
    const int wr = wave >> 1, wc = wave & 1;
    const int fr = lane & 15, kb = lane >> 4;
    const int lrow = lane >> 2;
    const int lcol = SWZ_LCOL(lane);
    const int rdo = SWZ_RD(kb, fr);

    f4v acc[4][4];
    #pragma unroll
    for (int i = 0; i < 4; i++)
        #pragma unroll
        for (int j = 0; j < 4; j++) { f4v z = {0.f, 0.f, 0.f, 0.f}; acc[i][j] = z; }

    for (int k0 = 0; k0 < K; k0 += 32) {
        __syncthreads();
        #pragma unroll
        for (int i = 0; i < 2; i++) {
            const int r = wave * 32 + i * 16;
            const size_t grow = (size_t)(r + lrow);
            GLOAD_LDS16(&pA[(m0 + grow) * K + k0 + lcol], &AS[r][0]);
            GLOAD_LDS16(&W [(n0 + grow) * K + k0 + lcol], &WS[r][0]);
        }
        __syncthreads();
        h8v af[4];
        #pragma unroll
        for (int mi = 0; mi < 4; mi++)
            af[mi] = *(const h8v*)&AS[wr * 64 + mi * 16 + fr][rdo];
        #pragma unroll
        for (int nj = 0; nj < 4; nj++) {
            h8v bf = *(const h8v*)&WS[wc * 64 + nj * 16 + fr][rdo];
            #pragma unroll
            for (int mi = 0; mi < 4; mi++)
                acc[mi][nj] = __builtin_amdgcn_mfma_f32_16x16x32_f16(af[mi], bf, acc[mi][nj], 0, 0, 0);
        }
    }
    #pragma unroll
    for (int mi = 0; mi < 4; mi++) {
        #pragma unroll
        for (int nj = 0; nj < 4; nj++) {
            int col = n0 + wc * 64 + nj * 16 + fr;
            float bb = bias[col];
            #pragma unroll
            for (int r = 0; r < 4; r++) {
                int row = m0 + wr * 64 + mi * 16 + (lane >> 4) * 4 + r;
                float v = acc[mi][nj][r] + bb;
                if (RELU) v = fmaxf(v, 0.f);
                int gcol = coff + col;
                if (gcol < scale_until) v *= scale;
                if (F16OUT) {
                    C16[(size_t)row * ldc + gcol] = (h16)v;
                } else {
                    Cf[(size_t)row * ldc + gcol] = v;
                }
            }
        }
    }
}

// ---------------------------------------------------------------- GEMM + residual + LayerNorm fused
// tile 32 rows x 256 cols, 8 waves (512 thr): wave w owns cols [w*32, w*32+32).
template<int PEMODE>
__global__ __launch_bounds__(512) void gemm_ln(
    const h16* __restrict__ A, const h16* __restrict__ W,
    const float* __restrict__ bias, const float* __restrict__ R1,
    const float* __restrict__ g, const float* __restrict__ bt,
    float* __restrict__ OutF, h16* __restrict__ O16,
    const float* __restrict__ PEp, h16* __restrict__ P16,
    int K)
{
    __shared__ __align__(16) h16 AS[32][32];
    __shared__ __align__(16) h16 WS[256][32];
    __shared__ float red_s[2][8][32];
    const int m0 = blockIdx.x * 32;
    const int tid = threadIdx.x;
    const int wave = tid >> 6, lane = tid & 63;
    const int fr = lane & 15, kb = lane >> 4;
    const int lrow = lane >> 2, lcol = SWZ_LCOL(lane);
    const int rdo = SWZ_RD(kb, fr);

    f4v acc[2][2];
    #pragma unroll
    for (int i = 0; i < 2; i++)
        #pragma unroll
        for (int j = 0; j < 2; j++) { f4v z = {0.f, 0.f, 0.f, 0.f}; acc[i][j] = z; }

    for (int k0 = 0; k0 < K; k0 += 32) {
        __syncthreads();
        if (wave < 2) {
            GLOAD_LDS16(&A[(size_t)(m0 + wave * 16 + lrow) * K + k0 + lcol], &AS[wave * 16][0]);
        }
        #pragma unroll
        for (int i = 0; i < 2; i++) {
            const int r = wave * 32 + i * 16;
            GLOAD_LDS16(&W[(size_t)(r + lrow) * K + k0 + lcol], &WS[r][0]);
        }
        __syncthreads();
        h8v af[2];
        #pragma unroll
        for (int mi = 0; mi < 2; mi++)
            af[mi] = *(const h8v*)&AS[mi * 16 + fr][rdo];
        #pragma unroll
        for (int nj = 0; nj < 2; nj++) {
            h8v bf = *(const h8v*)&WS[wave * 32 + nj * 16 + fr][rdo];
            #pragma unroll
            for (int mi = 0; mi < 2; mi++)
                acc[mi][nj] = __builtin_amdgcn_mfma_f32_16x16x32_f16(af[mi], bf, acc[mi][nj], 0, 0, 0);
        }
    }
    // ---- epilogue: x = R1 + (acc + bias); block-local LN over 256 cols
    float x[2][2][4];
    float rsum[2][4], rsq[2][4];
    #pragma unroll
    for (int mi = 0; mi < 2; mi++)
        #pragma unroll
        for (int r = 0; r < 4; r++) { rsum[mi][r] = 0.f; rsq[mi][r] = 0.f; }
    #pragma unroll
    for (int mi = 0; mi < 2; mi++) {
        #pragma unroll
        for (int nj = 0; nj < 2; nj++) {
            int col = wave * 32 + nj * 16 + fr;
            float bb = bias[col];
            #pragma unroll
            for (int r = 0; r < 4; r++) {
                int row = m0 + mi * 16 + kb * 4 + r;
                float v = acc[mi][nj][r] + bb + R1[(size_t)row * 256 + col];
                x[mi][nj][r] = v;
                rsum[mi][r] += v;
                rsq[mi][r] += v * v;
            }
        }
    }
    #pragma unroll
    for (int off = 1; off < 16; off <<= 1) {
        #pragma unroll
        for (int mi = 0; mi < 2; mi++)
            #pragma unroll
            for (int r = 0; r < 4; r++) {
                rsum[mi][r] += __shfl_xor(rsum[mi][r], off);
                rsq[mi][r]  += __shfl_xor(rsq[mi][r], off);
            }
    }
    if (fr == 0) {
        #pragma unroll
        for (int mi = 0; mi < 2; mi++)
            #pragma unroll
            for (int r = 0; r < 4; r++) {
                int rid = mi * 16 + kb * 4 + r;
                red_s[0][wave][rid] = rsum[mi][r];
                red_s[1][wave][rid] = rsq[mi][r];
            }
    }
    __syncthreads();
    #pragma unroll
    for (int mi = 0; mi < 2; mi++) {
        #pragma unroll
        for (int r = 0; r < 4; r++) {
            int rid = mi * 16 + kb * 4 + r;
            float s = 0.f, sq = 0.f;
            #pragma unroll
            for (int w = 0; w < 8; w++) { s += red_s[0][w][rid]; sq += red_s[1][w][rid]; }
            float mean = s * (1.f / 256.f);
            float var = sq * (1.f / 256.f) - mean * mean;
            float inv = rsqrtf(var + 1e-5f);
            #pragma unroll
            for (int nj = 0; nj < 2; nj++) {
                int col = wave * 32 + nj * 16 + fr;
                float o = (x[mi][nj][r] - mean) * inv * g[col] + bt[col];
                size_t idx = (size_t)(m0 + rid) * 256 + col;
                OutF[idx] = o;
                if (PEMODE == 0 || PEMODE == 1) O16[idx] = (h16)o;
                if (PEMODE == 1) P16[idx] = (h16)(o + PEp[idx]);
            }
        }
    }
}

// ---------------------------------------------------------------- local KNN attention (fp16 QKV)
// XCD-affinity swizzle + LDS-staged K gather. K slice = 512B, so one gload
// stages TWO slices (lanes<32 -> s, lanes>=32 -> s+1); chunk-XOR swizzle
// (phys = logical ^ (s&7)) applied on both source and read sides.
__global__ __launch_bounds__(256) void attn_kernel(
    const h16* __restrict__ QKV16, const int* __restrict__ IDX,
    h16* __restrict__ AO16)
{
    __shared__ __align__(16) h16 Ks[32][256];    // 32 slices, 512B each, NO pad
    __shared__ float p_s[2][HH][16];
    __shared__ int gid_s[2][16];
    const int sub = threadIdx.x >> 7;
    const int t = threadIdx.x & 127;
    const int wave = threadIdx.x >> 6, lane = threadIdx.x & 63;
    const int xcd = blockIdx.x & 7;
    const int j = blockIdx.x >> 3;            // 0..831
    const int b = (j / 416) * 8 + xcd;        // batch
    const int row = b * NN + (j % 416) * 2 + sub;
    const int h = t >> 4, k = t & 15;
    int nb = IDX[(size_t)row * 16 + k];
    int g = b * NN + nb;
    if (h == 0) gid_s[sub][k] = g;
    __syncthreads();
    // stage: wave w stages slice pairs {w*8+2i, w*8+2i+1}, i=0..3
    #pragma unroll
    for (int i = 0; i < 4; i++) {
        int s0 = wave * 8 + i * 2;
        int s = s0 + (lane >> 5);
        int gs = gid_s[s >> 4][s & 15];
        int clog = (lane & 31) ^ (s & 7);
        GLOAD_LDS16(&QKV16[(size_t)gs * 768 + 256 + clog * 8], &Ks[s0][0]);
    }
    __syncthreads();
    const h16* q = &QKV16[(size_t)row * 768 + h * HDX];
    const int sidx = sub * 16 + k;
    float s = 0.f;
    #pragma unroll
    for (int c = 0; c < 4; c++) {
        h8v q8 = *(const h8v*)&q[c * 8];
        h8v k8 = *(const h8v*)&Ks[sidx][(((h * 4 + c) ^ (sidx & 7)) * 8)];
        #pragma unroll
        for (int e = 0; e < 8; e++) s += (float)q8[e] * (float)k8[e];
    }
    float m = s;
    #pragma unroll
    for (int off = 8; off; off >>= 1) m = fmaxf(m, __shfl_xor(m, off, 16));
    float e = expf(s - m);
    float sum = e;
    #pragma unroll
    for (int off = 8; off; off >>= 1) sum += __shfl_xor(sum, off, 16);
    p_s[sub][h][k] = e / sum;
    __syncthreads();
    const int d0 = t * 2;
    const int hh = d0 >> 5, dd = d0 & 31;
    float o0 = 0.f, o1 = 0.f;
    #pragma unroll
    for (int kk = 0; kk < 16; kk++) {
        int gg = gid_s[sub][kk];
        const h16* vr = &QKV16[(size_t)gg * 768 + 512 + hh * HDX + dd];
        float p = p_s[sub][hh][kk];
        o0 += p * (float)vr[0];
        o1 += p * (float)vr[1];
    }
    size_t base = (size_t)row * DD + d0;
    AO16[base] = (h16)o0;
    AO16[base + 1] = (h16)o1;
}

// ----------------------------------------------------------------
extern "C" void kernel_launch(void* const* d_in, const int* in_sizes, int n_in,
                              void* d_out, int out_size, void* d_ws, size_t ws_size,
                              hipStream_t stream)
{
    const float* obj      = (const float*)d_in[0];
    const float* mp       = (const float*)d_in[1];
    const float* opos     = (const float*)d_in[2];
    const float* mpos     = (const float*)d_in[3];
    const float* a_pre_w  = (const float*)d_in[4];
    const float* a_pre_b  = (const float*)d_in[5];
    const float* a_mlp_w1 = (const float*)d_in[6];
    const float* a_mlp_b1 = (const float*)d_in[7];
    const float* a_mlp_w2 = (const float*)d_in[8];
    const float* a_mlp_b2 = (const float*)d_in[9];
    const float* a_out_w1 = (const float*)d_in[10];
    const float* a_out_b1 = (const float*)d_in[11];
    const float* a_out_w2 = (const float*)d_in[12];
    const float* a_out_b2 = (const float*)d_in[13];
    const float* m_pre_w1 = (const float*)d_in[14];
    const float* m_pre_b1 = (const float*)d_in[15];
    const float* m_pre_w2 = (const float*)d_in[16];
    const float* m_pre_b2 = (const float*)d_in[17];
    const float* m_pre_w3 = (const float*)d_in[18];
    const float* m_pre_b3 = (const float*)d_in[19];
    const float* m_mlp_w1 = (const float*)d_in[20];
    const float* m_mlp_b1 = (const float*)d_in[21];
    const float* m_mlp_w2 = (const float*)d_in[22];
    const float* m_mlp_b2 = (const float*)d_in[23];
    const float* m_out_w1 = (const float*)d_in[24];
    const float* m_out_b1 = (const float*)d_in[25];
    const float* m_out_w2 = (const float*)d_in[26];
    const float* m_out_b2 = (const float*)d_in[27];
    const float* attn_wqkv = (const float*)d_in[28];
    const float* attn_bqkv = (const float*)d_in[29];
    const float* attn_wo   = (const float*)d_in[30];
    const float* attn_bo   = (const float*)d_in[31];
    const float* ffn_w1    = (const float*)d_in[32];
    const float* ffn_b1    = (const float*)d_in[33];
    const float* ffn_w2    = (const float*)d_in[34];
    const float* ffn_b2    = (const float*)d_in[35];
    const float* ln1_g     = (const float*)d_in[36];
    const float* ln1_b     = (const float*)d_in[37];
    const float* ln2_g     = (const float*)d_in[38];
    const float* ln2_b     = (const float*)d_in[39];

    const size_t M = MTOT;  // 13312
    float* ws   = (float*)d_ws;
    float* X    = ws;                 // M*256 f32
    float* PE   = X   + M * 256;      // M*256 f32
    float* QKVr = PE  + M * 256;      // M*768 f32-sized region (aliased below)
    float* H    = QKVr + M * 768;     // M*256 f32
    h16* AO16   = (h16*)(H + M * 256);   // M*256 fp16
    h16* X16    = AO16 + M * 256;
    h16* XP16   = X16  + M * 256;
    h16* H16    = XP16 + M * 256;
    h16* whf    = H16  + M * 256;     // 4,718,592 fp16
    h16* wpnf   = whf  + 4718592;     // WPN_TOT fp16
    int* IDX    = (int*)(wpnf + WPN_TOT);

    // layer-loop aliases over the QKVr region (disjoint lifetimes):
    h16* QKV16 = (h16*)QKVr;          // M*768 fp16 (live QKV-gemm..attn)
    h16* F116  = (h16*)QKVr;          // M*1024 fp16 (live FFN1..FFN2)

    // pointnet-phase aliases (region QKVr..whf = ~82 MB dead window)
    h16* PN0f = (h16*)QKVr;           // MAPR*64 = 15,728,640 fp16 (31.5 MB)
    h16* PN1f = PN0f + 15728640;      // 31.5 MB
    h16* SB   = PN0f + 31457280;
    h16* PLf  = SB;                   // 12288*64 = 786432
    h16* GMf  = SB + 786432;          // 786432
    h16* HVf  = SB + 1572864;         // 786432
    h16* APLf = SB + 2359296;         // 1024*256 = 262144
    h16* AGMf = SB + 2621440;         // 262144
    h16* AHVf = SB + 2883584;         // 262144
    float* PCf = (float*)(SB + 3145728);  // 12288*64 f32
    float* APC = PCf + 786432;            // 1024*256 f32
    // end = 31457280+3145728 fp16 + (786432+262144) f32 = ~73.5 MB < 82 MB window

    // ---------------- pre-phase ----------------
    knn_kernel<<<BB * 208, 256, 0, stream>>>(opos, mpos, IDX);
    pe_kernel<<<MTOT, 256, 0, stream>>>(opos, mpos, PE);
    cvt_weights<<<4718592 / 256, 256, 0, stream>>>(attn_wqkv, attn_wo, ffn_w1, ffn_w2, whf);
    cvt_pn_weights<<<WPN_TOT / 256, 256, 0, stream>>>(
        m_pre_w1, m_pre_w2, m_pre_w3, m_mlp_w1, m_mlp_w2, m_out_w1, m_out_w2,
        a_pre_w, a_mlp_w1, a_mlp_w2, a_out_w1, a_out_w2, wpnf);

    // ---- agent pointnet as GEMM chain
    {
        h16* PA32 = PN1f;
        h16* PB   = PN0f;
        h16* PA2  = PN1f;
        prep_agent<<<21504 * 32 / 256, 256, 0, stream>>>(obj, PA32);
        gemm_pn<128, true, true, false><<<dim3(168, 2), 256, 0, stream>>>(
            PA32, wpnf + APW_O, a_pre_b, nullptr, 1, 0,
            nullptr, PB, 32, 256, 1, 0, 0);
        pool_max<21><<<1024, 256, 0, stream>>>(PB, APLf, 8, 0);
        gemm_pn<128, false, false, false><<<dim3(8, 2), 256, 0, stream>>>(
            APLf, wpnf + AW1B_O, a_mlp_b1, nullptr, 1, 0,
            APC, nullptr, 256, 256, 1, 0, 0);
        gemm_pn<128, true, true, false><<<dim3(168, 2), 256, 0, stream>>>(
            PB, wpnf + AW1A_O, nullptr, APC, 21, 256,
            nullptr, PA2, 256, 256, 1, 0, 0);
        gemm_pn<128, true, true, false><<<dim3(168, 2), 256, 0, stream>>>(
            PA2, wpnf + AW2S_O, a_mlp_b2, nullptr, 1, 0,
            nullptr, PB, 256, 256, 1, 0, 0);
        pool_max<21><<<1024, 256, 0, stream>>>(PB, AGMf, 8, 0);
        gemm_pn<128, true, true, false><<<dim3(8, 2), 256, 0, stream>>>(
            AGMf, wpnf + AOW1_O, a_out_b1, nullptr, 1, 0,
            nullptr, AHVf, 256, 256, 1, 0, 0);
        gemm_pn<128, false, false, true><<<dim3(8, 2), 256, 0, stream>>>(
            AHVf, wpnf + AOW2_O, a_out_b2, nullptr, 1, 0,
            X, nullptr, 256, 256, 64, 768, 0);
    }

    // ---- map pointnet as GEMM chain, SINGLE pass (M = 245760)
    {
        prep_map<<<MAPR * 32 / 256, 256, 0, stream>>>(mp, PN0f);
        gemm_pn<64, true, true, false><<<dim3(1920, 1), 256, 0, stream>>>(
            PN0f, wpnf + W1P_O, m_pre_b1, nullptr, 1, 0,
            nullptr, PN1f, 32, 64, 1, 0, 0);
        gemm_pn<64, true, true, false><<<dim3(1920, 1), 256, 0, stream>>>(
            PN1f, wpnf + W2S_O, m_pre_b2, nullptr, 1, 0,
            nullptr, PN0f, 64, 64, 1, 0, 0);
        gemm_pn<64, true, true, false><<<dim3(1920, 1), 256, 0, stream>>>(
            PN0f, wpnf + W3S_O, m_pre_b3, nullptr, 1, 0,
            nullptr, PN1f, 64, 64, 1, 0, 0);
        pool_max<20><<<12288 * 64 / 256, 256, 0, stream>>>(PN1f, PLf, 6, 0);
        gemm_pn<64, false, false, false><<<dim3(96, 1), 256, 0, stream>>>(
            PLf, wpnf + MW1B_O, m_mlp_b1, nullptr, 1, 0,
            PCf, nullptr, 64, 64, 1, 0, 0);
        gemm_pn<64, true, true, false><<<dim3(1920, 1), 256, 0, stream>>>(
            PN1f, wpnf + MW1A_O, nullptr, PCf, 20, 64,
            nullptr, PN0f, 64, 64, 1, 0, 0);
        gemm_pn<64, true, true, false><<<dim3(1920, 1), 256, 0, stream>>>(
            PN0f, wpnf + MW2S_O, m_mlp_b2, nullptr, 1, 0,
            nullptr, PN1f, 64, 64, 1, 0, 0);
        pool_max<20><<<12288 * 64 / 256, 256, 0, stream>>>(PN1f, GMf, 6, 0);
        gemm_pn<64, true, true, false><<<dim3(96, 1), 256, 0, stream>>>(
            GMf, wpnf + OW1S_O, m_out_b1, nullptr, 1, 0,
            nullptr, HVf, 64, 64, 1, 0, 0);
        gemm_pn<128, false, false, true><<<dim3(96, 2), 256, 0, stream>>>(
            HVf, wpnf + OW2S_O, m_out_b2, nullptr, 1, 0,
            X, nullptr, 64, 256, 768, 64, 64);
    }

    split_x0<<<(int)(M * 256 / 1024), 256, 0, stream>>>(X, PE, X16, XP16);

    // ---------------- transformer layers ----------------
    const float scal = 0.17677669529663687f;  // 32^-0.5
    const int MB = MTOT / 128;  // 104
    const int NOA2 = 0x7fffffff;
    for (int l = 0; l < LL; l++) {
        const size_t wb = (size_t)l * 786432;
        const h16* wqkv_f = whf + wb;
        const h16* wo_f   = whf + wb + 196608;
        const h16* f1_f   = whf + wb + 262144;
        const h16* f2_f   = whf + wb + 524288;
        const float* bqkv = attn_bqkv + (size_t)l * 768;
        // QKV (merged, fp16 out): cols [0,512) read XP16, cols [512,768) read X16
        gemm_mfma<false, true><<<dim3(MB, 6), 256, 0, stream>>>(
            XP16, X16, 512, wqkv_f, bqkv,
            nullptr, QKV16, 256, 768, 0, scal, 256);
        attn_kernel<<<MTOT / 2, 256, 0, stream>>>(QKV16, IDX, AO16);
        // O-proj + residual(X) + ln1 -> H, H16
        gemm_ln<0><<<MTOT / 32, 512, 0, stream>>>(
            AO16, wo_f, attn_bo + (size_t)l * 256, X,
            ln1_g + l * 256, ln1_b + l * 256,
            H, H16, nullptr, nullptr, 256);
        // FFN1 (relu) -> F116 (over dead QKV16)
        gemm_mfma<true, true><<<dim3(MB, 8), 256, 0, stream>>>(
            H16, nullptr, NOA2, f1_f, ffn_b1 + (size_t)l * 1024,
            nullptr, F116, 256, 1024, 0, 1.f, 0);
        // FFN2 + residual(H) + ln2 -> X (+cvt) or d_out
        if (l == LL - 1) {
            gemm_ln<2><<<MTOT / 32, 512, 0, stream>>>(
                F116, f2_f, ffn_b2 + (size_t)l * 256, H,
                ln2_g + l * 256, ln2_b + l * 256,
                (float*)d_out, nullptr, nullptr, nullptr, 1024);
        } else {
            gemm_ln<1><<<MTOT / 32, 512, 0, stream>>>(
                F116, f2_f, ffn_b2 + (size_t)l * 256, H,
                ln2_g + l * 256, ln2_b + l * 256,
                X, X16, PE, XP16, 1024);
        }
    }
}

// Round 17
// 843.749 us; speedup vs baseline: 2.1300x; 1.0217x over previous
//
#include <hip/hip_runtime.h>
#include <hip/hip_bf16.h>

typedef unsigned short u16;
typedef _Float16 h16;

#define BB 16
#define NO 64
#define TT 21
#define NM 768
#define PP 20
#define CAx 29
#define CMx 9
#define DD 256
#define HH 8
#define LL 6
#define KK 16
#define NN (NO + NM)        // 832
#define HDX (DD / HH)       // 32
#define MTOT (BB * NN)      // 13312
#define MAPR (BB * NM * PP) // 245760 map point-rows

typedef __attribute__((ext_vector_type(8))) h16 h8v;    // 8 fp16 in 4 VGPRs
typedef __attribute__((ext_vector_type(4))) h16 h4v;
typedef __attribute__((ext_vector_type(4))) float f4v;

#define GLOAD_LDS16(gptr, lptr)                                                             \
    __builtin_amdgcn_global_load_lds(                                                       \
        (const __attribute__((address_space(1))) void*)(gptr),                              \
        (__attribute__((address_space(3))) void*)(lptr), 16, 0, 0)

// Bank-conflict swizzle for [rows][32]-fp16 linear tiles (gload_lds-compatible):
// physical 16B slot s_phys at row R holds logical k-slot s_phys ^ ((R>>1)&3).
#define SWZ_LCOL(lane)   ((((lane) & 3) ^ (((lane) >> 3) & 3)) * 8)
#define SWZ_RD(kb, fr)   ((((kb) ^ (((fr) >> 1) & 3))) * 8)

// ---------------------------------------------------------------- KNN (top-16 smallest d2)
__global__ __launch_bounds__(256) void knn_kernel(
    const float* __restrict__ opos, const float* __restrict__ mpos, int* __restrict__ IDX)
{
    const int b = blockIdx.x / 208;
    const int blk = blockIdx.x % 208;
    __shared__ float px[NN], py[NN], pz[NN];
    for (int i = threadIdx.x; i < NN; i += 256) {
        const float* src = (i < NO) ? &opos[(size_t)(b * NO + i) * 3]
                                    : &mpos[(size_t)(b * NM + (i - NO)) * 3];
        px[i] = src[0]; py[i] = src[1]; pz[i] = src[2];
    }
    __syncthreads();
    const int wave = threadIdx.x >> 6, lane = threadIdx.x & 63;
    const int n = blk * 4 + wave;
    const float qx = px[n], qy = py[n], qz = pz[n];
    float d[13];
    #pragma unroll
    for (int s = 0; s < 13; s++) {
        int j = s * 64 + lane;
        float dx = qx - px[j], dy = qy - py[j], dz = qz - pz[j];
        d[s] = dx * dx + dy * dy + dz * dz;
    }
    int keep = 0;
    #pragma unroll
    for (int it = 0; it < 16; it++) {
        float bv = d[0]; int bs = 0;
        #pragma unroll
        for (int s = 1; s < 13; s++) { if (d[s] < bv) { bv = d[s]; bs = s; } }
        float v = bv; int jj = bs * 64 + lane;
        #pragma unroll
        for (int off = 32; off; off >>= 1) {
            float ov = __shfl_xor(v, off);
            int oj = __shfl_xor(jj, off);
            if (ov < v || (ov == v && oj < jj)) { v = ov; jj = oj; }
        }
        if (lane == (jj & 63)) {
            int sl = jj >> 6;
            #pragma unroll
            for (int s = 0; s < 13; s++) if (s == sl) d[s] = 3.4e38f;
        }
        if (lane == it) keep = jj;
    }
    if (lane < 16) IDX[((size_t)(b * NN + n)) * 16 + lane] = keep;
}

// ---------------------------------------------------------------- sine positional embedding (fp16 out)
__global__ __launch_bounds__(256) void pe_kernel(
    const float* __restrict__ opos, const float* __restrict__ mpos, h16* __restrict__ PE16)
{
    const int row = blockIdx.x;            // b*NN + n
    const int b = row / NN, n = row % NN;
    const int c = threadIdx.x;
    const float* p = (n < NO) ? &opos[(size_t)(b * NO + n) * 3]
                              : &mpos[(size_t)(b * NM + (n - NO)) * 3];
    float x = p[0], y = p[1];
    int j = c & 127;
    float v = (c < 128) ? y : x;
    float inv_dt = exp2f(-(float)(j & ~1) * 0.10381025296523f);
    float e = v * 6.283185307179586f * inv_dt;
    PE16[(size_t)row * DD + c] = (h16)((j & 1) ? cosf(e) : sinf(e));
}

// ---------------------------------------------------------------- transformer weight cvt->fp16
__global__ __launch_bounds__(256) void cvt_weights(
    const float* __restrict__ wqkv, const float* __restrict__ wo,
    const float* __restrict__ f1w, const float* __restrict__ f2w,
    h16* __restrict__ whf)
{
    size_t e = (size_t)blockIdx.x * 256 + threadIdx.x;
    int L = (int)(e / 786432);
    int r = (int)(e % 786432);
    float v;
    if (r < 196608)      v = wqkv[(size_t)L * 196608 + r];
    else if (r < 262144) v = wo[(size_t)L * 65536 + (r - 196608)];
    else if (r < 524288) v = f1w[(size_t)L * 262144 + (r - 262144)];
    else                 v = f2w[(size_t)L * 262144 + (r - 524288)];
    whf[e] = (h16)v;
}

// ---------------------------------------------------------------- pointnet weight cvt (packed)
#define W1P_O   0
#define W2S_O   2048
#define W3S_O   6144
#define MW1A_O  10240
#define MW1B_O  14336
#define MW2S_O  18432
#define OW1S_O  22528
#define OW2S_O  26624
#define APW_O   43008
#define AW1A_O  51200
#define AW1B_O  116736
#define AW2S_O  182272
#define AOW1_O  247808
#define AOW2_O  313344
#define WPN_TOT 378880
__global__ __launch_bounds__(256) void cvt_pn_weights(
    const float* __restrict__ m_pre_w1, const float* __restrict__ m_pre_w2,
    const float* __restrict__ m_pre_w3, const float* __restrict__ m_mlp_w1,
    const float* __restrict__ m_mlp_w2, const float* __restrict__ m_out_w1,
    const float* __restrict__ m_out_w2,
    const float* __restrict__ a_pre_w,  const float* __restrict__ a_mlp_w1,
    const float* __restrict__ a_mlp_w2, const float* __restrict__ a_out_w1,
    const float* __restrict__ a_out_w2,
    h16* __restrict__ wpnf)
{
    int e = blockIdx.x * 256 + threadIdx.x;
    float v;
    if (e < W2S_O)       { int n = e >> 5, k = e & 31; v = (k < 9) ? m_pre_w1[n * 9 + k] : 0.f; }
    else if (e < W3S_O)  v = m_pre_w2[e - W2S_O];
    else if (e < MW1A_O) v = m_pre_w3[e - W3S_O];
    else if (e < MW1B_O) { int r = e - MW1A_O; v = m_mlp_w1[(r >> 6) * 128 + (r & 63)]; }
    else if (e < MW2S_O) { int r = e - MW1B_O; v = m_mlp_w1[(r >> 6) * 128 + 64 + (r & 63)]; }
    else if (e < OW1S_O) v = m_mlp_w2[e - MW2S_O];
    else if (e < OW2S_O) v = m_out_w1[e - OW1S_O];
    else if (e < APW_O)  v = m_out_w2[e - OW2S_O];
    else if (e < AW1A_O) { int r = e - APW_O; int n = r >> 5, k = r & 31; v = (k < 30) ? a_pre_w[n * 30 + k] : 0.f; }
    else if (e < AW1B_O) { int r = e - AW1A_O; v = a_mlp_w1[(r >> 8) * 512 + (r & 255)]; }
    else if (e < AW2S_O) { int r = e - AW1B_O; v = a_mlp_w1[(r >> 8) * 512 + 256 + (r & 255)]; }
    else if (e < AOW1_O) v = a_mlp_w2[e - AW2S_O];
    else if (e < AOW2_O) v = a_out_w1[e - AOW1_O];
    else                 v = a_out_w2[e - AOW2_O];
    wpnf[e] = (h16)v;
}

// ---------------------------------------------------------------- pointnet input prep (pad + cvt)
__global__ __launch_bounds__(256) void prep_map(
    const float* __restrict__ mp, h16* __restrict__ pa)
{
    int e = blockIdx.x * 256 + threadIdx.x;
    int r = e >> 5, c = e & 31;
    float v = (c < CMx) ? mp[(size_t)r * CMx + c] : 0.f;
    pa[e] = (h16)v;
}
__global__ __launch_bounds__(256) void prep_agent(
    const float* __restrict__ obj, h16* __restrict__ pa)
{
    int e = blockIdx.x * 256 + threadIdx.x;
    int r = e >> 5, c = e & 31;
    float v = (c < CAx) ? obj[(size_t)r * CAx + c] : ((c == CAx) ? 1.0f : 0.f);
    pa[e] = (h16)v;
}

// ---------------------------------------------------------------- max-pool over P points
template<int P>
__global__ __launch_bounds__(256) void pool_max(
    const h16* __restrict__ in, h16* __restrict__ out, int cshift, int gout_off)
{
    int e = blockIdx.x * 256 + threadIdx.x;
    int C = 1 << cshift;
    int g = e >> cshift, c = e & (C - 1);
    float m = -3.4e38f;
    #pragma unroll
    for (int p = 0; p < P; p++) {
        float v = (float)in[(size_t)(g * P + p) * C + c];
        m = fmaxf(m, v);
    }
    out[(size_t)(gout_off + g) * C + c] = (h16)m;
}

// ---------------------------------------------------------------- pointnet GEMM (fp16 MFMA)
template<int BN, bool RELU, bool F16OUT, bool ROWMAP>
__global__ __launch_bounds__(256) void gemm_pn(
    const h16* __restrict__ A, const h16* __restrict__ W,
    const float* __restrict__ bias,
    const float* __restrict__ addrow, int ardiv, int arld,
    float* __restrict__ Cf, h16* __restrict__ C16,
    int K, int ldc, int rm_div, int rm_mul, int rm_add)
{
    constexpr int WAVES_M = (BN == 64) ? 4 : 2;
    constexpr int WM = 128 / (16 * WAVES_M);
    __shared__ __align__(16) h16 AS[128][32];
    __shared__ __align__(16) h16 WS[BN][32];
    const int m0 = blockIdx.x * 128;
    const int n0 = blockIdx.y * BN;
    const int tid = threadIdx.x;
    const int wave = tid >> 6, lane = tid & 63;
    const int wr = (BN == 64) ? wave : (wave >> 1);
    const int wc = (BN == 64) ? 0 : (wave & 1);
    const int fr = lane & 15, kb = lane >> 4;
    const int lrow = lane >> 2, lcol = SWZ_LCOL(lane);
    const int rdo = SWZ_RD(kb, fr);

    f4v acc[WM][4];
    #pragma unroll
    for (int i = 0; i < WM; i++)
        #pragma unroll
        for (int j = 0; j < 4; j++) { f4v z = {0.f, 0.f, 0.f, 0.f}; acc[i][j] = z; }

    for (int k0 = 0; k0 < K; k0 += 32) {
        __syncthreads();
        #pragma unroll
        for (int i = 0; i < 2; i++) {
            const int r = wave * 32 + i * 16;
            GLOAD_LDS16(&A[(size_t)(m0 + r + lrow) * K + k0 + lcol], &AS[r][0]);
        }
        if constexpr (BN == 64) {
            const int r = wave * 16;
            GLOAD_LDS16(&W[(size_t)(n0 + r + lrow) * K + k0 + lcol], &WS[r][0]);
        } else {
            #pragma unroll
            for (int i = 0; i < 2; i++) {
                const int r = wave * 32 + i * 16;
                GLOAD_LDS16(&W[(size_t)(n0 + r + lrow) * K + k0 + lcol], &WS[r][0]);
            }
        }
        __syncthreads();
        h8v af[WM];
        #pragma unroll
        for (int mi = 0; mi < WM; mi++)
            af[mi] = *(const h8v*)&AS[wr * (WM * 16) + mi * 16 + fr][rdo];
        #pragma unroll
        for (int nj = 0; nj < 4; nj++) {
            h8v bf = *(const h8v*)&WS[wc * 64 + nj * 16 + fr][rdo];
            #pragma unroll
            for (int mi = 0; mi < WM; mi++)
                acc[mi][nj] = __builtin_amdgcn_mfma_f32_16x16x32_f16(af[mi], bf, acc[mi][nj], 0, 0, 0);
        }
    }
    #pragma unroll
    for (int mi = 0; mi < WM; mi++) {
        #pragma unroll
        for (int nj = 0; nj < 4; nj++) {
            int col = n0 + wc * 64 + nj * 16 + fr;
            float bb = bias ? bias[col] : 0.f;
            #pragma unroll
            for (int r = 0; r < 4; r++) {
                int row = m0 + wr * (WM * 16) + mi * 16 + (lane >> 4) * 4 + r;
                float v = acc[mi][nj][r] + bb;
                if (addrow) v += addrow[(size_t)(row / ardiv) * arld + col];
                if (RELU) v = fmaxf(v, 0.f);
                if (F16OUT) {
                    C16[(size_t)row * ldc + col] = (h16)v;
                } else {
                    int drow = row;
                    if (ROWMAP) drow = row + rm_add + (row / rm_div) * rm_mul;
                    Cf[(size_t)drow * ldc + col] = v;
                }
            }
        }
    }
}

// ---------------------------------------------------------------- initial activation cvt
__global__ __launch_bounds__(256) void split_x0(
    const float* __restrict__ X, const h16* __restrict__ PE16,
    h16* __restrict__ X16, h16* __restrict__ XP16)
{
    size_t base = ((size_t)blockIdx.x * 256 + threadIdx.x) * 4;
    float4 x = *(const float4*)&X[base];
    h4v pe = *(const h4v*)&PE16[base];
    h4v a, b;
    a.x = (h16)x.x; a.y = (h16)x.y; a.z = (h16)x.z; a.w = (h16)x.w;
    b.x = (h16)(x.x + (float)pe.x); b.y = (h16)(x.y + (float)pe.y);
    b.z = (h16)(x.z + (float)pe.z); b.w = (h16)(x.w + (float)pe.w);
    *(h4v*)&X16[base] = a;
    *(h4v*)&XP16[base] = b;
}

// ---------------------------------------------------------------- transformer fp16 MFMA GEMM
template<bool RELU, bool F16OUT>
__global__ __launch_bounds__(256) void gemm_mfma(
    const h16* __restrict__ A, const h16* __restrict__ A2, int a2min,
    const h16* __restrict__ W, const float* __restrict__ bias,
    float* __restrict__ Cf, h16* __restrict__ C16,
    int K, int ldc, int coff, float scale, int scale_until)
{
    __shared__ __align__(16) h16 AS[128][32];
    __shared__ __align__(16) h16 WS[128][32];
    const int m0 = blockIdx.x * 128;
    const int n0 = blockIdx.y * 128;
    const h16* pA = (n0 >= a2min) ? A2 : A;
    const int tid = threadIdx.x;
    const int wave = tid >> 6, lane = tid & 63;
    const int wr = wave >> 1, wc = wave & 1;
    const int fr = lane & 15, kb = lane >> 4;
    const int lrow = lane >> 2;
    const int lcol = SWZ_LCOL(lane);
    const int rdo = SWZ_RD(kb, fr);

    f4v acc[4][4];
    #pragma unroll
    for (int i = 0; i < 4; i++)
        #pragma unroll
        for (int j = 0; j < 4; j++) { f4v z = {0.f, 0.f, 0.f, 0.f}; acc[i][j] = z; }

    for (int k0 = 0; k0 < K; k0 += 32) {
        __syncthreads();
        #pragma unroll
        for (int i = 0; i < 2; i++) {
            const int r = wave * 32 + i * 16;
            const size_t grow = (size_t)(r + lrow);
            GLOAD_LDS16(&pA[(m0 + grow) * K + k0 + lcol], &AS[r][0]);
            GLOAD_LDS16(&W [(n0 + grow) * K + k0 + lcol], &WS[r][0]);
        }
        __syncthreads();
        h8v af[4];
        #pragma unroll
        for (int mi = 0; mi < 4; mi++)
            af[mi] = *(const h8v*)&AS[wr * 64 + mi * 16 + fr][rdo];
        #pragma unroll
        for (int nj = 0; nj < 4; nj++) {
            h8v bf = *(const h8v*)&WS[wc * 64 + nj * 16 + fr][rdo];
            #pragma unroll
            for (int mi = 0; mi < 4; mi++)
                acc[mi][nj] = __builtin_amdgcn_mfma_f32_16x16x32_f16(af[mi], bf, acc[mi][nj], 0, 0, 0);
        }
    }
    #pragma unroll
    for (int mi = 0; mi < 4; mi++) {
        #pragma unroll
        for (int nj = 0; nj < 4; nj++) {
            int col = n0 + wc * 64 + nj * 16 + fr;
            float bb = bias[col];
            #pragma unroll
            for (int r = 0; r < 4; r++) {
                int row = m0 + wr * 64 + mi * 16 + (lane >> 4) * 4 + r;
                float v = acc[mi][nj][r] + bb;
                if (RELU) v = fmaxf(v, 0.f);
                int gcol = coff + col;
                if (gcol < scale_until) v *= scale;
                if (F16OUT) {
                    C16[(size_t)row * ldc + gcol] = (h16)v;
                } else {
                    Cf[(size_t)row * ldc + gcol] = v;
                }
            }
        }
    }
}

// ---------------------------------------------------------------- GEMM + residual + LayerNorm fused
// tile 32 rows x 256 cols, 8 waves (512 thr); fp16 residual stream (R16).
// PEMODE 0: out = H16.  PEMODE 1: out = X16 and XP16 (= h16(o + PE16)).
// PEMODE 2: out = OutF (fp32, final d_out).
template<int PEMODE>
__global__ __launch_bounds__(512) void gemm_ln(
    const h16* __restrict__ A, const h16* __restrict__ W,
    const float* __restrict__ bias, const h16* __restrict__ R16,
    const float* __restrict__ g, const float* __restrict__ bt,
    float* __restrict__ OutF, h16* __restrict__ O16,
    const h16* __restrict__ PE16p, h16* __restrict__ P16,
    int K)
{
    __shared__ __align__(16) h16 AS[32][32];
    __shared__ __align__(16) h16 WS[256][32];
    __shared__ float red_s[2][8][32];
    const int m0 = blockIdx.x * 32;
    const int tid = threadIdx.x;
    const int wave = tid >> 6, lane = tid & 63;
    const int fr = lane & 15, kb = lane >> 4;
    const int lrow = lane >> 2, lcol = SWZ_LCOL(lane);
    const int rdo = SWZ_RD(kb, fr);

    f4v acc[2][2];
    #pragma unroll
    for (int i = 0; i < 2; i++)
        #pragma unroll
        for (int j = 0; j < 2; j++) { f4v z = {0.f, 0.f, 0.f, 0.f}; acc[i][j] = z; }

    for (int k0 = 0; k0 < K; k0 += 32) {
        __syncthreads();
        if (wave < 2) {
            GLOAD_LDS16(&A[(size_t)(m0 + wave * 16 + lrow) * K + k0 + lcol], &AS[wave * 16][0]);
        }
        #pragma unroll
        for (int i = 0; i < 2; i++) {
            const int r = wave * 32 + i * 16;
            GLOAD_LDS16(&W[(size_t)(r + lrow) * K + k0 + lcol], &WS[r][0]);
        }
        __syncthreads();
        h8v af[2];
        #pragma unroll
        for (int mi = 0; mi < 2; mi++)
            af[mi] = *(const h8v*)&AS[mi * 16 + fr][rdo];
        #pragma unroll
        for (int nj = 0; nj < 2; nj++) {
            h8v bf = *(const h8v*)&WS[wave * 32 + nj * 16 + fr][rdo];
            #pragma unroll
            for (int mi = 0; mi < 2; mi++)
                acc[mi][nj] = __builtin_amdgcn_mfma_f32_16x16x32_f16(af[mi], bf, acc[mi][nj], 0, 0, 0);
        }
    }
    // ---- epilogue: x = R16 + (acc + bias); block-local LN over 256 cols
    float x[2][2][4];
    float rsum[2][4], rsq[2][4];
    #pragma unroll
    for (int mi = 0; mi < 2; mi++)
        #pragma unroll
        for (int r = 0; r < 4; r++) { rsum[mi][r] = 0.f; rsq[mi][r] = 0.f; }
    #pragma unroll
    for (int mi = 0; mi < 2; mi++) {
        #pragma unroll
        for (int nj = 0; nj < 2; nj++) {
            int col = wave * 32 + nj * 16 + fr;
            float bb = bias[col];
            #pragma unroll
            for (int r = 0; r < 4; r++) {
                int row = m0 + mi * 16 + kb * 4 + r;
                float v = acc[mi][nj][r] + bb + (float)R16[(size_t)row * 256 + col];
                x[mi][nj][r] = v;
                rsum[mi][r] += v;
                rsq[mi][r] += v * v;
            }
        }
    }
    #pragma unroll
    for (int off = 1; off < 16; off <<= 1) {
        #pragma unroll
        for (int mi = 0; mi < 2; mi++)
            #pragma unroll
            for (int r = 0; r < 4; r++) {
                rsum[mi][r] += __shfl_xor(rsum[mi][r], off);
                rsq[mi][r]  += __shfl_xor(rsq[mi][r], off);
            }
    }
    if (fr == 0) {
        #pragma unroll
        for (int mi = 0; mi < 2; mi++)
            #pragma unroll
            for (int r = 0; r < 4; r++) {
                int rid = mi * 16 + kb * 4 + r;
                red_s[0][wave][rid] = rsum[mi][r];
                red_s[1][wave][rid] = rsq[mi][r];
            }
    }
    __syncthreads();
    #pragma unroll
    for (int mi = 0; mi < 2; mi++) {
        #pragma unroll
        for (int r = 0; r < 4; r++) {
            int rid = mi * 16 + kb * 4 + r;
            float s = 0.f, sq = 0.f;
            #pragma unroll
            for (int w = 0; w < 8; w++) { s += red_s[0][w][rid]; sq += red_s[1][w][rid]; }
            float mean = s * (1.f / 256.f);
            float var = sq * (1.f / 256.f) - mean * mean;
            float inv = rsqrtf(var + 1e-5f);
            #pragma unroll
            for (int nj = 0; nj < 2; nj++) {
                int col = wave * 32 + nj * 16 + fr;
                float o = (x[mi][nj][r] - mean) * inv * g[col] + bt[col];
                size_t idx = (size_t)(m0 + rid) * 256 + col;
                if (PEMODE == 2) {
                    OutF[idx] = o;
                } else {
                    O16[idx] = (h16)o;
                }
                if (PEMODE == 1) P16[idx] = (h16)(o + (float)PE16p[idx]);
            }
        }
    }
}

// ---------------------------------------------------------------- local KNN attention (fp16 QKV)
__global__ __launch_bounds__(256) void attn_kernel(
    const h16* __restrict__ QKV16, const int* __restrict__ IDX,
    h16* __restrict__ AO16)
{
    __shared__ __align__(16) h16 Ks[32][256];    // 32 slices, 512B each, NO pad
    __shared__ float p_s[2][HH][16];
    __shared__ int gid_s[2][16];
    const int sub = threadIdx.x >> 7;
    const int t = threadIdx.x & 127;
    const int wave = threadIdx.x >> 6, lane = threadIdx.x & 63;
    const int xcd = blockIdx.x & 7;
    const int j = blockIdx.x >> 3;            // 0..831
    const int b = (j / 416) * 8 + xcd;        // batch
    const int row = b * NN + (j % 416) * 2 + sub;
    const int h = t >> 4, k = t & 15;
    int nb = IDX[(size_t)row * 16 + k];
    int g = b * NN + nb;
    if (h == 0) gid_s[sub][k] = g;
    __syncthreads();
    #pragma unroll
    for (int i = 0; i < 4; i++) {
        int s0 = wave * 8 + i * 2;
        int s = s0 + (lane >> 5);
        int gs = gid_s[s >> 4][s & 15];
        int clog = (lane & 31) ^ (s & 7);
        GLOAD_LDS16(&QKV16[(size_t)gs * 768 + 256 + clog * 8], &Ks[s0][0]);
    }
    __syncthreads();
    const h16* q = &QKV16[(size_t)row * 768 + h * HDX];
    const int sidx = sub * 16 + k;
    float s = 0.f;
    #pragma unroll
    for (int c = 0; c < 4; c++) {
        h8v q8 = *(const h8v*)&q[c * 8];
        h8v k8 = *(const h8v*)&Ks[sidx][(((h * 4 + c) ^ (sidx & 7)) * 8)];
        #pragma unroll
        for (int e = 0; e < 8; e++) s += (float)q8[e] * (float)k8[e];
    }
    float m = s;
    #pragma unroll
    for (int off = 8; off; off >>= 1) m = fmaxf(m, __shfl_xor(m, off, 16));
    float e = expf(s - m);
    float sum = e;
    #pragma unroll
    for (int off = 8; off; off >>= 1) sum += __shfl_xor(sum, off, 16);
    p_s[sub][h][k] = e / sum;
    __syncthreads();
    const int d0 = t * 2;
    const int hh = d0 >> 5, dd = d0 & 31;
    float o0 = 0.f, o1 = 0.f;
    #pragma unroll
    for (int kk = 0; kk < 16; kk++) {
        int gg = gid_s[sub][kk];
        const h16* vr = &QKV16[(size_t)gg * 768 + 512 + hh * HDX + dd];
        float p = p_s[sub][hh][kk];
        o0 += p * (float)vr[0];
        o1 += p * (float)vr[1];
    }
    size_t base = (size_t)row * DD + d0;
    AO16[base] = (h16)o0;
    AO16[base + 1] = (h16)o1;
}

// ----------------------------------------------------------------
extern "C" void kernel_launch(void* const* d_in, const int* in_sizes, int n_in,
                              void* d_out, int out_size, void* d_ws, size_t ws_size,
                              hipStream_t stream)
{
    const float* obj      = (const float*)d_in[0];
    const float* mp       = (const float*)d_in[1];
    const float* opos     = (const float*)d_in[2];
    const float* mpos     = (const float*)d_in[3];
    const float* a_pre_w  = (const float*)d_in[4];
    const float* a_pre_b  = (const float*)d_in[5];
    const float* a_mlp_w1 = (const float*)d_in[6];
    const float* a_mlp_b1 = (const float*)d_in[7];
    const float* a_mlp_w2 = (const float*)d_in[8];
    const float* a_mlp_b2 = (const float*)d_in[9];
    const float* a_out_w1 = (const float*)d_in[10];
    const float* a_out_b1 = (const float*)d_in[11];
    const float* a_out_w2 = (const float*)d_in[12];
    const float* a_out_b2 = (const float*)d_in[13];
    const float* m_pre_w1 = (const float*)d_in[14];
    const float* m_pre_b1 = (const float*)d_in[15];
    const float* m_pre_w2 = (const float*)d_in[16];
    const float* m_pre_b2 = (const float*)d_in[17];
    const float* m_pre_w3 = (const float*)d_in[18];
    const float* m_pre_b3 = (const float*)d_in[19];
    const float* m_mlp_w1 = (const float*)d_in[20];
    const float* m_mlp_b1 = (const float*)d_in[21];
    const float* m_mlp_w2 = (const float*)d_in[22];
    const float* m_mlp_b2 = (const float*)d_in[23];
    const float* m_out_w1 = (const float*)d_in[24];
    const float* m_out_b1 = (const float*)d_in[25];
    const float* m_out_w2 = (const float*)d_in[26];
    const float* m_out_b2 = (const float*)d_in[27];
    const float* attn_wqkv = (const float*)d_in[28];
    const float* attn_bqkv = (const float*)d_in[29];
    const float* attn_wo   = (const float*)d_in[30];
    const float* attn_bo   = (const float*)d_in[31];
    const float* ffn_w1    = (const float*)d_in[32];
    const float* ffn_b1    = (const float*)d_in[33];
    const float* ffn_w2    = (const float*)d_in[34];
    const float* ffn_b2    = (const float*)d_in[35];
    const float* ln1_g     = (const float*)d_in[36];
    const float* ln1_b     = (const float*)d_in[37];
    const float* ln2_g     = (const float*)d_in[38];
    const float* ln2_b     = (const float*)d_in[39];

    const size_t M = MTOT;  // 13312
    float* ws   = (float*)d_ws;
    float* X    = ws;                 // M*256 f32 (pre-phase only)
    float* PEr  = X   + M * 256;      // M*256 f32 region (PE16 uses first half)
    float* QKVr = PEr + M * 256;      // M*768 f32-sized region (aliased below)
    float* H    = QKVr + M * 768;     // M*256 f32 (unused in loop now; kept for layout)
    h16* AO16   = (h16*)(H + M * 256);   // M*256 fp16
    h16* X16    = AO16 + M * 256;
    h16* XP16   = X16  + M * 256;
    h16* H16    = XP16 + M * 256;
    h16* whf    = H16  + M * 256;     // 4,718,592 fp16
    h16* wpnf   = whf  + 4718592;     // WPN_TOT fp16
    int* IDX    = (int*)(wpnf + WPN_TOT);

    h16* PE16 = (h16*)PEr;            // M*256 fp16

    // layer-loop aliases over the QKVr region (disjoint lifetimes):
    h16* QKV16 = (h16*)QKVr;          // M*768 fp16 (live QKV-gemm..attn)
    h16* F116  = (h16*)QKVr;          // M*1024 fp16 (live FFN1..FFN2)

    // pointnet-phase aliases (region QKVr..whf dead window)
    h16* PN0f = (h16*)QKVr;           // MAPR*64 = 15,728,640 fp16
    h16* PN1f = PN0f + 15728640;
    h16* SB   = PN0f + 31457280;
    h16* PLf  = SB;
    h16* GMf  = SB + 786432;
    h16* HVf  = SB + 1572864;
    h16* APLf = SB + 2359296;
    h16* AGMf = SB + 2621440;
    h16* AHVf = SB + 2883584;
    float* PCf = (float*)(SB + 3145728);
    float* APC = PCf + 786432;

    // ---------------- pre-phase ----------------
    knn_kernel<<<BB * 208, 256, 0, stream>>>(opos, mpos, IDX);
    pe_kernel<<<MTOT, 256, 0, stream>>>(opos, mpos, PE16);
    cvt_weights<<<4718592 / 256, 256, 0, stream>>>(attn_wqkv, attn_wo, ffn_w1, ffn_w2, whf);
    cvt_pn_weights<<<WPN_TOT / 256, 256, 0, stream>>>(
        m_pre_w1, m_pre_w2, m_pre_w3, m_mlp_w1, m_mlp_w2, m_out_w1, m_out_w2,
        a_pre_w, a_mlp_w1, a_mlp_w2, a_out_w1, a_out_w2, wpnf);

    // ---- agent pointnet as GEMM chain
    {
        h16* PA32 = PN1f;
        h16* PB   = PN0f;
        h16* PA2  = PN1f;
        prep_agent<<<21504 * 32 / 256, 256, 0, stream>>>(obj, PA32);
        gemm_pn<128, true, true, false><<<dim3(168, 2), 256, 0, stream>>>(
            PA32, wpnf + APW_O, a_pre_b, nullptr, 1, 0,
            nullptr, PB, 32, 256, 1, 0, 0);
        pool_max<21><<<1024, 256, 0, stream>>>(PB, APLf, 8, 0);
        gemm_pn<128, false, false, false><<<dim3(8, 2), 256, 0, stream>>>(
            APLf, wpnf + AW1B_O, a_mlp_b1, nullptr, 1, 0,
            APC, nullptr, 256, 256, 1, 0, 0);
        gemm_pn<128, true, true, false><<<dim3(168, 2), 256, 0, stream>>>(
            PB, wpnf + AW1A_O, nullptr, APC, 21, 256,
            nullptr, PA2, 256, 256, 1, 0, 0);
        gemm_pn<128, true, true, false><<<dim3(168, 2), 256, 0, stream>>>(
            PA2, wpnf + AW2S_O, a_mlp_b2, nullptr, 1, 0,
            nullptr, PB, 256, 256, 1, 0, 0);
        pool_max<21><<<1024, 256, 0, stream>>>(PB, AGMf, 8, 0);
        gemm_pn<128, true, true, false><<<dim3(8, 2), 256, 0, stream>>>(
            AGMf, wpnf + AOW1_O, a_out_b1, nullptr, 1, 0,
            nullptr, AHVf, 256, 256, 1, 0, 0);
        gemm_pn<128, false, false, true><<<dim3(8, 2), 256, 0, stream>>>(
            AHVf, wpnf + AOW2_O, a_out_b2, nullptr, 1, 0,
            X, nullptr, 256, 256, 64, 768, 0);
    }

    // ---- map pointnet as GEMM chain, single pass (M = 245760)
    {
        prep_map<<<MAPR * 32 / 256, 256, 0, stream>>>(mp, PN0f);
        gemm_pn<64, true, true, false><<<dim3(1920, 1), 256, 0, stream>>>(
            PN0f, wpnf + W1P_O, m_pre_b1, nullptr, 1, 0,
            nullptr, PN1f, 32, 64, 1, 0, 0);
        gemm_pn<64, true, true, false><<<dim3(1920, 1), 256, 0, stream>>>(
            PN1f, wpnf + W2S_O, m_pre_b2, nullptr, 1, 0,
            nullptr, PN0f, 64, 64, 1, 0, 0);
        gemm_pn<64, true, true, false><<<dim3(1920, 1), 256, 0, stream>>>(
            PN0f, wpnf + W3S_O, m_pre_b3, nullptr, 1, 0,
            nullptr, PN1f, 64, 64, 1, 0, 0);
        pool_max<20><<<12288 * 64 / 256, 256, 0, stream>>>(PN1f, PLf, 6, 0);
        gemm_pn<64, false, false, false><<<dim3(96, 1), 256, 0, stream>>>(
            PLf, wpnf + MW1B_O, m_mlp_b1, nullptr, 1, 0,
            PCf, nullptr, 64, 64, 1, 0, 0);
        gemm_pn<64, true, true, false><<<dim3(1920, 1), 256, 0, stream>>>(
            PN1f, wpnf + MW1A_O, nullptr, PCf, 20, 64,
            nullptr, PN0f, 64, 64, 1, 0, 0);
        gemm_pn<64, true, true, false><<<dim3(1920, 1), 256, 0, stream>>>(
            PN0f, wpnf + MW2S_O, m_mlp_b2, nullptr, 1, 0,
            nullptr, PN1f, 64, 64, 1, 0, 0);
        pool_max<20><<<12288 * 64 / 256, 256, 0, stream>>>(PN1f, GMf, 6, 0);
        gemm_pn<64, true, true, false><<<dim3(96, 1), 256, 0, stream>>>(
            GMf, wpnf + OW1S_O, m_out_b1, nullptr, 1, 0,
            nullptr, HVf, 64, 64, 1, 0, 0);
        gemm_pn<128, false, false, true><<<dim3(96, 2), 256, 0, stream>>>(
            HVf, wpnf + OW2S_O, m_out_b2, nullptr, 1, 0,
            X, nullptr, 64, 256, 768, 64, 64);
    }

    split_x0<<<(int)(M * 256 / 1024), 256, 0, stream>>>(X, PE16, X16, XP16);

    // ---------------- transformer layers (all-fp16 streams) ----------------
    const float scal = 0.17677669529663687f;  // 32^-0.5
    const int MB = MTOT / 128;  // 104
    const int NOA2 = 0x7fffffff;
    for (int l = 0; l < LL; l++) {
        const size_t wb = (size_t)l * 786432;
        const h16* wqkv_f = whf + wb;
        const h16* wo_f   = whf + wb + 196608;
        const h16* f1_f   = whf + wb + 262144;
        const h16* f2_f   = whf + wb + 524288;
        const float* bqkv = attn_bqkv + (size_t)l * 768;
        // QKV (merged, fp16 out): cols [0,512) read XP16, cols [512,768) read X16
        gemm_mfma<false, true><<<dim3(MB, 6), 256, 0, stream>>>(
            XP16, X16, 512, wqkv_f, bqkv,
            nullptr, QKV16, 256, 768, 0, scal, 256);
        attn_kernel<<<MTOT / 2, 256, 0, stream>>>(QKV16, IDX, AO16);
        // O-proj + residual(X16) + ln1 -> H16
        gemm_ln<0><<<MTOT / 32, 512, 0, stream>>>(
            AO16, wo_f, attn_bo + (size_t)l * 256, X16,
            ln1_g + l * 256, ln1_b + l * 256,
            nullptr, H16, nullptr, nullptr, 256);
        // FFN1 (relu) -> F116 (over dead QKV16)
        gemm_mfma<true, true><<<dim3(MB, 8), 256, 0, stream>>>(
            H16, nullptr, NOA2, f1_f, ffn_b1 + (size_t)l * 1024,
            nullptr, F116, 256, 1024, 0, 1.f, 0);
        // FFN2 + residual(H16) + ln2 -> X16/XP16 or d_out
        if (l == LL - 1) {
            gemm_ln<2><<<MTOT / 32, 512, 0, stream>>>(
                F116, f2_f, ffn_b2 + (size_t)l * 256, H16,
                ln2_g + l * 256, ln2_b + l * 256,
                (float*)d_out, nullptr, nullptr, nullptr, 1024);
        } else {
            gemm_ln<1><<<MTOT / 32, 512, 0, stream>>>(
                F116, f2_f, ffn_b2 + (size_t)l * 256, H16,
                ln2_g + l * 256, ln2_b + l * 256,
                nullptr, X16, PE16, XP16, 1024);
        }
    }
}

// Round 18
// 732.995 us; speedup vs baseline: 2.4519x; 1.1511x over previous
//
#include <hip/hip_runtime.h>
#include <hip/hip_bf16.h>

typedef unsigned short u16;
typedef _Float16 h16;

#define BB 16
#define NO 64
#define TT 21
#define NM 768
#define PP 20
#define CAx 29
#define CMx 9
#define DD 256
#define HH 8
#define LL 6
#define KK 16
#define NN (NO + NM)        // 832
#define HDX (DD / HH)       // 32
#define MTOT (BB * NN)      // 13312
#define MAPR (BB * NM * PP) // 245760 map point-rows

typedef __attribute__((ext_vector_type(8))) h16 h8v;
typedef __attribute__((ext_vector_type(4))) h16 h4v;
typedef __attribute__((ext_vector_type(4))) float f4v;

#define GLOAD_LDS16(gptr, lptr)                                                             \
    __builtin_amdgcn_global_load_lds(                                                       \
        (const __attribute__((address_space(1))) void*)(gptr),                              \
        (__attribute__((address_space(3))) void*)(lptr), 16, 0, 0)

// Bank-conflict swizzle for [rows][32]-fp16 linear tiles (gload_lds-compatible):
// physical 16B slot s_phys at row R holds logical k-slot s_phys ^ ((R>>1)&3).
#define SWZ_LCOL(lane)   ((((lane) & 3) ^ (((lane) >> 3) & 3)) * 8)
#define SWZ_RD(kb, fr)   ((((kb) ^ (((fr) >> 1) & 3))) * 8)
// element address within a [*][32] tile row (h16 units) for logical col kl (0..31)
#define SWZ_ELEM(row, kl) (((((kl) >> 3) ^ (((row) >> 1) & 3)) << 3) | ((kl) & 7))

// ---------------------------------------------------------------- KNN (top-16 smallest d2)
__global__ __launch_bounds__(256) void knn_kernel(
    const float* __restrict__ opos, const float* __restrict__ mpos, int* __restrict__ IDX)
{
    const int b = blockIdx.x / 208;
    const int blk = blockIdx.x % 208;
    __shared__ float px[NN], py[NN], pz[NN];
    for (int i = threadIdx.x; i < NN; i += 256) {
        const float* src = (i < NO) ? &opos[(size_t)(b * NO + i) * 3]
                                    : &mpos[(size_t)(b * NM + (i - NO)) * 3];
        px[i] = src[0]; py[i] = src[1]; pz[i] = src[2];
    }
    __syncthreads();
    const int wave = threadIdx.x >> 6, lane = threadIdx.x & 63;
    const int n = blk * 4 + wave;
    const float qx = px[n], qy = py[n], qz = pz[n];
    float d[13];
    #pragma unroll
    for (int s = 0; s < 13; s++) {
        int j = s * 64 + lane;
        float dx = qx - px[j], dy = qy - py[j], dz = qz - pz[j];
        d[s] = dx * dx + dy * dy + dz * dz;
    }
    int keep = 0;
    #pragma unroll
    for (int it = 0; it < 16; it++) {
        float bv = d[0]; int bs = 0;
        #pragma unroll
        for (int s = 1; s < 13; s++) { if (d[s] < bv) { bv = d[s]; bs = s; } }
        float v = bv; int jj = bs * 64 + lane;
        #pragma unroll
        for (int off = 32; off; off >>= 1) {
            float ov = __shfl_xor(v, off);
            int oj = __shfl_xor(jj, off);
            if (ov < v || (ov == v && oj < jj)) { v = ov; jj = oj; }
        }
        if (lane == (jj & 63)) {
            int sl = jj >> 6;
            #pragma unroll
            for (int s = 0; s < 13; s++) if (s == sl) d[s] = 3.4e38f;
        }
        if (lane == it) keep = jj;
    }
    if (lane < 16) IDX[((size_t)(b * NN + n)) * 16 + lane] = keep;
}

// ---------------------------------------------------------------- sine positional embedding (fp16 out)
__global__ __launch_bounds__(256) void pe_kernel(
    const float* __restrict__ opos, const float* __restrict__ mpos, h16* __restrict__ PE16)
{
    const int row = blockIdx.x;            // b*NN + n
    const int b = row / NN, n = row % NN;
    const int c = threadIdx.x;
    const float* p = (n < NO) ? &opos[(size_t)(b * NO + n) * 3]
                              : &mpos[(size_t)(b * NM + (n - NO)) * 3];
    float x = p[0], y = p[1];
    int j = c & 127;
    float v = (c < 128) ? y : x;
    float inv_dt = exp2f(-(float)(j & ~1) * 0.10381025296523f);
    float e = v * 6.283185307179586f * inv_dt;
    PE16[(size_t)row * DD + c] = (h16)((j & 1) ? cosf(e) : sinf(e));
}

// ---------------------------------------------------------------- transformer weight cvt->fp16
__global__ __launch_bounds__(256) void cvt_weights(
    const float* __restrict__ wqkv, const float* __restrict__ wo,
    const float* __restrict__ f1w, const float* __restrict__ f2w,
    h16* __restrict__ whf)
{
    size_t e = (size_t)blockIdx.x * 256 + threadIdx.x;
    int L = (int)(e / 786432);
    int r = (int)(e % 786432);
    float v;
    if (r < 196608)      v = wqkv[(size_t)L * 196608 + r];
    else if (r < 262144) v = wo[(size_t)L * 65536 + (r - 196608)];
    else if (r < 524288) v = f1w[(size_t)L * 262144 + (r - 262144)];
    else                 v = f2w[(size_t)L * 262144 + (r - 524288)];
    whf[e] = (h16)v;
}

// ---------------------------------------------------------------- pointnet weight cvt (packed)
#define W1P_O   0
#define W2S_O   2048
#define W3S_O   6144
#define MW1A_O  10240
#define MW1B_O  14336
#define MW2S_O  18432
#define OW1S_O  22528
#define OW2S_O  26624
#define APW_O   43008
#define AW1A_O  51200
#define AW1B_O  116736
#define AW2S_O  182272
#define AOW1_O  247808
#define AOW2_O  313344
#define WPN_TOT 378880
__global__ __launch_bounds__(256) void cvt_pn_weights(
    const float* __restrict__ m_pre_w1, const float* __restrict__ m_pre_w2,
    const float* __restrict__ m_pre_w3, const float* __restrict__ m_mlp_w1,
    const float* __restrict__ m_mlp_w2, const float* __restrict__ m_out_w1,
    const float* __restrict__ m_out_w2,
    const float* __restrict__ a_pre_w,  const float* __restrict__ a_mlp_w1,
    const float* __restrict__ a_mlp_w2, const float* __restrict__ a_out_w1,
    const float* __restrict__ a_out_w2,
    h16* __restrict__ wpnf)
{
    int e = blockIdx.x * 256 + threadIdx.x;
    float v;
    if (e < W2S_O)       { int n = e >> 5, k = e & 31; v = (k < 9) ? m_pre_w1[n * 9 + k] : 0.f; }
    else if (e < W3S_O)  v = m_pre_w2[e - W2S_O];
    else if (e < MW1A_O) v = m_pre_w3[e - W3S_O];
    else if (e < MW1B_O) { int r = e - MW1A_O; v = m_mlp_w1[(r >> 6) * 128 + (r & 63)]; }
    else if (e < MW2S_O) { int r = e - MW1B_O; v = m_mlp_w1[(r >> 6) * 128 + 64 + (r & 63)]; }
    else if (e < OW1S_O) v = m_mlp_w2[e - MW2S_O];
    else if (e < OW2S_O) v = m_out_w1[e - OW1S_O];
    else if (e < APW_O)  v = m_out_w2[e - OW2S_O];
    else if (e < AW1A_O) { int r = e - APW_O; int n = r >> 5, k = r & 31; v = (k < 30) ? a_pre_w[n * 30 + k] : 0.f; }
    else if (e < AW1B_O) { int r = e - AW1A_O; v = a_mlp_w1[(r >> 8) * 512 + (r & 255)]; }
    else if (e < AW2S_O) { int r = e - AW1B_O; v = a_mlp_w1[(r >> 8) * 512 + 256 + (r & 255)]; }
    else if (e < AOW1_O) v = a_mlp_w2[e - AW2S_O];
    else if (e < AOW2_O) v = a_out_w1[e - AOW1_O];
    else                 v = a_out_w2[e - AOW2_O];
    wpnf[e] = (h16)v;
}

// ---------------------------------------------------------------- pointnet input prep (pad + cvt)
__global__ __launch_bounds__(256) void prep_map(
    const float* __restrict__ mp, h16* __restrict__ pa)
{
    int e = blockIdx.x * 256 + threadIdx.x;
    int r = e >> 5, c = e & 31;
    float v = (c < CMx) ? mp[(size_t)r * CMx + c] : 0.f;
    pa[e] = (h16)v;
}
__global__ __launch_bounds__(256) void prep_agent(
    const float* __restrict__ obj, h16* __restrict__ pa)
{
    int e = blockIdx.x * 256 + threadIdx.x;
    int r = e >> 5, c = e & 31;
    float v = (c < CAx) ? obj[(size_t)r * CAx + c] : ((c == CAx) ? 1.0f : 0.f);
    pa[e] = (h16)v;
}

// ---------------------------------------------------------------- max-pool over P points
template<int P>
__global__ __launch_bounds__(256) void pool_max(
    const h16* __restrict__ in, h16* __restrict__ out, int cshift, int gout_off)
{
    int e = blockIdx.x * 256 + threadIdx.x;
    int C = 1 << cshift;
    int g = e >> cshift, c = e & (C - 1);
    float m = -3.4e38f;
    #pragma unroll
    for (int p = 0; p < P; p++) {
        float v = (float)in[(size_t)(g * P + p) * C + c];
        m = fmaxf(m, v);
    }
    out[(size_t)(gout_off + g) * C + c] = (h16)m;
}

// ---------------------------------------------------------------- pointnet GEMM (fp16 MFMA)
template<int BN, bool RELU, bool F16OUT, bool ROWMAP>
__global__ __launch_bounds__(256) void gemm_pn(
    const h16* __restrict__ A, const h16* __restrict__ W,
    const float* __restrict__ bias,
    const float* __restrict__ addrow, int ardiv, int arld,
    float* __restrict__ Cf, h16* __restrict__ C16,
    int K, int ldc, int rm_div, int rm_mul, int rm_add)
{
    constexpr int WAVES_M = (BN == 64) ? 4 : 2;
    constexpr int WM = 128 / (16 * WAVES_M);
    __shared__ __align__(16) h16 AS[128][32];
    __shared__ __align__(16) h16 WS[BN][32];
    const int m0 = blockIdx.x * 128;
    const int n0 = blockIdx.y * BN;
    const int tid = threadIdx.x;
    const int wave = tid >> 6, lane = tid & 63;
    const int wr = (BN == 64) ? wave : (wave >> 1);
    const int wc = (BN == 64) ? 0 : (wave & 1);
    const int fr = lane & 15, kb = lane >> 4;
    const int lrow = lane >> 2, lcol = SWZ_LCOL(lane);
    const int rdo = SWZ_RD(kb, fr);

    f4v acc[WM][4];
    #pragma unroll
    for (int i = 0; i < WM; i++)
        #pragma unroll
        for (int j = 0; j < 4; j++) { f4v z = {0.f, 0.f, 0.f, 0.f}; acc[i][j] = z; }

    for (int k0 = 0; k0 < K; k0 += 32) {
        __syncthreads();
        #pragma unroll
        for (int i = 0; i < 2; i++) {
            const int r = wave * 32 + i * 16;
            GLOAD_LDS16(&A[(size_t)(m0 + r + lrow) * K + k0 + lcol], &AS[r][0]);
        }
        if constexpr (BN == 64) {
            const int r = wave * 16;
            GLOAD_LDS16(&W[(size_t)(n0 + r + lrow) * K + k0 + lcol], &WS[r][0]);
        } else {
            #pragma unroll
            for (int i = 0; i < 2; i++) {
                const int r = wave * 32 + i * 16;
                GLOAD_LDS16(&W[(size_t)(n0 + r + lrow) * K + k0 + lcol], &WS[r][0]);
            }
        }
        __syncthreads();
        h8v af[WM];
        #pragma unroll
        for (int mi = 0; mi < WM; mi++)
            af[mi] = *(const h8v*)&AS[wr * (WM * 16) + mi * 16 + fr][rdo];
        #pragma unroll
        for (int nj = 0; nj < 4; nj++) {
            h8v bf = *(const h8v*)&WS[wc * 64 + nj * 16 + fr][rdo];
            #pragma unroll
            for (int mi = 0; mi < WM; mi++)
                acc[mi][nj] = __builtin_amdgcn_mfma_f32_16x16x32_f16(af[mi], bf, acc[mi][nj], 0, 0, 0);
        }
    }
    #pragma unroll
    for (int mi = 0; mi < WM; mi++) {
        #pragma unroll
        for (int nj = 0; nj < 4; nj++) {
            int col = n0 + wc * 64 + nj * 16 + fr;
            float bb = bias ? bias[col] : 0.f;
            #pragma unroll
            for (int r = 0; r < 4; r++) {
                int row = m0 + wr * (WM * 16) + mi * 16 + (lane >> 4) * 4 + r;
                float v = acc[mi][nj][r] + bb;
                if (addrow) v += addrow[(size_t)(row / ardiv) * arld + col];
                if (RELU) v = fmaxf(v, 0.f);
                if (F16OUT) {
                    C16[(size_t)row * ldc + col] = (h16)v;
                } else {
                    int drow = row;
                    if (ROWMAP) drow = row + rm_add + (row / rm_div) * rm_mul;
                    Cf[(size_t)drow * ldc + col] = v;
                }
            }
        }
    }
}

// ---------------------------------------------------------------- fused map pre1->pre2->pre3
// 128 rows/block, 4 waves; intermediates chained through LDS (A-layout relayout).
__global__ __launch_bounds__(256) void fused_map3(
    const h16* __restrict__ A,   // [MAPR][32]
    const h16* __restrict__ W1,  // [64][32]
    const h16* __restrict__ W2, const h16* __restrict__ W3,  // [64][64]
    const float* __restrict__ b1, const float* __restrict__ b2, const float* __restrict__ b3,
    h16* __restrict__ Out)       // [MAPR][64]
{
    __shared__ __align__(16) h16 AS[128][32];
    __shared__ __align__(16) h16 G0[2][128][32];
    __shared__ __align__(16) h16 G1[2][128][32];
    __shared__ __align__(16) h16 W1S[64][32];
    __shared__ __align__(16) h16 W2S[2][64][32];
    __shared__ __align__(16) h16 W3S[2][64][32];
    const int m0 = blockIdx.x * 128;
    const int tid = threadIdx.x;
    const int wave = tid >> 6, lane = tid & 63;
    const int fr = lane & 15, kb = lane >> 4;
    const int lrow = lane >> 2, lcol = SWZ_LCOL(lane);
    const int rdo = SWZ_RD(kb, fr);

    #pragma unroll
    for (int q = 0; q < 2; q++)
        GLOAD_LDS16(&A[(size_t)(m0 + wave * 32 + q * 16 + lrow) * 32 + lcol],
                    &AS[wave * 32 + q * 16][0]);
    GLOAD_LDS16(&W1[(size_t)(wave * 16 + lrow) * 32 + lcol], &W1S[wave * 16][0]);
    #pragma unroll
    for (int t = 0; t < 2; t++) {
        GLOAD_LDS16(&W2[(size_t)(wave * 16 + lrow) * 64 + t * 32 + lcol], &W2S[t][wave * 16][0]);
        GLOAD_LDS16(&W3[(size_t)(wave * 16 + lrow) * 64 + t * 32 + lcol], &W3S[t][wave * 16][0]);
    }
    __syncthreads();
    // L1 (K=32) -> G0
    #pragma unroll
    for (int mi = 0; mi < 2; mi++) {
        h8v af = *(const h8v*)&AS[wave * 32 + mi * 16 + fr][rdo];
        #pragma unroll
        for (int nj = 0; nj < 4; nj++) {
            f4v a = {0.f, 0.f, 0.f, 0.f};
            h8v bf = *(const h8v*)&W1S[nj * 16 + fr][rdo];
            a = __builtin_amdgcn_mfma_f32_16x16x32_f16(af, bf, a, 0, 0, 0);
            int col = nj * 16 + fr, ch = col >> 5, kl = col & 31;
            float bb = b1[col];
            #pragma unroll
            for (int r = 0; r < 4; r++) {
                int row = wave * 32 + mi * 16 + kb * 4 + r;
                G0[ch][row][SWZ_ELEM(row, kl)] = (h16)fmaxf(a[r] + bb, 0.f);
            }
        }
    }
    __syncthreads();
    // L2 (K=64) -> G1
    #pragma unroll
    for (int mi = 0; mi < 2; mi++) {
        #pragma unroll
        for (int nj = 0; nj < 4; nj++) {
            f4v a = {0.f, 0.f, 0.f, 0.f};
            #pragma unroll
            for (int t = 0; t < 2; t++) {
                h8v af = *(const h8v*)&G0[t][wave * 32 + mi * 16 + fr][rdo];
                h8v bf = *(const h8v*)&W2S[t][nj * 16 + fr][rdo];
                a = __builtin_amdgcn_mfma_f32_16x16x32_f16(af, bf, a, 0, 0, 0);
            }
            int col = nj * 16 + fr, ch = col >> 5, kl = col & 31;
            float bb = b2[col];
            #pragma unroll
            for (int r = 0; r < 4; r++) {
                int row = wave * 32 + mi * 16 + kb * 4 + r;
                G1[ch][row][SWZ_ELEM(row, kl)] = (h16)fmaxf(a[r] + bb, 0.f);
            }
        }
    }
    __syncthreads();
    // L3 (K=64) -> global
    #pragma unroll
    for (int mi = 0; mi < 2; mi++) {
        #pragma unroll
        for (int nj = 0; nj < 4; nj++) {
            f4v a = {0.f, 0.f, 0.f, 0.f};
            #pragma unroll
            for (int t = 0; t < 2; t++) {
                h8v af = *(const h8v*)&G1[t][wave * 32 + mi * 16 + fr][rdo];
                h8v bf = *(const h8v*)&W3S[t][nj * 16 + fr][rdo];
                a = __builtin_amdgcn_mfma_f32_16x16x32_f16(af, bf, a, 0, 0, 0);
            }
            int col = nj * 16 + fr;
            float bb = b3[col];
            #pragma unroll
            for (int r = 0; r < 4; r++) {
                int row = m0 + wave * 32 + mi * 16 + kb * 4 + r;
                Out[(size_t)row * 64 + col] = (h16)fmaxf(a[r] + bb, 0.f);
            }
        }
    }
}

// ---------------------------------------------------------------- fused map mid1->mid2
__global__ __launch_bounds__(256) void fused_map2(
    const h16* __restrict__ A,   // [MAPR][64] (pre3 out)
    const h16* __restrict__ W1,  // MW1A [64][64]
    const h16* __restrict__ W2,  // MW2S [64][64]
    const float* __restrict__ b1, const float* __restrict__ b2,
    const float* __restrict__ pooled,  // PCf [12288][64] f32
    h16* __restrict__ Out)       // [MAPR][64]
{
    __shared__ __align__(16) h16 AS[2][128][32];
    __shared__ __align__(16) h16 G0[2][128][32];
    __shared__ __align__(16) h16 W1S[2][64][32];
    __shared__ __align__(16) h16 W2S[2][64][32];
    const int m0 = blockIdx.x * 128;
    const int tid = threadIdx.x;
    const int wave = tid >> 6, lane = tid & 63;
    const int fr = lane & 15, kb = lane >> 4;
    const int lrow = lane >> 2, lcol = SWZ_LCOL(lane);
    const int rdo = SWZ_RD(kb, fr);

    #pragma unroll
    for (int t = 0; t < 2; t++) {
        #pragma unroll
        for (int q = 0; q < 2; q++)
            GLOAD_LDS16(&A[(size_t)(m0 + wave * 32 + q * 16 + lrow) * 64 + t * 32 + lcol],
                        &AS[t][wave * 32 + q * 16][0]);
        GLOAD_LDS16(&W1[(size_t)(wave * 16 + lrow) * 64 + t * 32 + lcol], &W1S[t][wave * 16][0]);
        GLOAD_LDS16(&W2[(size_t)(wave * 16 + lrow) * 64 + t * 32 + lcol], &W2S[t][wave * 16][0]);
    }
    __syncthreads();
    // mid1 (K=64, + pooled row-broadcast) -> G0
    #pragma unroll
    for (int mi = 0; mi < 2; mi++) {
        #pragma unroll
        for (int nj = 0; nj < 4; nj++) {
            f4v a = {0.f, 0.f, 0.f, 0.f};
            #pragma unroll
            for (int t = 0; t < 2; t++) {
                h8v af = *(const h8v*)&AS[t][wave * 32 + mi * 16 + fr][rdo];
                h8v bf = *(const h8v*)&W1S[t][nj * 16 + fr][rdo];
                a = __builtin_amdgcn_mfma_f32_16x16x32_f16(af, bf, a, 0, 0, 0);
            }
            int col = nj * 16 + fr, ch = col >> 5, kl = col & 31;
            float bb = b1[col];
            #pragma unroll
            for (int r = 0; r < 4; r++) {
                int row = wave * 32 + mi * 16 + kb * 4 + r;
                int grow = m0 + row;
                float v = a[r] + bb + pooled[(size_t)(grow / PP) * 64 + col];
                G0[ch][row][SWZ_ELEM(row, kl)] = (h16)fmaxf(v, 0.f);
            }
        }
    }
    __syncthreads();
    // mid2 (K=64) -> global
    #pragma unroll
    for (int mi = 0; mi < 2; mi++) {
        #pragma unroll
        for (int nj = 0; nj < 4; nj++) {
            f4v a = {0.f, 0.f, 0.f, 0.f};
            #pragma unroll
            for (int t = 0; t < 2; t++) {
                h8v af = *(const h8v*)&G0[t][wave * 32 + mi * 16 + fr][rdo];
                h8v bf = *(const h8v*)&W2S[t][nj * 16 + fr][rdo];
                a = __builtin_amdgcn_mfma_f32_16x16x32_f16(af, bf, a, 0, 0, 0);
            }
            int col = nj * 16 + fr;
            float bb = b2[col];
            #pragma unroll
            for (int r = 0; r < 4; r++) {
                int row = m0 + wave * 32 + mi * 16 + kb * 4 + r;
                Out[(size_t)row * 64 + col] = (h16)fmaxf(a[r] + bb, 0.f);
            }
        }
    }
}

// ---------------------------------------------------------------- initial activation cvt
__global__ __launch_bounds__(256) void split_x0(
    const float* __restrict__ X, const h16* __restrict__ PE16,
    h16* __restrict__ X16, h16* __restrict__ XP16)
{
    size_t base = ((size_t)blockIdx.x * 256 + threadIdx.x) * 4;
    float4 x = *(const float4*)&X[base];
    h4v pe = *(const h4v*)&PE16[base];
    h4v a, b;
    a.x = (h16)x.x; a.y = (h16)x.y; a.z = (h16)x.z; a.w = (h16)x.w;
    b.x = (h16)(x.x + (float)pe.x); b.y = (h16)(x.y + (float)pe.y);
    b.z = (h16)(x.z + (float)pe.z); b.w = (h16)(x.w + (float)pe.w);
    *(h4v*)&X16[base] = a;
    *(h4v*)&XP16[base] = b;
}

// ---------------------------------------------------------------- transformer fp16 MFMA GEMM
template<bool RELU, bool F16OUT>
__global__ __launch_bounds__(256) void gemm_mfma(
    const h16* __restrict__ A, const h16* __restrict__ A2, int a2min,
    const h16* __restrict__ W, const float* __restrict__ bias,
    float* __restrict__ Cf, h16* __restrict__ C16,
    int K, int ldc, int coff, float scale, int scale_until)
{
    __shared__ __align__(16) h16 AS[128][32];
    __shared__ __align__(16) h16 WS[128][32];
    const int m0 = blockIdx.x * 128;
    const int n0 = blockIdx.y * 128;
    const h16* pA = (n0 >= a2min) ? A2 : A;
    const int tid = threadIdx.x;
    const int wave = tid >> 6, lane = tid & 63;
    const int wr = wave >> 1, wc = wave & 1;
    const int fr = lane & 15, kb = lane >> 4;
    const int lrow = lane >> 2;
    const int lcol = SWZ_LCOL(lane);
    const int rdo = SWZ_RD(kb, fr);

    f4v acc[4][4];
    #pragma unroll
    for (int i = 0; i < 4; i++)
        #pragma unroll
        for (int j = 0; j < 4; j++) { f4v z = {0.f, 0.f, 0.f, 0.f}; acc[i][j] = z; }

    for (int k0 = 0; k0 < K; k0 += 32) {
        __syncthreads();
        #pragma unroll
        for (int i = 0; i < 2; i++) {
            const int r = wave * 32 + i * 16;
            const size_t grow = (size_t)(r + lrow);
            GLOAD_LDS16(&pA[(m0 + grow) * K + k0 + lcol], &AS[r][0]);
            GLOAD_LDS16(&W [(n0 + grow) * K + k0 + lcol], &WS[r][0]);
        }
        __syncthreads();
        h8v af[4];
        #pragma unroll
        for (int mi = 0; mi < 4; mi++)
            af[mi] = *(const h8v*)&AS[wr * 64 + mi * 16 + fr][rdo];
        #pragma unroll
        for (int nj = 0; nj < 4; nj++) {
            h8v bf = *(const h8v*)&WS[wc * 64 + nj * 16 + fr][rdo];
            #pragma unroll
            for (int mi = 0; mi < 4; mi++)
                acc[mi][nj] = __builtin_amdgcn_mfma_f32_16x16x32_f16(af[mi], bf, acc[mi][nj], 0, 0, 0);
        }
    }
    #pragma unroll
    for (int mi = 0; mi < 4; mi++) {
        #pragma unroll
        for (int nj = 0; nj < 4; nj++) {
            int col = n0 + wc * 64 + nj * 16 + fr;
            float bb = bias[col];
            #pragma unroll
            for (int r = 0; r < 4; r++) {
                int row = m0 + wr * 64 + mi * 16 + (lane >> 4) * 4 + r;
                float v = acc[mi][nj][r] + bb;
                if (RELU) v = fmaxf(v, 0.f);
                int gcol = coff + col;
                if (gcol < scale_until) v *= scale;
                if (F16OUT) {
                    C16[(size_t)row * ldc + gcol] = (h16)v;
                } else {
                    Cf[(size_t)row * ldc + gcol] = v;
                }
            }
        }
    }
}

// ---------------------------------------------------------------- GEMM + residual + LayerNorm (O-proj)
__global__ __launch_bounds__(512) void gemm_ln0(
    const h16* __restrict__ A, const h16* __restrict__ W,
    const float* __restrict__ bias, const h16* __restrict__ R16,
    const float* __restrict__ g, const float* __restrict__ bt,
    h16* __restrict__ O16, int K)
{
    __shared__ __align__(16) h16 AS[32][32];
    __shared__ __align__(16) h16 WS[256][32];
    __shared__ float red_s[2][8][32];
    const int m0 = blockIdx.x * 32;
    const int tid = threadIdx.x;
    const int wave = tid >> 6, lane = tid & 63;
    const int fr = lane & 15, kb = lane >> 4;
    const int lrow = lane >> 2, lcol = SWZ_LCOL(lane);
    const int rdo = SWZ_RD(kb, fr);

    f4v acc[2][2];
    #pragma unroll
    for (int i = 0; i < 2; i++)
        #pragma unroll
        for (int j = 0; j < 2; j++) { f4v z = {0.f, 0.f, 0.f, 0.f}; acc[i][j] = z; }

    for (int k0 = 0; k0 < K; k0 += 32) {
        __syncthreads();
        if (wave < 2) {
            GLOAD_LDS16(&A[(size_t)(m0 + wave * 16 + lrow) * K + k0 + lcol], &AS[wave * 16][0]);
        }
        #pragma unroll
        for (int i = 0; i < 2; i++) {
            const int r = wave * 32 + i * 16;
            GLOAD_LDS16(&W[(size_t)(r + lrow) * K + k0 + lcol], &WS[r][0]);
        }
        __syncthreads();
        h8v af[2];
        #pragma unroll
        for (int mi = 0; mi < 2; mi++)
            af[mi] = *(const h8v*)&AS[mi * 16 + fr][rdo];
        #pragma unroll
        for (int nj = 0; nj < 2; nj++) {
            h8v bf = *(const h8v*)&WS[wave * 32 + nj * 16 + fr][rdo];
            #pragma unroll
            for (int mi = 0; mi < 2; mi++)
                acc[mi][nj] = __builtin_amdgcn_mfma_f32_16x16x32_f16(af[mi], bf, acc[mi][nj], 0, 0, 0);
        }
    }
    float x[2][2][4];
    float rsum[2][4], rsq[2][4];
    #pragma unroll
    for (int mi = 0; mi < 2; mi++)
        #pragma unroll
        for (int r = 0; r < 4; r++) { rsum[mi][r] = 0.f; rsq[mi][r] = 0.f; }
    #pragma unroll
    for (int mi = 0; mi < 2; mi++) {
        #pragma unroll
        for (int nj = 0; nj < 2; nj++) {
            int col = wave * 32 + nj * 16 + fr;
            float bb = bias[col];
            #pragma unroll
            for (int r = 0; r < 4; r++) {
                int row = m0 + mi * 16 + kb * 4 + r;
                float v = acc[mi][nj][r] + bb + (float)R16[(size_t)row * 256 + col];
                x[mi][nj][r] = v;
                rsum[mi][r] += v;
                rsq[mi][r] += v * v;
            }
        }
    }
    #pragma unroll
    for (int off = 1; off < 16; off <<= 1) {
        #pragma unroll
        for (int mi = 0; mi < 2; mi++)
            #pragma unroll
            for (int r = 0; r < 4; r++) {
                rsum[mi][r] += __shfl_xor(rsum[mi][r], off);
                rsq[mi][r]  += __shfl_xor(rsq[mi][r], off);
            }
    }
    if (fr == 0) {
        #pragma unroll
        for (int mi = 0; mi < 2; mi++)
            #pragma unroll
            for (int r = 0; r < 4; r++) {
                int rid = mi * 16 + kb * 4 + r;
                red_s[0][wave][rid] = rsum[mi][r];
                red_s[1][wave][rid] = rsq[mi][r];
            }
    }
    __syncthreads();
    #pragma unroll
    for (int mi = 0; mi < 2; mi++) {
        #pragma unroll
        for (int r = 0; r < 4; r++) {
            int rid = mi * 16 + kb * 4 + r;
            float s = 0.f, sq = 0.f;
            #pragma unroll
            for (int w = 0; w < 8; w++) { s += red_s[0][w][rid]; sq += red_s[1][w][rid]; }
            float mean = s * (1.f / 256.f);
            float var = sq * (1.f / 256.f) - mean * mean;
            float inv = rsqrtf(var + 1e-5f);
            #pragma unroll
            for (int nj = 0; nj < 2; nj++) {
                int col = wave * 32 + nj * 16 + fr;
                float o = (x[mi][nj][r] - mean) * inv * g[col] + bt[col];
                O16[(size_t)(m0 + rid) * 256 + col] = (h16)o;
            }
        }
    }
}

// ---------------------------------------------------------------- fused FFN1+FFN2+residual+LN
// 32 rows/block, 8 waves. H tile resident in LDS; hidden chunked by 64;
// G relayed C->A in LDS; W1/W2 chunks share a 32KB union buffer.
// PEMODE 1: write X16 + XP16(=h16(o+PE)).  PEMODE 2: write fp32 d_out.
template<int PEMODE>
__global__ __launch_bounds__(512) void fused_ffn(
    const h16* __restrict__ H16g, const h16* __restrict__ W1,  // [1024][256]
    const h16* __restrict__ W2,                                 // [256][1024]
    const float* __restrict__ b1, const float* __restrict__ b2,
    const float* __restrict__ g, const float* __restrict__ bt,
    float* __restrict__ OutF, h16* __restrict__ O16,
    const h16* __restrict__ PE16p, h16* __restrict__ P16)
{
    __shared__ __align__(16) h16 HS[8][32][32];    // 16 KB: H tile (also residual)
    __shared__ __align__(16) h16 GS[2][32][32];    // 4 KB: G chunk (64 hidden)
    __shared__ __align__(16) h16 WSu[16384];       // 32 KB: W1-chunk / W2-chunk union
    __shared__ float red_s[2][8][32];
    const int m0 = blockIdx.x * 32;
    const int tid = threadIdx.x;
    const int wave = tid >> 6, lane = tid & 63;
    const int fr = lane & 15, kb = lane >> 4;
    const int lrow = lane >> 2, lcol = SWZ_LCOL(lane);
    const int rdo = SWZ_RD(kb, fr);
    const int mi1 = wave >> 2, nj1 = wave & 3;

    // stage H tile: wave w -> k-tile t=w, 2 gloads
    #pragma unroll
    for (int q = 0; q < 2; q++)
        GLOAD_LDS16(&H16g[(size_t)(m0 + q * 16 + lrow) * 256 + wave * 32 + lcol],
                    &HS[wave][q * 16][0]);

    f4v acc2[2][2];
    #pragma unroll
    for (int i = 0; i < 2; i++)
        #pragma unroll
        for (int j = 0; j < 2; j++) { f4v z = {0.f, 0.f, 0.f, 0.f}; acc2[i][j] = z; }

    for (int c = 0; c < 16; c++) {
        const int H0 = c * 64;
        __syncthreads();   // WSu/GS free from previous chunk
        // stage W1 chunk: k-tile t=wave: rows [H0,H0+64), k=t*32
        #pragma unroll
        for (int q = 0; q < 4; q++)
            GLOAD_LDS16(&W1[(size_t)(H0 + q * 16 + lrow) * 256 + wave * 32 + lcol],
                        &WSu[wave * 2048 + (q * 16) * 32]);
        __syncthreads();   // W1 (and first-iter HS) visible
        // stage-1: one 16x16 fragment per wave (mi1, nj1), K=256
        f4v a1 = {0.f, 0.f, 0.f, 0.f};
        #pragma unroll
        for (int t = 0; t < 8; t++) {
            h8v af = *(const h8v*)&HS[t][mi1 * 16 + fr][rdo];
            h8v bf = *(const h8v*)&WSu[t * 2048 + (nj1 * 16 + fr) * 32 + rdo];
            a1 = __builtin_amdgcn_mfma_f32_16x16x32_f16(af, bf, a1, 0, 0, 0);
        }
        {
            int col = nj1 * 16 + fr, ch = col >> 5, kl = col & 31;
            float bb = b1[H0 + col];
            #pragma unroll
            for (int r = 0; r < 4; r++) {
                int row = mi1 * 16 + kb * 4 + r;
                GS[ch][row][SWZ_ELEM(row, kl)] = (h16)fmaxf(a1[r] + bb, 0.f);
            }
        }
        __syncthreads();   // GS visible; W1 reads done
        // stage W2 chunk: k-tiles t2=0,1 of [256][32]; wave w: rows [w*32,w*32+32)
        #pragma unroll
        for (int t2 = 0; t2 < 2; t2++)
            #pragma unroll
            for (int q = 0; q < 2; q++)
                GLOAD_LDS16(&W2[(size_t)(wave * 32 + q * 16 + lrow) * 1024 + H0 + t2 * 32 + lcol],
                            &WSu[t2 * 8192 + (wave * 32 + q * 16) * 32]);
        __syncthreads();   // W2 visible
        // stage-2: wave owns out cols [wave*32, wave*32+32)
        #pragma unroll
        for (int t2 = 0; t2 < 2; t2++) {
            #pragma unroll
            for (int mi = 0; mi < 2; mi++) {
                h8v af = *(const h8v*)&GS[t2][mi * 16 + fr][rdo];
                #pragma unroll
                for (int nj = 0; nj < 2; nj++) {
                    h8v bf = *(const h8v*)&WSu[t2 * 8192 + (wave * 32 + nj * 16 + fr) * 32 + rdo];
                    acc2[mi][nj] = __builtin_amdgcn_mfma_f32_16x16x32_f16(af, bf, acc2[mi][nj], 0, 0, 0);
                }
            }
        }
    }
    // epilogue: x = HS-residual + acc2 + b2; block-local LN; write
    float x[2][2][4];
    float rsum[2][4], rsq[2][4];
    #pragma unroll
    for (int mi = 0; mi < 2; mi++)
        #pragma unroll
        for (int r = 0; r < 4; r++) { rsum[mi][r] = 0.f; rsq[mi][r] = 0.f; }
    #pragma unroll
    for (int mi = 0; mi < 2; mi++) {
        #pragma unroll
        for (int nj = 0; nj < 2; nj++) {
            int col = wave * 32 + nj * 16 + fr;
            int ch = col >> 5, kl = col & 31;
            float bb = b2[col];
            #pragma unroll
            for (int r = 0; r < 4; r++) {
                int row = mi * 16 + kb * 4 + r;
                float res = (float)HS[ch][row][SWZ_ELEM(row, kl)];
                float v = acc2[mi][nj][r] + bb + res;
                x[mi][nj][r] = v;
                rsum[mi][r] += v;
                rsq[mi][r] += v * v;
            }
        }
    }
    #pragma unroll
    for (int off = 1; off < 16; off <<= 1) {
        #pragma unroll
        for (int mi = 0; mi < 2; mi++)
            #pragma unroll
            for (int r = 0; r < 4; r++) {
                rsum[mi][r] += __shfl_xor(rsum[mi][r], off);
                rsq[mi][r]  += __shfl_xor(rsq[mi][r], off);
            }
    }
    if (fr == 0) {
        #pragma unroll
        for (int mi = 0; mi < 2; mi++)
            #pragma unroll
            for (int r = 0; r < 4; r++) {
                int rid = mi * 16 + kb * 4 + r;
                red_s[0][wave][rid] = rsum[mi][r];
                red_s[1][wave][rid] = rsq[mi][r];
            }
    }
    __syncthreads();
    #pragma unroll
    for (int mi = 0; mi < 2; mi++) {
        #pragma unroll
        for (int r = 0; r < 4; r++) {
            int rid = mi * 16 + kb * 4 + r;
            float s = 0.f, sq = 0.f;
            #pragma unroll
            for (int w = 0; w < 8; w++) { s += red_s[0][w][rid]; sq += red_s[1][w][rid]; }
            float mean = s * (1.f / 256.f);
            float var = sq * (1.f / 256.f) - mean * mean;
            float inv = rsqrtf(var + 1e-5f);
            #pragma unroll
            for (int nj = 0; nj < 2; nj++) {
                int col = wave * 32 + nj * 16 + fr;
                float o = (x[mi][nj][r] - mean) * inv * g[col] + bt[col];
                size_t idx = (size_t)(m0 + rid) * 256 + col;
                if (PEMODE == 2) {
                    OutF[idx] = o;
                } else {
                    O16[idx] = (h16)o;
                    P16[idx] = (h16)(o + (float)PE16p[idx]);
                }
            }
        }
    }
}

// ---------------------------------------------------------------- local KNN attention (fp16 QKV)
__global__ __launch_bounds__(256) void attn_kernel(
    const h16* __restrict__ QKV16, const int* __restrict__ IDX,
    h16* __restrict__ AO16)
{
    __shared__ __align__(16) h16 Ks[32][256];
    __shared__ float p_s[2][HH][16];
    __shared__ int gid_s[2][16];
    const int sub = threadIdx.x >> 7;
    const int t = threadIdx.x & 127;
    const int wave = threadIdx.x >> 6, lane = threadIdx.x & 63;
    const int xcd = blockIdx.x & 7;
    const int j = blockIdx.x >> 3;            // 0..831
    const int b = (j / 416) * 8 + xcd;        // batch
    const int row = b * NN + (j % 416) * 2 + sub;
    const int h = t >> 4, k = t & 15;
    int nb = IDX[(size_t)row * 16 + k];
    int g = b * NN + nb;
    if (h == 0) gid_s[sub][k] = g;
    __syncthreads();
    #pragma unroll
    for (int i = 0; i < 4; i++) {
        int s0 = wave * 8 + i * 2;
        int s = s0 + (lane >> 5);
        int gs = gid_s[s >> 4][s & 15];
        int clog = (lane & 31) ^ (s & 7);
        GLOAD_LDS16(&QKV16[(size_t)gs * 768 + 256 + clog * 8], &Ks[s0][0]);
    }
    __syncthreads();
    const h16* q = &QKV16[(size_t)row * 768 + h * HDX];
    const int sidx = sub * 16 + k;
    float s = 0.f;
    #pragma unroll
    for (int c = 0; c < 4; c++) {
        h8v q8 = *(const h8v*)&q[c * 8];
        h8v k8 = *(const h8v*)&Ks[sidx][(((h * 4 + c) ^ (sidx & 7)) * 8)];
        #pragma unroll
        for (int e = 0; e < 8; e++) s += (float)q8[e] * (float)k8[e];
    }
    float m = s;
    #pragma unroll
    for (int off = 8; off; off >>= 1) m = fmaxf(m, __shfl_xor(m, off, 16));
    float e = expf(s - m);
    float sum = e;
    #pragma unroll
    for (int off = 8; off; off >>= 1) sum += __shfl_xor(sum, off, 16);
    p_s[sub][h][k] = e / sum;
    __syncthreads();
    const int d0 = t * 2;
    const int hh = d0 >> 5, dd = d0 & 31;
    float o0 = 0.f, o1 = 0.f;
    #pragma unroll
    for (int kk = 0; kk < 16; kk++) {
        int gg = gid_s[sub][kk];
        const h16* vr = &QKV16[(size_t)gg * 768 + 512 + hh * HDX + dd];
        float p = p_s[sub][hh][kk];
        o0 += p * (float)vr[0];
        o1 += p * (float)vr[1];
    }
    size_t base = (size_t)row * DD + d0;
    AO16[base] = (h16)o0;
    AO16[base + 1] = (h16)o1;
}

// ----------------------------------------------------------------
extern "C" void kernel_launch(void* const* d_in, const int* in_sizes, int n_in,
                              void* d_out, int out_size, void* d_ws, size_t ws_size,
                              hipStream_t stream)
{
    const float* obj      = (const float*)d_in[0];
    const float* mp       = (const float*)d_in[1];
    const float* opos     = (const float*)d_in[2];
    const float* mpos     = (const float*)d_in[3];
    const float* a_pre_w  = (const float*)d_in[4];
    const float* a_pre_b  = (const float*)d_in[5];
    const float* a_mlp_w1 = (const float*)d_in[6];
    const float* a_mlp_b1 = (const float*)d_in[7];
    const float* a_mlp_w2 = (const float*)d_in[8];
    const float* a_mlp_b2 = (const float*)d_in[9];
    const float* a_out_w1 = (const float*)d_in[10];
    const float* a_out_b1 = (const float*)d_in[11];
    const float* a_out_w2 = (const float*)d_in[12];
    const float* a_out_b2 = (const float*)d_in[13];
    const float* m_pre_w1 = (const float*)d_in[14];
    const float* m_pre_b1 = (const float*)d_in[15];
    const float* m_pre_w2 = (const float*)d_in[16];
    const float* m_pre_b2 = (const float*)d_in[17];
    const float* m_pre_w3 = (const float*)d_in[18];
    const float* m_pre_b3 = (const float*)d_in[19];
    const float* m_mlp_w1 = (const float*)d_in[20];
    const float* m_mlp_b1 = (const float*)d_in[21];
    const float* m_mlp_w2 = (const float*)d_in[22];
    const float* m_mlp_b2 = (const float*)d_in[23];
    const float* m_out_w1 = (const float*)d_in[24];
    const float* m_out_b1 = (const float*)d_in[25];
    const float* m_out_w2 = (const float*)d_in[26];
    const float* m_out_b2 = (const float*)d_in[27];
    const float* attn_wqkv = (const float*)d_in[28];
    const float* attn_bqkv = (const float*)d_in[29];
    const float* attn_wo   = (const float*)d_in[30];
    const float* attn_bo   = (const float*)d_in[31];
    const float* ffn_w1    = (const float*)d_in[32];
    const float* ffn_b1    = (const float*)d_in[33];
    const float* ffn_w2    = (const float*)d_in[34];
    const float* ffn_b2    = (const float*)d_in[35];
    const float* ln1_g     = (const float*)d_in[36];
    const float* ln1_b     = (const float*)d_in[37];
    const float* ln2_g     = (const float*)d_in[38];
    const float* ln2_b     = (const float*)d_in[39];

    const size_t M = MTOT;  // 13312
    float* ws   = (float*)d_ws;
    float* X    = ws;                 // M*256 f32 (pre-phase only)
    float* PEr  = X   + M * 256;      // PE16 region
    float* QKVr = PEr + M * 256;      // aliased region
    float* Hpad = QKVr + M * 768;     // padding region (layout stability)
    h16* AO16   = (h16*)(Hpad + M * 256);
    h16* X16    = AO16 + M * 256;
    h16* XP16   = X16  + M * 256;
    h16* H16    = XP16 + M * 256;
    h16* whf    = H16  + M * 256;     // 4,718,592 fp16
    h16* wpnf   = whf  + 4718592;
    int* IDX    = (int*)(wpnf + WPN_TOT);

    h16* PE16 = (h16*)PEr;

    h16* QKV16 = (h16*)QKVr;          // M*768 fp16 (live QKV-gemm..attn)

    // pointnet-phase aliases (QKVr.. dead window)
    h16* PN0f = (h16*)QKVr;
    h16* PN1f = PN0f + 15728640;
    h16* SB   = PN0f + 31457280;
    h16* PLf  = SB;
    h16* GMf  = SB + 786432;
    h16* HVf  = SB + 1572864;
    h16* APLf = SB + 2359296;
    h16* AGMf = SB + 2621440;
    h16* AHVf = SB + 2883584;
    float* PCf = (float*)(SB + 3145728);
    float* APC = PCf + 786432;

    // ---------------- pre-phase ----------------
    knn_kernel<<<BB * 208, 256, 0, stream>>>(opos, mpos, IDX);
    pe_kernel<<<MTOT, 256, 0, stream>>>(opos, mpos, PE16);
    cvt_weights<<<4718592 / 256, 256, 0, stream>>>(attn_wqkv, attn_wo, ffn_w1, ffn_w2, whf);
    cvt_pn_weights<<<WPN_TOT / 256, 256, 0, stream>>>(
        m_pre_w1, m_pre_w2, m_pre_w3, m_mlp_w1, m_mlp_w2, m_out_w1, m_out_w2,
        a_pre_w, a_mlp_w1, a_mlp_w2, a_out_w1, a_out_w2, wpnf);

    // ---- agent pointnet as GEMM chain
    {
        h16* PA32 = PN1f;
        h16* PB   = PN0f;
        h16* PA2  = PN1f;
        prep_agent<<<21504 * 32 / 256, 256, 0, stream>>>(obj, PA32);
        gemm_pn<128, true, true, false><<<dim3(168, 2), 256, 0, stream>>>(
            PA32, wpnf + APW_O, a_pre_b, nullptr, 1, 0,
            nullptr, PB, 32, 256, 1, 0, 0);
        pool_max<21><<<1024, 256, 0, stream>>>(PB, APLf, 8, 0);
        gemm_pn<128, false, false, false><<<dim3(8, 2), 256, 0, stream>>>(
            APLf, wpnf + AW1B_O, a_mlp_b1, nullptr, 1, 0,
            APC, nullptr, 256, 256, 1, 0, 0);
        gemm_pn<128, true, true, false><<<dim3(168, 2), 256, 0, stream>>>(
            PB, wpnf + AW1A_O, nullptr, APC, 21, 256,
            nullptr, PA2, 256, 256, 1, 0, 0);
        gemm_pn<128, true, true, false><<<dim3(168, 2), 256, 0, stream>>>(
            PA2, wpnf + AW2S_O, a_mlp_b2, nullptr, 1, 0,
            nullptr, PB, 256, 256, 1, 0, 0);
        pool_max<21><<<1024, 256, 0, stream>>>(PB, AGMf, 8, 0);
        gemm_pn<128, true, true, false><<<dim3(8, 2), 256, 0, stream>>>(
            AGMf, wpnf + AOW1_O, a_out_b1, nullptr, 1, 0,
            nullptr, AHVf, 256, 256, 1, 0, 0);
        gemm_pn<128, false, false, true><<<dim3(8, 2), 256, 0, stream>>>(
            AHVf, wpnf + AOW2_O, a_out_b2, nullptr, 1, 0,
            X, nullptr, 256, 256, 64, 768, 0);
    }

    // ---- map pointnet: fused chains
    {
        prep_map<<<MAPR * 32 / 256, 256, 0, stream>>>(mp, PN0f);
        fused_map3<<<MAPR / 128, 256, 0, stream>>>(
            PN0f, wpnf + W1P_O, wpnf + W2S_O, wpnf + W3S_O,
            m_pre_b1, m_pre_b2, m_pre_b3, PN1f);
        pool_max<20><<<12288 * 64 / 256, 256, 0, stream>>>(PN1f, PLf, 6, 0);
        gemm_pn<64, false, false, false><<<dim3(96, 1), 256, 0, stream>>>(
            PLf, wpnf + MW1B_O, m_mlp_b1, nullptr, 1, 0,
            PCf, nullptr, 64, 64, 1, 0, 0);
        fused_map2<<<MAPR / 128, 256, 0, stream>>>(
            PN1f, wpnf + MW1A_O, wpnf + MW2S_O,
            nullptr == nullptr ? (const float*)m_mlp_b1 - 0 + 0 : nullptr, m_mlp_b2, PCf, PN0f);
        pool_max<20><<<12288 * 64 / 256, 256, 0, stream>>>(PN0f, GMf, 6, 0);
        gemm_pn<64, true, true, false><<<dim3(96, 1), 256, 0, stream>>>(
            GMf, wpnf + OW1S_O, m_out_b1, nullptr, 1, 0,
            nullptr, HVf, 64, 64, 1, 0, 0);
        gemm_pn<128, false, false, true><<<dim3(96, 2), 256, 0, stream>>>(
            HVf, wpnf + OW2S_O, m_out_b2, nullptr, 1, 0,
            X, nullptr, 64, 256, 768, 64, 64);
    }

    split_x0<<<(int)(M * 256 / 1024), 256, 0, stream>>>(X, PE16, X16, XP16);

    // ---------------- transformer layers ----------------
    const float scal = 0.17677669529663687f;  // 32^-0.5
    const int MB = MTOT / 128;  // 104
    for (int l = 0; l < LL; l++) {
        const size_t wb = (size_t)l * 786432;
        const h16* wqkv_f = whf + wb;
        const h16* wo_f   = whf + wb + 196608;
        const h16* f1_f   = whf + wb + 262144;
        const h16* f2_f   = whf + wb + 524288;
        const float* bqkv = attn_bqkv + (size_t)l * 768;
        gemm_mfma<false, true><<<dim3(MB, 6), 256, 0, stream>>>(
            XP16, X16, 512, wqkv_f, bqkv,
            nullptr, QKV16, 256, 768, 0, scal, 256);
        attn_kernel<<<MTOT / 2, 256, 0, stream>>>(QKV16, IDX, AO16);
        gemm_ln0<<<MTOT / 32, 512, 0, stream>>>(
            AO16, wo_f, attn_bo + (size_t)l * 256, X16,
            ln1_g + l * 256, ln1_b + l * 256, H16, 256);
        if (l == LL - 1) {
            fused_ffn<2><<<MTOT / 32, 512, 0, stream>>>(
                H16, f1_f, f2_f, ffn_b1 + (size_t)l * 1024, ffn_b2 + (size_t)l * 256,
                ln2_g + l * 256, ln2_b + l * 256,
                (float*)d_out, nullptr, nullptr, nullptr);
        } else {
            fused_ffn<1><<<MTOT / 32, 512, 0, stream>>>(
                H16, f1_f, f2_f, ffn_b1 + (size_t)l * 1024, ffn_b2 + (size_t)l * 256,
                ln2_g + l * 256, ln2_b + l * 256,
                nullptr, X16, PE16, XP16);
        }
    }
}